// Round 8
// baseline (2610.285 us; speedup 1.0000x reference)
//
#include <hip/hip_runtime.h>
#include <math.h>

// Problem constants
#define NN     8192      // nodes
#define NEDGE  32768     // edges (before self loops)
#define NETOT  40960     // edges + self loops
#define NG     256       // graphs
#define FXD_   78
#define NH     10        // heads
#define DD2    780       // FXD*HEADS
#define FFD    2048
#define LMUT   735

static inline int cdiv_i(long long a, int b){ return (int)((a + (long long)b - 1) / b); }
static inline int pad32(int x){ return (x + 31) & ~31; }

typedef __attribute__((ext_vector_type(8))) short bf16x8;
typedef __attribute__((ext_vector_type(4))) float f32x4;

static __device__ __forceinline__ unsigned short f2bf(float f){
    unsigned u = __float_as_uint(f);
    u += 0x7FFFu + ((u >> 16) & 1u);
    return (unsigned short)(u >> 16);
}

// async global->LDS, 16B per lane; lds dest is wave-uniform base + lane*16
static __device__ __forceinline__ void gload16(const void* g, void* l){
    __builtin_amdgcn_global_load_lds((const __attribute__((address_space(1))) void*)g,
                                     (__attribute__((address_space(3))) void*)l, 16, 0, 0);
}

// ---------------- fills ----------------
__global__ void fill_f32_k(float* __restrict__ p, float v, long long n){
    long long i = (long long)blockIdx.x * 256 + threadIdx.x;
    if (i < n) p[i] = v;
}
__global__ void fill_u32_k(unsigned* __restrict__ p, unsigned v, long long n){
    long long i = (long long)blockIdx.x * 256 + threadIdx.x;
    if (i < n) p[i] = v;
}

// ---------------- f32 -> bf16 convert with K-padding ----------------
__global__ void cvt_pad_k(const float* __restrict__ src, unsigned short* __restrict__ dst,
                          long long n /*R*ldd*/, int C, int lds_, int ldd)
{
    long long i = (long long)blockIdx.x * 256 + threadIdx.x;
    if (i >= n) return;
    int r = (int)(i / ldd), c = (int)(i % ldd);
    dst[i] = (c < C) ? f2bf(src[(size_t)r * lds_ + c]) : (unsigned short)0;
}

// bf16 transpose: dst[c][r] = src[r][c]
__global__ void tr_bf16_k(const unsigned short* __restrict__ src, unsigned short* __restrict__ dst,
                          int R, int C, int lds_, int ldd)
{
    __shared__ unsigned short t[32][33];
    int cb = blockIdx.x * 32, rb = blockIdx.y * 32;
    int tx = threadIdx.x & 31, ty = threadIdx.x >> 5;   // 32 x 8
#pragma unroll
    for (int i = 0; i < 4; ++i){
        int r = rb + ty + i * 8, c = cb + tx;
        t[ty + i * 8][tx] = (r < R && c < C) ? src[(size_t)r * lds_ + c] : (unsigned short)0;
    }
    __syncthreads();
#pragma unroll
    for (int i = 0; i < 4; ++i){
        int dr = cb + ty + i * 8, dc = rb + tx;
        if (dr < C && dc < R) dst[(size_t)dr * ldd + dc] = t[tx][ty + i * 8];
    }
}

// padded qkv bias: out[s*Ep+c] = (c<E) ? b3[s*E+c] : 0, s=0..2
__global__ void qkv_bias_k(const float* __restrict__ b3, float* __restrict__ out, int E, int Ep)
{
    int idx = blockIdx.x * 256 + threadIdx.x;
    if (idx >= 3 * Ep) return;
    int s = idx / Ep, c = idx % Ep;
    out[idx] = (c < E) ? b3[s * E + c] : 0.f;
}

__global__ void bias_add_k(float* __restrict__ X, const float* __restrict__ b, long long n, int cols)
{
    long long i = (long long)blockIdx.x * 256 + threadIdx.x;
    if (i < n) X[i] += b[i % cols];
}

// ---------------- MFMA bf16 GEMM: 2-phase dbuf + XCD swizzle + BN=64/128 tiles ----------------
// C(M,N) = A(M,Kp) x B(N,Kp)^T + bias.  A,B bf16, Kp mult of 32, lda/ldb mult of 8.
// OUTC: 0=f32, 1=bf16.  ACT: 0 none, 1 relu, 2 sigmoid.  BROW: bias indexed by row.
// SPLITK>1: grid.z chunks over K, f32 atomicAdd into pre-zeroed C (no bias/act).
// BN: output tile cols (128 or 64). BN=64 doubles wg count for skinny-N shapes.
template<int OUTC, int ACT, int SPLITK, int BROW, int BN>
__global__ __launch_bounds__(256) void mgemm_k(
    const unsigned short* __restrict__ A, const unsigned short* __restrict__ B,
    const float* __restrict__ bias, void* __restrict__ Cv,
    int M, int N, int Kp, int lda, int ldb, int ldc, int swz)
{
    constexpr int NFJ   = BN / 32;        // col frags per wave
    constexpr int TILEA = 128 * 32;
    constexpr int TILEB = BN * 32;
    __shared__ unsigned short As[2 * TILEA];
    __shared__ unsigned short Bs[2 * TILEB];
    const int tid = threadIdx.x;
    const int lane = tid & 63, wid = tid >> 6;
    const int r16 = lane & 15, q = lane >> 4;
    const int wr = (wid >> 1) * 64, wc = (wid & 1) * (BN / 2);

    // bijective XCD-chunked remap (m204)
    const int gx = gridDim.x, gy = gridDim.y;
    const int nwg = gx * gy;
    int orig = swz ? ((int)blockIdx.x * gy + (int)blockIdx.y)
                   : ((int)blockIdx.y * gx + (int)blockIdx.x);
    int q8 = nwg >> 3, r8 = nwg & 7;
    int xcd = orig & 7, kk8 = orig >> 3;
    int wgid = (xcd < r8 ? xcd * (q8 + 1) : r8 * (q8 + 1) + (xcd - r8) * q8) + kk8;
    int bx, by;
    if (swz){ by = wgid % gy; bx = wgid / gy; }
    else    { bx = wgid % gx; by = wgid / gx; }
    const int row0 = by * 128, col0 = bx * BN;

    int kbeg = 0, kend = Kp;
    if (SPLITK > 1){
        int nt_ = Kp >> 5, cpt = (nt_ + SPLITK - 1) / SPLITK;
        kbeg = (int)blockIdx.z * cpt * 32;
        kend = min(Kp, kbeg + cpt * 32);
    }

    // A staging: 512 chunks of 16B; lane handles chunk c0 and c0+64
    const int c0 = wid * 128 + lane;
    const int r0a = c0 >> 2, k0a = (c0 & 3) << 3;
    const size_t gA0 = (size_t)min(row0 + r0a, M - 1) * lda + k0a;
    const size_t gA1 = (size_t)min(row0 + r0a + 16, M - 1) * lda + k0a;
    unsigned short* lA = As + wid * 1024;
    // B staging
    size_t gB0 = 0, gB1 = 0;
    unsigned short* lB;
    if (BN == 128){
        gB0 = (size_t)min(col0 + r0a, N - 1) * ldb + k0a;
        gB1 = (size_t)min(col0 + r0a + 16, N - 1) * ldb + k0a;
        lB = Bs + wid * 1024;
    } else {               // BN=64: 256 chunks, 1 per lane
        const int cb = wid * 64 + lane;
        const int rb_ = cb >> 2, kb_ = (cb & 3) << 3;
        gB0 = (size_t)min(col0 + rb_, N - 1) * ldb + kb_;
        lB = Bs + wid * 512;
    }

    f32x4 acc[4][NFJ];
#pragma unroll
    for (int i = 0; i < 4; ++i)
#pragma unroll
        for (int j = 0; j < NFJ; ++j){ f32x4 z = {0.f, 0.f, 0.f, 0.f}; acc[i][j] = z; }

    const int nt = (kend - kbeg) >> 5;
    if (nt > 0){
        gload16(A + gA0 + kbeg, lA);
        gload16(A + gA1 + kbeg, lA + 512);
        gload16(B + gB0 + kbeg, lB);
        if (BN == 128) gload16(B + gB1 + kbeg, lB + 512);
        __syncthreads();
        int cur = 0;
        for (int t = 0; t < nt; ++t){
            const int k0 = kbeg + (t << 5);
            if (t + 1 < nt){                  // stage next tile BEFORE compute (overlap)
                const int kn = k0 + 32, nb = cur ^ 1;
                gload16(A + gA0 + kn, lA + nb * TILEA);
                gload16(A + gA1 + kn, lA + nb * TILEA + 512);
                gload16(B + gB0 + kn, lB + nb * TILEB);
                if (BN == 128) gload16(B + gB1 + kn, lB + nb * TILEB + 512);
            }
            const unsigned short* Ab = As + cur * TILEA;
            const unsigned short* Bb = Bs + cur * TILEB;
            bf16x8 af[4], bfv[NFJ];
#pragma unroll
            for (int f = 0; f < 4; ++f)
                af[f] = *(const bf16x8*)(Ab + (size_t)(wr + f * 16 + r16) * 32 + (q << 3));
#pragma unroll
            for (int f = 0; f < NFJ; ++f)
                bfv[f] = *(const bf16x8*)(Bb + (size_t)(wc + f * 16 + r16) * 32 + (q << 3));
#pragma unroll
            for (int fi = 0; fi < 4; ++fi)
#pragma unroll
                for (int fj = 0; fj < NFJ; ++fj)
                    acc[fi][fj] = __builtin_amdgcn_mfma_f32_16x16x32_bf16(af[fi], bfv[fj], acc[fi][fj], 0, 0, 0);
            __syncthreads();
            cur ^= 1;
        }
    }

#pragma unroll
    for (int fi = 0; fi < 4; ++fi){
#pragma unroll
        for (int j = 0; j < 4; ++j){
            int r = row0 + wr + fi * 16 + q * 4 + j;   // C/D: row=(lane>>4)*4+reg
            if (r >= M) continue;
#pragma unroll
            for (int fj = 0; fj < NFJ; ++fj){
                int c = col0 + wc + fj * 16 + r16;     // C/D: col=lane&15
                if (c >= N) continue;
                float v = acc[fi][fj][j];
                if (SPLITK > 1){
                    atomicAdd((float*)Cv + (size_t)r * ldc + c, v);
                } else {
                    if (bias) v += BROW ? bias[r] : bias[c];
                    if (ACT == 1) v = fmaxf(v, 0.f);
                    if (ACT == 2) v = 1.f / (1.f + expf(-v));
                    if (OUTC == 0) ((float*)Cv)[(size_t)r * ldc + c] = v;
                    else ((unsigned short*)Cv)[(size_t)r * ldc + c] = f2bf(v);
                }
            }
        }
    }
}

template<int OUTC, int ACT, int SPLITK, int BROW, int BN>
static void mgemm(hipStream_t s, const unsigned short* A, const unsigned short* B,
                  const float* bias, void* C, int M, int N, int Kp,
                  int lda, int ldb, int ldc, int swz)
{
    dim3 g(cdiv_i(N, BN), cdiv_i(M, 128), SPLITK);
    mgemm_k<OUTC, ACT, SPLITK, BROW, BN><<<g, 256, 0, s>>>(A, B, bias, C, M, N, Kp, lda, ldb, ldc, swz);
}

// ---------------- softmax: in-place on bf16 rows (8192 cols), register-resident ----------------
__global__ __launch_bounds__(256) void softmax_bf16_k(unsigned short* __restrict__ SP, float scale)
{
    __shared__ float red[8];
    const int tid = threadIdx.x;
    uint4* prow = (uint4*)(SP + (size_t)blockIdx.x * NN);   // 1024 uint4 per row
    float v[32];
    float mx = -3.4e38f;
#pragma unroll
    for (int c = 0; c < 4; ++c){
        uint4 t = prow[c * 256 + tid];
        const unsigned* u = (const unsigned*)&t;
#pragma unroll
        for (int j = 0; j < 4; ++j){
            float lo = __uint_as_float(u[j] << 16) * scale;
            float hi = __uint_as_float(u[j] & 0xFFFF0000u) * scale;
            v[c * 8 + j * 2]     = lo;
            v[c * 8 + j * 2 + 1] = hi;
            mx = fmaxf(mx, fmaxf(lo, hi));
        }
    }
#pragma unroll
    for (int off = 32; off; off >>= 1) mx = fmaxf(mx, __shfl_xor(mx, off, 64));
    if ((tid & 63) == 0) red[tid >> 6] = mx;
    __syncthreads();
    mx = fmaxf(fmaxf(red[0], red[1]), fmaxf(red[2], red[3]));
    float sum = 0.f;
#pragma unroll
    for (int i = 0; i < 32; ++i){ v[i] = expf(v[i] - mx); sum += v[i]; }
#pragma unroll
    for (int off = 32; off; off >>= 1) sum += __shfl_xor(sum, off, 64);
    if ((tid & 63) == 0) red[4 + (tid >> 6)] = sum;
    __syncthreads();
    float inv = 1.f / (red[4] + red[5] + red[6] + red[7]);
#pragma unroll
    for (int c = 0; c < 4; ++c){
        uint4 t;
        unsigned* u = (unsigned*)&t;
#pragma unroll
        for (int j = 0; j < 4; ++j){
            unsigned lo = f2bf(v[c * 8 + j * 2] * inv);
            unsigned hi = f2bf(v[c * 8 + j * 2 + 1] * inv);
            u[j] = lo | (hi << 16);
        }
        prow[c * 256 + tid] = t;
    }
}

// ---------------- residual add (+optional Y bias) + layernorm ----------------
__global__ __launch_bounds__(256) void add_ln_k(
    const float* __restrict__ X, const float* __restrict__ Y, const float* __restrict__ ybias,
    const float* __restrict__ g, const float* __restrict__ b,
    float* __restrict__ out, unsigned short* __restrict__ obf, int E, int Ep)
{
    __shared__ float s1[256], s2[256];
    const int tid = threadIdx.x;
    long long base = (long long)blockIdx.x * E;
    float vals[4];
    float sum = 0.f, sq = 0.f;
    int i = 0;
    for (int c = tid; c < Ep; c += 256, ++i){
        float v = 0.f;
        if (c < E){
            v = X[base + c] + Y[base + c];
            if (ybias) v += ybias[c];
            sum += v; sq += v * v;
        }
        vals[i] = v;
    }
    s1[tid] = sum; s2[tid] = sq; __syncthreads();
    for (int s = 128; s; s >>= 1){
        if (tid < s){ s1[tid] += s1[tid + s]; s2[tid] += s2[tid + s]; }
        __syncthreads();
    }
    float mean = s1[0] / (float)E;
    float var = s2[0] / (float)E - mean * mean;
    if (var < 0.f) var = 0.f;
    float inv = 1.f / sqrtf(var + 1e-5f);
    i = 0;
    for (int c = tid; c < Ep; c += 256, ++i){
        if (c < E){
            float o = (vals[i] - mean) * inv * g[c] + b[c];
            out[base + c] = o;
            if (obf) obf[(size_t)blockIdx.x * Ep + c] = f2bf(o);
        } else if (obf) obf[(size_t)blockIdx.x * Ep + c] = 0;
    }
}

// ---------------- GAT ----------------
static __device__ __forceinline__ unsigned enc_f(float x){
    unsigned u = __float_as_uint(x);
    return (u & 0x80000000u) ? ~u : (u | 0x80000000u);
}
static __device__ __forceinline__ float dec_f(unsigned u){
    return (u & 0x80000000u) ? __uint_as_float(u & 0x7fffffffu) : __uint_as_float(~u);
}
static __device__ __forceinline__ void edge_sd(const int* __restrict__ ei, int e, int& s, int& d){
    if (e < NEDGE){ s = ei[e]; d = ei[NEDGE + e]; }
    else { s = e - NEDGE; d = e - NEDGE; }
}

__global__ void gat_srcdst_k(const float* __restrict__ h, const float* __restrict__ aw_src,
                             const float* __restrict__ aw_dst, float* __restrict__ asrc,
                             float* __restrict__ adst)
{
    int idx = blockIdx.x * 256 + threadIdx.x;
    if (idx >= NN * NH) return;
    int n = idx / NH, hh = idx % NH;
    const float* hp = h + (long long)n * DD2 + hh * FXD_;
    const float* ws = aw_src + hh * FXD_;
    const float* wd = aw_dst + hh * FXD_;
    float s1 = 0.f, s2 = 0.f;
    for (int f = 0; f < FXD_; ++f){ float v = hp[f]; s1 += v * ws[f]; s2 += v * wd[f]; }
    asrc[idx] = s1; adst[idx] = s2;
}

__global__ void gat_alpha_k(const int* __restrict__ ei, const float* __restrict__ asrc,
                            const float* __restrict__ adst, float* __restrict__ alpha,
                            unsigned* __restrict__ amax)
{
    int idx = blockIdx.x * 256 + threadIdx.x;
    if (idx >= NETOT * NH) return;
    int e = idx / NH, hh = idx % NH;
    int s, d; edge_sd(ei, e, s, d);
    float a = asrc[s * NH + hh] + adst[d * NH + hh];
    a = (a > 0.f) ? a : 0.2f * a;       // leaky_relu 0.2
    alpha[idx] = a;
    atomicMax(&amax[d * NH + hh], enc_f(a));
}

__global__ void gat_expsum_k(const int* __restrict__ ei, float* __restrict__ alpha,
                             const unsigned* __restrict__ amax, float* __restrict__ denom)
{
    int idx = blockIdx.x * 256 + threadIdx.x;
    if (idx >= NETOT * NH) return;
    int e = idx / NH, hh = idx % NH;
    int s, d; edge_sd(ei, e, s, d);
    float m = dec_f(amax[d * NH + hh]);
    float ex = expf(alpha[idx] - m);
    alpha[idx] = ex;
    atomicAdd(&denom[d * NH + hh], ex);
}

__global__ void deg_count_k(const int* __restrict__ ei, int* __restrict__ deg)
{
    int e = blockIdx.x * 256 + threadIdx.x;
    if (e >= NETOT) return;
    int s, d; edge_sd(ei, e, s, d);
    atomicAdd(&deg[d], 1);
}

__global__ void gat_agg_k(const int* __restrict__ ei, const float* __restrict__ ex,
                          const float* __restrict__ denom, const float* __restrict__ hfeat,
                          float* __restrict__ out)
{
    long long idx = (long long)blockIdx.x * 256 + threadIdx.x;
    if (idx >= (long long)NETOT * DD2) return;
    int e = (int)(idx / DD2), f = (int)(idx % DD2);
    int hh = f / FXD_;
    int s, d; edge_sd(ei, e, s, d);
    float coef = ex[e * NH + hh] / (denom[d * NH + hh] + 1e-16f);
    atomicAdd(&out[(long long)d * DD2 + f], coef * hfeat[(long long)s * DD2 + f]);
}

// bias+relu on f32 (ld=cols), optional padded-bf16 mirror (ld=ldp)
__global__ void bias_relu_k(float* __restrict__ X, const float* __restrict__ b,
                            unsigned short* __restrict__ obf, int rows, int cols, int ldp)
{
    long long i = (long long)blockIdx.x * 256 + threadIdx.x;
    if (i >= (long long)rows * ldp) return;
    int r = (int)(i / ldp), c = (int)(i % ldp);
    if (c < cols){
        float v = X[(size_t)r * cols + c] + b[c];
        v = v > 0.f ? v : 0.f;
        X[(size_t)r * cols + c] = v;
        if (obf) obf[i] = f2bf(v);
    } else if (obf) obf[i] = 0;
}

// ---------------- GCN ----------------
__global__ void dis_k(const int* __restrict__ deg, float* __restrict__ dis)
{
    int n = blockIdx.x * 256 + threadIdx.x;
    if (n >= NN) return;
    float d = (float)deg[n];
    dis[n] = (d > 0.f) ? 1.f / sqrtf(fmaxf(d, 1.f)) : 0.f;
}

__global__ void gcn_agg_k(const int* __restrict__ ei, const float* __restrict__ dis,
                          const float* __restrict__ xw, float* __restrict__ out)
{
    long long idx = (long long)blockIdx.x * 256 + threadIdx.x;
    if (idx >= (long long)NETOT * DD2) return;
    int e = (int)(idx / DD2), f = (int)(idx % DD2);
    int s, d; edge_sd(ei, e, s, d);
    float nrm = dis[s] * dis[d];
    atomicAdd(&out[(long long)d * DD2 + f], nrm * xw[(long long)s * DD2 + f]);
}

// ---------------- graph pooling ----------------
__global__ void pool_accum_k(const float* __restrict__ xg, const int* __restrict__ batch,
                             float* __restrict__ gm, float* __restrict__ ga, int* __restrict__ cnt)
{
    long long idx = (long long)blockIdx.x * 256 + threadIdx.x;
    if (idx >= (long long)NN * DD2) return;
    int n = (int)(idx / DD2), f = (int)(idx % DD2);
    int g = batch[n];
    float v = xg[idx];
    atomicMax((int*)(gm + (long long)g * DD2 + f), __float_as_int(v));
    atomicAdd(ga + (long long)g * DD2 + f, v);
    if (f == 0) atomicAdd(cnt + g, 1);
}

// -> padded bf16 (ld 1568)
__global__ void pool_fin_k(const float* __restrict__ gm, const float* __restrict__ ga,
                           const int* __restrict__ cnt, unsigned short* __restrict__ xdb)
{
    int idx = blockIdx.x * 256 + threadIdx.x;
    if (idx >= NG * 1568) return;
    int g = idx / 1568, c = idx % 1568;
    float v = 0.f;
    if (c < DD2)       v = gm[g * DD2 + c];
    else if (c < 1560) v = ga[g * DD2 + (c - DD2)] / fmaxf((float)cnt[g], 1.f);
    xdb[idx] = f2bf(v);
}

// ---------------- conv autoencoder: one block per graph, LDS-resident ----------------
#define BN_SCALE 0.9999950000374996f   // 1/sqrt(1+1e-5)

// enc1: (NG,32,91); tm row (735 f32) + w (32x8) in LDS
__global__ __launch_bounds__(256) void enc1_b(const float* __restrict__ tm, const float* __restrict__ w,
                                              const float* __restrict__ bias, const float* __restrict__ bng,
                                              const float* __restrict__ bnb, float* __restrict__ out)
{
    __shared__ float xs[736];
    __shared__ float ws[256], bs[32], gs[32], b2[32];
    const int g = blockIdx.x, tid = threadIdx.x;
    for (int i = tid; i < 735; i += 256) xs[i] = tm[(size_t)g * LMUT + i];
    ws[tid] = w[tid];
    if (tid < 32){ bs[tid] = bias[tid]; gs[tid] = bng[tid]; b2[tid] = bnb[tid]; }
    __syncthreads();
    for (int idx = tid; idx < 32 * 91; idx += 256){
        int o = idx / 91, t = idx % 91;
        float mx = -3.4e38f;
        for (int p = 0; p < 8; ++p){
            float s = bs[o];
#pragma unroll
            for (int k = 0; k < 8; ++k) s += xs[t * 8 + p + k] * ws[o * 8 + k];
            mx = fmaxf(mx, s);
        }
        float v = mx * gs[o] * BN_SCALE + b2[o];
        out[(size_t)g * 2912 + idx] = v > 0.f ? v : 0.01f * v;
    }
}

// enc2: (NG,64,12); in (32x91) in LDS, weights in 2 o-halves of 32KB
__global__ __launch_bounds__(256) void enc2_b(const float* __restrict__ in, const float* __restrict__ w,
                                              const float* __restrict__ bias, const float* __restrict__ bng,
                                              const float* __restrict__ bnb, float* __restrict__ out)
{
    __shared__ float xs[32][92];
    __shared__ float ws[32 * 32 * 8];   // 32 KB (one o-half)
    const int g = blockIdx.x, tid = threadIdx.x;
    for (int i = tid; i < 32 * 91; i += 256) xs[i / 91][i % 91] = in[(size_t)g * 2912 + i];
    for (int half = 0; half < 2; ++half){
        __syncthreads();
        for (int i = tid; i < 32 * 32 * 8; i += 256) ws[i] = w[half * 32 * 32 * 8 + i];
        __syncthreads();
        for (int idx = tid; idx < 32 * 12; idx += 256){
            int oo = idx / 12, t = idx % 12, o = half * 32 + oo;
            float mx = -3.4e38f;
            for (int p = 0; p < 7; ++p){
                float s = bias[o];
                int base = t * 7 + p;
                for (int i2 = 0; i2 < 32; ++i2){
                    const float* wp = ws + (oo * 32 + i2) * 8;
#pragma unroll
                    for (int k = 0; k < 8; ++k) s += xs[i2][base + k] * wp[k];
                }
                mx = fmaxf(mx, s);
            }
            float v = mx * bng[o] * BN_SCALE + bnb[o];
            out[(size_t)g * 768 + o * 12 + t] = v > 0.f ? v : 0.01f * v;
        }
    }
}

// enc3: (NG,128,5); in (64x12) LDS, w (256KB) from L2; emits f32 + bf16
__global__ __launch_bounds__(256) void enc3_b(const float* __restrict__ in, const float* __restrict__ w,
                                              const float* __restrict__ bias, float* __restrict__ out,
                                              unsigned short* __restrict__ obf)
{
    __shared__ float in3[64][13];
    const int g = blockIdx.x, tid = threadIdx.x;
    for (int i = tid; i < 64 * 12; i += 256) in3[i / 12][i % 12] = in[(size_t)g * 768 + i];
    __syncthreads();
    for (int idx = tid; idx < 128 * 5; idx += 256){
        int o = idx / 5, t = idx % 5;
        float s = bias[o];
        for (int i2 = 0; i2 < 64; ++i2){
            const float* wp = w + (o * 64 + i2) * 8;
#pragma unroll
            for (int k = 0; k < 8; ++k) s += in3[i2][t + k] * wp[k];
        }
        out[(size_t)g * 640 + idx] = s;
        obf[(size_t)g * 640 + idx] = f2bf(s);
    }
}

// dec3: (NG,64,12); e3 (128x5) LDS, w (256KB) from L2
__global__ __launch_bounds__(256) void dec3_b(const float* __restrict__ e3, const float* __restrict__ w,
                                              const float* __restrict__ bias, const float* __restrict__ bng,
                                              const float* __restrict__ bnb, float* __restrict__ out)
{
    __shared__ float e3s[128][6];
    const int g = blockIdx.x, tid = threadIdx.x;
    for (int i = tid; i < 128 * 5; i += 256) e3s[i / 5][i % 5] = e3[(size_t)g * 640 + i];
    __syncthreads();
    for (int idx = tid; idx < 64 * 12; idx += 256){
        int o = idx / 12, t = idx % 12;
        int jlo = t > 4 ? t - 4 : 0, jhi = t < 7 ? t : 7;   // tt=t-j in [0,5)
        float s = bias[o];
        for (int i2 = 0; i2 < 128; ++i2){
            const float* wp = w + (i2 * 64 + o) * 8;
            float a = 0.f;
            for (int j = jlo; j <= jhi; ++j) a += e3s[i2][t - j] * wp[j];
            s += a;
        }
        float v = s * bng[o] * BN_SCALE + bnb[o];
        out[(size_t)g * 768 + idx] = v > 0.f ? v : 0.01f * v;
    }
}

// dec2: (NG,32,91); dd3 (64x12) LDS, weights in 2 o-halves of 32KB
__global__ __launch_bounds__(256) void dec2_b(const float* __restrict__ dd3, const float* __restrict__ w,
                                              const float* __restrict__ bias, const float* __restrict__ bng,
                                              const float* __restrict__ bnb, float* __restrict__ out)
{
    __shared__ float d3s[64][12];
    __shared__ float ws[64 * 16 * 8];   // 32 KB (one o-half)
    const int g = blockIdx.x, tid = threadIdx.x;
    for (int i = tid; i < 64 * 12; i += 256) d3s[i / 12][i % 12] = dd3[(size_t)g * 768 + i];
    for (int half = 0; half < 2; ++half){
        __syncthreads();
        for (int i = tid; i < 64 * 16 * 8; i += 256){
            int i2 = i >> 7, rem = i & 127;                    // rem = oo*8+j
            ws[i] = w[i2 * 256 + half * 128 + rem];            // w[(i2*32 + half*16 + oo)*8 + j]
        }
        __syncthreads();
        for (int idx = tid; idx < 16 * 91; idx += 256){
            int oo = idx / 91, t = idx % 91, o = half * 16 + oo;
            int id7[8]; bool ok[8];
#pragma unroll
            for (int j = 0; j < 8; ++j){
                int tt = t - j;
                ok[j] = (tt >= 0 && tt < 84);
                id7[j] = ok[j] ? tt / 7 : 0;
            }
            float s = bias[o];
            for (int i2 = 0; i2 < 64; ++i2){
                const float* wp = ws + i2 * 128 + oo * 8;
                float a = 0.f;
#pragma unroll
                for (int j = 0; j < 8; ++j) if (ok[j]) a += d3s[i2][id7[j]] * wp[j];
                s += a;
            }
            float v = s * bng[o] * BN_SCALE + bnb[o];
            out[(size_t)g * 2912 + o * 91 + t] = v > 0.f ? v : 0.01f * v;
        }
    }
}

// dec1: (NG,735); dd2 (32x91) + w (32x8) in LDS
__global__ __launch_bounds__(256) void dec1_b(const float* __restrict__ dd2, const float* __restrict__ w,
                                              const float* __restrict__ bias, float* __restrict__ out)
{
    __shared__ float d2s[32][91];
    __shared__ float ws[256];
    const int g = blockIdx.x, tid = threadIdx.x;
    for (int i = tid; i < 32 * 91; i += 256) d2s[i / 91][i % 91] = dd2[(size_t)g * 2912 + i];
    ws[tid] = w[tid];
    __syncthreads();
    float b0 = bias[0];
    for (int t = tid; t < 735; t += 256){
        int id8[8]; bool ok[8];
#pragma unroll
        for (int j = 0; j < 8; ++j){
            int tt = t - j;
            ok[j] = (tt >= 0 && tt < 728);
            id8[j] = ok[j] ? (tt >> 3) : 0;
        }
        float s = b0;
        for (int i2 = 0; i2 < 32; ++i2){
            const float* wp = ws + i2 * 8;
            float a = 0.f;
#pragma unroll
            for (int j = 0; j < 8; ++j) if (ok[j]) a += d2s[i2][id8[j]] * wp[j];
            s += a;
        }
        out[(size_t)g * 735 + t] = s;
    }
}

__global__ void concat_xc_k(const float* __restrict__ xd, const float* __restrict__ z,
                            unsigned short* __restrict__ xcb)
{
    int idx = blockIdx.x * 256 + threadIdx.x;
    if (idx >= NG * 256) return;
    int g = idx >> 8, c = idx & 255;
    xcb[idx] = f2bf((c < 128) ? xd[g * 128 + c] : z[g * 128 + (c - 128)]);
}

// ---------------- host-side orchestration ----------------
extern "C" void kernel_launch(void* const* d_in, const int* in_sizes, int n_in,
                              void* d_out, int out_size, void* d_ws, size_t ws_size,
                              hipStream_t stream)
{
    (void)in_sizes; (void)n_in; (void)out_size;

    // ---- input pointers: setup_inputs() DICT order (t1 4-15, t2 16-27, gat 28-31) ----
    const float* x      = (const float*)d_in[0];
    const int*   ei     = (const int*)  d_in[1];
    const int*   batch  = (const int*)  d_in[2];
    const float* tmut   = (const float*)d_in[3];
    const float* t1w[12]; for (int i = 0; i < 12; ++i) t1w[i] = (const float*)d_in[4 + i];
    const float* t2w[12]; for (int i = 0; i < 12; ++i) t2w[i] = (const float*)d_in[16 + i];
    const float* gat_w    = (const float*)d_in[28];
    const float* gat_asrc = (const float*)d_in[29];
    const float* gat_adst = (const float*)d_in[30];
    const float* gat_b    = (const float*)d_in[31];
    const float* gcn_w  = (const float*)d_in[32];
    const float* gcn_b  = (const float*)d_in[33];
    const float* fcg1_w = (const float*)d_in[34];
    const float* fcg1_b = (const float*)d_in[35];
    const float* fcg2_w = (const float*)d_in[36];
    const float* fcg2_b = (const float*)d_in[37];
    const float* e1_w = (const float*)d_in[38]; const float* e1_b = (const float*)d_in[39];
    const float* bn1_g = (const float*)d_in[40]; const float* bn1_b = (const float*)d_in[41];
    const float* e2_w = (const float*)d_in[42]; const float* e2_b = (const float*)d_in[43];
    const float* bn2_g = (const float*)d_in[44]; const float* bn2_b = (const float*)d_in[45];
    const float* e3_w = (const float*)d_in[46]; const float* e3_b = (const float*)d_in[47];
    const float* enc_w = (const float*)d_in[48]; const float* enc_b = (const float*)d_in[49];
    const float* d3_w = (const float*)d_in[50]; const float* d3_b = (const float*)d_in[51];
    const float* dbn2_g = (const float*)d_in[52]; const float* dbn2_b = (const float*)d_in[53];
    const float* d2_w = (const float*)d_in[54]; const float* d2_b = (const float*)d_in[55];
    const float* dbn1_g = (const float*)d_in[56]; const float* dbn1_b = (const float*)d_in[57];
    const float* d1_w = (const float*)d_in[58]; const float* d1_b = (const float*)d_in[59];
    const float* fc1_w = (const float*)d_in[60]; const float* fc1_b = (const float*)d_in[61];
    const float* fc2_w = (const float*)d_in[62]; const float* fc2_b = (const float*)d_in[63];
    const float* outw = (const float*)d_in[64]; const float* outb = (const float*)d_in[65];

    // ---- workspace carve (adaptive attention row-block RB) ----
    float *A1, *A2, *A3, *A4, *X1f, *QBIASf;
    unsigned short *XB, *QKVb, *Vt, *HbPb;
    unsigned short *WQKVb, *WOUTb, *WL1b, *WL2b, *WGb, *WGCNb, *WFCG1b, *WFCG2b,
                   *WENCb, *WFC1b, *WFC2b, *WOUTWb, *XD16, *FG1b, *E3b, *XCb, *FH1b, *FH2b;
    float *asrc, *adst, *alpha, *denom, *dis, *gm, *ga, *c1p, *c2p, *e3o,
          *zz, *dd3, *dd2b;
    unsigned *amax; int *deg, *cnt;

    auto carve = [&](long long RB) -> size_t {
        char* wp_ = (char*)d_ws;
        auto alc = [&](size_t bytes) -> char* {
            char* p = wp_;
            wp_ += (bytes + 255) & ~(size_t)255;
            return p;
        };
        A1 = (float*)alc((size_t)NN * DD2 * 4);
        A2 = (float*)alc((size_t)NN * DD2 * 4);
        A3 = (float*)alc((size_t)NN * DD2 * 4);
        A4 = (float*)alc((size_t)NN * DD2 * 4);
        X1f = (float*)alc((size_t)NN * FXD_ * 4);
        XB   = (unsigned short*)alc((size_t)NN * 800 * 2);
        QKVb = (unsigned short*)alc((size_t)NN * 2400 * 2);
        Vt   = (unsigned short*)alc((size_t)800 * NN * 2);
        size_t hb = (size_t)NN * FFD * 2, pb = (size_t)RB * NN * 2;
        HbPb = (unsigned short*)alc(hb > pb ? hb : pb);   // FF hidden / attention P (bf16)
        WQKVb = (unsigned short*)alc((size_t)2400 * 800 * 2);
        QBIASf= (float*)alc((size_t)2400 * 4);
        WOUTb = (unsigned short*)alc((size_t)780 * 800 * 2);
        WL1b  = (unsigned short*)alc((size_t)2048 * 800 * 2);
        WL2b  = (unsigned short*)alc((size_t)780 * 2048 * 2);
        WGb   = (unsigned short*)alc((size_t)780 * 96 * 2);
        WGCNb = (unsigned short*)alc((size_t)780 * 800 * 2);
        WFCG1b= (unsigned short*)alc((size_t)1500 * 1568 * 2);
        WFCG2b= (unsigned short*)alc((size_t)128 * 1504 * 2);
        WENCb = (unsigned short*)alc((size_t)128 * 640 * 2);
        WFC1b = (unsigned short*)alc((size_t)1024 * 256 * 2);
        WFC2b = (unsigned short*)alc((size_t)128 * 1024 * 2);
        WOUTWb= (unsigned short*)alc((size_t)128 * 2);
        XD16  = (unsigned short*)alc((size_t)NG * 1568 * 2);
        FG1b  = (unsigned short*)alc((size_t)NG * 1504 * 2);
        E3b   = (unsigned short*)alc((size_t)NG * 640 * 2);
        XCb   = (unsigned short*)alc((size_t)NG * 256 * 2);
        FH1b  = (unsigned short*)alc((size_t)NG * 1024 * 2);
        FH2b  = (unsigned short*)alc((size_t)NG * 128 * 2);
        asrc = (float*)alc((size_t)NN * NH * 4);
        adst = (float*)alc((size_t)NN * NH * 4);
        alpha= (float*)alc((size_t)NETOT * NH * 4);
        amax = (unsigned*)alc((size_t)NN * NH * 4);
        denom= (float*)alc((size_t)NN * NH * 4);
        deg  = (int*)alc((size_t)NN * 4);
        dis  = (float*)alc((size_t)NN * 4);
        cnt  = (int*)alc((size_t)NG * 4);
        gm   = (float*)alc((size_t)NG * DD2 * 4);
        ga   = (float*)alc((size_t)NG * DD2 * 4);
        c1p  = (float*)alc((size_t)NG * 32 * 91 * 4);
        c2p  = (float*)alc((size_t)NG * 64 * 12 * 4);
        e3o  = (float*)alc((size_t)NG * 128 * 5 * 4);
        zz   = (float*)alc((size_t)NG * 128 * 4);
        dd3  = (float*)alc((size_t)NG * 64 * 12 * 4);
        dd2b = (float*)alc((size_t)NG * 32 * 91 * 4);
        return (size_t)(wp_ - (char*)d_ws);
    };

    long long RB = 512;
    const long long cands[4] = {8192, 2048, 1024, 512};
    for (int i = 0; i < 4; ++i){ if (carve(cands[i]) <= ws_size){ RB = cands[i]; break; } }
    carve(RB);   // commit chosen layout
    unsigned short* Pb = HbPb;

    float* out0   = (float*)d_out;                 // (256,1)
    float* xd_out = (float*)d_out + NG;            // (256,128)
    float* decode = (float*)d_out + NG + NG * 128; // (256,735)

    auto cvt = [&](const float* src, unsigned short* dst, int R, int C, int lds_, int ldd){
        long long n = (long long)R * ldd;
        cvt_pad_k<<<cdiv_i(n, 256), 256, 0, stream>>>(src, dst, n, C, lds_, ldd);
    };
    auto zero16 = [&](unsigned short* p, long long nshorts){
        fill_u32_k<<<cdiv_i(nshorts / 2, 256), 256, 0, stream>>>((unsigned*)p, 0u, nshorts / 2);
    };
    auto zerof = [&](float* p, long long n){
        fill_f32_k<<<cdiv_i(n, 256), 256, 0, stream>>>(p, 0.f, n);
    };

    // ---- transformer (shared for t1/t2); xin_bf = XB (padded Ep), residual xin f32 ----
    auto run_tf = [&](const float* xin, const float* const* W, float* outp, int E){
        const int Ep = pad32(E), E3p = 3 * Ep;
        float scale = (float)(1.0 / sqrt((double)E));
        // merged qkv: weights 3*Ep rows (pad rows zero), bias padded
        zero16(WQKVb, (long long)E3p * Ep);
        for (int s = 0; s < 3; ++s)
            cvt(W[0] + (size_t)s * E * E, WQKVb + (size_t)s * Ep * Ep, E, E, E, Ep);
        qkv_bias_k<<<cdiv_i(E3p, 256), 256, 0, stream>>>(W[1], QBIASf, E, Ep);
        mgemm<1,0,1,0,128>(stream, XB, WQKVb, QBIASf, QKVb, NN, E3p, Ep, Ep, Ep, E3p, 0);
        // V^T via bf16 transpose of the v-part
        {
            dim3 g(cdiv_i(E, 32), cdiv_i(NN, 32));
            tr_bf16_k<<<g, 256, 0, stream>>>(QKVb + 2 * Ep, Vt, NN, E, E3p, NN);
        }
        // attention: S (bf16, into Pb) -> in-place softmax -> PV
        if (E == FXD_) zerof(A4, (long long)NN * E);   // t1 PV uses split-K atomics
        for (long long r0 = 0; r0 < NN; r0 += RB){
            mgemm<1,0,1,0,128>(stream, QKVb + (size_t)r0 * E3p, QKVb + Ep, nullptr, Pb,
                               (int)RB, NN, Ep, E3p, E3p, NN, 0);
            softmax_bf16_k<<<(int)RB, 256, 0, stream>>>(Pb, scale);
            if (E == FXD_)   // N=78: BN=64 + split-K (atomic out only 2.5MB/slice)
                mgemm<0,0,8,0,64>(stream, Pb, Vt, nullptr, A4 + (size_t)r0 * E,
                                  (int)RB, E, NN, NN, NN, E, 0);
            else             // N=780: BN=64, direct bf16 into XB (pads already 0)
                mgemm<1,0,1,0,64>(stream, Pb, Vt, nullptr, XB + (size_t)r0 * Ep,
                                  (int)RB, E, NN, NN, NN, Ep, 0);
        }
        if (E == FXD_) cvt(A4, XB, NN, E, E, Ep);
        // proj + LN1
        cvt(W[2], WOUTb, E, E, E, Ep);
        mgemm<0,0,1,0,64>(stream, XB, WOUTb, W[3], A2, NN, E, Ep, Ep, Ep, E, 0);
        add_ln_k<<<NN, 256, 0, stream>>>(xin, A2, nullptr, W[4], W[5], A3, XB, E, Ep);
        // FF1 (relu, bf16) -> FF2 -> LN2
        cvt(W[6], WL1b, FFD, E, E, Ep);
        mgemm<1,1,1,0,128>(stream, XB, WL1b, W[7], HbPb, NN, FFD, Ep, Ep, Ep, FFD, 0);
        cvt(W[8], WL2b, E, FFD, FFD, FFD);
        mgemm<0,0,1,0,64>(stream, HbPb, WL2b, W[9], A2, NN, E, FFD, FFD, FFD, E, 0);
        add_ln_k<<<NN, 256, 0, stream>>>(A3, A2, nullptr, W[10], W[11], outp, XB, E, Ep);
    };

    // ================= t1 transformer (E=78) =================
    cvt(x, XB, NN, FXD_, FXD_, 96);
    run_tf(x, t1w, X1f, FXD_);          // leaves XB = t1 out (ld 96)

    // ================= GAT =================
    cvt(gat_w, WGb, DD2, FXD_, FXD_, 96);
    mgemm<0,0,1,0,64>(stream, XB, WGb, nullptr, A2, NN, DD2, 96, 96, 96, DD2, 0);   // hfeat
    gat_srcdst_k<<<cdiv_i((long long)NN * NH, 256), 256, 0, stream>>>(A2, gat_asrc, gat_adst, asrc, adst);
    fill_u32_k<<<cdiv_i((long long)NN * NH, 256), 256, 0, stream>>>(amax, 0x007FFFFFu, (long long)NN * NH);
    zerof(denom, (long long)NN * NH);
    fill_u32_k<<<cdiv_i(NN, 256), 256, 0, stream>>>((unsigned*)deg, 0u, NN);
    gat_alpha_k<<<cdiv_i((long long)NETOT * NH, 256), 256, 0, stream>>>(ei, asrc, adst, alpha, amax);
    gat_expsum_k<<<cdiv_i((long long)NETOT * NH, 256), 256, 0, stream>>>(ei, alpha, amax, denom);
    deg_count_k<<<cdiv_i(NETOT, 256), 256, 0, stream>>>(ei, deg);
    zerof(A1, (long long)NN * DD2);
    gat_agg_k<<<cdiv_i((long long)NETOT * DD2, 256), 256, 0, stream>>>(ei, alpha, denom, A2, A1);
    bias_relu_k<<<cdiv_i((long long)NN * 800, 256), 256, 0, stream>>>(A1, gat_b, XB, NN, DD2, 800);

    // ================= t2 transformer (E=780) =================
    run_tf(A1, t2w, A1, DD2);           // leaves XB = t2 out (ld 800)

    // ================= GCN =================
    dis_k<<<cdiv_i(NN, 256), 256, 0, stream>>>(deg, dis);
    cvt(gcn_w, WGCNb, DD2, DD2, DD2, 800);
    mgemm<0,0,1,0,64>(stream, XB, WGCNb, nullptr, A2, NN, DD2, 800, 800, 800, DD2, 0); // xw
    zerof(A3, (long long)NN * DD2);
    gcn_agg_k<<<cdiv_i((long long)NETOT * DD2, 256), 256, 0, stream>>>(ei, dis, A2, A3);
    bias_relu_k<<<cdiv_i((long long)NN * DD2, 256), 256, 0, stream>>>(A3, gcn_b, nullptr, NN, DD2, DD2);

    // ================= pooling + graph head =================
    zerof(gm, (long long)NG * DD2);
    zerof(ga, (long long)NG * DD2);
    fill_u32_k<<<cdiv_i(NG, 256), 256, 0, stream>>>((unsigned*)cnt, 0u, NG);
    pool_accum_k<<<cdiv_i((long long)NN * DD2, 256), 256, 0, stream>>>(A3, batch, gm, ga, cnt);
    pool_fin_k<<<cdiv_i((long long)NG * 1568, 256), 256, 0, stream>>>(gm, ga, cnt, XD16);
    cvt(fcg1_w, WFCG1b, 1500, 1560, 1560, 1568);
    zerof(A2, (long long)NG * 1500);
    mgemm<0,0,8,0,64>(stream, XD16, WFCG1b, nullptr, A2, NG, 1500, 1568, 1568, 1568, 1500, 0);
    bias_relu_k<<<cdiv_i((long long)NG * 1504, 256), 256, 0, stream>>>(A2, fcg1_b, FG1b, NG, 1500, 1504);
    cvt(fcg2_w, WFCG2b, 128, 1500, 1500, 1504);
    zerof(xd_out, (long long)NG * 128);
    mgemm<0,0,16,0,128>(stream, FG1b, WFCG2b, nullptr, xd_out, NG, 128, 1504, 1504, 1504, 128, 0);
    bias_add_k<<<cdiv_i((long long)NG * 128, 256), 256, 0, stream>>>(xd_out, fcg2_b, (long long)NG * 128, 128); // OUTPUT 1

    // ================= conv encoder (block per graph, LDS-resident) =================
    enc1_b<<<NG, 256, 0, stream>>>(tmut, e1_w, e1_b, bn1_g, bn1_b, c1p);
    enc2_b<<<NG, 256, 0, stream>>>(c1p, e2_w, e2_b, bn2_g, bn2_b, c2p);
    enc3_b<<<NG, 256, 0, stream>>>(c2p, e3_w, e3_b, e3o, E3b);
    cvt(enc_w, WENCb, 128, 640, 640, 640);
    mgemm<0,0,1,0,128>(stream, E3b, WENCb, enc_b, zz, NG, 128, 640, 640, 640, 128, 0);  // z

    // ================= conv decoder =================
    dec3_b<<<NG, 256, 0, stream>>>(e3o, d3_w, d3_b, dbn2_g, dbn2_b, dd3);
    dec2_b<<<NG, 256, 0, stream>>>(dd3, d2_w, d2_b, dbn1_g, dbn1_b, dd2b);
    dec1_b<<<NG, 256, 0, stream>>>(dd2b, d1_w, d1_b, decode);   // OUTPUT 2

    // ================= final head =================
    concat_xc_k<<<cdiv_i((long long)NG * 256, 256), 256, 0, stream>>>(xd_out, zz, XCb);
    cvt(fc1_w, WFC1b, 1024, 256, 256, 256);
    mgemm<1,1,1,0,128>(stream, XCb, WFC1b, fc1_b, FH1b, NG, 1024, 256, 256, 256, 1024, 0);
    cvt(fc2_w, WFC2b, 128, 1024, 1024, 1024);
    zerof(A3, (long long)NG * 128);
    mgemm<0,0,8,0,128>(stream, FH1b, WFC2b, nullptr, A3, NG, 128, 1024, 1024, 1024, 128, 0);
    bias_relu_k<<<cdiv_i((long long)NG * 128, 256), 256, 0, stream>>>(A3, fc2_b, FH2b, NG, 128, 128);
    cvt(outw, WOUTWb, 1, 128, 128, 128);
    mgemm<0,2,1,0,64>(stream, FH2b, WOUTWb, outb, out0, NG, 1, 128, 128, 128, 1, 0);   // OUTPUT 0 (sigmoid)
}

// Round 9
// 2380.448 us; speedup vs baseline: 1.0966x; 1.0966x over previous
//
#include <hip/hip_runtime.h>
#include <math.h>

// Problem constants
#define NN     8192      // nodes
#define NEDGE  32768     // edges (before self loops)
#define NETOT  40960     // edges + self loops
#define NG     256       // graphs
#define FXD_   78
#define NH     10        // heads
#define DD2    780       // FXD*HEADS
#define FFD    2048
#define LMUT   735

static inline int cdiv_i(long long a, int b){ return (int)((a + (long long)b - 1) / b); }
static inline int pad32(int x){ return (x + 31) & ~31; }

typedef __attribute__((ext_vector_type(8))) short bf16x8;
typedef __attribute__((ext_vector_type(4))) float f32x4;

static __device__ __forceinline__ unsigned short f2bf(float f){
    unsigned u = __float_as_uint(f);
    u += 0x7FFFu + ((u >> 16) & 1u);
    return (unsigned short)(u >> 16);
}

// async global->LDS, 16B per lane; lds dest is wave-uniform base + lane*16
static __device__ __forceinline__ void gload16(const void* g, void* l){
    __builtin_amdgcn_global_load_lds((const __attribute__((address_space(1))) void*)g,
                                     (__attribute__((address_space(3))) void*)l, 16, 0, 0);
}

// ---------------- fills ----------------
__global__ void fill_f32_k(float* __restrict__ p, float v, long long n){
    long long i = (long long)blockIdx.x * 256 + threadIdx.x;
    if (i < n) p[i] = v;
}
__global__ void fill_u32_k(unsigned* __restrict__ p, unsigned v, long long n){
    long long i = (long long)blockIdx.x * 256 + threadIdx.x;
    if (i < n) p[i] = v;
}

// ---------------- f32 -> bf16 convert with K-padding ----------------
__global__ void cvt_pad_k(const float* __restrict__ src, unsigned short* __restrict__ dst,
                          long long n /*R*ldd*/, int C, int lds_, int ldd)
{
    long long i = (long long)blockIdx.x * 256 + threadIdx.x;
    if (i >= n) return;
    int r = (int)(i / ldd), c = (int)(i % ldd);
    dst[i] = (c < C) ? f2bf(src[(size_t)r * lds_ + c]) : (unsigned short)0;
}

// bf16 transpose: dst[c][r] = src[r][c]
__global__ void tr_bf16_k(const unsigned short* __restrict__ src, unsigned short* __restrict__ dst,
                          int R, int C, int lds_, int ldd)
{
    __shared__ unsigned short t[32][33];
    int cb = blockIdx.x * 32, rb = blockIdx.y * 32;
    int tx = threadIdx.x & 31, ty = threadIdx.x >> 5;   // 32 x 8
#pragma unroll
    for (int i = 0; i < 4; ++i){
        int r = rb + ty + i * 8, c = cb + tx;
        t[ty + i * 8][tx] = (r < R && c < C) ? src[(size_t)r * lds_ + c] : (unsigned short)0;
    }
    __syncthreads();
#pragma unroll
    for (int i = 0; i < 4; ++i){
        int dr = cb + ty + i * 8, dc = rb + tx;
        if (dr < C && dc < R) dst[(size_t)dr * ldd + dc] = t[tx][ty + i * 8];
    }
}

// padded qkv bias: out[s*Ep+c] = (c<E) ? b3[s*E+c] : 0, s=0..2
__global__ void qkv_bias_k(const float* __restrict__ b3, float* __restrict__ out, int E, int Ep)
{
    int idx = blockIdx.x * 256 + threadIdx.x;
    if (idx >= 3 * Ep) return;
    int s = idx / Ep, c = idx % Ep;
    out[idx] = (c < E) ? b3[s * E + c] : 0.f;
}

__global__ void bias_add_k(float* __restrict__ X, const float* __restrict__ b, long long n, int cols)
{
    long long i = (long long)blockIdx.x * 256 + threadIdx.x;
    if (i < n) X[i] += b[i % cols];
}

// ---------------- MFMA bf16 GEMM: 2-phase dbuf + XCD swizzle + BN=64/128 tiles ----------------
template<int OUTC, int ACT, int SPLITK, int BROW, int BN>
__global__ __launch_bounds__(256) void mgemm_k(
    const unsigned short* __restrict__ A, const unsigned short* __restrict__ B,
    const float* __restrict__ bias, void* __restrict__ Cv,
    int M, int N, int Kp, int lda, int ldb, int ldc, int swz)
{
    constexpr int NFJ   = BN / 32;        // col frags per wave
    constexpr int TILEA = 128 * 32;
    constexpr int TILEB = BN * 32;
    __shared__ unsigned short As[2 * TILEA];
    __shared__ unsigned short Bs[2 * TILEB];
    const int tid = threadIdx.x;
    const int lane = tid & 63, wid = tid >> 6;
    const int r16 = lane & 15, q = lane >> 4;
    const int wr = (wid >> 1) * 64, wc = (wid & 1) * (BN / 2);

    // bijective XCD-chunked remap (m204)
    const int gx = gridDim.x, gy = gridDim.y;
    const int nwg = gx * gy;
    int orig = swz ? ((int)blockIdx.x * gy + (int)blockIdx.y)
                   : ((int)blockIdx.y * gx + (int)blockIdx.x);
    int q8 = nwg >> 3, r8 = nwg & 7;
    int xcd = orig & 7, kk8 = orig >> 3;
    int wgid = (xcd < r8 ? xcd * (q8 + 1) : r8 * (q8 + 1) + (xcd - r8) * q8) + kk8;
    int bx, by;
    if (swz){ by = wgid % gy; bx = wgid / gy; }
    else    { bx = wgid % gx; by = wgid / gx; }
    const int row0 = by * 128, col0 = bx * BN;

    int kbeg = 0, kend = Kp;
    if (SPLITK > 1){
        int nt_ = Kp >> 5, cpt = (nt_ + SPLITK - 1) / SPLITK;
        kbeg = (int)blockIdx.z * cpt * 32;
        kend = min(Kp, kbeg + cpt * 32);
    }

    // A staging: 512 chunks of 16B; lane handles chunk c0 and c0+64
    const int c0 = wid * 128 + lane;
    const int r0a = c0 >> 2, k0a = (c0 & 3) << 3;
    const size_t gA0 = (size_t)min(row0 + r0a, M - 1) * lda + k0a;
    const size_t gA1 = (size_t)min(row0 + r0a + 16, M - 1) * lda + k0a;
    unsigned short* lA = As + wid * 1024;
    // B staging
    size_t gB0 = 0, gB1 = 0;
    unsigned short* lB;
    if (BN == 128){
        gB0 = (size_t)min(col0 + r0a, N - 1) * ldb + k0a;
        gB1 = (size_t)min(col0 + r0a + 16, N - 1) * ldb + k0a;
        lB = Bs + wid * 1024;
    } else {               // BN=64: 256 chunks, 1 per lane
        const int cb = wid * 64 + lane;
        const int rb_ = cb >> 2, kb_ = (cb & 3) << 3;
        gB0 = (size_t)min(col0 + rb_, N - 1) * ldb + kb_;
        lB = Bs + wid * 512;
    }

    f32x4 acc[4][NFJ];
#pragma unroll
    for (int i = 0; i < 4; ++i)
#pragma unroll
        for (int j = 0; j < NFJ; ++j){ f32x4 z = {0.f, 0.f, 0.f, 0.f}; acc[i][j] = z; }

    const int nt = (kend - kbeg) >> 5;
    if (nt > 0){
        gload16(A + gA0 + kbeg, lA);
        gload16(A + gA1 + kbeg, lA + 512);
        gload16(B + gB0 + kbeg, lB);
        if (BN == 128) gload16(B + gB1 + kbeg, lB + 512);
        __syncthreads();
        int cur = 0;
        for (int t = 0; t < nt; ++t){
            const int k0 = kbeg + (t << 5);
            if (t + 1 < nt){                  // stage next tile BEFORE compute (overlap)
                const int kn = k0 + 32, nb = cur ^ 1;
                gload16(A + gA0 + kn, lA + nb * TILEA);
                gload16(A + gA1 + kn, lA + nb * TILEA + 512);
                gload16(B + gB0 + kn, lB + nb * TILEB);
                if (BN == 128) gload16(B + gB1 + kn, lB + nb * TILEB + 512);
            }
            const unsigned short* Ab = As + cur * TILEA;
            const unsigned short* Bb = Bs + cur * TILEB;
            bf16x8 af[4], bfv[NFJ];
#pragma unroll
            for (int f = 0; f < 4; ++f)
                af[f] = *(const bf16x8*)(Ab + (size_t)(wr + f * 16 + r16) * 32 + (q << 3));
#pragma unroll
            for (int f = 0; f < NFJ; ++f)
                bfv[f] = *(const bf16x8*)(Bb + (size_t)(wc + f * 16 + r16) * 32 + (q << 3));
#pragma unroll
            for (int fi = 0; fi < 4; ++fi)
#pragma unroll
                for (int fj = 0; fj < NFJ; ++fj)
                    acc[fi][fj] = __builtin_amdgcn_mfma_f32_16x16x32_bf16(af[fi], bfv[fj], acc[fi][fj], 0, 0, 0);
            __syncthreads();
            cur ^= 1;
        }
    }

#pragma unroll
    for (int fi = 0; fi < 4; ++fi){
#pragma unroll
        for (int j = 0; j < 4; ++j){
            int r = row0 + wr + fi * 16 + q * 4 + j;   // C/D: row=(lane>>4)*4+reg
            if (r >= M) continue;
#pragma unroll
            for (int fj = 0; fj < NFJ; ++fj){
                int c = col0 + wc + fj * 16 + r16;     // C/D: col=lane&15
                if (c >= N) continue;
                float v = acc[fi][fj][j];
                if (SPLITK > 1){
                    atomicAdd((float*)Cv + (size_t)r * ldc + c, v);
                } else {
                    if (bias) v += BROW ? bias[r] : bias[c];
                    if (ACT == 1) v = fmaxf(v, 0.f);
                    if (ACT == 2) v = 1.f / (1.f + expf(-v));
                    if (OUTC == 0) ((float*)Cv)[(size_t)r * ldc + c] = v;
                    else ((unsigned short*)Cv)[(size_t)r * ldc + c] = f2bf(v);
                }
            }
        }
    }
}

template<int OUTC, int ACT, int SPLITK, int BROW, int BN>
static void mgemm(hipStream_t s, const unsigned short* A, const unsigned short* B,
                  const float* bias, void* C, int M, int N, int Kp,
                  int lda, int ldb, int ldc, int swz)
{
    dim3 g(cdiv_i(N, BN), cdiv_i(M, 128), SPLITK);
    mgemm_k<OUTC, ACT, SPLITK, BROW, BN><<<g, 256, 0, s>>>(A, B, bias, C, M, N, Kp, lda, ldb, ldc, swz);
}

// ---------------- softmax: in-place on bf16 rows (8192 cols), register-resident ----------------
__global__ __launch_bounds__(256) void softmax_bf16_k(unsigned short* __restrict__ SP, float scale)
{
    __shared__ float red[8];
    const int tid = threadIdx.x;
    uint4* prow = (uint4*)(SP + (size_t)blockIdx.x * NN);   // 1024 uint4 per row
    float v[32];
    float mx = -3.4e38f;
#pragma unroll
    for (int c = 0; c < 4; ++c){
        uint4 t = prow[c * 256 + tid];
        const unsigned* u = (const unsigned*)&t;
#pragma unroll
        for (int j = 0; j < 4; ++j){
            float lo = __uint_as_float(u[j] << 16) * scale;
            float hi = __uint_as_float(u[j] & 0xFFFF0000u) * scale;
            v[c * 8 + j * 2]     = lo;
            v[c * 8 + j * 2 + 1] = hi;
            mx = fmaxf(mx, fmaxf(lo, hi));
        }
    }
#pragma unroll
    for (int off = 32; off; off >>= 1) mx = fmaxf(mx, __shfl_xor(mx, off, 64));
    if ((tid & 63) == 0) red[tid >> 6] = mx;
    __syncthreads();
    mx = fmaxf(fmaxf(red[0], red[1]), fmaxf(red[2], red[3]));
    float sum = 0.f;
#pragma unroll
    for (int i = 0; i < 32; ++i){ v[i] = expf(v[i] - mx); sum += v[i]; }
#pragma unroll
    for (int off = 32; off; off >>= 1) sum += __shfl_xor(sum, off, 64);
    if ((tid & 63) == 0) red[4 + (tid >> 6)] = sum;
    __syncthreads();
    float inv = 1.f / (red[4] + red[5] + red[6] + red[7]);
#pragma unroll
    for (int c = 0; c < 4; ++c){
        uint4 t;
        unsigned* u = (unsigned*)&t;
#pragma unroll
        for (int j = 0; j < 4; ++j){
            unsigned lo = f2bf(v[c * 8 + j * 2] * inv);
            unsigned hi = f2bf(v[c * 8 + j * 2 + 1] * inv);
            u[j] = lo | (hi << 16);
        }
        prow[c * 256 + tid] = t;
    }
}

// ---------------- residual add (+optional Y bias) + layernorm ----------------
__global__ __launch_bounds__(256) void add_ln_k(
    const float* __restrict__ X, const float* __restrict__ Y, const float* __restrict__ ybias,
    const float* __restrict__ g, const float* __restrict__ b,
    float* __restrict__ out, unsigned short* __restrict__ obf, int E, int Ep)
{
    __shared__ float s1[256], s2[256];
    const int tid = threadIdx.x;
    long long base = (long long)blockIdx.x * E;
    float vals[4];
    float sum = 0.f, sq = 0.f;
    int i = 0;
    for (int c = tid; c < Ep; c += 256, ++i){
        float v = 0.f;
        if (c < E){
            v = X[base + c] + Y[base + c];
            if (ybias) v += ybias[c];
            sum += v; sq += v * v;
        }
        vals[i] = v;
    }
    s1[tid] = sum; s2[tid] = sq; __syncthreads();
    for (int s = 128; s; s >>= 1){
        if (tid < s){ s1[tid] += s1[tid + s]; s2[tid] += s2[tid + s]; }
        __syncthreads();
    }
    float mean = s1[0] / (float)E;
    float var = s2[0] / (float)E - mean * mean;
    if (var < 0.f) var = 0.f;
    float inv = 1.f / sqrtf(var + 1e-5f);
    i = 0;
    for (int c = tid; c < Ep; c += 256, ++i){
        if (c < E){
            float o = (vals[i] - mean) * inv * g[c] + b[c];
            out[base + c] = o;
            if (obf) obf[(size_t)blockIdx.x * Ep + c] = f2bf(o);
        } else if (obf) obf[(size_t)blockIdx.x * Ep + c] = 0;
    }
}

// ---------------- GAT ----------------
static __device__ __forceinline__ unsigned enc_f(float x){
    unsigned u = __float_as_uint(x);
    return (u & 0x80000000u) ? ~u : (u | 0x80000000u);
}
static __device__ __forceinline__ float dec_f(unsigned u){
    return (u & 0x80000000u) ? __uint_as_float(u & 0x7fffffffu) : __uint_as_float(~u);
}
static __device__ __forceinline__ void edge_sd(const int* __restrict__ ei, int e, int& s, int& d){
    if (e < NEDGE){ s = ei[e]; d = ei[NEDGE + e]; }
    else { s = e - NEDGE; d = e - NEDGE; }
}

__global__ void gat_srcdst_k(const float* __restrict__ h, const float* __restrict__ aw_src,
                             const float* __restrict__ aw_dst, float* __restrict__ asrc,
                             float* __restrict__ adst)
{
    int idx = blockIdx.x * 256 + threadIdx.x;
    if (idx >= NN * NH) return;
    int n = idx / NH, hh = idx % NH;
    const float* hp = h + (long long)n * DD2 + hh * FXD_;
    const float* ws = aw_src + hh * FXD_;
    const float* wd = aw_dst + hh * FXD_;
    float s1 = 0.f, s2 = 0.f;
    for (int f = 0; f < FXD_; ++f){ float v = hp[f]; s1 += v * ws[f]; s2 += v * wd[f]; }
    asrc[idx] = s1; adst[idx] = s2;
}

__global__ void gat_alpha_k(const int* __restrict__ ei, const float* __restrict__ asrc,
                            const float* __restrict__ adst, float* __restrict__ alpha,
                            unsigned* __restrict__ amax)
{
    int idx = blockIdx.x * 256 + threadIdx.x;
    if (idx >= NETOT * NH) return;
    int e = idx / NH, hh = idx % NH;
    int s, d; edge_sd(ei, e, s, d);
    float a = asrc[s * NH + hh] + adst[d * NH + hh];
    a = (a > 0.f) ? a : 0.2f * a;       // leaky_relu 0.2
    alpha[idx] = a;
    atomicMax(&amax[d * NH + hh], enc_f(a));
}

__global__ void gat_expsum_k(const int* __restrict__ ei, float* __restrict__ alpha,
                             const unsigned* __restrict__ amax, float* __restrict__ denom)
{
    int idx = blockIdx.x * 256 + threadIdx.x;
    if (idx >= NETOT * NH) return;
    int e = idx / NH, hh = idx % NH;
    int s, d; edge_sd(ei, e, s, d);
    float m = dec_f(amax[d * NH + hh]);
    float ex = expf(alpha[idx] - m);
    alpha[idx] = ex;
    atomicAdd(&denom[d * NH + hh], ex);
}

__global__ void deg_count_k(const int* __restrict__ ei, int* __restrict__ deg)
{
    int e = blockIdx.x * 256 + threadIdx.x;
    if (e >= NETOT) return;
    int s, d; edge_sd(ei, e, s, d);
    atomicAdd(&deg[d], 1);
}

__global__ void gat_agg_k(const int* __restrict__ ei, const float* __restrict__ ex,
                          const float* __restrict__ denom, const float* __restrict__ hfeat,
                          float* __restrict__ out)
{
    long long idx = (long long)blockIdx.x * 256 + threadIdx.x;
    if (idx >= (long long)NETOT * DD2) return;
    int e = (int)(idx / DD2), f = (int)(idx % DD2);
    int hh = f / FXD_;
    int s, d; edge_sd(ei, e, s, d);
    float coef = ex[e * NH + hh] / (denom[d * NH + hh] + 1e-16f);
    atomicAdd(&out[(long long)d * DD2 + f], coef * hfeat[(long long)s * DD2 + f]);
}

// bias+relu on f32 (ld=cols), optional padded-bf16 mirror (ld=ldp)
__global__ void bias_relu_k(float* __restrict__ X, const float* __restrict__ b,
                            unsigned short* __restrict__ obf, int rows, int cols, int ldp)
{
    long long i = (long long)blockIdx.x * 256 + threadIdx.x;
    if (i >= (long long)rows * ldp) return;
    int r = (int)(i / ldp), c = (int)(i % ldp);
    if (c < cols){
        float v = X[(size_t)r * cols + c] + b[c];
        v = v > 0.f ? v : 0.f;
        X[(size_t)r * cols + c] = v;
        if (obf) obf[i] = f2bf(v);
    } else if (obf) obf[i] = 0;
}

// ---------------- GCN ----------------
__global__ void dis_k(const int* __restrict__ deg, float* __restrict__ dis)
{
    int n = blockIdx.x * 256 + threadIdx.x;
    if (n >= NN) return;
    float d = (float)deg[n];
    dis[n] = (d > 0.f) ? 1.f / sqrtf(fmaxf(d, 1.f)) : 0.f;
}

__global__ void gcn_agg_k(const int* __restrict__ ei, const float* __restrict__ dis,
                          const float* __restrict__ xw, float* __restrict__ out)
{
    long long idx = (long long)blockIdx.x * 256 + threadIdx.x;
    if (idx >= (long long)NETOT * DD2) return;
    int e = (int)(idx / DD2), f = (int)(idx % DD2);
    int s, d; edge_sd(ei, e, s, d);
    float nrm = dis[s] * dis[d];
    atomicAdd(&out[(long long)d * DD2 + f], nrm * xw[(long long)s * DD2 + f]);
}

// ---------------- graph pooling ----------------
__global__ void pool_accum_k(const float* __restrict__ xg, const int* __restrict__ batch,
                             float* __restrict__ gm, float* __restrict__ ga, int* __restrict__ cnt)
{
    long long idx = (long long)blockIdx.x * 256 + threadIdx.x;
    if (idx >= (long long)NN * DD2) return;
    int n = (int)(idx / DD2), f = (int)(idx % DD2);
    int g = batch[n];
    float v = xg[idx];
    atomicMax((int*)(gm + (long long)g * DD2 + f), __float_as_int(v));
    atomicAdd(ga + (long long)g * DD2 + f, v);
    if (f == 0) atomicAdd(cnt + g, 1);
}

// -> padded bf16 (ld 1568)
__global__ void pool_fin_k(const float* __restrict__ gm, const float* __restrict__ ga,
                           const int* __restrict__ cnt, unsigned short* __restrict__ xdb)
{
    int idx = blockIdx.x * 256 + threadIdx.x;
    if (idx >= NG * 1568) return;
    int g = idx / 1568, c = idx % 1568;
    float v = 0.f;
    if (c < DD2)       v = gm[g * DD2 + c];
    else if (c < 1560) v = ga[g * DD2 + (c - DD2)] / fmaxf((float)cnt[g], 1.f);
    xdb[idx] = f2bf(v);
}

// ---------------- conv autoencoder: LDS-resident, high block count ----------------
#define BN_SCALE 0.9999950000374996f   // 1/sqrt(1+1e-5)

// enc1: (NG,32,91); tm row (735 f32) + w (32x8) in LDS; grid NG
__global__ __launch_bounds__(256) void enc1_b(const float* __restrict__ tm, const float* __restrict__ w,
                                              const float* __restrict__ bias, const float* __restrict__ bng,
                                              const float* __restrict__ bnb, float* __restrict__ out)
{
    __shared__ float xs[736];
    __shared__ float ws[256], bs[32], gs[32], b2[32];
    const int g = blockIdx.x, tid = threadIdx.x;
    for (int i = tid; i < 735; i += 256) xs[i] = tm[(size_t)g * LMUT + i];
    ws[tid] = w[tid];
    if (tid < 32){ bs[tid] = bias[tid]; gs[tid] = bng[tid]; b2[tid] = bnb[tid]; }
    __syncthreads();
    for (int idx = tid; idx < 32 * 91; idx += 256){
        int o = idx / 91, t = idx % 91;
        float mx = -3.4e38f;
        for (int p = 0; p < 8; ++p){
            float s = bs[o];
#pragma unroll
            for (int k = 0; k < 8; ++k) s += xs[t * 8 + p + k] * ws[o * 8 + k];
            mx = fmaxf(mx, s);
        }
        float v = mx * gs[o] * BN_SCALE + b2[o];
        out[(size_t)g * 2912 + idx] = v > 0.f ? v : 0.01f * v;
    }
}

// enc2: (NG,64,12); grid (NG,4) o-quarters: 16 o's, weights 16KB, acts 12KB, 1 out/thread
__global__ __launch_bounds__(256) void enc2_b(const float* __restrict__ in, const float* __restrict__ w,
                                              const float* __restrict__ bias, const float* __restrict__ bng,
                                              const float* __restrict__ bnb, float* __restrict__ out)
{
    __shared__ float xs[32][92];
    __shared__ float ws[16 * 32 * 8];   // 16 KB (one o-quarter)
    const int g = blockIdx.x, qq = blockIdx.y, tid = threadIdx.x;
    for (int i = tid; i < 32 * 91; i += 256) xs[i / 91][i % 91] = in[(size_t)g * 2912 + i];
    for (int i = tid; i < 16 * 32 * 8; i += 256) ws[i] = w[qq * 4096 + i];
    __syncthreads();
    if (tid < 16 * 12){
        int oo = tid / 12, t = tid % 12, o = qq * 16 + oo;
        float mx = -3.4e38f;
        for (int p = 0; p < 7; ++p){
            float s = bias[o];
            int base = t * 7 + p;
            for (int i2 = 0; i2 < 32; ++i2){
                const float* wp = ws + (oo * 32 + i2) * 8;
#pragma unroll
                for (int k = 0; k < 8; ++k) s += xs[i2][base + k] * wp[k];
            }
            mx = fmaxf(mx, s);
        }
        float v = mx * bng[o] * BN_SCALE + bnb[o];
        out[(size_t)g * 768 + o * 12 + t] = v > 0.f ? v : 0.01f * v;
    }
}

// enc3: (NG,128,5); grid (NG,2) o-halves; in (64x12) LDS, w from L2; emits f32 + bf16
__global__ __launch_bounds__(256) void enc3_b(const float* __restrict__ in, const float* __restrict__ w,
                                              const float* __restrict__ bias, float* __restrict__ out,
                                              unsigned short* __restrict__ obf)
{
    __shared__ float in3[64][13];
    const int g = blockIdx.x, half = blockIdx.y, tid = threadIdx.x;
    for (int i = tid; i < 64 * 12; i += 256) in3[i / 12][i % 12] = in[(size_t)g * 768 + i];
    __syncthreads();
    for (int idx = tid; idx < 64 * 5; idx += 256){
        int o = half * 64 + idx / 5, t = idx % 5;
        float s = bias[o];
        for (int i2 = 0; i2 < 64; ++i2){
            const float* wp = w + (o * 64 + i2) * 8;
#pragma unroll
            for (int k = 0; k < 8; ++k) s += in3[i2][t + k] * wp[k];
        }
        out[(size_t)g * 640 + o * 5 + t] = s;
        obf[(size_t)g * 640 + o * 5 + t] = f2bf(s);
    }
}

// dec3: (NG,64,12); grid (NG,2) o-halves; e3 (128x5) LDS, w from L2
__global__ __launch_bounds__(256) void dec3_b(const float* __restrict__ e3, const float* __restrict__ w,
                                              const float* __restrict__ bias, const float* __restrict__ bng,
                                              const float* __restrict__ bnb, float* __restrict__ out)
{
    __shared__ float e3s[128][6];
    const int g = blockIdx.x, half = blockIdx.y, tid = threadIdx.x;
    for (int i = tid; i < 128 * 5; i += 256) e3s[i / 5][i % 5] = e3[(size_t)g * 640 + i];
    __syncthreads();
    for (int idx = tid; idx < 32 * 12; idx += 256){
        int o = half * 32 + idx / 12, t = idx % 12;
        int jlo = t > 4 ? t - 4 : 0, jhi = t < 7 ? t : 7;   // tt=t-j in [0,5)
        float s = bias[o];
        for (int i2 = 0; i2 < 128; ++i2){
            const float* wp = w + (i2 * 64 + o) * 8;
            float a = 0.f;
            for (int j = jlo; j <= jhi; ++j) a += e3s[i2][t - j] * wp[j];
            s += a;
        }
        float v = s * bng[o] * BN_SCALE + bnb[o];
        out[(size_t)g * 768 + o * 12 + t] = v > 0.f ? v : 0.01f * v;
    }
}

// dec2: (NG,32,91); grid (NG,4) o-quarters: 8 o's, weights 16KB, acts 3KB
__global__ __launch_bounds__(256) void dec2_b(const float* __restrict__ dd3, const float* __restrict__ w,
                                              const float* __restrict__ bias, const float* __restrict__ bng,
                                              const float* __restrict__ bnb, float* __restrict__ out)
{
    __shared__ float d3s[64][12];
    __shared__ float ws[64 * 64];       // 16 KB: ws[i2][oo*8+j]
    const int g = blockIdx.x, qq = blockIdx.y, tid = threadIdx.x;
    for (int i = tid; i < 64 * 12; i += 256) d3s[i / 12][i % 12] = dd3[(size_t)g * 768 + i];
    for (int i = tid; i < 64 * 64; i += 256){
        int i2 = i >> 6, rem = i & 63;                    // rem = oo*8+j
        ws[i] = w[i2 * 256 + qq * 64 + rem];              // w[(i2*32 + qq*8 + oo)*8 + j]
    }
    __syncthreads();
    for (int idx = tid; idx < 8 * 91; idx += 256){
        int oo = idx / 91, t = idx % 91, o = qq * 8 + oo;
        int id7[8]; bool ok[8];
#pragma unroll
        for (int j = 0; j < 8; ++j){
            int tt = t - j;
            ok[j] = (tt >= 0 && tt < 84);
            id7[j] = ok[j] ? tt / 7 : 0;
        }
        float s = bias[o];
        for (int i2 = 0; i2 < 64; ++i2){
            const float* wp = ws + i2 * 64 + oo * 8;
            float a = 0.f;
#pragma unroll
            for (int j = 0; j < 8; ++j) if (ok[j]) a += d3s[i2][id7[j]] * wp[j];
            s += a;
        }
        float v = s * bng[o] * BN_SCALE + bnb[o];
        out[(size_t)g * 2912 + o * 91 + t] = v > 0.f ? v : 0.01f * v;
    }
}

// dec1: (NG,735); grid (NG,3) t-chunks of 245; dd2 (32x91) + w (32x8) in LDS
__global__ __launch_bounds__(256) void dec1_b(const float* __restrict__ dd2, const float* __restrict__ w,
                                              const float* __restrict__ bias, float* __restrict__ out)
{
    __shared__ float d2s[32][91];
    __shared__ float ws[256];
    const int g = blockIdx.x, tid = threadIdx.x;
    const int t0 = (int)blockIdx.y * 245;
    for (int i = tid; i < 32 * 91; i += 256) d2s[i / 91][i % 91] = dd2[(size_t)g * 2912 + i];
    ws[tid] = w[tid];
    __syncthreads();
    if (tid < 245){
        int t = t0 + tid;
        int id8[8]; bool ok[8];
#pragma unroll
        for (int j = 0; j < 8; ++j){
            int tt = t - j;
            ok[j] = (tt >= 0 && tt < 728);
            id8[j] = ok[j] ? (tt >> 3) : 0;
        }
        float s = bias[0];
        for (int i2 = 0; i2 < 32; ++i2){
            const float* wp = ws + i2 * 8;
            float a = 0.f;
#pragma unroll
            for (int j = 0; j < 8; ++j) if (ok[j]) a += d2s[i2][id8[j]] * wp[j];
            s += a;
        }
        out[(size_t)g * 735 + t] = s;
    }
}

__global__ void concat_xc_k(const float* __restrict__ xd, const float* __restrict__ z,
                            unsigned short* __restrict__ xcb)
{
    int idx = blockIdx.x * 256 + threadIdx.x;
    if (idx >= NG * 256) return;
    int g = idx >> 8, c = idx & 255;
    xcb[idx] = f2bf((c < 128) ? xd[g * 128 + c] : z[g * 128 + (c - 128)]);
}

// ---------------- host-side orchestration ----------------
extern "C" void kernel_launch(void* const* d_in, const int* in_sizes, int n_in,
                              void* d_out, int out_size, void* d_ws, size_t ws_size,
                              hipStream_t stream)
{
    (void)in_sizes; (void)n_in; (void)out_size;

    // ---- input pointers: setup_inputs() DICT order (t1 4-15, t2 16-27, gat 28-31) ----
    const float* x      = (const float*)d_in[0];
    const int*   ei     = (const int*)  d_in[1];
    const int*   batch  = (const int*)  d_in[2];
    const float* tmut   = (const float*)d_in[3];
    const float* t1w[12]; for (int i = 0; i < 12; ++i) t1w[i] = (const float*)d_in[4 + i];
    const float* t2w[12]; for (int i = 0; i < 12; ++i) t2w[i] = (const float*)d_in[16 + i];
    const float* gat_w    = (const float*)d_in[28];
    const float* gat_asrc = (const float*)d_in[29];
    const float* gat_adst = (const float*)d_in[30];
    const float* gat_b    = (const float*)d_in[31];
    const float* gcn_w  = (const float*)d_in[32];
    const float* gcn_b  = (const float*)d_in[33];
    const float* fcg1_w = (const float*)d_in[34];
    const float* fcg1_b = (const float*)d_in[35];
    const float* fcg2_w = (const float*)d_in[36];
    const float* fcg2_b = (const float*)d_in[37];
    const float* e1_w = (const float*)d_in[38]; const float* e1_b = (const float*)d_in[39];
    const float* bn1_g = (const float*)d_in[40]; const float* bn1_b = (const float*)d_in[41];
    const float* e2_w = (const float*)d_in[42]; const float* e2_b = (const float*)d_in[43];
    const float* bn2_g = (const float*)d_in[44]; const float* bn2_b = (const float*)d_in[45];
    const float* e3_w = (const float*)d_in[46]; const float* e3_b = (const float*)d_in[47];
    const float* enc_w = (const float*)d_in[48]; const float* enc_b = (const float*)d_in[49];
    const float* d3_w = (const float*)d_in[50]; const float* d3_b = (const float*)d_in[51];
    const float* dbn2_g = (const float*)d_in[52]; const float* dbn2_b = (const float*)d_in[53];
    const float* d2_w = (const float*)d_in[54]; const float* d2_b = (const float*)d_in[55];
    const float* dbn1_g = (const float*)d_in[56]; const float* dbn1_b = (const float*)d_in[57];
    const float* d1_w = (const float*)d_in[58]; const float* d1_b = (const float*)d_in[59];
    const float* fc1_w = (const float*)d_in[60]; const float* fc1_b = (const float*)d_in[61];
    const float* fc2_w = (const float*)d_in[62]; const float* fc2_b = (const float*)d_in[63];
    const float* outw = (const float*)d_in[64]; const float* outb = (const float*)d_in[65];

    // ---- workspace carve (adaptive attention row-block RB) ----
    float *A1, *A2, *A3, *A4, *X1f, *QBIASf;
    unsigned short *XB, *QKVb, *Vt, *HbPb;
    unsigned short *WQKVb, *WOUTb, *WL1b, *WL2b, *WGb, *WGCNb, *WFCG1b, *WFCG2b,
                   *WENCb, *WFC1b, *WFC2b, *WOUTWb, *XD16, *FG1b, *E3b, *XCb, *FH1b, *FH2b;
    float *asrc, *adst, *alpha, *denom, *dis, *gm, *ga, *c1p, *c2p, *e3o,
          *zz, *dd3, *dd2b;
    unsigned *amax; int *deg, *cnt;

    auto carve = [&](long long RB) -> size_t {
        char* wp_ = (char*)d_ws;
        auto alc = [&](size_t bytes) -> char* {
            char* p = wp_;
            wp_ += (bytes + 255) & ~(size_t)255;
            return p;
        };
        A1 = (float*)alc((size_t)NN * DD2 * 4);
        A2 = (float*)alc((size_t)NN * DD2 * 4);
        A3 = (float*)alc((size_t)NN * DD2 * 4);
        A4 = (float*)alc((size_t)NN * DD2 * 4);
        X1f = (float*)alc((size_t)NN * FXD_ * 4);
        XB   = (unsigned short*)alc((size_t)NN * 800 * 2);
        QKVb = (unsigned short*)alc((size_t)NN * 2400 * 2);
        Vt   = (unsigned short*)alc((size_t)800 * NN * 2);
        size_t hb = (size_t)NN * FFD * 2, pb = (size_t)RB * NN * 2;
        HbPb = (unsigned short*)alc(hb > pb ? hb : pb);   // FF hidden / attention P (bf16)
        WQKVb = (unsigned short*)alc((size_t)2400 * 800 * 2);
        QBIASf= (float*)alc((size_t)2400 * 4);
        WOUTb = (unsigned short*)alc((size_t)780 * 800 * 2);
        WL1b  = (unsigned short*)alc((size_t)2048 * 800 * 2);
        WL2b  = (unsigned short*)alc((size_t)780 * 2048 * 2);
        WGb   = (unsigned short*)alc((size_t)780 * 96 * 2);
        WGCNb = (unsigned short*)alc((size_t)780 * 800 * 2);
        WFCG1b= (unsigned short*)alc((size_t)1500 * 1568 * 2);
        WFCG2b= (unsigned short*)alc((size_t)128 * 1504 * 2);
        WENCb = (unsigned short*)alc((size_t)128 * 640 * 2);
        WFC1b = (unsigned short*)alc((size_t)1024 * 256 * 2);
        WFC2b = (unsigned short*)alc((size_t)128 * 1024 * 2);
        WOUTWb= (unsigned short*)alc((size_t)128 * 2);
        XD16  = (unsigned short*)alc((size_t)NG * 1568 * 2);
        FG1b  = (unsigned short*)alc((size_t)NG * 1504 * 2);
        E3b   = (unsigned short*)alc((size_t)NG * 640 * 2);
        XCb   = (unsigned short*)alc((size_t)NG * 256 * 2);
        FH1b  = (unsigned short*)alc((size_t)NG * 1024 * 2);
        FH2b  = (unsigned short*)alc((size_t)NG * 128 * 2);
        asrc = (float*)alc((size_t)NN * NH * 4);
        adst = (float*)alc((size_t)NN * NH * 4);
        alpha= (float*)alc((size_t)NETOT * NH * 4);
        amax = (unsigned*)alc((size_t)NN * NH * 4);
        denom= (float*)alc((size_t)NN * NH * 4);
        deg  = (int*)alc((size_t)NN * 4);
        dis  = (float*)alc((size_t)NN * 4);
        cnt  = (int*)alc((size_t)NG * 4);
        gm   = (float*)alc((size_t)NG * DD2 * 4);
        ga   = (float*)alc((size_t)NG * DD2 * 4);
        c1p  = (float*)alc((size_t)NG * 32 * 91 * 4);
        c2p  = (float*)alc((size_t)NG * 64 * 12 * 4);
        e3o  = (float*)alc((size_t)NG * 128 * 5 * 4);
        zz   = (float*)alc((size_t)NG * 128 * 4);
        dd3  = (float*)alc((size_t)NG * 64 * 12 * 4);
        dd2b = (float*)alc((size_t)NG * 32 * 91 * 4);
        return (size_t)(wp_ - (char*)d_ws);
    };

    long long RB = 512;
    const long long cands[4] = {8192, 2048, 1024, 512};
    for (int i = 0; i < 4; ++i){ if (carve(cands[i]) <= ws_size){ RB = cands[i]; break; } }
    carve(RB);   // commit chosen layout
    unsigned short* Pb = HbPb;

    float* out0   = (float*)d_out;                 // (256,1)
    float* xd_out = (float*)d_out + NG;            // (256,128)
    float* decode = (float*)d_out + NG + NG * 128; // (256,735)

    auto cvt = [&](const float* src, unsigned short* dst, int R, int C, int lds_, int ldd){
        long long n = (long long)R * ldd;
        cvt_pad_k<<<cdiv_i(n, 256), 256, 0, stream>>>(src, dst, n, C, lds_, ldd);
    };
    auto zero16 = [&](unsigned short* p, long long nshorts){
        fill_u32_k<<<cdiv_i(nshorts / 2, 256), 256, 0, stream>>>((unsigned*)p, 0u, nshorts / 2);
    };
    auto zerof = [&](float* p, long long n){
        fill_f32_k<<<cdiv_i(n, 256), 256, 0, stream>>>(p, 0.f, n);
    };

    // ---- transformer (shared for t1/t2); xin_bf = XB (padded Ep), residual xin f32 ----
    auto run_tf = [&](const float* xin, const float* const* W, float* outp, int E){
        const int Ep = pad32(E), E3p = 3 * Ep;
        float scale = (float)(1.0 / sqrt((double)E));
        // merged qkv: weights 3*Ep rows (pad rows zero), bias padded
        zero16(WQKVb, (long long)E3p * Ep);
        for (int s = 0; s < 3; ++s)
            cvt(W[0] + (size_t)s * E * E, WQKVb + (size_t)s * Ep * Ep, E, E, E, Ep);
        qkv_bias_k<<<cdiv_i(E3p, 256), 256, 0, stream>>>(W[1], QBIASf, E, Ep);
        mgemm<1,0,1,0,128>(stream, XB, WQKVb, QBIASf, QKVb, NN, E3p, Ep, Ep, Ep, E3p, 0);
        // V^T via bf16 transpose of the v-part
        {
            dim3 g(cdiv_i(E, 32), cdiv_i(NN, 32));
            tr_bf16_k<<<g, 256, 0, stream>>>(QKVb + 2 * Ep, Vt, NN, E, E3p, NN);
        }
        // attention: S (bf16, into Pb) -> in-place softmax -> PV
        if (E == FXD_) zerof(A4, (long long)NN * E);   // t1 PV uses split-K atomics
        for (long long r0 = 0; r0 < NN; r0 += RB){
            mgemm<1,0,1,0,128>(stream, QKVb + (size_t)r0 * E3p, QKVb + Ep, nullptr, Pb,
                               (int)RB, NN, Ep, E3p, E3p, NN, 0);
            softmax_bf16_k<<<(int)RB, 256, 0, stream>>>(Pb, scale);
            if (E == FXD_)   // N=78: BN=64 + split-K (atomic out only 2.5MB/slice)
                mgemm<0,0,8,0,64>(stream, Pb, Vt, nullptr, A4 + (size_t)r0 * E,
                                  (int)RB, E, NN, NN, NN, E, 0);
            else             // N=780: BN=64, direct bf16 into XB (pads already 0)
                mgemm<1,0,1,0,64>(stream, Pb, Vt, nullptr, XB + (size_t)r0 * Ep,
                                  (int)RB, E, NN, NN, NN, Ep, 0);
        }
        if (E == FXD_) cvt(A4, XB, NN, E, E, Ep);
        // proj + LN1
        cvt(W[2], WOUTb, E, E, E, Ep);
        mgemm<0,0,1,0,64>(stream, XB, WOUTb, W[3], A2, NN, E, Ep, Ep, Ep, E, 0);
        add_ln_k<<<NN, 256, 0, stream>>>(xin, A2, nullptr, W[4], W[5], A3, XB, E, Ep);
        // FF1 (relu, bf16) -> FF2 -> LN2
        cvt(W[6], WL1b, FFD, E, E, Ep);
        mgemm<1,1,1,0,128>(stream, XB, WL1b, W[7], HbPb, NN, FFD, Ep, Ep, Ep, FFD, 0);
        cvt(W[8], WL2b, E, FFD, FFD, FFD);
        mgemm<0,0,1,0,64>(stream, HbPb, WL2b, W[9], A2, NN, E, FFD, FFD, FFD, E, 0);
        add_ln_k<<<NN, 256, 0, stream>>>(A3, A2, nullptr, W[10], W[11], outp, XB, E, Ep);
    };

    // ================= t1 transformer (E=78) =================
    cvt(x, XB, NN, FXD_, FXD_, 96);
    run_tf(x, t1w, X1f, FXD_);          // leaves XB = t1 out (ld 96)

    // ================= GAT =================
    cvt(gat_w, WGb, DD2, FXD_, FXD_, 96);
    mgemm<0,0,1,0,64>(stream, XB, WGb, nullptr, A2, NN, DD2, 96, 96, 96, DD2, 0);   // hfeat
    gat_srcdst_k<<<cdiv_i((long long)NN * NH, 256), 256, 0, stream>>>(A2, gat_asrc, gat_adst, asrc, adst);
    fill_u32_k<<<cdiv_i((long long)NN * NH, 256), 256, 0, stream>>>(amax, 0x007FFFFFu, (long long)NN * NH);
    zerof(denom, (long long)NN * NH);
    fill_u32_k<<<cdiv_i(NN, 256), 256, 0, stream>>>((unsigned*)deg, 0u, NN);
    gat_alpha_k<<<cdiv_i((long long)NETOT * NH, 256), 256, 0, stream>>>(ei, asrc, adst, alpha, amax);
    gat_expsum_k<<<cdiv_i((long long)NETOT * NH, 256), 256, 0, stream>>>(ei, alpha, amax, denom);
    deg_count_k<<<cdiv_i(NETOT, 256), 256, 0, stream>>>(ei, deg);
    zerof(A1, (long long)NN * DD2);
    gat_agg_k<<<cdiv_i((long long)NETOT * DD2, 256), 256, 0, stream>>>(ei, alpha, denom, A2, A1);
    bias_relu_k<<<cdiv_i((long long)NN * 800, 256), 256, 0, stream>>>(A1, gat_b, XB, NN, DD2, 800);

    // ================= t2 transformer (E=780) =================
    run_tf(A1, t2w, A1, DD2);           // leaves XB = t2 out (ld 800)

    // ================= GCN =================
    dis_k<<<cdiv_i(NN, 256), 256, 0, stream>>>(deg, dis);
    cvt(gcn_w, WGCNb, DD2, DD2, DD2, 800);
    mgemm<0,0,1,0,64>(stream, XB, WGCNb, nullptr, A2, NN, DD2, 800, 800, 800, DD2, 0); // xw
    zerof(A3, (long long)NN * DD2);
    gcn_agg_k<<<cdiv_i((long long)NETOT * DD2, 256), 256, 0, stream>>>(ei, dis, A2, A3);
    bias_relu_k<<<cdiv_i((long long)NN * DD2, 256), 256, 0, stream>>>(A3, gcn_b, nullptr, NN, DD2, DD2);

    // ================= pooling + graph head =================
    zerof(gm, (long long)NG * DD2);
    zerof(ga, (long long)NG * DD2);
    fill_u32_k<<<cdiv_i(NG, 256), 256, 0, stream>>>((unsigned*)cnt, 0u, NG);
    pool_accum_k<<<cdiv_i((long long)NN * DD2, 256), 256, 0, stream>>>(A3, batch, gm, ga, cnt);
    pool_fin_k<<<cdiv_i((long long)NG * 1568, 256), 256, 0, stream>>>(gm, ga, cnt, XD16);
    cvt(fcg1_w, WFCG1b, 1500, 1560, 1560, 1568);
    zerof(A2, (long long)NG * 1500);
    mgemm<0,0,8,0,64>(stream, XD16, WFCG1b, nullptr, A2, NG, 1500, 1568, 1568, 1568, 1500, 0);
    bias_relu_k<<<cdiv_i((long long)NG * 1504, 256), 256, 0, stream>>>(A2, fcg1_b, FG1b, NG, 1500, 1504);
    cvt(fcg2_w, WFCG2b, 128, 1500, 1500, 1504);
    zerof(xd_out, (long long)NG * 128);
    mgemm<0,0,16,0,128>(stream, FG1b, WFCG2b, nullptr, xd_out, NG, 128, 1504, 1504, 1504, 128, 0);
    bias_add_k<<<cdiv_i((long long)NG * 128, 256), 256, 0, stream>>>(xd_out, fcg2_b, (long long)NG * 128, 128); // OUTPUT 1

    // ================= conv encoder (LDS-resident, high block count) =================
    enc1_b<<<NG, 256, 0, stream>>>(tmut, e1_w, e1_b, bn1_g, bn1_b, c1p);
    { dim3 g(NG, 4); enc2_b<<<g, 256, 0, stream>>>(c1p, e2_w, e2_b, bn2_g, bn2_b, c2p); }
    { dim3 g(NG, 2); enc3_b<<<g, 256, 0, stream>>>(c2p, e3_w, e3_b, e3o, E3b); }
    cvt(enc_w, WENCb, 128, 640, 640, 640);
    mgemm<0,0,1,0,128>(stream, E3b, WENCb, enc_b, zz, NG, 128, 640, 640, 640, 128, 0);  // z

    // ================= conv decoder =================
    { dim3 g(NG, 2); dec3_b<<<g, 256, 0, stream>>>(e3o, d3_w, d3_b, dbn2_g, dbn2_b, dd3); }
    { dim3 g(NG, 4); dec2_b<<<g, 256, 0, stream>>>(dd3, d2_w, d2_b, dbn1_g, dbn1_b, dd2b); }
    { dim3 g(NG, 3); dec1_b<<<g, 256, 0, stream>>>(dd2b, d1_w, d1_b, decode); }   // OUTPUT 2

    // ================= final head =================
    concat_xc_k<<<cdiv_i((long long)NG * 256, 256), 256, 0, stream>>>(xd_out, zz, XCb);
    cvt(fc1_w, WFC1b, 1024, 256, 256, 256);
    mgemm<1,1,1,0,128>(stream, XCb, WFC1b, fc1_b, FH1b, NG, 1024, 256, 256, 256, 1024, 0);
    cvt(fc2_w, WFC2b, 128, 1024, 1024, 1024);
    zerof(A3, (long long)NG * 128);
    mgemm<0,0,8,0,128>(stream, FH1b, WFC2b, nullptr, A3, NG, 128, 1024, 1024, 1024, 128, 0);
    bias_relu_k<<<cdiv_i((long long)NG * 128, 256), 256, 0, stream>>>(A3, fc2_b, FH2b, NG, 128, 128);
    cvt(outw, WOUTWb, 1, 128, 128, 128);
    mgemm<0,2,1,0,64>(stream, FH2b, WOUTWb, outb, out0, NG, 1, 128, 128, 128, 1, 0);   // OUTPUT 0 (sigmoid)
}

// Round 10
// 2103.755 us; speedup vs baseline: 1.2408x; 1.1315x over previous
//
#include <hip/hip_runtime.h>
#include <math.h>

// Problem constants
#define NN     8192      // nodes
#define NEDGE  32768     // edges (before self loops)
#define NETOT  40960     // edges + self loops
#define NG     256       // graphs
#define FXD_   78
#define NH     10        // heads
#define DD2    780       // FXD*HEADS
#define FFD    2048
#define LMUT   735

static inline int cdiv_i(long long a, int b){ return (int)((a + (long long)b - 1) / b); }
static inline int pad32(int x){ return (x + 31) & ~31; }

typedef __attribute__((ext_vector_type(8))) short bf16x8;
typedef __attribute__((ext_vector_type(4))) float f32x4;

static __device__ __forceinline__ unsigned short f2bf(float f){
    unsigned u = __float_as_uint(f);
    u += 0x7FFFu + ((u >> 16) & 1u);
    return (unsigned short)(u >> 16);
}

// async global->LDS, 16B per lane; lds dest is wave-uniform base + lane*16
static __device__ __forceinline__ void gload16(const void* g, void* l){
    __builtin_amdgcn_global_load_lds((const __attribute__((address_space(1))) void*)g,
                                     (__attribute__((address_space(3))) void*)l, 16, 0, 0);
}

// ---------------- fills ----------------
__global__ void fill_f32_k(float* __restrict__ p, float v, long long n){
    long long i = (long long)blockIdx.x * 256 + threadIdx.x;
    if (i < n) p[i] = v;
}
__global__ void fill_u32_k(unsigned* __restrict__ p, unsigned v, long long n){
    long long i = (long long)blockIdx.x * 256 + threadIdx.x;
    if (i < n) p[i] = v;
}

// ---------------- f32 -> bf16 convert with K-padding ----------------
__global__ void cvt_pad_k(const float* __restrict__ src, unsigned short* __restrict__ dst,
                          long long n /*R*ldd*/, int C, int lds_, int ldd)
{
    long long i = (long long)blockIdx.x * 256 + threadIdx.x;
    if (i >= n) return;
    int r = (int)(i / ldd), c = (int)(i % ldd);
    dst[i] = (c < C) ? f2bf(src[(size_t)r * lds_ + c]) : (unsigned short)0;
}

// bf16 transpose: dst[c][r] = src[r][c]
__global__ void tr_bf16_k(const unsigned short* __restrict__ src, unsigned short* __restrict__ dst,
                          int R, int C, int lds_, int ldd)
{
    __shared__ unsigned short t[32][33];
    int cb = blockIdx.x * 32, rb = blockIdx.y * 32;
    int tx = threadIdx.x & 31, ty = threadIdx.x >> 5;   // 32 x 8
#pragma unroll
    for (int i = 0; i < 4; ++i){
        int r = rb + ty + i * 8, c = cb + tx;
        t[ty + i * 8][tx] = (r < R && c < C) ? src[(size_t)r * lds_ + c] : (unsigned short)0;
    }
    __syncthreads();
#pragma unroll
    for (int i = 0; i < 4; ++i){
        int dr = cb + ty + i * 8, dc = rb + tx;
        if (dr < C && dc < R) dst[(size_t)dr * ldd + dc] = t[tx][ty + i * 8];
    }
}

// padded qkv bias: out[s*Ep+c] = (c<E) ? b3[s*E+c] : 0, s=0..2
__global__ void qkv_bias_k(const float* __restrict__ b3, float* __restrict__ out, int E, int Ep)
{
    int idx = blockIdx.x * 256 + threadIdx.x;
    if (idx >= 3 * Ep) return;
    int s = idx / Ep, c = idx % Ep;
    out[idx] = (c < E) ? b3[s * E + c] : 0.f;
}

__global__ void bias_add_k(float* __restrict__ X, const float* __restrict__ b, long long n, int cols)
{
    long long i = (long long)blockIdx.x * 256 + threadIdx.x;
    if (i < n) X[i] += b[i % cols];
}

// ---------------- MFMA bf16 GEMM: 2-phase dbuf + XCD swizzle + BN=64/128 tiles ----------------
template<int OUTC, int ACT, int SPLITK, int BROW, int BN>
__global__ __launch_bounds__(256) void mgemm_k(
    const unsigned short* __restrict__ A, const unsigned short* __restrict__ B,
    const float* __restrict__ bias, void* __restrict__ Cv,
    int M, int N, int Kp, int lda, int ldb, int ldc, int swz)
{
    constexpr int NFJ   = BN / 32;        // col frags per wave
    constexpr int TILEA = 128 * 32;
    constexpr int TILEB = BN * 32;
    __shared__ unsigned short As[2 * TILEA];
    __shared__ unsigned short Bs[2 * TILEB];
    const int tid = threadIdx.x;
    const int lane = tid & 63, wid = tid >> 6;
    const int r16 = lane & 15, q = lane >> 4;
    const int wr = (wid >> 1) * 64, wc = (wid & 1) * (BN / 2);

    // bijective XCD-chunked remap (m204)
    const int gx = gridDim.x, gy = gridDim.y;
    const int nwg = gx * gy;
    int orig = swz ? ((int)blockIdx.x * gy + (int)blockIdx.y)
                   : ((int)blockIdx.y * gx + (int)blockIdx.x);
    int q8 = nwg >> 3, r8 = nwg & 7;
    int xcd = orig & 7, kk8 = orig >> 3;
    int wgid = (xcd < r8 ? xcd * (q8 + 1) : r8 * (q8 + 1) + (xcd - r8) * q8) + kk8;
    int bx, by;
    if (swz){ by = wgid % gy; bx = wgid / gy; }
    else    { bx = wgid % gx; by = wgid / gx; }
    const int row0 = by * 128, col0 = bx * BN;

    int kbeg = 0, kend = Kp;
    if (SPLITK > 1){
        int nt_ = Kp >> 5, cpt = (nt_ + SPLITK - 1) / SPLITK;
        kbeg = (int)blockIdx.z * cpt * 32;
        kend = min(Kp, kbeg + cpt * 32);
    }

    // A staging: 512 chunks of 16B; lane handles chunk c0 and c0+64
    const int c0 = wid * 128 + lane;
    const int r0a = c0 >> 2, k0a = (c0 & 3) << 3;
    const size_t gA0 = (size_t)min(row0 + r0a, M - 1) * lda + k0a;
    const size_t gA1 = (size_t)min(row0 + r0a + 16, M - 1) * lda + k0a;
    unsigned short* lA = As + wid * 1024;
    // B staging
    size_t gB0 = 0, gB1 = 0;
    unsigned short* lB;
    if (BN == 128){
        gB0 = (size_t)min(col0 + r0a, N - 1) * ldb + k0a;
        gB1 = (size_t)min(col0 + r0a + 16, N - 1) * ldb + k0a;
        lB = Bs + wid * 1024;
    } else {               // BN=64: 256 chunks, 1 per lane
        const int cb = wid * 64 + lane;
        const int rb_ = cb >> 2, kb_ = (cb & 3) << 3;
        gB0 = (size_t)min(col0 + rb_, N - 1) * ldb + kb_;
        lB = Bs + wid * 512;
    }

    f32x4 acc[4][NFJ];
#pragma unroll
    for (int i = 0; i < 4; ++i)
#pragma unroll
        for (int j = 0; j < NFJ; ++j){ f32x4 z = {0.f, 0.f, 0.f, 0.f}; acc[i][j] = z; }

    const int nt = (kend - kbeg) >> 5;
    if (nt > 0){
        gload16(A + gA0 + kbeg, lA);
        gload16(A + gA1 + kbeg, lA + 512);
        gload16(B + gB0 + kbeg, lB);
        if (BN == 128) gload16(B + gB1 + kbeg, lB + 512);
        __syncthreads();
        int cur = 0;
        for (int t = 0; t < nt; ++t){
            const int k0 = kbeg + (t << 5);
            if (t + 1 < nt){                  // stage next tile BEFORE compute (overlap)
                const int kn = k0 + 32, nb = cur ^ 1;
                gload16(A + gA0 + kn, lA + nb * TILEA);
                gload16(A + gA1 + kn, lA + nb * TILEA + 512);
                gload16(B + gB0 + kn, lB + nb * TILEB);
                if (BN == 128) gload16(B + gB1 + kn, lB + nb * TILEB + 512);
            }
            const unsigned short* Ab = As + cur * TILEA;
            const unsigned short* Bb = Bs + cur * TILEB;
            bf16x8 af[4], bfv[NFJ];
#pragma unroll
            for (int f = 0; f < 4; ++f)
                af[f] = *(const bf16x8*)(Ab + (size_t)(wr + f * 16 + r16) * 32 + (q << 3));
#pragma unroll
            for (int f = 0; f < NFJ; ++f)
                bfv[f] = *(const bf16x8*)(Bb + (size_t)(wc + f * 16 + r16) * 32 + (q << 3));
#pragma unroll
            for (int fi = 0; fi < 4; ++fi)
#pragma unroll
                for (int fj = 0; fj < NFJ; ++fj)
                    acc[fi][fj] = __builtin_amdgcn_mfma_f32_16x16x32_bf16(af[fi], bfv[fj], acc[fi][fj], 0, 0, 0);
            __syncthreads();
            cur ^= 1;
        }
    }

#pragma unroll
    for (int fi = 0; fi < 4; ++fi){
#pragma unroll
        for (int j = 0; j < 4; ++j){
            int r = row0 + wr + fi * 16 + q * 4 + j;   // C/D: row=(lane>>4)*4+reg
            if (r >= M) continue;
#pragma unroll
            for (int fj = 0; fj < NFJ; ++fj){
                int c = col0 + wc + fj * 16 + r16;     // C/D: col=lane&15
                if (c >= N) continue;
                float v = acc[fi][fj][j];
                if (SPLITK > 1){
                    atomicAdd((float*)Cv + (size_t)r * ldc + c, v);
                } else {
                    if (bias) v += BROW ? bias[r] : bias[c];
                    if (ACT == 1) v = fmaxf(v, 0.f);
                    if (ACT == 2) v = 1.f / (1.f + expf(-v));
                    if (OUTC == 0) ((float*)Cv)[(size_t)r * ldc + c] = v;
                    else ((unsigned short*)Cv)[(size_t)r * ldc + c] = f2bf(v);
                }
            }
        }
    }
}

template<int OUTC, int ACT, int SPLITK, int BROW, int BN>
static void mgemm(hipStream_t s, const unsigned short* A, const unsigned short* B,
                  const float* bias, void* C, int M, int N, int Kp,
                  int lda, int ldb, int ldc, int swz)
{
    dim3 g(cdiv_i(N, BN), cdiv_i(M, 128), SPLITK);
    mgemm_k<OUTC, ACT, SPLITK, BROW, BN><<<g, 256, 0, s>>>(A, B, bias, C, M, N, Kp, lda, ldb, ldc, swz);
}

// ---------------- softmax: in-place on bf16 rows (8192 cols), register-resident ----------------
__global__ __launch_bounds__(256) void softmax_bf16_k(unsigned short* __restrict__ SP, float scale)
{
    __shared__ float red[8];
    const int tid = threadIdx.x;
    uint4* prow = (uint4*)(SP + (size_t)blockIdx.x * NN);   // 1024 uint4 per row
    float v[32];
    float mx = -3.4e38f;
#pragma unroll
    for (int c = 0; c < 4; ++c){
        uint4 t = prow[c * 256 + tid];
        const unsigned* u = (const unsigned*)&t;
#pragma unroll
        for (int j = 0; j < 4; ++j){
            float lo = __uint_as_float(u[j] << 16) * scale;
            float hi = __uint_as_float(u[j] & 0xFFFF0000u) * scale;
            v[c * 8 + j * 2]     = lo;
            v[c * 8 + j * 2 + 1] = hi;
            mx = fmaxf(mx, fmaxf(lo, hi));
        }
    }
#pragma unroll
    for (int off = 32; off; off >>= 1) mx = fmaxf(mx, __shfl_xor(mx, off, 64));
    if ((tid & 63) == 0) red[tid >> 6] = mx;
    __syncthreads();
    mx = fmaxf(fmaxf(red[0], red[1]), fmaxf(red[2], red[3]));
    float sum = 0.f;
#pragma unroll
    for (int i = 0; i < 32; ++i){ v[i] = expf(v[i] - mx); sum += v[i]; }
#pragma unroll
    for (int off = 32; off; off >>= 1) sum += __shfl_xor(sum, off, 64);
    if ((tid & 63) == 0) red[4 + (tid >> 6)] = sum;
    __syncthreads();
    float inv = 1.f / (red[4] + red[5] + red[6] + red[7]);
#pragma unroll
    for (int c = 0; c < 4; ++c){
        uint4 t;
        unsigned* u = (unsigned*)&t;
#pragma unroll
        for (int j = 0; j < 4; ++j){
            unsigned lo = f2bf(v[c * 8 + j * 2] * inv);
            unsigned hi = f2bf(v[c * 8 + j * 2 + 1] * inv);
            u[j] = lo | (hi << 16);
        }
        prow[c * 256 + tid] = t;
    }
}

// ---------------- residual add (+optional Y bias) + layernorm ----------------
__global__ __launch_bounds__(256) void add_ln_k(
    const float* __restrict__ X, const float* __restrict__ Y, const float* __restrict__ ybias,
    const float* __restrict__ g, const float* __restrict__ b,
    float* __restrict__ out, unsigned short* __restrict__ obf, int E, int Ep)
{
    __shared__ float s1[256], s2[256];
    const int tid = threadIdx.x;
    long long base = (long long)blockIdx.x * E;
    float vals[4];
    float sum = 0.f, sq = 0.f;
    int i = 0;
    for (int c = tid; c < Ep; c += 256, ++i){
        float v = 0.f;
        if (c < E){
            v = X[base + c] + Y[base + c];
            if (ybias) v += ybias[c];
            sum += v; sq += v * v;
        }
        vals[i] = v;
    }
    s1[tid] = sum; s2[tid] = sq; __syncthreads();
    for (int s = 128; s; s >>= 1){
        if (tid < s){ s1[tid] += s1[tid + s]; s2[tid] += s2[tid + s]; }
        __syncthreads();
    }
    float mean = s1[0] / (float)E;
    float var = s2[0] / (float)E - mean * mean;
    if (var < 0.f) var = 0.f;
    float inv = 1.f / sqrtf(var + 1e-5f);
    i = 0;
    for (int c = tid; c < Ep; c += 256, ++i){
        if (c < E){
            float o = (vals[i] - mean) * inv * g[c] + b[c];
            out[base + c] = o;
            if (obf) obf[(size_t)blockIdx.x * Ep + c] = f2bf(o);
        } else if (obf) obf[(size_t)blockIdx.x * Ep + c] = 0;
    }
}

// ---------------- GAT ----------------
static __device__ __forceinline__ unsigned enc_f(float x){
    unsigned u = __float_as_uint(x);
    return (u & 0x80000000u) ? ~u : (u | 0x80000000u);
}
static __device__ __forceinline__ float dec_f(unsigned u){
    return (u & 0x80000000u) ? __uint_as_float(u & 0x7fffffffu) : __uint_as_float(~u);
}
static __device__ __forceinline__ void edge_sd(const int* __restrict__ ei, int e, int& s, int& d){
    if (e < NEDGE){ s = ei[e]; d = ei[NEDGE + e]; }
    else { s = e - NEDGE; d = e - NEDGE; }
}

__global__ void gat_srcdst_k(const float* __restrict__ h, const float* __restrict__ aw_src,
                             const float* __restrict__ aw_dst, float* __restrict__ asrc,
                             float* __restrict__ adst)
{
    int idx = blockIdx.x * 256 + threadIdx.x;
    if (idx >= NN * NH) return;
    int n = idx / NH, hh = idx % NH;
    const float* hp = h + (long long)n * DD2 + hh * FXD_;
    const float* ws = aw_src + hh * FXD_;
    const float* wd = aw_dst + hh * FXD_;
    float s1 = 0.f, s2 = 0.f;
    for (int f = 0; f < FXD_; ++f){ float v = hp[f]; s1 += v * ws[f]; s2 += v * wd[f]; }
    asrc[idx] = s1; adst[idx] = s2;
}

__global__ void gat_alpha_k(const int* __restrict__ ei, const float* __restrict__ asrc,
                            const float* __restrict__ adst, float* __restrict__ alpha,
                            unsigned* __restrict__ amax)
{
    int idx = blockIdx.x * 256 + threadIdx.x;
    if (idx >= NETOT * NH) return;
    int e = idx / NH, hh = idx % NH;
    int s, d; edge_sd(ei, e, s, d);
    float a = asrc[s * NH + hh] + adst[d * NH + hh];
    a = (a > 0.f) ? a : 0.2f * a;       // leaky_relu 0.2
    alpha[idx] = a;
    atomicMax(&amax[d * NH + hh], enc_f(a));
}

__global__ void gat_expsum_k(const int* __restrict__ ei, float* __restrict__ alpha,
                             const unsigned* __restrict__ amax, float* __restrict__ denom)
{
    int idx = blockIdx.x * 256 + threadIdx.x;
    if (idx >= NETOT * NH) return;
    int e = idx / NH, hh = idx % NH;
    int s, d; edge_sd(ei, e, s, d);
    float m = dec_f(amax[d * NH + hh]);
    float ex = expf(alpha[idx] - m);
    alpha[idx] = ex;
    atomicAdd(&denom[d * NH + hh], ex);
}

__global__ void deg_count_k(const int* __restrict__ ei, int* __restrict__ deg)
{
    int e = blockIdx.x * 256 + threadIdx.x;
    if (e >= NETOT) return;
    int s, d; edge_sd(ei, e, s, d);
    atomicAdd(&deg[d], 1);
}

__global__ void gat_agg_k(const int* __restrict__ ei, const float* __restrict__ ex,
                          const float* __restrict__ denom, const float* __restrict__ hfeat,
                          float* __restrict__ out)
{
    long long idx = (long long)blockIdx.x * 256 + threadIdx.x;
    if (idx >= (long long)NETOT * DD2) return;
    int e = (int)(idx / DD2), f = (int)(idx % DD2);
    int hh = f / FXD_;
    int s, d; edge_sd(ei, e, s, d);
    float coef = ex[e * NH + hh] / (denom[d * NH + hh] + 1e-16f);
    atomicAdd(&out[(long long)d * DD2 + f], coef * hfeat[(long long)s * DD2 + f]);
}

// bias+relu on f32 (ld=cols), optional padded-bf16 mirror (ld=ldp)
__global__ void bias_relu_k(float* __restrict__ X, const float* __restrict__ b,
                            unsigned short* __restrict__ obf, int rows, int cols, int ldp)
{
    long long i = (long long)blockIdx.x * 256 + threadIdx.x;
    if (i >= (long long)rows * ldp) return;
    int r = (int)(i / ldp), c = (int)(i % ldp);
    if (c < cols){
        float v = X[(size_t)r * cols + c] + b[c];
        v = v > 0.f ? v : 0.f;
        X[(size_t)r * cols + c] = v;
        if (obf) obf[i] = f2bf(v);
    } else if (obf) obf[i] = 0;
}

// ---------------- GCN ----------------
__global__ void dis_k(const int* __restrict__ deg, float* __restrict__ dis)
{
    int n = blockIdx.x * 256 + threadIdx.x;
    if (n >= NN) return;
    float d = (float)deg[n];
    dis[n] = (d > 0.f) ? 1.f / sqrtf(fmaxf(d, 1.f)) : 0.f;
}

__global__ void gcn_agg_k(const int* __restrict__ ei, const float* __restrict__ dis,
                          const float* __restrict__ xw, float* __restrict__ out)
{
    long long idx = (long long)blockIdx.x * 256 + threadIdx.x;
    if (idx >= (long long)NETOT * DD2) return;
    int e = (int)(idx / DD2), f = (int)(idx % DD2);
    int s, d; edge_sd(ei, e, s, d);
    float nrm = dis[s] * dis[d];
    atomicAdd(&out[(long long)d * DD2 + f], nrm * xw[(long long)s * DD2 + f]);
}

// ---------------- graph pooling ----------------
__global__ void pool_accum_k(const float* __restrict__ xg, const int* __restrict__ batch,
                             float* __restrict__ gm, float* __restrict__ ga, int* __restrict__ cnt)
{
    long long idx = (long long)blockIdx.x * 256 + threadIdx.x;
    if (idx >= (long long)NN * DD2) return;
    int n = (int)(idx / DD2), f = (int)(idx % DD2);
    int g = batch[n];
    float v = xg[idx];
    atomicMax((int*)(gm + (long long)g * DD2 + f), __float_as_int(v));
    atomicAdd(ga + (long long)g * DD2 + f, v);
    if (f == 0) atomicAdd(cnt + g, 1);
}

// -> padded bf16 (ld 1568)
__global__ void pool_fin_k(const float* __restrict__ gm, const float* __restrict__ ga,
                           const int* __restrict__ cnt, unsigned short* __restrict__ xdb)
{
    int idx = blockIdx.x * 256 + threadIdx.x;
    if (idx >= NG * 1568) return;
    int g = idx / 1568, c = idx % 1568;
    float v = 0.f;
    if (c < DD2)       v = gm[g * DD2 + c];
    else if (c < 1560) v = ga[g * DD2 + (c - DD2)] / fmaxf((float)cnt[g], 1.f);
    xdb[idx] = f2bf(v);
}

// ---------------- conv autoencoder ----------------
#define BN_SCALE 0.9999950000374996f   // 1/sqrt(1+1e-5)

// enc1: (NG,32,91); tm row (735 f32) + w (32x8) in LDS; grid NG
__global__ __launch_bounds__(256) void enc1_b(const float* __restrict__ tm, const float* __restrict__ w,
                                              const float* __restrict__ bias, const float* __restrict__ bng,
                                              const float* __restrict__ bnb, float* __restrict__ out)
{
    __shared__ float xs[736];
    __shared__ float ws[256], bs[32], gs[32], b2[32];
    const int g = blockIdx.x, tid = threadIdx.x;
    for (int i = tid; i < 735; i += 256) xs[i] = tm[(size_t)g * LMUT + i];
    ws[tid] = w[tid];
    if (tid < 32){ bs[tid] = bias[tid]; gs[tid] = bng[tid]; b2[tid] = bnb[tid]; }
    __syncthreads();
    for (int idx = tid; idx < 32 * 91; idx += 256){
        int o = idx / 91, t = idx % 91;
        float mx = -3.4e38f;
        for (int p = 0; p < 8; ++p){
            float s = bs[o];
#pragma unroll
            for (int k = 0; k < 8; ++k) s += xs[t * 8 + p + k] * ws[o * 8 + k];
            mx = fmaxf(mx, s);
        }
        float v = mx * gs[o] * BN_SCALE + b2[o];
        out[(size_t)g * 2912 + idx] = v > 0.f ? v : 0.01f * v;
    }
}

// ---- GEMM-ified AE middle layers: im2col / weight-reshape / post kernels ----
// enc2 im2col: A[(g*84+u)][i*8+k] = c1p[g][i][u+k]   (21504 x 256)
__global__ void i2c_enc2_k(const float* __restrict__ in, unsigned short* __restrict__ A){
    int idx = blockIdx.x * 256 + threadIdx.x;
    if (idx >= NG * 84 * 256) return;
    int col = idx & 255, row = idx >> 8;
    int g = row / 84, u = row % 84;
    int i = col >> 3, k = col & 7;
    A[idx] = f2bf(in[(size_t)g * 2912 + i * 91 + u + k]);
}
// enc2 post: maxpool7 + bias + BN + leaky -> c2p[g][o][t]
__global__ void post_enc2_k(const float* __restrict__ G, const float* __restrict__ b,
                            const float* __restrict__ bng, const float* __restrict__ bnb,
                            float* __restrict__ out){
    int idx = blockIdx.x * 256 + threadIdx.x;
    if (idx >= NG * 768) return;
    int t = idx % 12, o = (idx / 12) & 63, g = idx / 768;
    float mx = -3.4e38f;
#pragma unroll
    for (int p = 0; p < 7; ++p) mx = fmaxf(mx, G[(size_t)(g * 84 + t * 7 + p) * 64 + o]);
    float v = (mx + b[o]) * bng[o] * BN_SCALE + bnb[o];
    out[(size_t)g * 768 + o * 12 + t] = v > 0.f ? v : 0.01f * v;
}
// enc3 im2col: A[(g*5+t)][i2*8+k] = c2p[g][i2][t+k]   (1280 x 512)
__global__ void i2c_enc3_k(const float* __restrict__ in, unsigned short* __restrict__ A){
    int idx = blockIdx.x * 256 + threadIdx.x;
    if (idx >= NG * 5 * 512) return;
    int col = idx & 511, row = idx >> 9;
    int g = row / 5, t = row % 5;
    int i2 = col >> 3, k = col & 7;
    A[idx] = f2bf(in[(size_t)g * 768 + i2 * 12 + t + k]);
}
// enc3 post: +bias -> e3o f32 (o-major) + bf16 flat
__global__ void post_enc3_k(const float* __restrict__ G, const float* __restrict__ b,
                            float* __restrict__ e3o, unsigned short* __restrict__ obf){
    int idx = blockIdx.x * 256 + threadIdx.x;
    if (idx >= NG * 640) return;
    int t = idx % 5, o = (idx / 5) & 127, g = idx / 640;
    float v = G[(size_t)(g * 5 + t) * 128 + o] + b[o];
    e3o[(size_t)g * 640 + o * 5 + t] = v;
    obf[(size_t)g * 640 + o * 5 + t] = f2bf(v);
}
// weight reshape for convT: dst[o][i*8+j] = src[(i*O+o)*8+j]
__global__ void wshuf_k(const float* __restrict__ src, unsigned short* __restrict__ dst, int I, int O){
    int idx = blockIdx.x * 256 + threadIdx.x;
    if (idx >= I * O * 8) return;
    int o = idx / (I * 8), rem = idx % (I * 8);
    int i = rem >> 3, j = rem & 7;
    dst[idx] = f2bf(src[(size_t)(i * O + o) * 8 + j]);
}
// dec3 im2col: A[(g*12+t)][i2*8+j] = (t-j in [0,5)) ? e3o[g][i2][t-j] : 0   (3072 x 1024)
__global__ void i2c_dec3_k(const float* __restrict__ e3o, unsigned short* __restrict__ A){
    int idx = blockIdx.x * 256 + threadIdx.x;
    if (idx >= NG * 12 * 1024) return;
    int col = idx & 1023, row = idx >> 10;
    int g = row / 12, t = row % 12;
    int i2 = col >> 3, j = col & 7;
    int tt = t - j;
    A[idx] = (tt >= 0 && tt < 5) ? f2bf(e3o[(size_t)g * 640 + i2 * 5 + tt]) : (unsigned short)0;
}
// dec3 post: +bias + BN + leaky -> dd3[g][o][t]
__global__ void post_dec3_k(const float* __restrict__ G, const float* __restrict__ b,
                            const float* __restrict__ bng, const float* __restrict__ bnb,
                            float* __restrict__ dd3){
    int idx = blockIdx.x * 256 + threadIdx.x;
    if (idx >= NG * 768) return;
    int t = idx % 12, o = (idx / 12) & 63, g = idx / 768;
    float v = (G[(size_t)(g * 12 + t) * 64 + o] + b[o]) * bng[o] * BN_SCALE + bnb[o];
    dd3[(size_t)g * 768 + o * 12 + t] = v > 0.f ? v : 0.01f * v;
}
// dec2 im2col (repeat(7) folded): A[(g*91+t)][i2*8+j] = (t-j in [0,84)) ? dd3[g][i2][(t-j)/7] : 0  (23296 x 512)
__global__ void i2c_dec2_k(const float* __restrict__ dd3, unsigned short* __restrict__ A){
    int idx = blockIdx.x * 256 + threadIdx.x;
    if (idx >= NG * 91 * 512) return;
    int col = idx & 511, row = idx >> 9;
    int g = row / 91, t = row % 91;
    int i2 = col >> 3, j = col & 7;
    int tt = t - j;
    A[idx] = (tt >= 0 && tt < 84) ? f2bf(dd3[(size_t)g * 768 + i2 * 12 + tt / 7]) : (unsigned short)0;
}
// dec2 post: +bias + BN + leaky -> dd2[g][o][t]
__global__ void post_dec2_k(const float* __restrict__ G, const float* __restrict__ b,
                            const float* __restrict__ bng, const float* __restrict__ bnb,
                            float* __restrict__ dd2){
    int idx = blockIdx.x * 256 + threadIdx.x;
    if (idx >= NG * 2912) return;
    int t = idx % 91, o = (idx / 91) & 31, g = idx / 2912;
    float v = (G[(size_t)(g * 91 + t) * 32 + o] + b[o]) * bng[o] * BN_SCALE + bnb[o];
    dd2[(size_t)g * 2912 + o * 91 + t] = v > 0.f ? v : 0.01f * v;
}

// dec1: (NG,735); grid (NG,3) t-chunks of 245; dd2 (32x91) + w (32x8) in LDS
__global__ __launch_bounds__(256) void dec1_b(const float* __restrict__ dd2, const float* __restrict__ w,
                                              const float* __restrict__ bias, float* __restrict__ out)
{
    __shared__ float d2s[32][91];
    __shared__ float ws[256];
    const int g = blockIdx.x, tid = threadIdx.x;
    const int t0 = (int)blockIdx.y * 245;
    for (int i = tid; i < 32 * 91; i += 256) d2s[i / 91][i % 91] = dd2[(size_t)g * 2912 + i];
    ws[tid] = w[tid];
    __syncthreads();
    if (tid < 245){
        int t = t0 + tid;
        int id8[8]; bool ok[8];
#pragma unroll
        for (int j = 0; j < 8; ++j){
            int tt = t - j;
            ok[j] = (tt >= 0 && tt < 728);
            id8[j] = ok[j] ? (tt >> 3) : 0;
        }
        float s = bias[0];
        for (int i2 = 0; i2 < 32; ++i2){
            const float* wp = ws + i2 * 8;
            float a = 0.f;
#pragma unroll
            for (int j = 0; j < 8; ++j) if (ok[j]) a += d2s[i2][id8[j]] * wp[j];
            s += a;
        }
        out[(size_t)g * 735 + t] = s;
    }
}

__global__ void concat_xc_k(const float* __restrict__ xd, const float* __restrict__ z,
                            unsigned short* __restrict__ xcb)
{
    int idx = blockIdx.x * 256 + threadIdx.x;
    if (idx >= NG * 256) return;
    int g = idx >> 8, c = idx & 255;
    xcb[idx] = f2bf((c < 128) ? xd[g * 128 + c] : z[g * 128 + (c - 128)]);
}

// ---------------- host-side orchestration ----------------
extern "C" void kernel_launch(void* const* d_in, const int* in_sizes, int n_in,
                              void* d_out, int out_size, void* d_ws, size_t ws_size,
                              hipStream_t stream)
{
    (void)in_sizes; (void)n_in; (void)out_size;

    // ---- input pointers: setup_inputs() DICT order (t1 4-15, t2 16-27, gat 28-31) ----
    const float* x      = (const float*)d_in[0];
    const int*   ei     = (const int*)  d_in[1];
    const int*   batch  = (const int*)  d_in[2];
    const float* tmut   = (const float*)d_in[3];
    const float* t1w[12]; for (int i = 0; i < 12; ++i) t1w[i] = (const float*)d_in[4 + i];
    const float* t2w[12]; for (int i = 0; i < 12; ++i) t2w[i] = (const float*)d_in[16 + i];
    const float* gat_w    = (const float*)d_in[28];
    const float* gat_asrc = (const float*)d_in[29];
    const float* gat_adst = (const float*)d_in[30];
    const float* gat_b    = (const float*)d_in[31];
    const float* gcn_w  = (const float*)d_in[32];
    const float* gcn_b  = (const float*)d_in[33];
    const float* fcg1_w = (const float*)d_in[34];
    const float* fcg1_b = (const float*)d_in[35];
    const float* fcg2_w = (const float*)d_in[36];
    const float* fcg2_b = (const float*)d_in[37];
    const float* e1_w = (const float*)d_in[38]; const float* e1_b = (const float*)d_in[39];
    const float* bn1_g = (const float*)d_in[40]; const float* bn1_b = (const float*)d_in[41];
    const float* e2_w = (const float*)d_in[42]; const float* e2_b = (const float*)d_in[43];
    const float* bn2_g = (const float*)d_in[44]; const float* bn2_b = (const float*)d_in[45];
    const float* e3_w = (const float*)d_in[46]; const float* e3_b = (const float*)d_in[47];
    const float* enc_w = (const float*)d_in[48]; const float* enc_b = (const float*)d_in[49];
    const float* d3_w = (const float*)d_in[50]; const float* d3_b = (const float*)d_in[51];
    const float* dbn2_g = (const float*)d_in[52]; const float* dbn2_b = (const float*)d_in[53];
    const float* d2_w = (const float*)d_in[54]; const float* d2_b = (const float*)d_in[55];
    const float* dbn1_g = (const float*)d_in[56]; const float* dbn1_b = (const float*)d_in[57];
    const float* d1_w = (const float*)d_in[58]; const float* d1_b = (const float*)d_in[59];
    const float* fc1_w = (const float*)d_in[60]; const float* fc1_b = (const float*)d_in[61];
    const float* fc2_w = (const float*)d_in[62]; const float* fc2_b = (const float*)d_in[63];
    const float* outw = (const float*)d_in[64]; const float* outb = (const float*)d_in[65];

    // ---- workspace carve (adaptive attention row-block RB) ----
    float *A1, *A2, *A3, *A4, *X1f, *QBIASf;
    unsigned short *XB, *QKVb, *Vt, *HbPb;
    unsigned short *WQKVb, *WOUTb, *WL1b, *WL2b, *WGb, *WGCNb, *WFCG1b, *WFCG2b,
                   *WENCb, *WFC1b, *WFC2b, *WOUTWb, *XD16, *FG1b, *E3b, *XCb, *FH1b, *FH2b, *Wcvb;
    float *asrc, *adst, *alpha, *denom, *dis, *gm, *ga, *c1p, *c2p, *e3o,
          *zz, *dd3, *dd2b;
    unsigned *amax; int *deg, *cnt;

    auto carve = [&](long long RB) -> size_t {
        char* wp_ = (char*)d_ws;
        auto alc = [&](size_t bytes) -> char* {
            char* p = wp_;
            wp_ += (bytes + 255) & ~(size_t)255;
            return p;
        };
        A1 = (float*)alc((size_t)NN * DD2 * 4);
        A2 = (float*)alc((size_t)NN * DD2 * 4);
        A3 = (float*)alc((size_t)NN * DD2 * 4);
        A4 = (float*)alc((size_t)NN * DD2 * 4);
        X1f = (float*)alc((size_t)NN * FXD_ * 4);
        XB   = (unsigned short*)alc((size_t)NN * 800 * 2);
        QKVb = (unsigned short*)alc((size_t)NN * 2400 * 2);
        Vt   = (unsigned short*)alc((size_t)800 * NN * 2);
        size_t hb = (size_t)NN * FFD * 2, pb = (size_t)RB * NN * 2;
        HbPb = (unsigned short*)alc(hb > pb ? hb : pb);   // FF hidden / attention P / AE im2col
        WQKVb = (unsigned short*)alc((size_t)2400 * 800 * 2);
        QBIASf= (float*)alc((size_t)2400 * 4);
        WOUTb = (unsigned short*)alc((size_t)780 * 800 * 2);
        WL1b  = (unsigned short*)alc((size_t)2048 * 800 * 2);
        WL2b  = (unsigned short*)alc((size_t)780 * 2048 * 2);
        WGb   = (unsigned short*)alc((size_t)780 * 96 * 2);
        WGCNb = (unsigned short*)alc((size_t)780 * 800 * 2);
        WFCG1b= (unsigned short*)alc((size_t)1500 * 1568 * 2);
        WFCG2b= (unsigned short*)alc((size_t)128 * 1504 * 2);
        WENCb = (unsigned short*)alc((size_t)128 * 640 * 2);
        WFC1b = (unsigned short*)alc((size_t)1024 * 256 * 2);
        WFC2b = (unsigned short*)alc((size_t)128 * 1024 * 2);
        WOUTWb= (unsigned short*)alc((size_t)128 * 2);
        Wcvb  = (unsigned short*)alc((size_t)128 * 1024 * 2);   // AE reshaped weights (<=128KB)
        XD16  = (unsigned short*)alc((size_t)NG * 1568 * 2);
        FG1b  = (unsigned short*)alc((size_t)NG * 1504 * 2);
        E3b   = (unsigned short*)alc((size_t)NG * 640 * 2);
        XCb   = (unsigned short*)alc((size_t)NG * 256 * 2);
        FH1b  = (unsigned short*)alc((size_t)NG * 1024 * 2);
        FH2b  = (unsigned short*)alc((size_t)NG * 128 * 2);
        asrc = (float*)alc((size_t)NN * NH * 4);
        adst = (float*)alc((size_t)NN * NH * 4);
        alpha= (float*)alc((size_t)NETOT * NH * 4);
        amax = (unsigned*)alc((size_t)NN * NH * 4);
        denom= (float*)alc((size_t)NN * NH * 4);
        deg  = (int*)alc((size_t)NN * 4);
        dis  = (float*)alc((size_t)NN * 4);
        cnt  = (int*)alc((size_t)NG * 4);
        gm   = (float*)alc((size_t)NG * DD2 * 4);
        ga   = (float*)alc((size_t)NG * DD2 * 4);
        c1p  = (float*)alc((size_t)NG * 32 * 91 * 4);
        c2p  = (float*)alc((size_t)NG * 64 * 12 * 4);
        e3o  = (float*)alc((size_t)NG * 128 * 5 * 4);
        zz   = (float*)alc((size_t)NG * 128 * 4);
        dd3  = (float*)alc((size_t)NG * 64 * 12 * 4);
        dd2b = (float*)alc((size_t)NG * 32 * 91 * 4);
        return (size_t)(wp_ - (char*)d_ws);
    };

    long long RB = 512;
    const long long cands[4] = {8192, 2048, 1024, 512};
    for (int i = 0; i < 4; ++i){ if (carve(cands[i]) <= ws_size){ RB = cands[i]; break; } }
    carve(RB);   // commit chosen layout
    unsigned short* Pb = HbPb;
    unsigned short* AIM = HbPb;      // AE im2col arena (HbPb dead after t2; >= 24 MB needed)

    float* out0   = (float*)d_out;                 // (256,1)
    float* xd_out = (float*)d_out + NG;            // (256,128)
    float* decode = (float*)d_out + NG + NG * 128; // (256,735)

    auto cvt = [&](const float* src, unsigned short* dst, int R, int C, int lds_, int ldd){
        long long n = (long long)R * ldd;
        cvt_pad_k<<<cdiv_i(n, 256), 256, 0, stream>>>(src, dst, n, C, lds_, ldd);
    };
    auto zero16 = [&](unsigned short* p, long long nshorts){
        fill_u32_k<<<cdiv_i(nshorts / 2, 256), 256, 0, stream>>>((unsigned*)p, 0u, nshorts / 2);
    };
    auto zerof = [&](float* p, long long n){
        fill_f32_k<<<cdiv_i(n, 256), 256, 0, stream>>>(p, 0.f, n);
    };

    // ---- transformer (shared for t1/t2); xin_bf = XB (padded Ep), residual xin f32 ----
    auto run_tf = [&](const float* xin, const float* const* W, float* outp, int E){
        const int Ep = pad32(E), E3p = 3 * Ep;
        float scale = (float)(1.0 / sqrt((double)E));
        // merged qkv: weights 3*Ep rows (pad rows zero), bias padded
        zero16(WQKVb, (long long)E3p * Ep);
        for (int s = 0; s < 3; ++s)
            cvt(W[0] + (size_t)s * E * E, WQKVb + (size_t)s * Ep * Ep, E, E, E, Ep);
        qkv_bias_k<<<cdiv_i(E3p, 256), 256, 0, stream>>>(W[1], QBIASf, E, Ep);
        mgemm<1,0,1,0,128>(stream, XB, WQKVb, QBIASf, QKVb, NN, E3p, Ep, Ep, Ep, E3p, 0);
        // V^T via bf16 transpose of the v-part
        {
            dim3 g(cdiv_i(E, 32), cdiv_i(NN, 32));
            tr_bf16_k<<<g, 256, 0, stream>>>(QKVb + 2 * Ep, Vt, NN, E, E3p, NN);
        }
        // attention: S (bf16, into Pb) -> in-place softmax -> PV
        if (E == FXD_) zerof(A4, (long long)NN * E);   // t1 PV uses split-K atomics
        for (long long r0 = 0; r0 < NN; r0 += RB){
            mgemm<1,0,1,0,128>(stream, QKVb + (size_t)r0 * E3p, QKVb + Ep, nullptr, Pb,
                               (int)RB, NN, Ep, E3p, E3p, NN, 0);
            softmax_bf16_k<<<(int)RB, 256, 0, stream>>>(Pb, scale);
            if (E == FXD_)   // N=78: BN=64 + split-K (atomic out only 2.5MB/slice)
                mgemm<0,0,8,0,64>(stream, Pb, Vt, nullptr, A4 + (size_t)r0 * E,
                                  (int)RB, E, NN, NN, NN, E, 0);
            else             // N=780: BN=64, direct bf16 into XB (pads already 0)
                mgemm<1,0,1,0,64>(stream, Pb, Vt, nullptr, XB + (size_t)r0 * Ep,
                                  (int)RB, E, NN, NN, NN, Ep, 0);
        }
        if (E == FXD_) cvt(A4, XB, NN, E, E, Ep);
        // proj + LN1
        cvt(W[2], WOUTb, E, E, E, Ep);
        mgemm<0,0,1,0,64>(stream, XB, WOUTb, W[3], A2, NN, E, Ep, Ep, Ep, E, 0);
        add_ln_k<<<NN, 256, 0, stream>>>(xin, A2, nullptr, W[4], W[5], A3, XB, E, Ep);
        // FF1 (relu, bf16) -> FF2 -> LN2
        cvt(W[6], WL1b, FFD, E, E, Ep);
        mgemm<1,1,1,0,128>(stream, XB, WL1b, W[7], HbPb, NN, FFD, Ep, Ep, Ep, FFD, 0);
        cvt(W[8], WL2b, E, FFD, FFD, FFD);
        mgemm<0,0,1,0,64>(stream, HbPb, WL2b, W[9], A2, NN, E, FFD, FFD, FFD, E, 0);
        add_ln_k<<<NN, 256, 0, stream>>>(A3, A2, nullptr, W[10], W[11], outp, XB, E, Ep);
    };

    // ================= t1 transformer (E=78) =================
    cvt(x, XB, NN, FXD_, FXD_, 96);
    run_tf(x, t1w, X1f, FXD_);          // leaves XB = t1 out (ld 96)

    // ================= GAT =================
    cvt(gat_w, WGb, DD2, FXD_, FXD_, 96);
    mgemm<0,0,1,0,64>(stream, XB, WGb, nullptr, A2, NN, DD2, 96, 96, 96, DD2, 0);   // hfeat
    gat_srcdst_k<<<cdiv_i((long long)NN * NH, 256), 256, 0, stream>>>(A2, gat_asrc, gat_adst, asrc, adst);
    fill_u32_k<<<cdiv_i((long long)NN * NH, 256), 256, 0, stream>>>(amax, 0x007FFFFFu, (long long)NN * NH);
    zerof(denom, (long long)NN * NH);
    fill_u32_k<<<cdiv_i(NN, 256), 256, 0, stream>>>((unsigned*)deg, 0u, NN);
    gat_alpha_k<<<cdiv_i((long long)NETOT * NH, 256), 256, 0, stream>>>(ei, asrc, adst, alpha, amax);
    gat_expsum_k<<<cdiv_i((long long)NETOT * NH, 256), 256, 0, stream>>>(ei, alpha, amax, denom);
    deg_count_k<<<cdiv_i(NETOT, 256), 256, 0, stream>>>(ei, deg);
    zerof(A1, (long long)NN * DD2);
    gat_agg_k<<<cdiv_i((long long)NETOT * DD2, 256), 256, 0, stream>>>(ei, alpha, denom, A2, A1);
    bias_relu_k<<<cdiv_i((long long)NN * 800, 256), 256, 0, stream>>>(A1, gat_b, XB, NN, DD2, 800);

    // ================= t2 transformer (E=780) =================
    run_tf(A1, t2w, A1, DD2);           // leaves XB = t2 out (ld 800)

    // ================= GCN =================
    dis_k<<<cdiv_i(NN, 256), 256, 0, stream>>>(deg, dis);
    cvt(gcn_w, WGCNb, DD2, DD2, DD2, 800);
    mgemm<0,0,1,0,64>(stream, XB, WGCNb, nullptr, A2, NN, DD2, 800, 800, 800, DD2, 0); // xw
    zerof(A3, (long long)NN * DD2);
    gcn_agg_k<<<cdiv_i((long long)NETOT * DD2, 256), 256, 0, stream>>>(ei, dis, A2, A3);
    bias_relu_k<<<cdiv_i((long long)NN * DD2, 256), 256, 0, stream>>>(A3, gcn_b, nullptr, NN, DD2, DD2);

    // ================= pooling + graph head =================
    zerof(gm, (long long)NG * DD2);
    zerof(ga, (long long)NG * DD2);
    fill_u32_k<<<cdiv_i(NG, 256), 256, 0, stream>>>((unsigned*)cnt, 0u, NG);
    pool_accum_k<<<cdiv_i((long long)NN * DD2, 256), 256, 0, stream>>>(A3, batch, gm, ga, cnt);
    pool_fin_k<<<cdiv_i((long long)NG * 1568, 256), 256, 0, stream>>>(gm, ga, cnt, XD16);
    cvt(fcg1_w, WFCG1b, 1500, 1560, 1560, 1568);
    zerof(A2, (long long)NG * 1500);
    mgemm<0,0,8,0,64>(stream, XD16, WFCG1b, nullptr, A2, NG, 1500, 1568, 1568, 1568, 1500, 0);
    bias_relu_k<<<cdiv_i((long long)NG * 1504, 256), 256, 0, stream>>>(A2, fcg1_b, FG1b, NG, 1500, 1504);
    cvt(fcg2_w, WFCG2b, 128, 1500, 1500, 1504);
    zerof(xd_out, (long long)NG * 128);
    mgemm<0,0,16,0,128>(stream, FG1b, WFCG2b, nullptr, xd_out, NG, 128, 1504, 1504, 1504, 128, 0);
    bias_add_k<<<cdiv_i((long long)NG * 128, 256), 256, 0, stream>>>(xd_out, fcg2_b, (long long)NG * 128, 128); // OUTPUT 1

    // ================= conv encoder (GEMM-ified; AIM=HbPb arena, Gout=A2) =================
    enc1_b<<<NG, 256, 0, stream>>>(tmut, e1_w, e1_b, bn1_g, bn1_b, c1p);
    // enc2: (21504 x 256) x (64 x 256)^T
    i2c_enc2_k<<<cdiv_i((long long)NG * 84 * 256, 256), 256, 0, stream>>>(c1p, AIM);
    cvt(e2_w, Wcvb, 64, 256, 256, 256);
    mgemm<0,0,1,0,64>(stream, AIM, Wcvb, nullptr, A2, NG * 84, 64, 256, 256, 256, 64, 0);
    post_enc2_k<<<cdiv_i((long long)NG * 768, 256), 256, 0, stream>>>(A2, e2_b, bn2_g, bn2_b, c2p);
    // enc3: (1280 x 512) x (128 x 512)^T, split-K 4
    i2c_enc3_k<<<cdiv_i((long long)NG * 5 * 512, 256), 256, 0, stream>>>(c2p, AIM);
    cvt(e3_w, Wcvb, 128, 512, 512, 512);
    zerof(A2, (long long)NG * 5 * 128);
    mgemm<0,0,4,0,128>(stream, AIM, Wcvb, nullptr, A2, NG * 5, 128, 512, 512, 512, 128, 0);
    post_enc3_k<<<cdiv_i((long long)NG * 640, 256), 256, 0, stream>>>(A2, e3_b, e3o, E3b);
    // z
    cvt(enc_w, WENCb, 128, 640, 640, 640);
    mgemm<0,0,1,0,128>(stream, E3b, WENCb, enc_b, zz, NG, 128, 640, 640, 640, 128, 0);

    // ================= conv decoder (GEMM-ified) =================
    // dec3: (3072 x 1024) x (64 x 1024)^T, split-K 4
    wshuf_k<<<cdiv_i(128 * 64 * 8, 256), 256, 0, stream>>>(d3_w, Wcvb, 128, 64);
    i2c_dec3_k<<<cdiv_i((long long)NG * 12 * 1024, 256), 256, 0, stream>>>(e3o, AIM);
    zerof(A2, (long long)NG * 12 * 64);
    mgemm<0,0,4,0,64>(stream, AIM, Wcvb, nullptr, A2, NG * 12, 64, 1024, 1024, 1024, 64, 0);
    post_dec3_k<<<cdiv_i((long long)NG * 768, 256), 256, 0, stream>>>(A2, d3_b, dbn2_g, dbn2_b, dd3);
    // dec2: (23296 x 512) x (32 x 512)^T
    wshuf_k<<<cdiv_i(64 * 32 * 8, 256), 256, 0, stream>>>(d2_w, Wcvb, 64, 32);
    i2c_dec2_k<<<cdiv_i((long long)NG * 91 * 512, 256), 256, 0, stream>>>(dd3, AIM);
    mgemm<0,0,1,0,64>(stream, AIM, Wcvb, nullptr, A2, NG * 91, 32, 512, 512, 512, 32, 0);
    post_dec2_k<<<cdiv_i((long long)NG * 2912, 256), 256, 0, stream>>>(A2, d2_b, dbn1_g, dbn1_b, dd2b);
    // dec1 (LDS kernel, 768 blocks)
    { dim3 g(NG, 3); dec1_b<<<g, 256, 0, stream>>>(dd2b, d1_w, d1_b, decode); }   // OUTPUT 2

    // ================= final head =================
    concat_xc_k<<<cdiv_i((long long)NG * 256, 256), 256, 0, stream>>>(xd_out, zz, XCb);
    cvt(fc1_w, WFC1b, 1024, 256, 256, 256);
    mgemm<1,1,1,0,128>(stream, XCb, WFC1b, fc1_b, FH1b, NG, 1024, 256, 256, 256, 1024, 0);
    cvt(fc2_w, WFC2b, 128, 1024, 1024, 1024);
    zerof(A3, (long long)NG * 128);
    mgemm<0,0,8,0,128>(stream, FH1b, WFC2b, nullptr, A3, NG, 128, 1024, 1024, 1024, 128, 0);
    bias_relu_k<<<cdiv_i((long long)NG * 128, 256), 256, 0, stream>>>(A3, fc2_b, FH2b, NG, 128, 128);
    cvt(outw, WOUTWb, 1, 128, 128, 128);
    mgemm<0,2,1,0,64>(stream, FH2b, WOUTWb, outb, out0, NG, 1, 128, 128, 128, 1, 0);   // OUTPUT 0 (sigmoid)
}

// Round 11
// 1786.901 us; speedup vs baseline: 1.4608x; 1.1773x over previous
//
#include <hip/hip_runtime.h>
#include <math.h>

// Problem constants
#define NN     8192      // nodes
#define NEDGE  32768     // edges (before self loops)
#define NETOT  40960     // edges + self loops
#define NG     256       // graphs
#define FXD_   78
#define NH     10        // heads
#define DD2    780       // FXD*HEADS
#define FFD    2048
#define LMUT   735

static inline int cdiv_i(long long a, int b){ return (int)((a + (long long)b - 1) / b); }
static inline int pad32(int x){ return (x + 31) & ~31; }

typedef __attribute__((ext_vector_type(8))) short bf16x8;
typedef __attribute__((ext_vector_type(4))) float f32x4;

static __device__ __forceinline__ unsigned short f2bf(float f){
    unsigned u = __float_as_uint(f);
    u += 0x7FFFu + ((u >> 16) & 1u);
    return (unsigned short)(u >> 16);
}

// async global->LDS, 16B per lane; lds dest is wave-uniform base + lane*16
static __device__ __forceinline__ void gload16(const void* g, void* l){
    __builtin_amdgcn_global_load_lds((const __attribute__((address_space(1))) void*)g,
                                     (__attribute__((address_space(3))) void*)l, 16, 0, 0);
}

// ---------------- fills ----------------
__global__ void fill_f32_k(float* __restrict__ p, float v, long long n){
    long long i = (long long)blockIdx.x * 256 + threadIdx.x;
    if (i < n) p[i] = v;
}
__global__ void fill_u32_k(unsigned* __restrict__ p, unsigned v, long long n){
    long long i = (long long)blockIdx.x * 256 + threadIdx.x;
    if (i < n) p[i] = v;
}

// ---------------- f32 -> bf16 convert with K-padding ----------------
__global__ void cvt_pad_k(const float* __restrict__ src, unsigned short* __restrict__ dst,
                          long long n /*R*ldd*/, int C, int lds_, int ldd)
{
    long long i = (long long)blockIdx.x * 256 + threadIdx.x;
    if (i >= n) return;
    int r = (int)(i / ldd), c = (int)(i % ldd);
    dst[i] = (c < C) ? f2bf(src[(size_t)r * lds_ + c]) : (unsigned short)0;
}

// bf16 transpose: dst[c][r] = src[r][c]
__global__ void tr_bf16_k(const unsigned short* __restrict__ src, unsigned short* __restrict__ dst,
                          int R, int C, int lds_, int ldd)
{
    __shared__ unsigned short t[32][33];
    int cb = blockIdx.x * 32, rb = blockIdx.y * 32;
    int tx = threadIdx.x & 31, ty = threadIdx.x >> 5;   // 32 x 8
#pragma unroll
    for (int i = 0; i < 4; ++i){
        int r = rb + ty + i * 8, c = cb + tx;
        t[ty + i * 8][tx] = (r < R && c < C) ? src[(size_t)r * lds_ + c] : (unsigned short)0;
    }
    __syncthreads();
#pragma unroll
    for (int i = 0; i < 4; ++i){
        int dr = cb + ty + i * 8, dc = rb + tx;
        if (dr < C && dc < R) dst[(size_t)dr * ldd + dc] = t[tx][ty + i * 8];
    }
}

// padded qkv bias: out[s*Ep+c] = (c<E) ? b3[s*E+c] : 0, s=0..2
__global__ void qkv_bias_k(const float* __restrict__ b3, float* __restrict__ out, int E, int Ep)
{
    int idx = blockIdx.x * 256 + threadIdx.x;
    if (idx >= 3 * Ep) return;
    int s = idx / Ep, c = idx % Ep;
    out[idx] = (c < E) ? b3[s * E + c] : 0.f;
}

__global__ void bias_add_k(float* __restrict__ X, const float* __restrict__ b, long long n, int cols)
{
    long long i = (long long)blockIdx.x * 256 + threadIdx.x;
    if (i < n) X[i] += b[i % cols];
}

// ---------------- MFMA bf16 GEMM: 2-phase dbuf + XCD swizzle + BN=64/128 tiles ----------------
template<int OUTC, int ACT, int SPLITK, int BROW, int BN>
__global__ __launch_bounds__(256) void mgemm_k(
    const unsigned short* __restrict__ A, const unsigned short* __restrict__ B,
    const float* __restrict__ bias, void* __restrict__ Cv,
    int M, int N, int Kp, int lda, int ldb, int ldc, int swz)
{
    constexpr int NFJ   = BN / 32;        // col frags per wave
    constexpr int TILEA = 128 * 32;
    constexpr int TILEB = BN * 32;
    __shared__ unsigned short As[2 * TILEA];
    __shared__ unsigned short Bs[2 * TILEB];
    const int tid = threadIdx.x;
    const int lane = tid & 63, wid = tid >> 6;
    const int r16 = lane & 15, q = lane >> 4;
    const int wr = (wid >> 1) * 64, wc = (wid & 1) * (BN / 2);

    // bijective XCD-chunked remap (m204)
    const int gx = gridDim.x, gy = gridDim.y;
    const int nwg = gx * gy;
    int orig = swz ? ((int)blockIdx.x * gy + (int)blockIdx.y)
                   : ((int)blockIdx.y * gx + (int)blockIdx.x);
    int q8 = nwg >> 3, r8 = nwg & 7;
    int xcd = orig & 7, kk8 = orig >> 3;
    int wgid = (xcd < r8 ? xcd * (q8 + 1) : r8 * (q8 + 1) + (xcd - r8) * q8) + kk8;
    int bx, by;
    if (swz){ by = wgid % gy; bx = wgid / gy; }
    else    { bx = wgid % gx; by = wgid / gx; }
    const int row0 = by * 128, col0 = bx * BN;

    int kbeg = 0, kend = Kp;
    if (SPLITK > 1){
        int nt_ = Kp >> 5, cpt = (nt_ + SPLITK - 1) / SPLITK;
        kbeg = (int)blockIdx.z * cpt * 32;
        kend = min(Kp, kbeg + cpt * 32);
    }

    // A staging: 512 chunks of 16B; lane handles chunk c0 and c0+64
    const int c0 = wid * 128 + lane;
    const int r0a = c0 >> 2, k0a = (c0 & 3) << 3;
    const size_t gA0 = (size_t)min(row0 + r0a, M - 1) * lda + k0a;
    const size_t gA1 = (size_t)min(row0 + r0a + 16, M - 1) * lda + k0a;
    unsigned short* lA = As + wid * 1024;
    // B staging
    size_t gB0 = 0, gB1 = 0;
    unsigned short* lB;
    if (BN == 128){
        gB0 = (size_t)min(col0 + r0a, N - 1) * ldb + k0a;
        gB1 = (size_t)min(col0 + r0a + 16, N - 1) * ldb + k0a;
        lB = Bs + wid * 1024;
    } else {               // BN=64: 256 chunks, 1 per lane
        const int cb = wid * 64 + lane;
        const int rb_ = cb >> 2, kb_ = (cb & 3) << 3;
        gB0 = (size_t)min(col0 + rb_, N - 1) * ldb + kb_;
        lB = Bs + wid * 512;
    }

    f32x4 acc[4][NFJ];
#pragma unroll
    for (int i = 0; i < 4; ++i)
#pragma unroll
        for (int j = 0; j < NFJ; ++j){ f32x4 z = {0.f, 0.f, 0.f, 0.f}; acc[i][j] = z; }

    const int nt = (kend - kbeg) >> 5;
    if (nt > 0){
        gload16(A + gA0 + kbeg, lA);
        gload16(A + gA1 + kbeg, lA + 512);
        gload16(B + gB0 + kbeg, lB);
        if (BN == 128) gload16(B + gB1 + kbeg, lB + 512);
        __syncthreads();
        int cur = 0;
        for (int t = 0; t < nt; ++t){
            const int k0 = kbeg + (t << 5);
            if (t + 1 < nt){                  // stage next tile BEFORE compute (overlap)
                const int kn = k0 + 32, nb = cur ^ 1;
                gload16(A + gA0 + kn, lA + nb * TILEA);
                gload16(A + gA1 + kn, lA + nb * TILEA + 512);
                gload16(B + gB0 + kn, lB + nb * TILEB);
                if (BN == 128) gload16(B + gB1 + kn, lB + nb * TILEB + 512);
            }
            const unsigned short* Ab = As + cur * TILEA;
            const unsigned short* Bb = Bs + cur * TILEB;
            bf16x8 af[4], bfv[NFJ];
#pragma unroll
            for (int f = 0; f < 4; ++f)
                af[f] = *(const bf16x8*)(Ab + (size_t)(wr + f * 16 + r16) * 32 + (q << 3));
#pragma unroll
            for (int f = 0; f < NFJ; ++f)
                bfv[f] = *(const bf16x8*)(Bb + (size_t)(wc + f * 16 + r16) * 32 + (q << 3));
#pragma unroll
            for (int fi = 0; fi < 4; ++fi)
#pragma unroll
                for (int fj = 0; fj < NFJ; ++fj)
                    acc[fi][fj] = __builtin_amdgcn_mfma_f32_16x16x32_bf16(af[fi], bfv[fj], acc[fi][fj], 0, 0, 0);
            __syncthreads();
            cur ^= 1;
        }
    }

#pragma unroll
    for (int fi = 0; fi < 4; ++fi){
#pragma unroll
        for (int j = 0; j < 4; ++j){
            int r = row0 + wr + fi * 16 + q * 4 + j;   // C/D: row=(lane>>4)*4+reg
            if (r >= M) continue;
#pragma unroll
            for (int fj = 0; fj < NFJ; ++fj){
                int c = col0 + wc + fj * 16 + r16;     // C/D: col=lane&15
                if (c >= N) continue;
                float v = acc[fi][fj][j];
                if (SPLITK > 1){
                    atomicAdd((float*)Cv + (size_t)r * ldc + c, v);
                } else {
                    if (bias) v += BROW ? bias[r] : bias[c];
                    if (ACT == 1) v = fmaxf(v, 0.f);
                    if (ACT == 2) v = 1.f / (1.f + expf(-v));
                    if (OUTC == 0) ((float*)Cv)[(size_t)r * ldc + c] = v;
                    else ((unsigned short*)Cv)[(size_t)r * ldc + c] = f2bf(v);
                }
            }
        }
    }
}

template<int OUTC, int ACT, int SPLITK, int BROW, int BN>
static void mgemm(hipStream_t s, const unsigned short* A, const unsigned short* B,
                  const float* bias, void* C, int M, int N, int Kp,
                  int lda, int ldb, int ldc, int swz)
{
    dim3 g(cdiv_i(N, BN), cdiv_i(M, 128), SPLITK);
    mgemm_k<OUTC, ACT, SPLITK, BROW, BN><<<g, 256, 0, s>>>(A, B, bias, C, M, N, Kp, lda, ldb, ldc, swz);
}

// ---------------- softmax: in-place on bf16 rows (8192 cols), register-resident ----------------
__global__ __launch_bounds__(256) void softmax_bf16_k(unsigned short* __restrict__ SP, float scale)
{
    __shared__ float red[8];
    const int tid = threadIdx.x;
    uint4* prow = (uint4*)(SP + (size_t)blockIdx.x * NN);   // 1024 uint4 per row
    float v[32];
    float mx = -3.4e38f;
#pragma unroll
    for (int c = 0; c < 4; ++c){
        uint4 t = prow[c * 256 + tid];
        const unsigned* u = (const unsigned*)&t;
#pragma unroll
        for (int j = 0; j < 4; ++j){
            float lo = __uint_as_float(u[j] << 16) * scale;
            float hi = __uint_as_float(u[j] & 0xFFFF0000u) * scale;
            v[c * 8 + j * 2]     = lo;
            v[c * 8 + j * 2 + 1] = hi;
            mx = fmaxf(mx, fmaxf(lo, hi));
        }
    }
#pragma unroll
    for (int off = 32; off; off >>= 1) mx = fmaxf(mx, __shfl_xor(mx, off, 64));
    if ((tid & 63) == 0) red[tid >> 6] = mx;
    __syncthreads();
    mx = fmaxf(fmaxf(red[0], red[1]), fmaxf(red[2], red[3]));
    float sum = 0.f;
#pragma unroll
    for (int i = 0; i < 32; ++i){ v[i] = expf(v[i] - mx); sum += v[i]; }
#pragma unroll
    for (int off = 32; off; off >>= 1) sum += __shfl_xor(sum, off, 64);
    if ((tid & 63) == 0) red[4 + (tid >> 6)] = sum;
    __syncthreads();
    float inv = 1.f / (red[4] + red[5] + red[6] + red[7]);
#pragma unroll
    for (int c = 0; c < 4; ++c){
        uint4 t;
        unsigned* u = (unsigned*)&t;
#pragma unroll
        for (int j = 0; j < 4; ++j){
            unsigned lo = f2bf(v[c * 8 + j * 2] * inv);
            unsigned hi = f2bf(v[c * 8 + j * 2 + 1] * inv);
            u[j] = lo | (hi << 16);
        }
        prow[c * 256 + tid] = t;
    }
}

// ---------------- residual add + layernorm ----------------
__global__ __launch_bounds__(256) void add_ln_k(
    const float* __restrict__ X, const float* __restrict__ Y, const float* __restrict__ ybias,
    const float* __restrict__ g, const float* __restrict__ b,
    float* __restrict__ out, unsigned short* __restrict__ obf, int E, int Ep)
{
    __shared__ float s1[256], s2[256];
    const int tid = threadIdx.x;
    long long base = (long long)blockIdx.x * E;
    float vals[4];
    float sum = 0.f, sq = 0.f;
    int i = 0;
    for (int c = tid; c < Ep; c += 256, ++i){
        float v = 0.f;
        if (c < E){
            v = X[base + c] + Y[base + c];
            if (ybias) v += ybias[c];
            sum += v; sq += v * v;
        }
        vals[i] = v;
    }
    s1[tid] = sum; s2[tid] = sq; __syncthreads();
    for (int s = 128; s; s >>= 1){
        if (tid < s){ s1[tid] += s1[tid + s]; s2[tid] += s2[tid + s]; }
        __syncthreads();
    }
    float mean = s1[0] / (float)E;
    float var = s2[0] / (float)E - mean * mean;
    if (var < 0.f) var = 0.f;
    float inv = 1.f / sqrtf(var + 1e-5f);
    i = 0;
    for (int c = tid; c < Ep; c += 256, ++i){
        if (c < E){
            float o = (vals[i] - mean) * inv * g[c] + b[c];
            out[base + c] = o;
            if (obf) obf[(size_t)blockIdx.x * Ep + c] = f2bf(o);
        } else if (obf) obf[(size_t)blockIdx.x * Ep + c] = 0;
    }
}

// ---------------- GAT / graph common ----------------
static __device__ __forceinline__ unsigned enc_f(float x){
    unsigned u = __float_as_uint(x);
    return (u & 0x80000000u) ? ~u : (u | 0x80000000u);
}
static __device__ __forceinline__ float dec_f(unsigned u){
    return (u & 0x80000000u) ? __uint_as_float(u & 0x7fffffffu) : __uint_as_float(~u);
}
static __device__ __forceinline__ void edge_sd(const int* __restrict__ ei, int e, int& s, int& d){
    if (e < NEDGE){ s = ei[e]; d = ei[NEDGE + e]; }
    else { s = e - NEDGE; d = e - NEDGE; }
}

__global__ void gat_srcdst_k(const float* __restrict__ h, const float* __restrict__ aw_src,
                             const float* __restrict__ aw_dst, float* __restrict__ asrc,
                             float* __restrict__ adst)
{
    int idx = blockIdx.x * 256 + threadIdx.x;
    if (idx >= NN * NH) return;
    int n = idx / NH, hh = idx % NH;
    const float* hp = h + (long long)n * DD2 + hh * FXD_;
    const float* ws = aw_src + hh * FXD_;
    const float* wd = aw_dst + hh * FXD_;
    float s1 = 0.f, s2 = 0.f;
    for (int f = 0; f < FXD_; ++f){ float v = hp[f]; s1 += v * ws[f]; s2 += v * wd[f]; }
    asrc[idx] = s1; adst[idx] = s2;
}

__global__ void gat_alpha_k(const int* __restrict__ ei, const float* __restrict__ asrc,
                            const float* __restrict__ adst, float* __restrict__ alpha,
                            unsigned* __restrict__ amax)
{
    int idx = blockIdx.x * 256 + threadIdx.x;
    if (idx >= NETOT * NH) return;
    int e = idx / NH, hh = idx % NH;
    int s, d; edge_sd(ei, e, s, d);
    float a = asrc[s * NH + hh] + adst[d * NH + hh];
    a = (a > 0.f) ? a : 0.2f * a;       // leaky_relu 0.2
    alpha[idx] = a;
    atomicMax(&amax[d * NH + hh], enc_f(a));
}

__global__ void gat_expsum_k(const int* __restrict__ ei, float* __restrict__ alpha,
                             const unsigned* __restrict__ amax, float* __restrict__ denom)
{
    int idx = blockIdx.x * 256 + threadIdx.x;
    if (idx >= NETOT * NH) return;
    int e = idx / NH, hh = idx % NH;
    int s, d; edge_sd(ei, e, s, d);
    float m = dec_f(amax[d * NH + hh]);
    float ex = expf(alpha[idx] - m);
    alpha[idx] = ex;
    atomicAdd(&denom[d * NH + hh], ex);
}

__global__ void deg_count_k(const int* __restrict__ ei, int* __restrict__ deg)
{
    int e = blockIdx.x * 256 + threadIdx.x;
    if (e >= NETOT) return;
    int s, d; edge_sd(ei, e, s, d);
    atomicAdd(&deg[d], 1);
}

// ---- CSR build: exclusive scan of deg (single block) + fill ----
__global__ __launch_bounds__(256) void csr_off_k(const int* __restrict__ deg,
                                                 int* __restrict__ off, int* __restrict__ cur)
{
    __shared__ int pref[257];
    const int tid = threadIdx.x;
    int loc[32];
    int base = tid * 32, sum = 0;
#pragma unroll
    for (int i = 0; i < 32; ++i){ loc[i] = sum; sum += deg[base + i]; }
    __shared__ int part[256];
    part[tid] = sum; __syncthreads();
    if (tid == 0){
        pref[0] = 0;
        for (int i = 0; i < 256; ++i) pref[i + 1] = pref[i] + part[i];
    }
    __syncthreads();
    int p0 = pref[tid];
#pragma unroll
    for (int i = 0; i < 32; ++i){ off[base + i] = p0 + loc[i]; cur[base + i] = p0 + loc[i]; }
    if (tid == 0) off[NN] = pref[256];
}

__global__ void csr_fill_k(const int* __restrict__ ei, int* __restrict__ cur,
                           int* __restrict__ csr_s, int* __restrict__ csr_e)
{
    int e = blockIdx.x * 256 + threadIdx.x;
    if (e >= NETOT) return;
    int s, d; edge_sd(ei, e, s, d);
    int pos = atomicAdd(&cur[d], 1);
    csr_s[pos] = s; csr_e[pos] = e;
}

// GAT gather: one block per dst node; no atomics
__global__ __launch_bounds__(256) void gat_gather_k(
    const int* __restrict__ off, const int* __restrict__ csr_s, const int* __restrict__ csr_e,
    const float* __restrict__ ex, const float* __restrict__ denom,
    const float* __restrict__ hfeat, float* __restrict__ out)
{
    const int d = blockIdx.x, tid = threadIdx.x;
    const int beg = off[d], end = off[d + 1];
    for (int f = tid; f < DD2; f += 256){
        int hh = f / FXD_;
        float acc = 0.f;
        for (int p = beg; p < end; ++p)
            acc += ex[csr_e[p] * NH + hh] * hfeat[(size_t)csr_s[p] * DD2 + f];
        out[(size_t)d * DD2 + f] = acc / (denom[d * NH + hh] + 1e-16f);
    }
}

// GCN gather
__global__ __launch_bounds__(256) void gcn_gather_k(
    const int* __restrict__ off, const int* __restrict__ csr_s,
    const float* __restrict__ dis, const float* __restrict__ xw, float* __restrict__ out)
{
    const int d = blockIdx.x, tid = threadIdx.x;
    const int beg = off[d], end = off[d + 1];
    const float dd_ = dis[d];
    for (int f = tid; f < DD2; f += 256){
        float acc = 0.f;
        for (int p = beg; p < end; ++p){
            int s = csr_s[p];
            acc += dis[s] * xw[(size_t)s * DD2 + f];
        }
        out[(size_t)d * DD2 + f] = acc * dd_;
    }
}

// bias+relu on f32 (ld=cols), optional padded-bf16 mirror (ld=ldp)
__global__ void bias_relu_k(float* __restrict__ X, const float* __restrict__ b,
                            unsigned short* __restrict__ obf, int rows, int cols, int ldp)
{
    long long i = (long long)blockIdx.x * 256 + threadIdx.x;
    if (i >= (long long)rows * ldp) return;
    int r = (int)(i / ldp), c = (int)(i % ldp);
    if (c < cols){
        float v = X[(size_t)r * cols + c] + b[c];
        v = v > 0.f ? v : 0.f;
        X[(size_t)r * cols + c] = v;
        if (obf) obf[i] = f2bf(v);
    } else if (obf) obf[i] = 0;
}

__global__ void dis_k(const int* __restrict__ deg, float* __restrict__ dis)
{
    int n = blockIdx.x * 256 + threadIdx.x;
    if (n >= NN) return;
    float d = (float)deg[n];
    dis[n] = (d > 0.f) ? 1.f / sqrtf(fmaxf(d, 1.f)) : 0.f;
}

// ---------------- graph pooling ----------------
__global__ void pool_accum_k(const float* __restrict__ xg, const int* __restrict__ batch,
                             float* __restrict__ gm, float* __restrict__ ga, int* __restrict__ cnt)
{
    long long idx = (long long)blockIdx.x * 256 + threadIdx.x;
    if (idx >= (long long)NN * DD2) return;
    int n = (int)(idx / DD2), f = (int)(idx % DD2);
    int g = batch[n];
    float v = xg[idx];
    atomicMax((int*)(gm + (long long)g * DD2 + f), __float_as_int(v));
    atomicAdd(ga + (long long)g * DD2 + f, v);
    if (f == 0) atomicAdd(cnt + g, 1);
}

// -> padded bf16 (ld 1568)
__global__ void pool_fin_k(const float* __restrict__ gm, const float* __restrict__ ga,
                           const int* __restrict__ cnt, unsigned short* __restrict__ xdb)
{
    int idx = blockIdx.x * 256 + threadIdx.x;
    if (idx >= NG * 1568) return;
    int g = idx / 1568, c = idx % 1568;
    float v = 0.f;
    if (c < DD2)       v = gm[g * DD2 + c];
    else if (c < 1560) v = ga[g * DD2 + (c - DD2)] / fmaxf((float)cnt[g], 1.f);
    xdb[idx] = f2bf(v);
}

// ---------------- conv autoencoder ----------------
#define BN_SCALE 0.9999950000374996f   // 1/sqrt(1+1e-5)

// enc1: (NG,32,91); tm row (735 f32) + w (32x8) in LDS; grid NG
__global__ __launch_bounds__(256) void enc1_b(const float* __restrict__ tm, const float* __restrict__ w,
                                              const float* __restrict__ bias, const float* __restrict__ bng,
                                              const float* __restrict__ bnb, float* __restrict__ out)
{
    __shared__ float xs[736];
    __shared__ float ws[256], bs[32], gs[32], b2[32];
    const int g = blockIdx.x, tid = threadIdx.x;
    for (int i = tid; i < 735; i += 256) xs[i] = tm[(size_t)g * LMUT + i];
    ws[tid] = w[tid];
    if (tid < 32){ bs[tid] = bias[tid]; gs[tid] = bng[tid]; b2[tid] = bnb[tid]; }
    __syncthreads();
    for (int idx = tid; idx < 32 * 91; idx += 256){
        int o = idx / 91, t = idx % 91;
        float mx = -3.4e38f;
        for (int p = 0; p < 8; ++p){
            float s = bs[o];
#pragma unroll
            for (int k = 0; k < 8; ++k) s += xs[t * 8 + p + k] * ws[o * 8 + k];
            mx = fmaxf(mx, s);
        }
        float v = mx * gs[o] * BN_SCALE + b2[o];
        out[(size_t)g * 2912 + idx] = v > 0.f ? v : 0.01f * v;
    }
}

// ---- GEMM-ified AE middle layers: im2col / weight-reshape / post kernels ----
__global__ void i2c_enc2_k(const float* __restrict__ in, unsigned short* __restrict__ A){
    int idx = blockIdx.x * 256 + threadIdx.x;
    if (idx >= NG * 84 * 256) return;
    int col = idx & 255, row = idx >> 8;
    int g = row / 84, u = row % 84;
    int i = col >> 3, k = col & 7;
    A[idx] = f2bf(in[(size_t)g * 2912 + i * 91 + u + k]);
}
__global__ void post_enc2_k(const float* __restrict__ G, const float* __restrict__ b,
                            const float* __restrict__ bng, const float* __restrict__ bnb,
                            float* __restrict__ out){
    int idx = blockIdx.x * 256 + threadIdx.x;
    if (idx >= NG * 768) return;
    int t = idx % 12, o = (idx / 12) & 63, g = idx / 768;
    float mx = -3.4e38f;
#pragma unroll
    for (int p = 0; p < 7; ++p) mx = fmaxf(mx, G[(size_t)(g * 84 + t * 7 + p) * 64 + o]);
    float v = (mx + b[o]) * bng[o] * BN_SCALE + bnb[o];
    out[(size_t)g * 768 + o * 12 + t] = v > 0.f ? v : 0.01f * v;
}
__global__ void i2c_enc3_k(const float* __restrict__ in, unsigned short* __restrict__ A){
    int idx = blockIdx.x * 256 + threadIdx.x;
    if (idx >= NG * 5 * 512) return;
    int col = idx & 511, row = idx >> 9;
    int g = row / 5, t = row % 5;
    int i2 = col >> 3, k = col & 7;
    A[idx] = f2bf(in[(size_t)g * 768 + i2 * 12 + t + k]);
}
__global__ void post_enc3_k(const float* __restrict__ G, const float* __restrict__ b,
                            float* __restrict__ e3o, unsigned short* __restrict__ obf){
    int idx = blockIdx.x * 256 + threadIdx.x;
    if (idx >= NG * 640) return;
    int t = idx % 5, o = (idx / 5) & 127, g = idx / 640;
    float v = G[(size_t)(g * 5 + t) * 128 + o] + b[o];
    e3o[(size_t)g * 640 + o * 5 + t] = v;
    obf[(size_t)g * 640 + o * 5 + t] = f2bf(v);
}
__global__ void wshuf_k(const float* __restrict__ src, unsigned short* __restrict__ dst, int I, int O){
    int idx = blockIdx.x * 256 + threadIdx.x;
    if (idx >= I * O * 8) return;
    int o = idx / (I * 8), rem = idx % (I * 8);
    int i = rem >> 3, j = rem & 7;
    dst[idx] = f2bf(src[(size_t)(i * O + o) * 8 + j]);
}
__global__ void i2c_dec3_k(const float* __restrict__ e3o, unsigned short* __restrict__ A){
    int idx = blockIdx.x * 256 + threadIdx.x;
    if (idx >= NG * 12 * 1024) return;
    int col = idx & 1023, row = idx >> 10;
    int g = row / 12, t = row % 12;
    int i2 = col >> 3, j = col & 7;
    int tt = t - j;
    A[idx] = (tt >= 0 && tt < 5) ? f2bf(e3o[(size_t)g * 640 + i2 * 5 + tt]) : (unsigned short)0;
}
__global__ void post_dec3_k(const float* __restrict__ G, const float* __restrict__ b,
                            const float* __restrict__ bng, const float* __restrict__ bnb,
                            float* __restrict__ dd3){
    int idx = blockIdx.x * 256 + threadIdx.x;
    if (idx >= NG * 768) return;
    int t = idx % 12, o = (idx / 12) & 63, g = idx / 768;
    float v = (G[(size_t)(g * 12 + t) * 64 + o] + b[o]) * bng[o] * BN_SCALE + bnb[o];
    dd3[(size_t)g * 768 + o * 12 + t] = v > 0.f ? v : 0.01f * v;
}
__global__ void i2c_dec2_k(const float* __restrict__ dd3, unsigned short* __restrict__ A){
    int idx = blockIdx.x * 256 + threadIdx.x;
    if (idx >= NG * 91 * 512) return;
    int col = idx & 511, row = idx >> 9;
    int g = row / 91, t = row % 91;
    int i2 = col >> 3, j = col & 7;
    int tt = t - j;
    A[idx] = (tt >= 0 && tt < 84) ? f2bf(dd3[(size_t)g * 768 + i2 * 12 + tt / 7]) : (unsigned short)0;
}
__global__ void post_dec2_k(const float* __restrict__ G, const float* __restrict__ b,
                            const float* __restrict__ bng, const float* __restrict__ bnb,
                            float* __restrict__ dd2){
    int idx = blockIdx.x * 256 + threadIdx.x;
    if (idx >= NG * 2912) return;
    int t = idx % 91, o = (idx / 91) & 31, g = idx / 2912;
    float v = (G[(size_t)(g * 91 + t) * 32 + o] + b[o]) * bng[o] * BN_SCALE + bnb[o];
    dd2[(size_t)g * 2912 + o * 91 + t] = v > 0.f ? v : 0.01f * v;
}

// dec1: (NG,735); grid (NG,3) t-chunks of 245; dd2 (32x91) + w (32x8) in LDS
__global__ __launch_bounds__(256) void dec1_b(const float* __restrict__ dd2, const float* __restrict__ w,
                                              const float* __restrict__ bias, float* __restrict__ out)
{
    __shared__ float d2s[32][91];
    __shared__ float ws[256];
    const int g = blockIdx.x, tid = threadIdx.x;
    const int t0 = (int)blockIdx.y * 245;
    for (int i = tid; i < 32 * 91; i += 256) d2s[i / 91][i % 91] = dd2[(size_t)g * 2912 + i];
    ws[tid] = w[tid];
    __syncthreads();
    if (tid < 245){
        int t = t0 + tid;
        int id8[8]; bool ok[8];
#pragma unroll
        for (int j = 0; j < 8; ++j){
            int tt = t - j;
            ok[j] = (tt >= 0 && tt < 728);
            id8[j] = ok[j] ? (tt >> 3) : 0;
        }
        float s = bias[0];
        for (int i2 = 0; i2 < 32; ++i2){
            const float* wp = ws + i2 * 8;
            float a = 0.f;
#pragma unroll
            for (int j = 0; j < 8; ++j) if (ok[j]) a += d2s[i2][id8[j]] * wp[j];
            s += a;
        }
        out[(size_t)g * 735 + t] = s;
    }
}

__global__ void concat_xc_k(const float* __restrict__ xd, const float* __restrict__ z,
                            unsigned short* __restrict__ xcb)
{
    int idx = blockIdx.x * 256 + threadIdx.x;
    if (idx >= NG * 256) return;
    int g = idx >> 8, c = idx & 255;
    xcb[idx] = f2bf((c < 128) ? xd[g * 128 + c] : z[g * 128 + (c - 128)]);
}

// ---------------- host-side orchestration ----------------
extern "C" void kernel_launch(void* const* d_in, const int* in_sizes, int n_in,
                              void* d_out, int out_size, void* d_ws, size_t ws_size,
                              hipStream_t stream)
{
    (void)in_sizes; (void)n_in; (void)out_size;

    // ---- input pointers: setup_inputs() DICT order (t1 4-15, t2 16-27, gat 28-31) ----
    const float* x      = (const float*)d_in[0];
    const int*   ei     = (const int*)  d_in[1];
    const int*   batch  = (const int*)  d_in[2];
    const float* tmut   = (const float*)d_in[3];
    const float* t1w[12]; for (int i = 0; i < 12; ++i) t1w[i] = (const float*)d_in[4 + i];
    const float* t2w[12]; for (int i = 0; i < 12; ++i) t2w[i] = (const float*)d_in[16 + i];
    const float* gat_w    = (const float*)d_in[28];
    const float* gat_asrc = (const float*)d_in[29];
    const float* gat_adst = (const float*)d_in[30];
    const float* gat_b    = (const float*)d_in[31];
    const float* gcn_w  = (const float*)d_in[32];
    const float* gcn_b  = (const float*)d_in[33];
    const float* fcg1_w = (const float*)d_in[34];
    const float* fcg1_b = (const float*)d_in[35];
    const float* fcg2_w = (const float*)d_in[36];
    const float* fcg2_b = (const float*)d_in[37];
    const float* e1_w = (const float*)d_in[38]; const float* e1_b = (const float*)d_in[39];
    const float* bn1_g = (const float*)d_in[40]; const float* bn1_b = (const float*)d_in[41];
    const float* e2_w = (const float*)d_in[42]; const float* e2_b = (const float*)d_in[43];
    const float* bn2_g = (const float*)d_in[44]; const float* bn2_b = (const float*)d_in[45];
    const float* e3_w = (const float*)d_in[46]; const float* e3_b = (const float*)d_in[47];
    const float* enc_w = (const float*)d_in[48]; const float* enc_b = (const float*)d_in[49];
    const float* d3_w = (const float*)d_in[50]; const float* d3_b = (const float*)d_in[51];
    const float* dbn2_g = (const float*)d_in[52]; const float* dbn2_b = (const float*)d_in[53];
    const float* d2_w = (const float*)d_in[54]; const float* d2_b = (const float*)d_in[55];
    const float* dbn1_g = (const float*)d_in[56]; const float* dbn1_b = (const float*)d_in[57];
    const float* d1_w = (const float*)d_in[58]; const float* d1_b = (const float*)d_in[59];
    const float* fc1_w = (const float*)d_in[60]; const float* fc1_b = (const float*)d_in[61];
    const float* fc2_w = (const float*)d_in[62]; const float* fc2_b = (const float*)d_in[63];
    const float* outw = (const float*)d_in[64]; const float* outb = (const float*)d_in[65];

    // ---- workspace carve (adaptive attention row-block RB) ----
    float *A1, *A2, *A3, *A4, *X1f, *QBIASf;
    unsigned short *XB, *QKVb, *Vt, *HbPb;
    unsigned short *WQKVb, *WOUTb, *WL1b, *WL2b, *WGb, *WGCNb, *WFCG1b, *WFCG2b,
                   *WENCb, *WFC1b, *WFC2b, *WOUTWb, *XD16, *FG1b, *E3b, *XCb, *FH1b, *FH2b, *Wcvb;
    float *asrc, *adst, *alpha, *denom, *dis, *gm, *ga, *c1p, *c2p, *e3o,
          *zz, *dd3, *dd2b;
    unsigned *amax; int *deg, *cnt, *csr_off, *csr_cur, *csr_s, *csr_e;

    auto carve = [&](long long RB) -> size_t {
        char* wp_ = (char*)d_ws;
        auto alc = [&](size_t bytes) -> char* {
            char* p = wp_;
            wp_ += (bytes + 255) & ~(size_t)255;
            return p;
        };
        A1 = (float*)alc((size_t)NN * DD2 * 4);
        A2 = (float*)alc((size_t)NN * DD2 * 4);
        A3 = (float*)alc((size_t)NN * DD2 * 4);
        A4 = (float*)alc((size_t)NN * DD2 * 4);
        X1f = (float*)alc((size_t)NN * FXD_ * 4);
        XB   = (unsigned short*)alc((size_t)NN * 800 * 2);
        QKVb = (unsigned short*)alc((size_t)NN * 2400 * 2);
        Vt   = (unsigned short*)alc((size_t)800 * NN * 2);
        size_t hb = (size_t)NN * FFD * 2, pb = (size_t)RB * NN * 2;
        HbPb = (unsigned short*)alc(hb > pb ? hb : pb);   // FF hidden / attention P / AE im2col
        WQKVb = (unsigned short*)alc((size_t)2400 * 800 * 2);
        QBIASf= (float*)alc((size_t)2400 * 4);
        WOUTb = (unsigned short*)alc((size_t)780 * 800 * 2);
        WL1b  = (unsigned short*)alc((size_t)2048 * 800 * 2);
        WL2b  = (unsigned short*)alc((size_t)780 * 2048 * 2);
        WGb   = (unsigned short*)alc((size_t)780 * 96 * 2);
        WGCNb = (unsigned short*)alc((size_t)780 * 800 * 2);
        WFCG1b= (unsigned short*)alc((size_t)1500 * 1568 * 2);
        WFCG2b= (unsigned short*)alc((size_t)128 * 1504 * 2);
        WENCb = (unsigned short*)alc((size_t)128 * 640 * 2);
        WFC1b = (unsigned short*)alc((size_t)1024 * 256 * 2);
        WFC2b = (unsigned short*)alc((size_t)128 * 1024 * 2);
        WOUTWb= (unsigned short*)alc((size_t)128 * 2);
        Wcvb  = (unsigned short*)alc((size_t)128 * 1024 * 2);   // AE reshaped weights
        XD16  = (unsigned short*)alc((size_t)NG * 1568 * 2);
        FG1b  = (unsigned short*)alc((size_t)NG * 1504 * 2);
        E3b   = (unsigned short*)alc((size_t)NG * 640 * 2);
        XCb   = (unsigned short*)alc((size_t)NG * 256 * 2);
        FH1b  = (unsigned short*)alc((size_t)NG * 1024 * 2);
        FH2b  = (unsigned short*)alc((size_t)NG * 128 * 2);
        asrc = (float*)alc((size_t)NN * NH * 4);
        adst = (float*)alc((size_t)NN * NH * 4);
        alpha= (float*)alc((size_t)NETOT * NH * 4);
        amax = (unsigned*)alc((size_t)NN * NH * 4);
        denom= (float*)alc((size_t)NN * NH * 4);
        deg  = (int*)alc((size_t)NN * 4);
        dis  = (float*)alc((size_t)NN * 4);
        cnt  = (int*)alc((size_t)NG * 4);
        csr_off = (int*)alc((size_t)(NN + 1) * 4);
        csr_cur = (int*)alc((size_t)NN * 4);
        csr_s   = (int*)alc((size_t)NETOT * 4);
        csr_e   = (int*)alc((size_t)NETOT * 4);
        gm   = (float*)alc((size_t)NG * DD2 * 4);
        ga   = (float*)alc((size_t)NG * DD2 * 4);
        c1p  = (float*)alc((size_t)NG * 32 * 91 * 4);
        c2p  = (float*)alc((size_t)NG * 64 * 12 * 4);
        e3o  = (float*)alc((size_t)NG * 128 * 5 * 4);
        zz   = (float*)alc((size_t)NG * 128 * 4);
        dd3  = (float*)alc((size_t)NG * 64 * 12 * 4);
        dd2b = (float*)alc((size_t)NG * 32 * 91 * 4);
        return (size_t)(wp_ - (char*)d_ws);
    };

    long long RB = 512;
    const long long cands[5] = {8192, 4096, 2048, 1024, 512};
    for (int i = 0; i < 5; ++i){ if (carve(cands[i]) <= ws_size){ RB = cands[i]; break; } }
    carve(RB);   // commit chosen layout
    unsigned short* Pb = HbPb;
    unsigned short* AIM = HbPb;      // AE im2col arena (HbPb dead after t2)

    float* out0   = (float*)d_out;                 // (256,1)
    float* xd_out = (float*)d_out + NG;            // (256,128)
    float* decode = (float*)d_out + NG + NG * 128; // (256,735)

    auto cvt = [&](const float* src, unsigned short* dst, int R, int C, int lds_, int ldd){
        long long n = (long long)R * ldd;
        cvt_pad_k<<<cdiv_i(n, 256), 256, 0, stream>>>(src, dst, n, C, lds_, ldd);
    };
    auto zero16 = [&](unsigned short* p, long long nshorts){
        fill_u32_k<<<cdiv_i(nshorts / 2, 256), 256, 0, stream>>>((unsigned*)p, 0u, nshorts / 2);
    };
    auto zerof = [&](float* p, long long n){
        fill_f32_k<<<cdiv_i(n, 256), 256, 0, stream>>>(p, 0.f, n);
    };

    // ---- transformer (shared for t1/t2); xin_bf = XB (padded Ep), residual xin f32 ----
    auto run_tf = [&](const float* xin, const float* const* W, float* outp, int E){
        const int Ep = pad32(E), E3p = 3 * Ep;
        float scale = (float)(1.0 / sqrt((double)E));
        // merged qkv: weights 3*Ep rows (pad rows zero), bias padded
        zero16(WQKVb, (long long)E3p * Ep);
        for (int s = 0; s < 3; ++s)
            cvt(W[0] + (size_t)s * E * E, WQKVb + (size_t)s * Ep * Ep, E, E, E, Ep);
        qkv_bias_k<<<cdiv_i(E3p, 256), 256, 0, stream>>>(W[1], QBIASf, E, Ep);
        mgemm<1,0,1,0,128>(stream, XB, WQKVb, QBIASf, QKVb, NN, E3p, Ep, Ep, Ep, E3p, 0);
        // V^T via bf16 transpose of the v-part
        {
            dim3 g(cdiv_i(E, 32), cdiv_i(NN, 32));
            tr_bf16_k<<<g, 256, 0, stream>>>(QKVb + 2 * Ep, Vt, NN, E, E3p, NN);
        }
        // attention: S (bf16, into Pb) -> in-place softmax -> PV (split-K, f32 atomics -> A4)
        zerof(A4, (long long)NN * E);
        for (long long r0 = 0; r0 < NN; r0 += RB){
            mgemm<1,0,1,0,128>(stream, QKVb + (size_t)r0 * E3p, QKVb + Ep, nullptr, Pb,
                               (int)RB, NN, Ep, E3p, E3p, NN, 0);
            softmax_bf16_k<<<(int)RB, 256, 0, stream>>>(Pb, scale);
            if (E == FXD_)
                mgemm<0,0,8,0,64>(stream, Pb, Vt, nullptr, A4 + (size_t)r0 * E,
                                  (int)RB, E, NN, NN, NN, E, 0);
            else
                mgemm<0,0,4,0,64>(stream, Pb, Vt, nullptr, A4 + (size_t)r0 * E,
                                  (int)RB, E, NN, NN, NN, E, 0);
        }
        cvt(A4, XB, NN, E, E, Ep);
        // proj + LN1
        cvt(W[2], WOUTb, E, E, E, Ep);
        mgemm<0,0,1,0,64>(stream, XB, WOUTb, W[3], A2, NN, E, Ep, Ep, Ep, E, 0);
        add_ln_k<<<NN, 256, 0, stream>>>(xin, A2, nullptr, W[4], W[5], A3, XB, E, Ep);
        // FF1 (relu, bf16) -> FF2 -> LN2
        cvt(W[6], WL1b, FFD, E, E, Ep);
        mgemm<1,1,1,0,128>(stream, XB, WL1b, W[7], HbPb, NN, FFD, Ep, Ep, Ep, FFD, 0);
        cvt(W[8], WL2b, E, FFD, FFD, FFD);
        mgemm<0,0,1,0,64>(stream, HbPb, WL2b, W[9], A2, NN, E, FFD, FFD, FFD, E, 0);
        add_ln_k<<<NN, 256, 0, stream>>>(A3, A2, nullptr, W[10], W[11], outp, XB, E, Ep);
    };

    // ================= t1 transformer (E=78) =================
    cvt(x, XB, NN, FXD_, FXD_, 96);
    run_tf(x, t1w, X1f, FXD_);          // leaves XB = t1 out (ld 96)

    // ================= graph structure: deg + CSR (used by GAT & GCN) =================
    fill_u32_k<<<cdiv_i(NN, 256), 256, 0, stream>>>((unsigned*)deg, 0u, NN);
    deg_count_k<<<cdiv_i(NETOT, 256), 256, 0, stream>>>(ei, deg);
    csr_off_k<<<1, 256, 0, stream>>>(deg, csr_off, csr_cur);
    csr_fill_k<<<cdiv_i(NETOT, 256), 256, 0, stream>>>(ei, csr_cur, csr_s, csr_e);

    // ================= GAT =================
    cvt(gat_w, WGb, DD2, FXD_, FXD_, 96);
    mgemm<0,0,1,0,64>(stream, XB, WGb, nullptr, A2, NN, DD2, 96, 96, 96, DD2, 0);   // hfeat
    gat_srcdst_k<<<cdiv_i((long long)NN * NH, 256), 256, 0, stream>>>(A2, gat_asrc, gat_adst, asrc, adst);
    fill_u32_k<<<cdiv_i((long long)NN * NH, 256), 256, 0, stream>>>(amax, 0x007FFFFFu, (long long)NN * NH);
    zerof(denom, (long long)NN * NH);
    gat_alpha_k<<<cdiv_i((long long)NETOT * NH, 256), 256, 0, stream>>>(ei, asrc, adst, alpha, amax);
    gat_expsum_k<<<cdiv_i((long long)NETOT * NH, 256), 256, 0, stream>>>(ei, alpha, amax, denom);
    gat_gather_k<<<NN, 256, 0, stream>>>(csr_off, csr_s, csr_e, alpha, denom, A2, A1);
    bias_relu_k<<<cdiv_i((long long)NN * 800, 256), 256, 0, stream>>>(A1, gat_b, XB, NN, DD2, 800);

    // ================= t2 transformer (E=780) =================
    run_tf(A1, t2w, A1, DD2);           // leaves XB = t2 out (ld 800)

    // ================= GCN =================
    dis_k<<<cdiv_i(NN, 256), 256, 0, stream>>>(deg, dis);
    cvt(gcn_w, WGCNb, DD2, DD2, DD2, 800);
    mgemm<0,0,1,0,64>(stream, XB, WGCNb, nullptr, A2, NN, DD2, 800, 800, 800, DD2, 0); // xw
    gcn_gather_k<<<NN, 256, 0, stream>>>(csr_off, csr_s, dis, A2, A3);
    bias_relu_k<<<cdiv_i((long long)NN * DD2, 256), 256, 0, stream>>>(A3, gcn_b, nullptr, NN, DD2, DD2);

    // ================= pooling + graph head =================
    zerof(gm, (long long)NG * DD2);
    zerof(ga, (long long)NG * DD2);
    fill_u32_k<<<cdiv_i(NG, 256), 256, 0, stream>>>((unsigned*)cnt, 0u, NG);
    pool_accum_k<<<cdiv_i((long long)NN * DD2, 256), 256, 0, stream>>>(A3, batch, gm, ga, cnt);
    pool_fin_k<<<cdiv_i((long long)NG * 1568, 256), 256, 0, stream>>>(gm, ga, cnt, XD16);
    cvt(fcg1_w, WFCG1b, 1500, 1560, 1560, 1568);
    zerof(A2, (long long)NG * 1500);
    mgemm<0,0,8,0,64>(stream, XD16, WFCG1b, nullptr, A2, NG, 1500, 1568, 1568, 1568, 1500, 0);
    bias_relu_k<<<cdiv_i((long long)NG * 1504, 256), 256, 0, stream>>>(A2, fcg1_b, FG1b, NG, 1500, 1504);
    cvt(fcg2_w, WFCG2b, 128, 1500, 1500, 1504);
    zerof(xd_out, (long long)NG * 128);
    mgemm<0,0,16,0,128>(stream, FG1b, WFCG2b, nullptr, xd_out, NG, 128, 1504, 1504, 1504, 128, 0);
    bias_add_k<<<cdiv_i((long long)NG * 128, 256), 256, 0, stream>>>(xd_out, fcg2_b, (long long)NG * 128, 128); // OUTPUT 1

    // ================= conv encoder (GEMM-ified; AIM=HbPb arena, Gout=A2) =================
    enc1_b<<<NG, 256, 0, stream>>>(tmut, e1_w, e1_b, bn1_g, bn1_b, c1p);
    // enc2: (21504 x 256) x (64 x 256)^T
    i2c_enc2_k<<<cdiv_i((long long)NG * 84 * 256, 256), 256, 0, stream>>>(c1p, AIM);
    cvt(e2_w, Wcvb, 64, 256, 256, 256);
    mgemm<0,0,1,0,64>(stream, AIM, Wcvb, nullptr, A2, NG * 84, 64, 256, 256, 256, 64, 0);
    post_enc2_k<<<cdiv_i((long long)NG * 768, 256), 256, 0, stream>>>(A2, e2_b, bn2_g, bn2_b, c2p);
    // enc3: (1280 x 512) x (128 x 512)^T, split-K 4
    i2c_enc3_k<<<cdiv_i((long long)NG * 5 * 512, 256), 256, 0, stream>>>(c2p, AIM);
    cvt(e3_w, Wcvb, 128, 512, 512, 512);
    zerof(A2, (long long)NG * 5 * 128);
    mgemm<0,0,4,0,128>(stream, AIM, Wcvb, nullptr, A2, NG * 5, 128, 512, 512, 512, 128, 0);
    post_enc3_k<<<cdiv_i((long long)NG * 640, 256), 256, 0, stream>>>(A2, e3_b, e3o, E3b);
    // z
    cvt(enc_w, WENCb, 128, 640, 640, 640);
    mgemm<0,0,1,0,128>(stream, E3b, WENCb, enc_b, zz, NG, 128, 640, 640, 640, 128, 0);

    // ================= conv decoder (GEMM-ified) =================
    // dec3: (3072 x 1024) x (64 x 1024)^T, split-K 4
    wshuf_k<<<cdiv_i(128 * 64 * 8, 256), 256, 0, stream>>>(d3_w, Wcvb, 128, 64);
    i2c_dec3_k<<<cdiv_i((long long)NG * 12 * 1024, 256), 256, 0, stream>>>(e3o, AIM);
    zerof(A2, (long long)NG * 12 * 64);
    mgemm<0,0,4,0,64>(stream, AIM, Wcvb, nullptr, A2, NG * 12, 64, 1024, 1024, 1024, 64, 0);
    post_dec3_k<<<cdiv_i((long long)NG * 768, 256), 256, 0, stream>>>(A2, d3_b, dbn2_g, dbn2_b, dd3);
    // dec2: (23296 x 512) x (32 x 512)^T
    wshuf_k<<<cdiv_i(64 * 32 * 8, 256), 256, 0, stream>>>(d2_w, Wcvb, 64, 32);
    i2c_dec2_k<<<cdiv_i((long long)NG * 91 * 512, 256), 256, 0, stream>>>(dd3, AIM);
    mgemm<0,0,1,0,64>(stream, AIM, Wcvb, nullptr, A2, NG * 91, 32, 512, 512, 512, 32, 0);
    post_dec2_k<<<cdiv_i((long long)NG * 2912, 256), 256, 0, stream>>>(A2, d2_b, dbn1_g, dbn1_b, dd2b);
    // dec1 (LDS kernel, 768 blocks)
    { dim3 g(NG, 3); dec1_b<<<g, 256, 0, stream>>>(dd2b, d1_w, d1_b, decode); }   // OUTPUT 2

    // ================= final head =================
    concat_xc_k<<<cdiv_i((long long)NG * 256, 256), 256, 0, stream>>>(xd_out, zz, XCb);
    cvt(fc1_w, WFC1b, 1024, 256, 256, 256);
    mgemm<1,1,1,0,128>(stream, XCb, WFC1b, fc1_b, FH1b, NG, 1024, 256, 256, 256, 1024, 0);
    cvt(fc2_w, WFC2b, 128, 1024, 1024, 1024);
    zerof(A3, (long long)NG * 128);
    mgemm<0,0,8,0,128>(stream, FH1b, WFC2b, nullptr, A3, NG, 128, 1024, 1024, 1024, 128, 0);
    bias_relu_k<<<cdiv_i((long long)NG * 128, 256), 256, 0, stream>>>(A3, fc2_b, FH2b, NG, 128, 128);
    cvt(outw, WOUTWb, 1, 128, 128, 128);
    mgemm<0,2,1,0,64>(stream, FH2b, WOUTWb, outb, out0, NG, 1, 128, 128, 128, 1, 0);   // OUTPUT 0 (sigmoid)
}

// Round 12
// 1765.962 us; speedup vs baseline: 1.4781x; 1.0119x over previous
//
#include <hip/hip_runtime.h>
#include <math.h>

// Problem constants
#define NN     8192      // nodes
#define NEDGE  32768     // edges (before self loops)
#define NETOT  40960     // edges + self loops
#define NG     256       // graphs
#define FXD_   78
#define NH     10        // heads
#define DD2    780       // FXD*HEADS
#define FFD    2048
#define LMUT   735

static inline int cdiv_i(long long a, int b){ return (int)((a + (long long)b - 1) / b); }
static inline int pad32(int x){ return (x + 31) & ~31; }

typedef __attribute__((ext_vector_type(8))) short bf16x8;
typedef __attribute__((ext_vector_type(4))) float f32x4;

static __device__ __forceinline__ unsigned short f2bf(float f){
    unsigned u = __float_as_uint(f);
    u += 0x7FFFu + ((u >> 16) & 1u);
    return (unsigned short)(u >> 16);
}

// async global->LDS, 16B per lane; lds dest is wave-uniform base + lane*16
static __device__ __forceinline__ void gload16(const void* g, void* l){
    __builtin_amdgcn_global_load_lds((const __attribute__((address_space(1))) void*)g,
                                     (__attribute__((address_space(3))) void*)l, 16, 0, 0);
}

// ---------------- fills ----------------
__global__ void fill_f32_k(float* __restrict__ p, float v, long long n){
    long long i = (long long)blockIdx.x * 256 + threadIdx.x;
    if (i < n) p[i] = v;
}
__global__ void fill_u32_k(unsigned* __restrict__ p, unsigned v, long long n){
    long long i = (long long)blockIdx.x * 256 + threadIdx.x;
    if (i < n) p[i] = v;
}

// ---------------- f32 -> bf16 convert with K-padding ----------------
__global__ void cvt_pad_k(const float* __restrict__ src, unsigned short* __restrict__ dst,
                          long long n /*R*ldd*/, int C, int lds_, int ldd)
{
    long long i = (long long)blockIdx.x * 256 + threadIdx.x;
    if (i >= n) return;
    int r = (int)(i / ldd), c = (int)(i % ldd);
    dst[i] = (c < C) ? f2bf(src[(size_t)r * lds_ + c]) : (unsigned short)0;
}

// bf16 transpose: dst[c][r] = src[r][c]
__global__ void tr_bf16_k(const unsigned short* __restrict__ src, unsigned short* __restrict__ dst,
                          int R, int C, int lds_, int ldd)
{
    __shared__ unsigned short t[32][33];
    int cb = blockIdx.x * 32, rb = blockIdx.y * 32;
    int tx = threadIdx.x & 31, ty = threadIdx.x >> 5;   // 32 x 8
#pragma unroll
    for (int i = 0; i < 4; ++i){
        int r = rb + ty + i * 8, c = cb + tx;
        t[ty + i * 8][tx] = (r < R && c < C) ? src[(size_t)r * lds_ + c] : (unsigned short)0;
    }
    __syncthreads();
#pragma unroll
    for (int i = 0; i < 4; ++i){
        int dr = cb + ty + i * 8, dc = rb + tx;
        if (dr < C && dc < R) dst[(size_t)dr * ldd + dc] = t[tx][ty + i * 8];
    }
}

// padded qkv bias: out[s*Ep+c] = (c<E) ? b3[s*E+c] : 0, s=0..2
__global__ void qkv_bias_k(const float* __restrict__ b3, float* __restrict__ out, int E, int Ep)
{
    int idx = blockIdx.x * 256 + threadIdx.x;
    if (idx >= 3 * Ep) return;
    int s = idx / Ep, c = idx % Ep;
    out[idx] = (c < E) ? b3[s * E + c] : 0.f;
}

__global__ void bias_add_k(float* __restrict__ X, const float* __restrict__ b, long long n, int cols)
{
    long long i = (long long)blockIdx.x * 256 + threadIdx.x;
    if (i < n) X[i] += b[i % cols];
}

// ---------------- MFMA bf16 GEMM: 2-phase dbuf + XCD swizzle + BN=64/128 tiles ----------------
template<int OUTC, int ACT, int SPLITK, int BROW, int BN>
__global__ __launch_bounds__(256) void mgemm_k(
    const unsigned short* __restrict__ A, const unsigned short* __restrict__ B,
    const float* __restrict__ bias, void* __restrict__ Cv,
    int M, int N, int Kp, int lda, int ldb, int ldc, int swz)
{
    constexpr int NFJ   = BN / 32;        // col frags per wave
    constexpr int TILEA = 128 * 32;
    constexpr int TILEB = BN * 32;
    __shared__ unsigned short As[2 * TILEA];
    __shared__ unsigned short Bs[2 * TILEB];
    const int tid = threadIdx.x;
    const int lane = tid & 63, wid = tid >> 6;
    const int r16 = lane & 15, q = lane >> 4;
    const int wr = (wid >> 1) * 64, wc = (wid & 1) * (BN / 2);

    // bijective XCD-chunked remap (m204)
    const int gx = gridDim.x, gy = gridDim.y;
    const int nwg = gx * gy;
    int orig = swz ? ((int)blockIdx.x * gy + (int)blockIdx.y)
                   : ((int)blockIdx.y * gx + (int)blockIdx.x);
    int q8 = nwg >> 3, r8 = nwg & 7;
    int xcd = orig & 7, kk8 = orig >> 3;
    int wgid = (xcd < r8 ? xcd * (q8 + 1) : r8 * (q8 + 1) + (xcd - r8) * q8) + kk8;
    int bx, by;
    if (swz){ by = wgid % gy; bx = wgid / gy; }
    else    { bx = wgid % gx; by = wgid / gx; }
    const int row0 = by * 128, col0 = bx * BN;

    int kbeg = 0, kend = Kp;
    if (SPLITK > 1){
        int nt_ = Kp >> 5, cpt = (nt_ + SPLITK - 1) / SPLITK;
        kbeg = (int)blockIdx.z * cpt * 32;
        kend = min(Kp, kbeg + cpt * 32);
    }

    // A staging: 512 chunks of 16B; lane handles chunk c0 and c0+64
    const int c0 = wid * 128 + lane;
    const int r0a = c0 >> 2, k0a = (c0 & 3) << 3;
    const size_t gA0 = (size_t)min(row0 + r0a, M - 1) * lda + k0a;
    const size_t gA1 = (size_t)min(row0 + r0a + 16, M - 1) * lda + k0a;
    unsigned short* lA = As + wid * 1024;
    // B staging
    size_t gB0 = 0, gB1 = 0;
    unsigned short* lB;
    if (BN == 128){
        gB0 = (size_t)min(col0 + r0a, N - 1) * ldb + k0a;
        gB1 = (size_t)min(col0 + r0a + 16, N - 1) * ldb + k0a;
        lB = Bs + wid * 1024;
    } else {               // BN=64: 256 chunks, 1 per lane
        const int cb = wid * 64 + lane;
        const int rb_ = cb >> 2, kb_ = (cb & 3) << 3;
        gB0 = (size_t)min(col0 + rb_, N - 1) * ldb + kb_;
        lB = Bs + wid * 512;
    }

    f32x4 acc[4][NFJ];
#pragma unroll
    for (int i = 0; i < 4; ++i)
#pragma unroll
        for (int j = 0; j < NFJ; ++j){ f32x4 z = {0.f, 0.f, 0.f, 0.f}; acc[i][j] = z; }

    const int nt = (kend - kbeg) >> 5;
    if (nt > 0){
        gload16(A + gA0 + kbeg, lA);
        gload16(A + gA1 + kbeg, lA + 512);
        gload16(B + gB0 + kbeg, lB);
        if (BN == 128) gload16(B + gB1 + kbeg, lB + 512);
        __syncthreads();
        int cur = 0;
        for (int t = 0; t < nt; ++t){
            const int k0 = kbeg + (t << 5);
            if (t + 1 < nt){                  // stage next tile BEFORE compute (overlap)
                const int kn = k0 + 32, nb = cur ^ 1;
                gload16(A + gA0 + kn, lA + nb * TILEA);
                gload16(A + gA1 + kn, lA + nb * TILEA + 512);
                gload16(B + gB0 + kn, lB + nb * TILEB);
                if (BN == 128) gload16(B + gB1 + kn, lB + nb * TILEB + 512);
            }
            const unsigned short* Ab = As + cur * TILEA;
            const unsigned short* Bb = Bs + cur * TILEB;
            bf16x8 af[4], bfv[NFJ];
#pragma unroll
            for (int f = 0; f < 4; ++f)
                af[f] = *(const bf16x8*)(Ab + (size_t)(wr + f * 16 + r16) * 32 + (q << 3));
#pragma unroll
            for (int f = 0; f < NFJ; ++f)
                bfv[f] = *(const bf16x8*)(Bb + (size_t)(wc + f * 16 + r16) * 32 + (q << 3));
#pragma unroll
            for (int fi = 0; fi < 4; ++fi)
#pragma unroll
                for (int fj = 0; fj < NFJ; ++fj)
                    acc[fi][fj] = __builtin_amdgcn_mfma_f32_16x16x32_bf16(af[fi], bfv[fj], acc[fi][fj], 0, 0, 0);
            __syncthreads();
            cur ^= 1;
        }
    }

#pragma unroll
    for (int fi = 0; fi < 4; ++fi){
#pragma unroll
        for (int j = 0; j < 4; ++j){
            int r = row0 + wr + fi * 16 + q * 4 + j;   // C/D: row=(lane>>4)*4+reg
            if (r >= M) continue;
#pragma unroll
            for (int fj = 0; fj < NFJ; ++fj){
                int c = col0 + wc + fj * 16 + r16;     // C/D: col=lane&15
                if (c >= N) continue;
                float v = acc[fi][fj][j];
                if (SPLITK > 1){
                    atomicAdd((float*)Cv + (size_t)r * ldc + c, v);
                } else {
                    if (bias) v += BROW ? bias[r] : bias[c];
                    if (ACT == 1) v = fmaxf(v, 0.f);
                    if (ACT == 2) v = 1.f / (1.f + expf(-v));
                    if (OUTC == 0) ((float*)Cv)[(size_t)r * ldc + c] = v;
                    else ((unsigned short*)Cv)[(size_t)r * ldc + c] = f2bf(v);
                }
            }
        }
    }
}

template<int OUTC, int ACT, int SPLITK, int BROW, int BN>
static void mgemm(hipStream_t s, const unsigned short* A, const unsigned short* B,
                  const float* bias, void* C, int M, int N, int Kp,
                  int lda, int ldb, int ldc, int swz)
{
    dim3 g(cdiv_i(N, BN), cdiv_i(M, 128), SPLITK);
    mgemm_k<OUTC, ACT, SPLITK, BROW, BN><<<g, 256, 0, s>>>(A, B, bias, C, M, N, Kp, lda, ldb, ldc, swz);
}

// ---------------- softmax: in-place on bf16 rows (8192 cols), register-resident ----------------
__global__ __launch_bounds__(256) void softmax_bf16_k(unsigned short* __restrict__ SP, float scale)
{
    __shared__ float red[8];
    const int tid = threadIdx.x;
    uint4* prow = (uint4*)(SP + (size_t)blockIdx.x * NN);   // 1024 uint4 per row
    float v[32];
    float mx = -3.4e38f;
#pragma unroll
    for (int c = 0; c < 4; ++c){
        uint4 t = prow[c * 256 + tid];
        const unsigned* u = (const unsigned*)&t;
#pragma unroll
        for (int j = 0; j < 4; ++j){
            float lo = __uint_as_float(u[j] << 16) * scale;
            float hi = __uint_as_float(u[j] & 0xFFFF0000u) * scale;
            v[c * 8 + j * 2]     = lo;
            v[c * 8 + j * 2 + 1] = hi;
            mx = fmaxf(mx, fmaxf(lo, hi));
        }
    }
#pragma unroll
    for (int off = 32; off; off >>= 1) mx = fmaxf(mx, __shfl_xor(mx, off, 64));
    if ((tid & 63) == 0) red[tid >> 6] = mx;
    __syncthreads();
    mx = fmaxf(fmaxf(red[0], red[1]), fmaxf(red[2], red[3]));
    float sum = 0.f;
#pragma unroll
    for (int i = 0; i < 32; ++i){ v[i] = expf(v[i] - mx); sum += v[i]; }
#pragma unroll
    for (int off = 32; off; off >>= 1) sum += __shfl_xor(sum, off, 64);
    if ((tid & 63) == 0) red[4 + (tid >> 6)] = sum;
    __syncthreads();
    float inv = 1.f / (red[4] + red[5] + red[6] + red[7]);
#pragma unroll
    for (int c = 0; c < 4; ++c){
        uint4 t;
        unsigned* u = (unsigned*)&t;
#pragma unroll
        for (int j = 0; j < 4; ++j){
            unsigned lo = f2bf(v[c * 8 + j * 2] * inv);
            unsigned hi = f2bf(v[c * 8 + j * 2 + 1] * inv);
            u[j] = lo | (hi << 16);
        }
        prow[c * 256 + tid] = t;
    }
}

// ---------------- residual add + layernorm ----------------
__global__ __launch_bounds__(256) void add_ln_k(
    const float* __restrict__ X, const float* __restrict__ Y, const float* __restrict__ ybias,
    const float* __restrict__ g, const float* __restrict__ b,
    float* __restrict__ out, unsigned short* __restrict__ obf, int E, int Ep)
{
    __shared__ float s1[256], s2[256];
    const int tid = threadIdx.x;
    long long base = (long long)blockIdx.x * E;
    float vals[4];
    float sum = 0.f, sq = 0.f;
    int i = 0;
    for (int c = tid; c < Ep; c += 256, ++i){
        float v = 0.f;
        if (c < E){
            v = X[base + c] + Y[base + c];
            if (ybias) v += ybias[c];
            sum += v; sq += v * v;
        }
        vals[i] = v;
    }
    s1[tid] = sum; s2[tid] = sq; __syncthreads();
    for (int s = 128; s; s >>= 1){
        if (tid < s){ s1[tid] += s1[tid + s]; s2[tid] += s2[tid + s]; }
        __syncthreads();
    }
    float mean = s1[0] / (float)E;
    float var = s2[0] / (float)E - mean * mean;
    if (var < 0.f) var = 0.f;
    float inv = 1.f / sqrtf(var + 1e-5f);
    i = 0;
    for (int c = tid; c < Ep; c += 256, ++i){
        if (c < E){
            float o = (vals[i] - mean) * inv * g[c] + b[c];
            out[base + c] = o;
            if (obf) obf[(size_t)blockIdx.x * Ep + c] = f2bf(o);
        } else if (obf) obf[(size_t)blockIdx.x * Ep + c] = 0;
    }
}

// ---------------- GAT / graph common ----------------
static __device__ __forceinline__ unsigned enc_f(float x){
    unsigned u = __float_as_uint(x);
    return (u & 0x80000000u) ? ~u : (u | 0x80000000u);
}
static __device__ __forceinline__ float dec_f(unsigned u){
    return (u & 0x80000000u) ? __uint_as_float(u & 0x7fffffffu) : __uint_as_float(~u);
}
static __device__ __forceinline__ void edge_sd(const int* __restrict__ ei, int e, int& s, int& d){
    if (e < NEDGE){ s = ei[e]; d = ei[NEDGE + e]; }
    else { s = e - NEDGE; d = e - NEDGE; }
}

__global__ void gat_srcdst_k(const float* __restrict__ h, const float* __restrict__ aw_src,
                             const float* __restrict__ aw_dst, float* __restrict__ asrc,
                             float* __restrict__ adst)
{
    int idx = blockIdx.x * 256 + threadIdx.x;
    if (idx >= NN * NH) return;
    int n = idx / NH, hh = idx % NH;
    const float* hp = h + (long long)n * DD2 + hh * FXD_;
    const float* ws = aw_src + hh * FXD_;
    const float* wd = aw_dst + hh * FXD_;
    float s1 = 0.f, s2 = 0.f;
    for (int f = 0; f < FXD_; ++f){ float v = hp[f]; s1 += v * ws[f]; s2 += v * wd[f]; }
    asrc[idx] = s1; adst[idx] = s2;
}

__global__ void gat_alpha_k(const int* __restrict__ ei, const float* __restrict__ asrc,
                            const float* __restrict__ adst, float* __restrict__ alpha,
                            unsigned* __restrict__ amax)
{
    int idx = blockIdx.x * 256 + threadIdx.x;
    if (idx >= NETOT * NH) return;
    int e = idx / NH, hh = idx % NH;
    int s, d; edge_sd(ei, e, s, d);
    float a = asrc[s * NH + hh] + adst[d * NH + hh];
    a = (a > 0.f) ? a : 0.2f * a;       // leaky_relu 0.2
    alpha[idx] = a;
    atomicMax(&amax[d * NH + hh], enc_f(a));
}

__global__ void gat_expsum_k(const int* __restrict__ ei, float* __restrict__ alpha,
                             const unsigned* __restrict__ amax, float* __restrict__ denom)
{
    int idx = blockIdx.x * 256 + threadIdx.x;
    if (idx >= NETOT * NH) return;
    int e = idx / NH, hh = idx % NH;
    int s, d; edge_sd(ei, e, s, d);
    float m = dec_f(amax[d * NH + hh]);
    float ex = expf(alpha[idx] - m);
    alpha[idx] = ex;
    atomicAdd(&denom[d * NH + hh], ex);
}

__global__ void deg_count_k(const int* __restrict__ ei, int* __restrict__ deg)
{
    int e = blockIdx.x * 256 + threadIdx.x;
    if (e >= NETOT) return;
    int s, d; edge_sd(ei, e, s, d);
    atomicAdd(&deg[d], 1);
}

// ---- CSR build: exclusive scan of deg (single block) + fill ----
__global__ __launch_bounds__(256) void csr_off_k(const int* __restrict__ deg,
                                                 int* __restrict__ off, int* __restrict__ cur)
{
    __shared__ int pref[257];
    const int tid = threadIdx.x;
    int loc[32];
    int base = tid * 32, sum = 0;
#pragma unroll
    for (int i = 0; i < 32; ++i){ loc[i] = sum; sum += deg[base + i]; }
    __shared__ int part[256];
    part[tid] = sum; __syncthreads();
    if (tid == 0){
        pref[0] = 0;
        for (int i = 0; i < 256; ++i) pref[i + 1] = pref[i] + part[i];
    }
    __syncthreads();
    int p0 = pref[tid];
#pragma unroll
    for (int i = 0; i < 32; ++i){ off[base + i] = p0 + loc[i]; cur[base + i] = p0 + loc[i]; }
    if (tid == 0) off[NN] = pref[256];
}

__global__ void csr_fill_k(const int* __restrict__ ei, int* __restrict__ cur,
                           int* __restrict__ csr_s, int* __restrict__ csr_e)
{
    int e = blockIdx.x * 256 + threadIdx.x;
    if (e >= NETOT) return;
    int s, d; edge_sd(ei, e, s, d);
    int pos = atomicAdd(&cur[d], 1);
    csr_s[pos] = s; csr_e[pos] = e;
}

// GAT gather: one block per dst node; no atomics
__global__ __launch_bounds__(256) void gat_gather_k(
    const int* __restrict__ off, const int* __restrict__ csr_s, const int* __restrict__ csr_e,
    const float* __restrict__ ex, const float* __restrict__ denom,
    const float* __restrict__ hfeat, float* __restrict__ out)
{
    const int d = blockIdx.x, tid = threadIdx.x;
    const int beg = off[d], end = off[d + 1];
    for (int f = tid; f < DD2; f += 256){
        int hh = f / FXD_;
        float acc = 0.f;
        for (int p = beg; p < end; ++p)
            acc += ex[csr_e[p] * NH + hh] * hfeat[(size_t)csr_s[p] * DD2 + f];
        out[(size_t)d * DD2 + f] = acc / (denom[d * NH + hh] + 1e-16f);
    }
}

// GCN gather
__global__ __launch_bounds__(256) void gcn_gather_k(
    const int* __restrict__ off, const int* __restrict__ csr_s,
    const float* __restrict__ dis, const float* __restrict__ xw, float* __restrict__ out)
{
    const int d = blockIdx.x, tid = threadIdx.x;
    const int beg = off[d], end = off[d + 1];
    const float dd_ = dis[d];
    for (int f = tid; f < DD2; f += 256){
        float acc = 0.f;
        for (int p = beg; p < end; ++p){
            int s = csr_s[p];
            acc += dis[s] * xw[(size_t)s * DD2 + f];
        }
        out[(size_t)d * DD2 + f] = acc * dd_;
    }
}

// bias+relu on f32 (ld=cols), optional padded-bf16 mirror (ld=ldp)
__global__ void bias_relu_k(float* __restrict__ X, const float* __restrict__ b,
                            unsigned short* __restrict__ obf, int rows, int cols, int ldp)
{
    long long i = (long long)blockIdx.x * 256 + threadIdx.x;
    if (i >= (long long)rows * ldp) return;
    int r = (int)(i / ldp), c = (int)(i % ldp);
    if (c < cols){
        float v = X[(size_t)r * cols + c] + b[c];
        v = v > 0.f ? v : 0.f;
        X[(size_t)r * cols + c] = v;
        if (obf) obf[i] = f2bf(v);
    } else if (obf) obf[i] = 0;
}

__global__ void dis_k(const int* __restrict__ deg, float* __restrict__ dis)
{
    int n = blockIdx.x * 256 + threadIdx.x;
    if (n >= NN) return;
    float d = (float)deg[n];
    dis[n] = (d > 0.f) ? 1.f / sqrtf(fmaxf(d, 1.f)) : 0.f;
}

// ---------------- graph pooling (sorted batch -> segment gather, no atomics) ----------------
// start[g] for g in 0..NG; start[NG]=NN
__global__ void seg_start_k(const int* __restrict__ batch, int* __restrict__ start)
{
    int n = blockIdx.x * 256 + threadIdx.x;
    if (n >= NN) return;
    int b = batch[n];
    int bp = (n == 0) ? -1 : batch[n - 1];
    for (int g = bp + 1; g <= b; ++g) start[g] = n;
    if (n == NN - 1){
        for (int g = b + 1; g <= NG; ++g) start[g] = NN;
    }
}

// per-graph max/avg gather -> padded bf16 XD16 (ld 1568)
__global__ __launch_bounds__(256) void pool_seg_k(const float* __restrict__ xg,
                                                  const int* __restrict__ start,
                                                  unsigned short* __restrict__ xdb)
{
    const int g = blockIdx.x, tid = threadIdx.x;
    const int s0 = start[g], s1 = start[g + 1];
    const float inv = 1.f / fmaxf((float)(s1 - s0), 1.f);
    for (int f = tid; f < DD2; f += 256){
        float mx = 0.f, sm = 0.f;   // xg >= 0 (post-relu); empty segment -> 0 matches ref
        for (int n = s0; n < s1; ++n){
            float v = xg[(size_t)n * DD2 + f];
            mx = fmaxf(mx, v); sm += v;
        }
        xdb[(size_t)g * 1568 + f] = f2bf(mx);
        xdb[(size_t)g * 1568 + DD2 + f] = f2bf(sm * inv);
    }
    if (tid < 8) xdb[(size_t)g * 1568 + 1560 + tid] = 0;   // pad cols
}

// ---------------- conv autoencoder ----------------
#define BN_SCALE 0.9999950000374996f   // 1/sqrt(1+1e-5)

// enc1: (NG,32,91); tm row (735 f32) + w (32x8) in LDS; grid NG
__global__ __launch_bounds__(256) void enc1_b(const float* __restrict__ tm, const float* __restrict__ w,
                                              const float* __restrict__ bias, const float* __restrict__ bng,
                                              const float* __restrict__ bnb, float* __restrict__ out)
{
    __shared__ float xs[736];
    __shared__ float ws[256], bs[32], gs[32], b2[32];
    const int g = blockIdx.x, tid = threadIdx.x;
    for (int i = tid; i < 735; i += 256) xs[i] = tm[(size_t)g * LMUT + i];
    ws[tid] = w[tid];
    if (tid < 32){ bs[tid] = bias[tid]; gs[tid] = bng[tid]; b2[tid] = bnb[tid]; }
    __syncthreads();
    for (int idx = tid; idx < 32 * 91; idx += 256){
        int o = idx / 91, t = idx % 91;
        float mx = -3.4e38f;
        for (int p = 0; p < 8; ++p){
            float s = bs[o];
#pragma unroll
            for (int k = 0; k < 8; ++k) s += xs[t * 8 + p + k] * ws[o * 8 + k];
            mx = fmaxf(mx, s);
        }
        float v = mx * gs[o] * BN_SCALE + b2[o];
        out[(size_t)g * 2912 + idx] = v > 0.f ? v : 0.01f * v;
    }
}

// ---- GEMM-ified AE middle layers: im2col / weight-reshape / post kernels ----
__global__ void i2c_enc2_k(const float* __restrict__ in, unsigned short* __restrict__ A){
    int idx = blockIdx.x * 256 + threadIdx.x;
    if (idx >= NG * 84 * 256) return;
    int col = idx & 255, row = idx >> 8;
    int g = row / 84, u = row % 84;
    int i = col >> 3, k = col & 7;
    A[idx] = f2bf(in[(size_t)g * 2912 + i * 91 + u + k]);
}
__global__ void post_enc2_k(const float* __restrict__ G, const float* __restrict__ b,
                            const float* __restrict__ bng, const float* __restrict__ bnb,
                            float* __restrict__ out){
    int idx = blockIdx.x * 256 + threadIdx.x;
    if (idx >= NG * 768) return;
    int t = idx % 12, o = (idx / 12) & 63, g = idx / 768;
    float mx = -3.4e38f;
#pragma unroll
    for (int p = 0; p < 7; ++p) mx = fmaxf(mx, G[(size_t)(g * 84 + t * 7 + p) * 64 + o]);
    float v = (mx + b[o]) * bng[o] * BN_SCALE + bnb[o];
    out[(size_t)g * 768 + o * 12 + t] = v > 0.f ? v : 0.01f * v;
}
__global__ void i2c_enc3_k(const float* __restrict__ in, unsigned short* __restrict__ A){
    int idx = blockIdx.x * 256 + threadIdx.x;
    if (idx >= NG * 5 * 512) return;
    int col = idx & 511, row = idx >> 9;
    int g = row / 5, t = row % 5;
    int i2 = col >> 3, k = col & 7;
    A[idx] = f2bf(in[(size_t)g * 768 + i2 * 12 + t + k]);
}
__global__ void post_enc3_k(const float* __restrict__ G, const float* __restrict__ b,
                            float* __restrict__ e3o, unsigned short* __restrict__ obf){
    int idx = blockIdx.x * 256 + threadIdx.x;
    if (idx >= NG * 640) return;
    int t = idx % 5, o = (idx / 5) & 127, g = idx / 640;
    float v = G[(size_t)(g * 5 + t) * 128 + o] + b[o];
    e3o[(size_t)g * 640 + o * 5 + t] = v;
    obf[(size_t)g * 640 + o * 5 + t] = f2bf(v);
}
__global__ void wshuf_k(const float* __restrict__ src, unsigned short* __restrict__ dst, int I, int O){
    int idx = blockIdx.x * 256 + threadIdx.x;
    if (idx >= I * O * 8) return;
    int o = idx / (I * 8), rem = idx % (I * 8);
    int i = rem >> 3, j = rem & 7;
    dst[idx] = f2bf(src[(size_t)(i * O + o) * 8 + j]);
}
__global__ void i2c_dec3_k(const float* __restrict__ e3o, unsigned short* __restrict__ A){
    int idx = blockIdx.x * 256 + threadIdx.x;
    if (idx >= NG * 12 * 1024) return;
    int col = idx & 1023, row = idx >> 10;
    int g = row / 12, t = row % 12;
    int i2 = col >> 3, j = col & 7;
    int tt = t - j;
    A[idx] = (tt >= 0 && tt < 5) ? f2bf(e3o[(size_t)g * 640 + i2 * 5 + tt]) : (unsigned short)0;
}
__global__ void post_dec3_k(const float* __restrict__ G, const float* __restrict__ b,
                            const float* __restrict__ bng, const float* __restrict__ bnb,
                            float* __restrict__ dd3){
    int idx = blockIdx.x * 256 + threadIdx.x;
    if (idx >= NG * 768) return;
    int t = idx % 12, o = (idx / 12) & 63, g = idx / 768;
    float v = (G[(size_t)(g * 12 + t) * 64 + o] + b[o]) * bng[o] * BN_SCALE + bnb[o];
    dd3[(size_t)g * 768 + o * 12 + t] = v > 0.f ? v : 0.01f * v;
}
__global__ void i2c_dec2_k(const float* __restrict__ dd3, unsigned short* __restrict__ A){
    int idx = blockIdx.x * 256 + threadIdx.x;
    if (idx >= NG * 91 * 512) return;
    int col = idx & 511, row = idx >> 9;
    int g = row / 91, t = row % 91;
    int i2 = col >> 3, j = col & 7;
    int tt = t - j;
    A[idx] = (tt >= 0 && tt < 84) ? f2bf(dd3[(size_t)g * 768 + i2 * 12 + tt / 7]) : (unsigned short)0;
}
__global__ void post_dec2_k(const float* __restrict__ G, const float* __restrict__ b,
                            const float* __restrict__ bng, const float* __restrict__ bnb,
                            float* __restrict__ dd2){
    int idx = blockIdx.x * 256 + threadIdx.x;
    if (idx >= NG * 2912) return;
    int t = idx % 91, o = (idx / 91) & 31, g = idx / 2912;
    float v = (G[(size_t)(g * 91 + t) * 32 + o] + b[o]) * bng[o] * BN_SCALE + bnb[o];
    dd2[(size_t)g * 2912 + o * 91 + t] = v > 0.f ? v : 0.01f * v;
}

// dec1: (NG,735); grid (NG,3) t-chunks of 245; dd2 (32x91) + w (32x8) in LDS
__global__ __launch_bounds__(256) void dec1_b(const float* __restrict__ dd2, const float* __restrict__ w,
                                              const float* __restrict__ bias, float* __restrict__ out)
{
    __shared__ float d2s[32][91];
    __shared__ float ws[256];
    const int g = blockIdx.x, tid = threadIdx.x;
    const int t0 = (int)blockIdx.y * 245;
    for (int i = tid; i < 32 * 91; i += 256) d2s[i / 91][i % 91] = dd2[(size_t)g * 2912 + i];
    ws[tid] = w[tid];
    __syncthreads();
    if (tid < 245){
        int t = t0 + tid;
        int id8[8]; bool ok[8];
#pragma unroll
        for (int j = 0; j < 8; ++j){
            int tt = t - j;
            ok[j] = (tt >= 0 && tt < 728);
            id8[j] = ok[j] ? (tt >> 3) : 0;
        }
        float s = bias[0];
        for (int i2 = 0; i2 < 32; ++i2){
            const float* wp = ws + i2 * 8;
            float a = 0.f;
#pragma unroll
            for (int j = 0; j < 8; ++j) if (ok[j]) a += d2s[i2][id8[j]] * wp[j];
            s += a;
        }
        out[(size_t)g * 735 + t] = s;
    }
}

__global__ void concat_xc_k(const float* __restrict__ xd, const float* __restrict__ z,
                            unsigned short* __restrict__ xcb)
{
    int idx = blockIdx.x * 256 + threadIdx.x;
    if (idx >= NG * 256) return;
    int g = idx >> 8, c = idx & 255;
    xcb[idx] = f2bf((c < 128) ? xd[g * 128 + c] : z[g * 128 + (c - 128)]);
}

// ---------------- host-side orchestration ----------------
extern "C" void kernel_launch(void* const* d_in, const int* in_sizes, int n_in,
                              void* d_out, int out_size, void* d_ws, size_t ws_size,
                              hipStream_t stream)
{
    (void)in_sizes; (void)n_in; (void)out_size;

    // ---- input pointers: setup_inputs() DICT order (t1 4-15, t2 16-27, gat 28-31) ----
    const float* x      = (const float*)d_in[0];
    const int*   ei     = (const int*)  d_in[1];
    const int*   batch  = (const int*)  d_in[2];
    const float* tmut   = (const float*)d_in[3];
    const float* t1w[12]; for (int i = 0; i < 12; ++i) t1w[i] = (const float*)d_in[4 + i];
    const float* t2w[12]; for (int i = 0; i < 12; ++i) t2w[i] = (const float*)d_in[16 + i];
    const float* gat_w    = (const float*)d_in[28];
    const float* gat_asrc = (const float*)d_in[29];
    const float* gat_adst = (const float*)d_in[30];
    const float* gat_b    = (const float*)d_in[31];
    const float* gcn_w  = (const float*)d_in[32];
    const float* gcn_b  = (const float*)d_in[33];
    const float* fcg1_w = (const float*)d_in[34];
    const float* fcg1_b = (const float*)d_in[35];
    const float* fcg2_w = (const float*)d_in[36];
    const float* fcg2_b = (const float*)d_in[37];
    const float* e1_w = (const float*)d_in[38]; const float* e1_b = (const float*)d_in[39];
    const float* bn1_g = (const float*)d_in[40]; const float* bn1_b = (const float*)d_in[41];
    const float* e2_w = (const float*)d_in[42]; const float* e2_b = (const float*)d_in[43];
    const float* bn2_g = (const float*)d_in[44]; const float* bn2_b = (const float*)d_in[45];
    const float* e3_w = (const float*)d_in[46]; const float* e3_b = (const float*)d_in[47];
    const float* enc_w = (const float*)d_in[48]; const float* enc_b = (const float*)d_in[49];
    const float* d3_w = (const float*)d_in[50]; const float* d3_b = (const float*)d_in[51];
    const float* dbn2_g = (const float*)d_in[52]; const float* dbn2_b = (const float*)d_in[53];
    const float* d2_w = (const float*)d_in[54]; const float* d2_b = (const float*)d_in[55];
    const float* dbn1_g = (const float*)d_in[56]; const float* dbn1_b = (const float*)d_in[57];
    const float* d1_w = (const float*)d_in[58]; const float* d1_b = (const float*)d_in[59];
    const float* fc1_w = (const float*)d_in[60]; const float* fc1_b = (const float*)d_in[61];
    const float* fc2_w = (const float*)d_in[62]; const float* fc2_b = (const float*)d_in[63];
    const float* outw = (const float*)d_in[64]; const float* outb = (const float*)d_in[65];

    // ---- workspace carve (RB=2048: P buffer L3-resident) ----
    float *A1, *A2, *A3, *A4, *X1f, *QBIASf;
    unsigned short *XB, *QKVb, *Vt, *HbPb;
    unsigned short *WQKVb, *WOUTb, *WL1b, *WL2b, *WGb, *WGCNb, *WFCG1b, *WFCG2b,
                   *WENCb, *WFC1b, *WFC2b, *WOUTWb, *XD16, *FG1b, *E3b, *XCb, *FH1b, *FH2b, *Wcvb;
    float *asrc, *adst, *alpha, *denom, *dis, *c1p, *c2p, *e3o, *zz, *dd3, *dd2b;
    unsigned *amax; int *deg, *seg, *csr_off, *csr_cur, *csr_s, *csr_e;

    auto carve = [&](long long RB) -> size_t {
        char* wp_ = (char*)d_ws;
        auto alc = [&](size_t bytes) -> char* {
            char* p = wp_;
            wp_ += (bytes + 255) & ~(size_t)255;
            return p;
        };
        A1 = (float*)alc((size_t)NN * DD2 * 4);
        A2 = (float*)alc((size_t)NN * DD2 * 4);
        A3 = (float*)alc((size_t)NN * DD2 * 4);
        A4 = (float*)alc((size_t)NN * DD2 * 4);
        X1f = (float*)alc((size_t)NN * FXD_ * 4);
        XB   = (unsigned short*)alc((size_t)NN * 800 * 2);
        QKVb = (unsigned short*)alc((size_t)NN * 2400 * 2);
        Vt   = (unsigned short*)alc((size_t)800 * NN * 2);
        size_t hb = (size_t)NN * FFD * 2, pb = (size_t)RB * NN * 2;
        HbPb = (unsigned short*)alc(hb > pb ? hb : pb);   // FF hidden / attention P / AE im2col
        WQKVb = (unsigned short*)alc((size_t)2400 * 800 * 2);
        QBIASf= (float*)alc((size_t)2400 * 4);
        WOUTb = (unsigned short*)alc((size_t)780 * 800 * 2);
        WL1b  = (unsigned short*)alc((size_t)2048 * 800 * 2);
        WL2b  = (unsigned short*)alc((size_t)780 * 2048 * 2);
        WGb   = (unsigned short*)alc((size_t)780 * 96 * 2);
        WGCNb = (unsigned short*)alc((size_t)780 * 800 * 2);
        WFCG1b= (unsigned short*)alc((size_t)1500 * 1568 * 2);
        WFCG2b= (unsigned short*)alc((size_t)128 * 1504 * 2);
        WENCb = (unsigned short*)alc((size_t)128 * 640 * 2);
        WFC1b = (unsigned short*)alc((size_t)1024 * 256 * 2);
        WFC2b = (unsigned short*)alc((size_t)128 * 1024 * 2);
        WOUTWb= (unsigned short*)alc((size_t)128 * 2);
        Wcvb  = (unsigned short*)alc((size_t)128 * 1024 * 2);   // AE reshaped weights
        XD16  = (unsigned short*)alc((size_t)NG * 1568 * 2);
        FG1b  = (unsigned short*)alc((size_t)NG * 1504 * 2);
        E3b   = (unsigned short*)alc((size_t)NG * 640 * 2);
        XCb   = (unsigned short*)alc((size_t)NG * 256 * 2);
        FH1b  = (unsigned short*)alc((size_t)NG * 1024 * 2);
        FH2b  = (unsigned short*)alc((size_t)NG * 128 * 2);
        asrc = (float*)alc((size_t)NN * NH * 4);
        adst = (float*)alc((size_t)NN * NH * 4);
        alpha= (float*)alc((size_t)NETOT * NH * 4);
        amax = (unsigned*)alc((size_t)NN * NH * 4);
        denom= (float*)alc((size_t)NN * NH * 4);
        deg  = (int*)alc((size_t)NN * 4);
        dis  = (float*)alc((size_t)NN * 4);
        seg  = (int*)alc((size_t)(NG + 1) * 4);
        csr_off = (int*)alc((size_t)(NN + 1) * 4);
        csr_cur = (int*)alc((size_t)NN * 4);
        csr_s   = (int*)alc((size_t)NETOT * 4);
        csr_e   = (int*)alc((size_t)NETOT * 4);
        c1p  = (float*)alc((size_t)NG * 32 * 91 * 4);
        c2p  = (float*)alc((size_t)NG * 64 * 12 * 4);
        e3o  = (float*)alc((size_t)NG * 128 * 5 * 4);
        zz   = (float*)alc((size_t)NG * 128 * 4);
        dd3  = (float*)alc((size_t)NG * 64 * 12 * 4);
        dd2b = (float*)alc((size_t)NG * 32 * 91 * 4);
        return (size_t)(wp_ - (char*)d_ws);
    };

    long long RB = 512;
    const long long cands[3] = {2048, 1024, 512};   // 2048: P=33.5MB, L3-resident
    for (int i = 0; i < 3; ++i){ if (carve(cands[i]) <= ws_size){ RB = cands[i]; break; } }
    carve(RB);   // commit chosen layout
    unsigned short* Pb = HbPb;
    unsigned short* AIM = HbPb;      // AE im2col arena (HbPb dead after t2)

    float* out0   = (float*)d_out;                 // (256,1)
    float* xd_out = (float*)d_out + NG;            // (256,128)
    float* decode = (float*)d_out + NG + NG * 128; // (256,735)

    auto cvt = [&](const float* src, unsigned short* dst, int R, int C, int lds_, int ldd){
        long long n = (long long)R * ldd;
        cvt_pad_k<<<cdiv_i(n, 256), 256, 0, stream>>>(src, dst, n, C, lds_, ldd);
    };
    auto zero16 = [&](unsigned short* p, long long nshorts){
        fill_u32_k<<<cdiv_i(nshorts / 2, 256), 256, 0, stream>>>((unsigned*)p, 0u, nshorts / 2);
    };
    auto zerof = [&](float* p, long long n){
        fill_f32_k<<<cdiv_i(n, 256), 256, 0, stream>>>(p, 0.f, n);
    };

    // ---- transformer (shared for t1/t2); xin_bf = XB (padded Ep), residual xin f32 ----
    auto run_tf = [&](const float* xin, const float* const* W, float* outp, int E){
        const int Ep = pad32(E), E3p = 3 * Ep;
        float scale = (float)(1.0 / sqrt((double)E));
        // merged qkv: weights 3*Ep rows (pad rows zero), bias padded
        zero16(WQKVb, (long long)E3p * Ep);
        for (int s = 0; s < 3; ++s)
            cvt(W[0] + (size_t)s * E * E, WQKVb + (size_t)s * Ep * Ep, E, E, E, Ep);
        qkv_bias_k<<<cdiv_i(E3p, 256), 256, 0, stream>>>(W[1], QBIASf, E, Ep);
        mgemm<1,0,1,0,128>(stream, XB, WQKVb, QBIASf, QKVb, NN, E3p, Ep, Ep, Ep, E3p, 0);
        // V^T via bf16 transpose of the v-part
        {
            dim3 g(cdiv_i(E, 32), cdiv_i(NN, 32));
            tr_bf16_k<<<g, 256, 0, stream>>>(QKVb + 2 * Ep, Vt, NN, E, E3p, NN);
        }
        // attention: S (bf16, into Pb, y-fast swizzle) -> in-place softmax -> PV (split-K -> A4)
        zerof(A4, (long long)NN * E);
        for (long long r0 = 0; r0 < NN; r0 += RB){
            mgemm<1,0,1,0,128>(stream, QKVb + (size_t)r0 * E3p, QKVb + Ep, nullptr, Pb,
                               (int)RB, NN, Ep, E3p, E3p, NN, 1);
            softmax_bf16_k<<<(int)RB, 256, 0, stream>>>(Pb, scale);
            if (E == FXD_)
                mgemm<0,0,8,0,64>(stream, Pb, Vt, nullptr, A4 + (size_t)r0 * E,
                                  (int)RB, E, NN, NN, NN, E, 0);
            else
                mgemm<0,0,4,0,64>(stream, Pb, Vt, nullptr, A4 + (size_t)r0 * E,
                                  (int)RB, E, NN, NN, NN, E, 0);
        }
        cvt(A4, XB, NN, E, E, Ep);
        // proj + LN1
        cvt(W[2], WOUTb, E, E, E, Ep);
        mgemm<0,0,1,0,64>(stream, XB, WOUTb, W[3], A2, NN, E, Ep, Ep, Ep, E, 0);
        add_ln_k<<<NN, 256, 0, stream>>>(xin, A2, nullptr, W[4], W[5], A3, XB, E, Ep);
        // FF1 (relu, bf16) -> FF2 -> LN2
        cvt(W[6], WL1b, FFD, E, E, Ep);
        mgemm<1,1,1,0,128>(stream, XB, WL1b, W[7], HbPb, NN, FFD, Ep, Ep, Ep, FFD, 0);
        cvt(W[8], WL2b, E, FFD, FFD, FFD);
        mgemm<0,0,1,0,64>(stream, HbPb, WL2b, W[9], A2, NN, E, FFD, FFD, FFD, E, 0);
        add_ln_k<<<NN, 256, 0, stream>>>(A3, A2, nullptr, W[10], W[11], outp, XB, E, Ep);
    };

    // ================= t1 transformer (E=78) =================
    cvt(x, XB, NN, FXD_, FXD_, 96);
    run_tf(x, t1w, X1f, FXD_);          // leaves XB = t1 out (ld 96)

    // ================= graph structure: deg + CSR + segment bounds =================
    fill_u32_k<<<cdiv_i(NN, 256), 256, 0, stream>>>((unsigned*)deg, 0u, NN);
    deg_count_k<<<cdiv_i(NETOT, 256), 256, 0, stream>>>(ei, deg);
    csr_off_k<<<1, 256, 0, stream>>>(deg, csr_off, csr_cur);
    csr_fill_k<<<cdiv_i(NETOT, 256), 256, 0, stream>>>(ei, csr_cur, csr_s, csr_e);
    seg_start_k<<<cdiv_i(NN, 256), 256, 0, stream>>>(batch, seg);

    // ================= GAT =================
    cvt(gat_w, WGb, DD2, FXD_, FXD_, 96);
    mgemm<0,0,1,0,64>(stream, XB, WGb, nullptr, A2, NN, DD2, 96, 96, 96, DD2, 0);   // hfeat
    gat_srcdst_k<<<cdiv_i((long long)NN * NH, 256), 256, 0, stream>>>(A2, gat_asrc, gat_adst, asrc, adst);
    fill_u32_k<<<cdiv_i((long long)NN * NH, 256), 256, 0, stream>>>(amax, 0x007FFFFFu, (long long)NN * NH);
    zerof(denom, (long long)NN * NH);
    gat_alpha_k<<<cdiv_i((long long)NETOT * NH, 256), 256, 0, stream>>>(ei, asrc, adst, alpha, amax);
    gat_expsum_k<<<cdiv_i((long long)NETOT * NH, 256), 256, 0, stream>>>(ei, alpha, amax, denom);
    gat_gather_k<<<NN, 256, 0, stream>>>(csr_off, csr_s, csr_e, alpha, denom, A2, A1);
    bias_relu_k<<<cdiv_i((long long)NN * 800, 256), 256, 0, stream>>>(A1, gat_b, XB, NN, DD2, 800);

    // ================= t2 transformer (E=780) =================
    run_tf(A1, t2w, A1, DD2);           // leaves XB = t2 out (ld 800)

    // ================= GCN =================
    dis_k<<<cdiv_i(NN, 256), 256, 0, stream>>>(deg, dis);
    cvt(gcn_w, WGCNb, DD2, DD2, DD2, 800);
    mgemm<0,0,1,0,64>(stream, XB, WGCNb, nullptr, A2, NN, DD2, 800, 800, 800, DD2, 0); // xw
    gcn_gather_k<<<NN, 256, 0, stream>>>(csr_off, csr_s, dis, A2, A3);
    bias_relu_k<<<cdiv_i((long long)NN * DD2, 256), 256, 0, stream>>>(A3, gcn_b, nullptr, NN, DD2, DD2);

    // ================= pooling (segment gather) + graph head =================
    pool_seg_k<<<NG, 256, 0, stream>>>(A3, seg, XD16);
    cvt(fcg1_w, WFCG1b, 1500, 1560, 1560, 1568);
    zerof(A2, (long long)NG * 1500);
    mgemm<0,0,8,0,64>(stream, XD16, WFCG1b, nullptr, A2, NG, 1500, 1568, 1568, 1568, 1500, 0);
    bias_relu_k<<<cdiv_i((long long)NG * 1504, 256), 256, 0, stream>>>(A2, fcg1_b, FG1b, NG, 1500, 1504);
    cvt(fcg2_w, WFCG2b, 128, 1500, 1500, 1504);
    zerof(xd_out, (long long)NG * 128);
    mgemm<0,0,16,0,128>(stream, FG1b, WFCG2b, nullptr, xd_out, NG, 128, 1504, 1504, 1504, 128, 0);
    bias_add_k<<<cdiv_i((long long)NG * 128, 256), 256, 0, stream>>>(xd_out, fcg2_b, (long long)NG * 128, 128); // OUTPUT 1

    // ================= conv encoder (GEMM-ified; AIM=HbPb arena, Gout=A2) =================
    enc1_b<<<NG, 256, 0, stream>>>(tmut, e1_w, e1_b, bn1_g, bn1_b, c1p);
    // enc2: (21504 x 256) x (64 x 256)^T
    i2c_enc2_k<<<cdiv_i((long long)NG * 84 * 256, 256), 256, 0, stream>>>(c1p, AIM);
    cvt(e2_w, Wcvb, 64, 256, 256, 256);
    mgemm<0,0,1,0,64>(stream, AIM, Wcvb, nullptr, A2, NG * 84, 64, 256, 256, 256, 64, 0);
    post_enc2_k<<<cdiv_i((long long)NG * 768, 256), 256, 0, stream>>>(A2, e2_b, bn2_g, bn2_b, c2p);
    // enc3: (1280 x 512) x (128 x 512)^T, split-K 4
    i2c_enc3_k<<<cdiv_i((long long)NG * 5 * 512, 256), 256, 0, stream>>>(c2p, AIM);
    cvt(e3_w, Wcvb, 128, 512, 512, 512);
    zerof(A2, (long long)NG * 5 * 128);
    mgemm<0,0,4,0,128>(stream, AIM, Wcvb, nullptr, A2, NG * 5, 128, 512, 512, 512, 128, 0);
    post_enc3_k<<<cdiv_i((long long)NG * 640, 256), 256, 0, stream>>>(A2, e3_b, e3o, E3b);
    // z
    cvt(enc_w, WENCb, 128, 640, 640, 640);
    mgemm<0,0,1,0,128>(stream, E3b, WENCb, enc_b, zz, NG, 128, 640, 640, 640, 128, 0);

    // ================= conv decoder (GEMM-ified) =================
    // dec3: (3072 x 1024) x (64 x 1024)^T, split-K 4
    wshuf_k<<<cdiv_i(128 * 64 * 8, 256), 256, 0, stream>>>(d3_w, Wcvb, 128, 64);
    i2c_dec3_k<<<cdiv_i((long long)NG * 12 * 1024, 256), 256, 0, stream>>>(e3o, AIM);
    zerof(A2, (long long)NG * 12 * 64);
    mgemm<0,0,4,0,64>(stream, AIM, Wcvb, nullptr, A2, NG * 12, 64, 1024, 1024, 1024, 64, 0);
    post_dec3_k<<<cdiv_i((long long)NG * 768, 256), 256, 0, stream>>>(A2, d3_b, dbn2_g, dbn2_b, dd3);
    // dec2: (23296 x 512) x (32 x 512)^T
    wshuf_k<<<cdiv_i(64 * 32 * 8, 256), 256, 0, stream>>>(d2_w, Wcvb, 64, 32);
    i2c_dec2_k<<<cdiv_i((long long)NG * 91 * 512, 256), 256, 0, stream>>>(dd3, AIM);
    mgemm<0,0,1,0,64>(stream, AIM, Wcvb, nullptr, A2, NG * 91, 32, 512, 512, 512, 32, 0);
    post_dec2_k<<<cdiv_i((long long)NG * 2912, 256), 256, 0, stream>>>(A2, d2_b, dbn1_g, dbn1_b, dd2b);
    // dec1 (LDS kernel, 768 blocks)
    { dim3 g(NG, 3); dec1_b<<<g, 256, 0, stream>>>(dd2b, d1_w, d1_b, decode); }   // OUTPUT 2

    // ================= final head =================
    concat_xc_k<<<cdiv_i((long long)NG * 256, 256), 256, 0, stream>>>(xd_out, zz, XCb);
    cvt(fc1_w, WFC1b, 1024, 256, 256, 256);
    mgemm<1,1,1,0,128>(stream, XCb, WFC1b, fc1_b, FH1b, NG, 1024, 256, 256, 256, 1024, 0);
    cvt(fc2_w, WFC2b, 128, 1024, 1024, 1024);
    zerof(A3, (long long)NG * 128);
    mgemm<0,0,8,0,128>(stream, FH1b, WFC2b, nullptr, A3, NG, 128, 1024, 1024, 1024, 128, 0);
    bias_relu_k<<<cdiv_i((long long)NG * 128, 256), 256, 0, stream>>>(A3, fc2_b, FH2b, NG, 128, 128);
    cvt(outw, WOUTWb, 1, 128, 128, 128);
    mgemm<0,2,1,0,64>(stream, FH2b, WOUTWb, outb, out0, NG, 1, 128, 128, 128, 1, 0);   // OUTPUT 0 (sigmoid)
}

// Round 13
// 1642.702 us; speedup vs baseline: 1.5890x; 1.0750x over previous
//
#include <hip/hip_runtime.h>
#include <math.h>

// Problem constants
#define NN     8192      // nodes
#define NEDGE  32768     // edges (before self loops)
#define NETOT  40960     // edges + self loops
#define NG     256       // graphs
#define FXD_   78
#define NH     10        // heads
#define DD2    780       // FXD*HEADS
#define FFD    2048
#define LMUT   735

static inline int cdiv_i(long long a, int b){ return (int)((a + (long long)b - 1) / b); }
static inline int pad32(int x){ return (x + 31) & ~31; }

typedef __attribute__((ext_vector_type(8))) short bf16x8;
typedef __attribute__((ext_vector_type(4))) float f32x4;

static __device__ __forceinline__ unsigned short f2bf(float f){
    unsigned u = __float_as_uint(f);
    u += 0x7FFFu + ((u >> 16) & 1u);
    return (unsigned short)(u >> 16);
}

// async global->LDS, 16B per lane; lds dest is wave-uniform base + lane*16
static __device__ __forceinline__ void gload16(const void* g, void* l){
    __builtin_amdgcn_global_load_lds((const __attribute__((address_space(1))) void*)g,
                                     (__attribute__((address_space(3))) void*)l, 16, 0, 0);
}

// ---------------- fills ----------------
__global__ void fill_f32_k(float* __restrict__ p, float v, long long n){
    long long i = (long long)blockIdx.x * 256 + threadIdx.x;
    if (i < n) p[i] = v;
}
__global__ void fill_u32_k(unsigned* __restrict__ p, unsigned v, long long n){
    long long i = (long long)blockIdx.x * 256 + threadIdx.x;
    if (i < n) p[i] = v;
}

// ---------------- f32 -> bf16 convert with K-padding ----------------
__global__ void cvt_pad_k(const float* __restrict__ src, unsigned short* __restrict__ dst,
                          long long n /*R*ldd*/, int C, int lds_, int ldd)
{
    long long i = (long long)blockIdx.x * 256 + threadIdx.x;
    if (i >= n) return;
    int r = (int)(i / ldd), c = (int)(i % ldd);
    dst[i] = (c < C) ? f2bf(src[(size_t)r * lds_ + c]) : (unsigned short)0;
}

// normalize by sum-column + cvt: XB[r][c] = bf16(A4[r][c]/A4[r][E]), pads 0
__global__ void norm_cvt_k(const float* __restrict__ A4, unsigned short* __restrict__ XB,
                           int E, int Ep)
{
    long long i = (long long)blockIdx.x * 256 + threadIdx.x;
    if (i >= (long long)NN * Ep) return;
    int r = (int)(i / Ep), c = (int)(i % Ep);
    XB[i] = (c < E) ? f2bf(A4[(size_t)r * Ep + c] / A4[(size_t)r * Ep + E]) : (unsigned short)0;
}

// bf16 transpose: dst[c][r] = src[r][c]
__global__ void tr_bf16_k(const unsigned short* __restrict__ src, unsigned short* __restrict__ dst,
                          int R, int C, int lds_, int ldd)
{
    __shared__ unsigned short t[32][33];
    int cb = blockIdx.x * 32, rb = blockIdx.y * 32;
    int tx = threadIdx.x & 31, ty = threadIdx.x >> 5;   // 32 x 8
#pragma unroll
    for (int i = 0; i < 4; ++i){
        int r = rb + ty + i * 8, c = cb + tx;
        t[ty + i * 8][tx] = (r < R && c < C) ? src[(size_t)r * lds_ + c] : (unsigned short)0;
    }
    __syncthreads();
#pragma unroll
    for (int i = 0; i < 4; ++i){
        int dr = cb + ty + i * 8, dc = rb + tx;
        if (dr < C && dc < R) dst[(size_t)dr * ldd + dc] = t[tx][ty + i * 8];
    }
}

// padded qkv bias: out[s*Ep+c] = (c<E) ? b3[s*E+c] : 0, s=0..2
__global__ void qkv_bias_k(const float* __restrict__ b3, float* __restrict__ out, int E, int Ep)
{
    int idx = blockIdx.x * 256 + threadIdx.x;
    if (idx >= 3 * Ep) return;
    int s = idx / Ep, c = idx % Ep;
    out[idx] = (c < E) ? b3[s * E + c] : 0.f;
}

__global__ void bias_add_k(float* __restrict__ X, const float* __restrict__ b, long long n, int cols)
{
    long long i = (long long)blockIdx.x * 256 + threadIdx.x;
    if (i < n) X[i] += b[i % cols];
}

// ---------------- MFMA bf16 GEMM: 2-phase dbuf + XCD swizzle + BN=64/128 tiles ----------------
// ACT: 0 none, 1 relu, 2 sigmoid, 3 exp(v*escale)
template<int OUTC, int ACT, int SPLITK, int BROW, int BN>
__global__ __launch_bounds__(256) void mgemm_k(
    const unsigned short* __restrict__ A, const unsigned short* __restrict__ B,
    const float* __restrict__ bias, void* __restrict__ Cv,
    int M, int N, int Kp, int lda, int ldb, int ldc, int swz, float escale)
{
    constexpr int NFJ   = BN / 32;        // col frags per wave
    constexpr int TILEA = 128 * 32;
    constexpr int TILEB = BN * 32;
    __shared__ unsigned short As[2 * TILEA];
    __shared__ unsigned short Bs[2 * TILEB];
    const int tid = threadIdx.x;
    const int lane = tid & 63, wid = tid >> 6;
    const int r16 = lane & 15, q = lane >> 4;
    const int wr = (wid >> 1) * 64, wc = (wid & 1) * (BN / 2);

    // bijective XCD-chunked remap (m204)
    const int gx = gridDim.x, gy = gridDim.y;
    const int nwg = gx * gy;
    int orig = swz ? ((int)blockIdx.x * gy + (int)blockIdx.y)
                   : ((int)blockIdx.y * gx + (int)blockIdx.x);
    int q8 = nwg >> 3, r8 = nwg & 7;
    int xcd = orig & 7, kk8 = orig >> 3;
    int wgid = (xcd < r8 ? xcd * (q8 + 1) : r8 * (q8 + 1) + (xcd - r8) * q8) + kk8;
    int bx, by;
    if (swz){ by = wgid % gy; bx = wgid / gy; }
    else    { bx = wgid % gx; by = wgid / gx; }
    const int row0 = by * 128, col0 = bx * BN;

    int kbeg = 0, kend = Kp;
    if (SPLITK > 1){
        int nt_ = Kp >> 5, cpt = (nt_ + SPLITK - 1) / SPLITK;
        kbeg = (int)blockIdx.z * cpt * 32;
        kend = min(Kp, kbeg + cpt * 32);
    }

    // A staging: 512 chunks of 16B; lane handles chunk c0 and c0+64
    const int c0 = wid * 128 + lane;
    const int r0a = c0 >> 2, k0a = (c0 & 3) << 3;
    const size_t gA0 = (size_t)min(row0 + r0a, M - 1) * lda + k0a;
    const size_t gA1 = (size_t)min(row0 + r0a + 16, M - 1) * lda + k0a;
    unsigned short* lA = As + wid * 1024;
    // B staging
    size_t gB0 = 0, gB1 = 0;
    unsigned short* lB;
    if (BN == 128){
        gB0 = (size_t)min(col0 + r0a, N - 1) * ldb + k0a;
        gB1 = (size_t)min(col0 + r0a + 16, N - 1) * ldb + k0a;
        lB = Bs + wid * 1024;
    } else {               // BN=64: 256 chunks, 1 per lane
        const int cb = wid * 64 + lane;
        const int rb_ = cb >> 2, kb_ = (cb & 3) << 3;
        gB0 = (size_t)min(col0 + rb_, N - 1) * ldb + kb_;
        lB = Bs + wid * 512;
    }

    f32x4 acc[4][NFJ];
#pragma unroll
    for (int i = 0; i < 4; ++i)
#pragma unroll
        for (int j = 0; j < NFJ; ++j){ f32x4 z = {0.f, 0.f, 0.f, 0.f}; acc[i][j] = z; }

    const int nt = (kend - kbeg) >> 5;
    if (nt > 0){
        gload16(A + gA0 + kbeg, lA);
        gload16(A + gA1 + kbeg, lA + 512);
        gload16(B + gB0 + kbeg, lB);
        if (BN == 128) gload16(B + gB1 + kbeg, lB + 512);
        __syncthreads();
        int cur = 0;
        for (int t = 0; t < nt; ++t){
            const int k0 = kbeg + (t << 5);
            if (t + 1 < nt){                  // stage next tile BEFORE compute (overlap)
                const int kn = k0 + 32, nb = cur ^ 1;
                gload16(A + gA0 + kn, lA + nb * TILEA);
                gload16(A + gA1 + kn, lA + nb * TILEA + 512);
                gload16(B + gB0 + kn, lB + nb * TILEB);
                if (BN == 128) gload16(B + gB1 + kn, lB + nb * TILEB + 512);
            }
            const unsigned short* Ab = As + cur * TILEA;
            const unsigned short* Bb = Bs + cur * TILEB;
            bf16x8 af[4], bfv[NFJ];
#pragma unroll
            for (int f = 0; f < 4; ++f)
                af[f] = *(const bf16x8*)(Ab + (size_t)(wr + f * 16 + r16) * 32 + (q << 3));
#pragma unroll
            for (int f = 0; f < NFJ; ++f)
                bfv[f] = *(const bf16x8*)(Bb + (size_t)(wc + f * 16 + r16) * 32 + (q << 3));
#pragma unroll
            for (int fi = 0; fi < 4; ++fi)
#pragma unroll
                for (int fj = 0; fj < NFJ; ++fj)
                    acc[fi][fj] = __builtin_amdgcn_mfma_f32_16x16x32_bf16(af[fi], bfv[fj], acc[fi][fj], 0, 0, 0);
            __syncthreads();
            cur ^= 1;
        }
    }

#pragma unroll
    for (int fi = 0; fi < 4; ++fi){
#pragma unroll
        for (int j = 0; j < 4; ++j){
            int r = row0 + wr + fi * 16 + q * 4 + j;   // C/D: row=(lane>>4)*4+reg
            if (r >= M) continue;
#pragma unroll
            for (int fj = 0; fj < NFJ; ++fj){
                int c = col0 + wc + fj * 16 + r16;     // C/D: col=lane&15
                if (c >= N) continue;
                float v = acc[fi][fj][j];
                if (SPLITK > 1){
                    atomicAdd((float*)Cv + (size_t)r * ldc + c, v);
                } else {
                    if (bias) v += BROW ? bias[r] : bias[c];
                    if (ACT == 1) v = fmaxf(v, 0.f);
                    if (ACT == 2) v = 1.f / (1.f + expf(-v));
                    if (ACT == 3) v = expf(v * escale);
                    if (OUTC == 0) ((float*)Cv)[(size_t)r * ldc + c] = v;
                    else ((unsigned short*)Cv)[(size_t)r * ldc + c] = f2bf(v);
                }
            }
        }
    }
}

template<int OUTC, int ACT, int SPLITK, int BROW, int BN>
static void mgemm(hipStream_t s, const unsigned short* A, const unsigned short* B,
                  const float* bias, void* C, int M, int N, int Kp,
                  int lda, int ldb, int ldc, int swz, float escale = 1.f)
{
    dim3 g(cdiv_i(N, BN), cdiv_i(M, 128), SPLITK);
    mgemm_k<OUTC, ACT, SPLITK, BROW, BN><<<g, 256, 0, s>>>(A, B, bias, C, M, N, Kp, lda, ldb, ldc, swz, escale);
}

// ---------------- residual add + layernorm ----------------
__global__ __launch_bounds__(256) void add_ln_k(
    const float* __restrict__ X, const float* __restrict__ Y, const float* __restrict__ ybias,
    const float* __restrict__ g, const float* __restrict__ b,
    float* __restrict__ out, unsigned short* __restrict__ obf, int E, int Ep)
{
    __shared__ float s1[256], s2[256];
    const int tid = threadIdx.x;
    long long base = (long long)blockIdx.x * E;
    float vals[4];
    float sum = 0.f, sq = 0.f;
    int i = 0;
    for (int c = tid; c < Ep; c += 256, ++i){
        float v = 0.f;
        if (c < E){
            v = X[base + c] + Y[base + c];
            if (ybias) v += ybias[c];
            sum += v; sq += v * v;
        }
        vals[i] = v;
    }
    s1[tid] = sum; s2[tid] = sq; __syncthreads();
    for (int s = 128; s; s >>= 1){
        if (tid < s){ s1[tid] += s1[tid + s]; s2[tid] += s2[tid + s]; }
        __syncthreads();
    }
    float mean = s1[0] / (float)E;
    float var = s2[0] / (float)E - mean * mean;
    if (var < 0.f) var = 0.f;
    float inv = 1.f / sqrtf(var + 1e-5f);
    i = 0;
    for (int c = tid; c < Ep; c += 256, ++i){
        if (c < E){
            float o = (vals[i] - mean) * inv * g[c] + b[c];
            out[base + c] = o;
            if (obf) obf[(size_t)blockIdx.x * Ep + c] = f2bf(o);
        } else if (obf) obf[(size_t)blockIdx.x * Ep + c] = 0;
    }
}

// ---------------- GAT / graph common ----------------
static __device__ __forceinline__ unsigned enc_f(float x){
    unsigned u = __float_as_uint(x);
    return (u & 0x80000000u) ? ~u : (u | 0x80000000u);
}
static __device__ __forceinline__ float dec_f(unsigned u){
    return (u & 0x80000000u) ? __uint_as_float(u & 0x7fffffffu) : __uint_as_float(~u);
}
static __device__ __forceinline__ void edge_sd(const int* __restrict__ ei, int e, int& s, int& d){
    if (e < NEDGE){ s = ei[e]; d = ei[NEDGE + e]; }
    else { s = e - NEDGE; d = e - NEDGE; }
}

__global__ void gat_srcdst_k(const float* __restrict__ h, const float* __restrict__ aw_src,
                             const float* __restrict__ aw_dst, float* __restrict__ asrc,
                             float* __restrict__ adst)
{
    int idx = blockIdx.x * 256 + threadIdx.x;
    if (idx >= NN * NH) return;
    int n = idx / NH, hh = idx % NH;
    const float* hp = h + (long long)n * DD2 + hh * FXD_;
    const float* ws = aw_src + hh * FXD_;
    const float* wd = aw_dst + hh * FXD_;
    float s1 = 0.f, s2 = 0.f;
    for (int f = 0; f < FXD_; ++f){ float v = hp[f]; s1 += v * ws[f]; s2 += v * wd[f]; }
    asrc[idx] = s1; adst[idx] = s2;
}

__global__ void gat_alpha_k(const int* __restrict__ ei, const float* __restrict__ asrc,
                            const float* __restrict__ adst, float* __restrict__ alpha,
                            unsigned* __restrict__ amax)
{
    int idx = blockIdx.x * 256 + threadIdx.x;
    if (idx >= NETOT * NH) return;
    int e = idx / NH, hh = idx % NH;
    int s, d; edge_sd(ei, e, s, d);
    float a = asrc[s * NH + hh] + adst[d * NH + hh];
    a = (a > 0.f) ? a : 0.2f * a;       // leaky_relu 0.2
    alpha[idx] = a;
    atomicMax(&amax[d * NH + hh], enc_f(a));
}

__global__ void gat_expsum_k(const int* __restrict__ ei, float* __restrict__ alpha,
                             const unsigned* __restrict__ amax, float* __restrict__ denom)
{
    int idx = blockIdx.x * 256 + threadIdx.x;
    if (idx >= NETOT * NH) return;
    int e = idx / NH, hh = idx % NH;
    int s, d; edge_sd(ei, e, s, d);
    float m = dec_f(amax[d * NH + hh]);
    float ex = expf(alpha[idx] - m);
    alpha[idx] = ex;
    atomicAdd(&denom[d * NH + hh], ex);
}

__global__ void deg_count_k(const int* __restrict__ ei, int* __restrict__ deg)
{
    int e = blockIdx.x * 256 + threadIdx.x;
    if (e >= NETOT) return;
    int s, d; edge_sd(ei, e, s, d);
    atomicAdd(&deg[d], 1);
}

// ---- CSR build: exclusive scan of deg (single block) + fill ----
__global__ __launch_bounds__(256) void csr_off_k(const int* __restrict__ deg,
                                                 int* __restrict__ off, int* __restrict__ cur)
{
    __shared__ int pref[257];
    const int tid = threadIdx.x;
    int loc[32];
    int base = tid * 32, sum = 0;
#pragma unroll
    for (int i = 0; i < 32; ++i){ loc[i] = sum; sum += deg[base + i]; }
    __shared__ int part[256];
    part[tid] = sum; __syncthreads();
    if (tid == 0){
        pref[0] = 0;
        for (int i = 0; i < 256; ++i) pref[i + 1] = pref[i] + part[i];
    }
    __syncthreads();
    int p0 = pref[tid];
#pragma unroll
    for (int i = 0; i < 32; ++i){ off[base + i] = p0 + loc[i]; cur[base + i] = p0 + loc[i]; }
    if (tid == 0) off[NN] = pref[256];
}

__global__ void csr_fill_k(const int* __restrict__ ei, int* __restrict__ cur,
                           int* __restrict__ csr_s, int* __restrict__ csr_e)
{
    int e = blockIdx.x * 256 + threadIdx.x;
    if (e >= NETOT) return;
    int s, d; edge_sd(ei, e, s, d);
    int pos = atomicAdd(&cur[d], 1);
    csr_s[pos] = s; csr_e[pos] = e;
}

// GAT gather: one block per dst node; no atomics
__global__ __launch_bounds__(256) void gat_gather_k(
    const int* __restrict__ off, const int* __restrict__ csr_s, const int* __restrict__ csr_e,
    const float* __restrict__ ex, const float* __restrict__ denom,
    const float* __restrict__ hfeat, float* __restrict__ out)
{
    const int d = blockIdx.x, tid = threadIdx.x;
    const int beg = off[d], end = off[d + 1];
    for (int f = tid; f < DD2; f += 256){
        int hh = f / FXD_;
        float acc = 0.f;
        for (int p = beg; p < end; ++p)
            acc += ex[csr_e[p] * NH + hh] * hfeat[(size_t)csr_s[p] * DD2 + f];
        out[(size_t)d * DD2 + f] = acc / (denom[d * NH + hh] + 1e-16f);
    }
}

// GCN gather
__global__ __launch_bounds__(256) void gcn_gather_k(
    const int* __restrict__ off, const int* __restrict__ csr_s,
    const float* __restrict__ dis, const float* __restrict__ xw, float* __restrict__ out)
{
    const int d = blockIdx.x, tid = threadIdx.x;
    const int beg = off[d], end = off[d + 1];
    const float dd_ = dis[d];
    for (int f = tid; f < DD2; f += 256){
        float acc = 0.f;
        for (int p = beg; p < end; ++p){
            int s = csr_s[p];
            acc += dis[s] * xw[(size_t)s * DD2 + f];
        }
        out[(size_t)d * DD2 + f] = acc * dd_;
    }
}

// bias+relu on f32 (ld=cols), optional padded-bf16 mirror (ld=ldp)
__global__ void bias_relu_k(float* __restrict__ X, const float* __restrict__ b,
                            unsigned short* __restrict__ obf, int rows, int cols, int ldp)
{
    long long i = (long long)blockIdx.x * 256 + threadIdx.x;
    if (i >= (long long)rows * ldp) return;
    int r = (int)(i / ldp), c = (int)(i % ldp);
    if (c < cols){
        float v = X[(size_t)r * cols + c] + b[c];
        v = v > 0.f ? v : 0.f;
        X[(size_t)r * cols + c] = v;
        if (obf) obf[i] = f2bf(v);
    } else if (obf) obf[i] = 0;
}

__global__ void dis_k(const int* __restrict__ deg, float* __restrict__ dis)
{
    int n = blockIdx.x * 256 + threadIdx.x;
    if (n >= NN) return;
    float d = (float)deg[n];
    dis[n] = (d > 0.f) ? 1.f / sqrtf(fmaxf(d, 1.f)) : 0.f;
}

// ---------------- graph pooling (sorted batch -> segment gather, no atomics) ----------------
__global__ void seg_start_k(const int* __restrict__ batch, int* __restrict__ start)
{
    int n = blockIdx.x * 256 + threadIdx.x;
    if (n >= NN) return;
    int b = batch[n];
    int bp = (n == 0) ? -1 : batch[n - 1];
    for (int g = bp + 1; g <= b; ++g) start[g] = n;
    if (n == NN - 1){
        for (int g = b + 1; g <= NG; ++g) start[g] = NN;
    }
}

// per-graph max/avg gather -> padded bf16 XD16 (ld 1568)
__global__ __launch_bounds__(256) void pool_seg_k(const float* __restrict__ xg,
                                                  const int* __restrict__ start,
                                                  unsigned short* __restrict__ xdb)
{
    const int g = blockIdx.x, tid = threadIdx.x;
    const int s0 = start[g], s1 = start[g + 1];
    const float inv = 1.f / fmaxf((float)(s1 - s0), 1.f);
    for (int f = tid; f < DD2; f += 256){
        float mx = 0.f, sm = 0.f;   // xg >= 0 (post-relu); empty segment -> 0 matches ref
        for (int n = s0; n < s1; ++n){
            float v = xg[(size_t)n * DD2 + f];
            mx = fmaxf(mx, v); sm += v;
        }
        xdb[(size_t)g * 1568 + f] = f2bf(mx);
        xdb[(size_t)g * 1568 + DD2 + f] = f2bf(sm * inv);
    }
    if (tid < 8) xdb[(size_t)g * 1568 + 1560 + tid] = 0;   // pad cols
}

// ---------------- conv autoencoder ----------------
#define BN_SCALE 0.9999950000374996f   // 1/sqrt(1+1e-5)

// enc1: (NG,32,91); tm row (735 f32) + w (32x8) in LDS; grid NG
__global__ __launch_bounds__(256) void enc1_b(const float* __restrict__ tm, const float* __restrict__ w,
                                              const float* __restrict__ bias, const float* __restrict__ bng,
                                              const float* __restrict__ bnb, float* __restrict__ out)
{
    __shared__ float xs[736];
    __shared__ float ws[256], bs[32], gs[32], b2[32];
    const int g = blockIdx.x, tid = threadIdx.x;
    for (int i = tid; i < 735; i += 256) xs[i] = tm[(size_t)g * LMUT + i];
    ws[tid] = w[tid];
    if (tid < 32){ bs[tid] = bias[tid]; gs[tid] = bng[tid]; b2[tid] = bnb[tid]; }
    __syncthreads();
    for (int idx = tid; idx < 32 * 91; idx += 256){
        int o = idx / 91, t = idx % 91;
        float mx = -3.4e38f;
        for (int p = 0; p < 8; ++p){
            float s = bs[o];
#pragma unroll
            for (int k = 0; k < 8; ++k) s += xs[t * 8 + p + k] * ws[o * 8 + k];
            mx = fmaxf(mx, s);
        }
        float v = mx * gs[o] * BN_SCALE + b2[o];
        out[(size_t)g * 2912 + idx] = v > 0.f ? v : 0.01f * v;
    }
}

// ---- GEMM-ified AE middle layers: im2col / weight-reshape / post kernels ----
__global__ void i2c_enc2_k(const float* __restrict__ in, unsigned short* __restrict__ A){
    int idx = blockIdx.x * 256 + threadIdx.x;
    if (idx >= NG * 84 * 256) return;
    int col = idx & 255, row = idx >> 8;
    int g = row / 84, u = row % 84;
    int i = col >> 3, k = col & 7;
    A[idx] = f2bf(in[(size_t)g * 2912 + i * 91 + u + k]);
}
__global__ void post_enc2_k(const float* __restrict__ G, const float* __restrict__ b,
                            const float* __restrict__ bng, const float* __restrict__ bnb,
                            float* __restrict__ out){
    int idx = blockIdx.x * 256 + threadIdx.x;
    if (idx >= NG * 768) return;
    int t = idx % 12, o = (idx / 12) & 63, g = idx / 768;
    float mx = -3.4e38f;
#pragma unroll
    for (int p = 0; p < 7; ++p) mx = fmaxf(mx, G[(size_t)(g * 84 + t * 7 + p) * 64 + o]);
    float v = (mx + b[o]) * bng[o] * BN_SCALE + bnb[o];
    out[(size_t)g * 768 + o * 12 + t] = v > 0.f ? v : 0.01f * v;
}
__global__ void i2c_enc3_k(const float* __restrict__ in, unsigned short* __restrict__ A){
    int idx = blockIdx.x * 256 + threadIdx.x;
    if (idx >= NG * 5 * 512) return;
    int col = idx & 511, row = idx >> 9;
    int g = row / 5, t = row % 5;
    int i2 = col >> 3, k = col & 7;
    A[idx] = f2bf(in[(size_t)g * 768 + i2 * 12 + t + k]);
}
__global__ void post_enc3_k(const float* __restrict__ G, const float* __restrict__ b,
                            float* __restrict__ e3o, unsigned short* __restrict__ obf){
    int idx = blockIdx.x * 256 + threadIdx.x;
    if (idx >= NG * 640) return;
    int t = idx % 5, o = (idx / 5) & 127, g = idx / 640;
    float v = G[(size_t)(g * 5 + t) * 128 + o] + b[o];
    e3o[(size_t)g * 640 + o * 5 + t] = v;
    obf[(size_t)g * 640 + o * 5 + t] = f2bf(v);
}
__global__ void wshuf_k(const float* __restrict__ src, unsigned short* __restrict__ dst, int I, int O){
    int idx = blockIdx.x * 256 + threadIdx.x;
    if (idx >= I * O * 8) return;
    int o = idx / (I * 8), rem = idx % (I * 8);
    int i = rem >> 3, j = rem & 7;
    dst[idx] = f2bf(src[(size_t)(i * O + o) * 8 + j]);
}
__global__ void i2c_dec3_k(const float* __restrict__ e3o, unsigned short* __restrict__ A){
    int idx = blockIdx.x * 256 + threadIdx.x;
    if (idx >= NG * 12 * 1024) return;
    int col = idx & 1023, row = idx >> 10;
    int g = row / 12, t = row % 12;
    int i2 = col >> 3, j = col & 7;
    int tt = t - j;
    A[idx] = (tt >= 0 && tt < 5) ? f2bf(e3o[(size_t)g * 640 + i2 * 5 + tt]) : (unsigned short)0;
}
__global__ void post_dec3_k(const float* __restrict__ G, const float* __restrict__ b,
                            const float* __restrict__ bng, const float* __restrict__ bnb,
                            float* __restrict__ dd3){
    int idx = blockIdx.x * 256 + threadIdx.x;
    if (idx >= NG * 768) return;
    int t = idx % 12, o = (idx / 12) & 63, g = idx / 768;
    float v = (G[(size_t)(g * 12 + t) * 64 + o] + b[o]) * bng[o] * BN_SCALE + bnb[o];
    dd3[(size_t)g * 768 + o * 12 + t] = v > 0.f ? v : 0.01f * v;
}
__global__ void i2c_dec2_k(const float* __restrict__ dd3, unsigned short* __restrict__ A){
    int idx = blockIdx.x * 256 + threadIdx.x;
    if (idx >= NG * 91 * 512) return;
    int col = idx & 511, row = idx >> 9;
    int g = row / 91, t = row % 91;
    int i2 = col >> 3, j = col & 7;
    int tt = t - j;
    A[idx] = (tt >= 0 && tt < 84) ? f2bf(dd3[(size_t)g * 768 + i2 * 12 + tt / 7]) : (unsigned short)0;
}
__global__ void post_dec2_k(const float* __restrict__ G, const float* __restrict__ b,
                            const float* __restrict__ bng, const float* __restrict__ bnb,
                            float* __restrict__ dd2){
    int idx = blockIdx.x * 256 + threadIdx.x;
    if (idx >= NG * 2912) return;
    int t = idx % 91, o = (idx / 91) & 31, g = idx / 2912;
    float v = (G[(size_t)(g * 91 + t) * 32 + o] + b[o]) * bng[o] * BN_SCALE + bnb[o];
    dd2[(size_t)g * 2912 + o * 91 + t] = v > 0.f ? v : 0.01f * v;
}

// dec1: (NG,735); grid (NG,3) t-chunks of 245; dd2 (32x91) + w (32x8) in LDS
__global__ __launch_bounds__(256) void dec1_b(const float* __restrict__ dd2, const float* __restrict__ w,
                                              const float* __restrict__ bias, float* __restrict__ out)
{
    __shared__ float d2s[32][91];
    __shared__ float ws[256];
    const int g = blockIdx.x, tid = threadIdx.x;
    const int t0 = (int)blockIdx.y * 245;
    for (int i = tid; i < 32 * 91; i += 256) d2s[i / 91][i % 91] = dd2[(size_t)g * 2912 + i];
    ws[tid] = w[tid];
    __syncthreads();
    if (tid < 245){
        int t = t0 + tid;
        int id8[8]; bool ok[8];
#pragma unroll
        for (int j = 0; j < 8; ++j){
            int tt = t - j;
            ok[j] = (tt >= 0 && tt < 728);
            id8[j] = ok[j] ? (tt >> 3) : 0;
        }
        float s = bias[0];
        for (int i2 = 0; i2 < 32; ++i2){
            const float* wp = ws + i2 * 8;
            float a = 0.f;
#pragma unroll
            for (int j = 0; j < 8; ++j) if (ok[j]) a += d2s[i2][id8[j]] * wp[j];
            s += a;
        }
        out[(size_t)g * 735 + t] = s;
    }
}

__global__ void concat_xc_k(const float* __restrict__ xd, const float* __restrict__ z,
                            unsigned short* __restrict__ xcb)
{
    int idx = blockIdx.x * 256 + threadIdx.x;
    if (idx >= NG * 256) return;
    int g = idx >> 8, c = idx & 255;
    xcb[idx] = f2bf((c < 128) ? xd[g * 128 + c] : z[g * 128 + (c - 128)]);
}

// ---------------- host-side orchestration ----------------
extern "C" void kernel_launch(void* const* d_in, const int* in_sizes, int n_in,
                              void* d_out, int out_size, void* d_ws, size_t ws_size,
                              hipStream_t stream)
{
    (void)in_sizes; (void)n_in; (void)out_size;

    // ---- input pointers: setup_inputs() DICT order (t1 4-15, t2 16-27, gat 28-31) ----
    const float* x      = (const float*)d_in[0];
    const int*   ei     = (const int*)  d_in[1];
    const int*   batch  = (const int*)  d_in[2];
    const float* tmut   = (const float*)d_in[3];
    const float* t1w[12]; for (int i = 0; i < 12; ++i) t1w[i] = (const float*)d_in[4 + i];
    const float* t2w[12]; for (int i = 0; i < 12; ++i) t2w[i] = (const float*)d_in[16 + i];
    const float* gat_w    = (const float*)d_in[28];
    const float* gat_asrc = (const float*)d_in[29];
    const float* gat_adst = (const float*)d_in[30];
    const float* gat_b    = (const float*)d_in[31];
    const float* gcn_w  = (const float*)d_in[32];
    const float* gcn_b  = (const float*)d_in[33];
    const float* fcg1_w = (const float*)d_in[34];
    const float* fcg1_b = (const float*)d_in[35];
    const float* fcg2_w = (const float*)d_in[36];
    const float* fcg2_b = (const float*)d_in[37];
    const float* e1_w = (const float*)d_in[38]; const float* e1_b = (const float*)d_in[39];
    const float* bn1_g = (const float*)d_in[40]; const float* bn1_b = (const float*)d_in[41];
    const float* e2_w = (const float*)d_in[42]; const float* e2_b = (const float*)d_in[43];
    const float* bn2_g = (const float*)d_in[44]; const float* bn2_b = (const float*)d_in[45];
    const float* e3_w = (const float*)d_in[46]; const float* e3_b = (const float*)d_in[47];
    const float* enc_w = (const float*)d_in[48]; const float* enc_b = (const float*)d_in[49];
    const float* d3_w = (const float*)d_in[50]; const float* d3_b = (const float*)d_in[51];
    const float* dbn2_g = (const float*)d_in[52]; const float* dbn2_b = (const float*)d_in[53];
    const float* d2_w = (const float*)d_in[54]; const float* d2_b = (const float*)d_in[55];
    const float* dbn1_g = (const float*)d_in[56]; const float* dbn1_b = (const float*)d_in[57];
    const float* d1_w = (const float*)d_in[58]; const float* d1_b = (const float*)d_in[59];
    const float* fc1_w = (const float*)d_in[60]; const float* fc1_b = (const float*)d_in[61];
    const float* fc2_w = (const float*)d_in[62]; const float* fc2_b = (const float*)d_in[63];
    const float* outw = (const float*)d_in[64]; const float* outb = (const float*)d_in[65];

    // ---- workspace carve ----
    float *A1, *A2, *A3, *A4, *X1f, *QBIASf;
    unsigned short *XB, *QKVb, *Vt, *HbPb;
    unsigned short *WQKVb, *WOUTb, *WL1b, *WL2b, *WGb, *WGCNb, *WFCG1b, *WFCG2b,
                   *WENCb, *WFC1b, *WFC2b, *WOUTWb, *XD16, *FG1b, *E3b, *XCb, *FH1b, *FH2b, *Wcvb;
    float *asrc, *adst, *alpha, *denom, *dis, *c1p, *c2p, *e3o, *zz, *dd3, *dd2b;
    unsigned *amax; int *deg, *seg, *csr_off, *csr_cur, *csr_s, *csr_e;

    auto carve = [&](long long RB) -> size_t {
        char* wp_ = (char*)d_ws;
        auto alc = [&](size_t bytes) -> char* {
            char* p = wp_;
            wp_ += (bytes + 255) & ~(size_t)255;
            return p;
        };
        A1 = (float*)alc((size_t)NN * DD2 * 4);
        A2 = (float*)alc((size_t)NN * DD2 * 4);
        A3 = (float*)alc((size_t)NN * DD2 * 4);
        A4 = (float*)alc((size_t)NN * 800 * 4);   // attention out + sum column (ld Ep)
        X1f = (float*)alc((size_t)NN * FXD_ * 4);
        XB   = (unsigned short*)alc((size_t)NN * 800 * 2);
        QKVb = (unsigned short*)alc((size_t)NN * 2400 * 2);
        Vt   = (unsigned short*)alc((size_t)801 * NN * 2);   // +1 ones-row
        size_t hb = (size_t)NN * FFD * 2, pb = (size_t)RB * NN * 2;
        HbPb = (unsigned short*)alc(hb > pb ? hb : pb);   // FF hidden / attention P / AE im2col
        WQKVb = (unsigned short*)alc((size_t)2400 * 800 * 2);
        QBIASf= (float*)alc((size_t)2400 * 4);
        WOUTb = (unsigned short*)alc((size_t)780 * 800 * 2);
        WL1b  = (unsigned short*)alc((size_t)2048 * 800 * 2);
        WL2b  = (unsigned short*)alc((size_t)780 * 2048 * 2);
        WGb   = (unsigned short*)alc((size_t)780 * 96 * 2);
        WGCNb = (unsigned short*)alc((size_t)780 * 800 * 2);
        WFCG1b= (unsigned short*)alc((size_t)1500 * 1568 * 2);
        WFCG2b= (unsigned short*)alc((size_t)128 * 1504 * 2);
        WENCb = (unsigned short*)alc((size_t)128 * 640 * 2);
        WFC1b = (unsigned short*)alc((size_t)1024 * 256 * 2);
        WFC2b = (unsigned short*)alc((size_t)128 * 1024 * 2);
        WOUTWb= (unsigned short*)alc((size_t)128 * 2);
        Wcvb  = (unsigned short*)alc((size_t)128 * 1024 * 2);   // AE reshaped weights
        XD16  = (unsigned short*)alc((size_t)NG * 1568 * 2);
        FG1b  = (unsigned short*)alc((size_t)NG * 1504 * 2);
        E3b   = (unsigned short*)alc((size_t)NG * 640 * 2);
        XCb   = (unsigned short*)alc((size_t)NG * 256 * 2);
        FH1b  = (unsigned short*)alc((size_t)NG * 1024 * 2);
        FH2b  = (unsigned short*)alc((size_t)NG * 128 * 2);
        asrc = (float*)alc((size_t)NN * NH * 4);
        adst = (float*)alc((size_t)NN * NH * 4);
        alpha= (float*)alc((size_t)NETOT * NH * 4);
        amax = (unsigned*)alc((size_t)NN * NH * 4);
        denom= (float*)alc((size_t)NN * NH * 4);
        deg  = (int*)alc((size_t)NN * 4);
        dis  = (float*)alc((size_t)NN * 4);
        seg  = (int*)alc((size_t)(NG + 1) * 4);
        csr_off = (int*)alc((size_t)(NN + 1) * 4);
        csr_cur = (int*)alc((size_t)NN * 4);
        csr_s   = (int*)alc((size_t)NETOT * 4);
        csr_e   = (int*)alc((size_t)NETOT * 4);
        c1p  = (float*)alc((size_t)NG * 32 * 91 * 4);
        c2p  = (float*)alc((size_t)NG * 64 * 12 * 4);
        e3o  = (float*)alc((size_t)NG * 128 * 5 * 4);
        zz   = (float*)alc((size_t)NG * 128 * 4);
        dd3  = (float*)alc((size_t)NG * 64 * 12 * 4);
        dd2b = (float*)alc((size_t)NG * 32 * 91 * 4);
        return (size_t)(wp_ - (char*)d_ws);
    };

    long long RB = 512;
    const long long cands[3] = {2048, 1024, 512};
    for (int i = 0; i < 3; ++i){ if (carve(cands[i]) <= ws_size){ RB = cands[i]; break; } }
    carve(RB);   // commit chosen layout
    unsigned short* Pb = HbPb;
    unsigned short* AIM = HbPb;      // AE im2col arena (HbPb dead after t2)

    float* out0   = (float*)d_out;                 // (256,1)
    float* xd_out = (float*)d_out + NG;            // (256,128)
    float* decode = (float*)d_out + NG + NG * 128; // (256,735)

    auto cvt = [&](const float* src, unsigned short* dst, int R, int C, int lds_, int ldd){
        long long n = (long long)R * ldd;
        cvt_pad_k<<<cdiv_i(n, 256), 256, 0, stream>>>(src, dst, n, C, lds_, ldd);
    };
    auto zero16 = [&](unsigned short* p, long long nshorts){
        fill_u32_k<<<cdiv_i(nshorts / 2, 256), 256, 0, stream>>>((unsigned*)p, 0u, nshorts / 2);
    };
    auto zerof = [&](float* p, long long n){
        fill_f32_k<<<cdiv_i(n, 256), 256, 0, stream>>>(p, 0.f, n);
    };

    // ---- transformer (shared for t1/t2); xin_bf = XB (padded Ep), residual xin f32 ----
    auto run_tf = [&](const float* xin, const float* const* W, float* outp, int E){
        const int Ep = pad32(E), E3p = 3 * Ep;
        float scale = (float)(1.0 / sqrt((double)E));
        // merged qkv: weights 3*Ep rows (pad rows zero), bias padded
        zero16(WQKVb, (long long)E3p * Ep);
        for (int s = 0; s < 3; ++s)
            cvt(W[0] + (size_t)s * E * E, WQKVb + (size_t)s * Ep * Ep, E, E, E, Ep);
        qkv_bias_k<<<cdiv_i(E3p, 256), 256, 0, stream>>>(W[1], QBIASf, E, Ep);
        mgemm<1,0,1,0,128>(stream, XB, WQKVb, QBIASf, QKVb, NN, E3p, Ep, Ep, Ep, E3p, 0);
        // V^T via bf16 transpose of the v-part; row E = ones (softmax denominator column)
        {
            dim3 g(cdiv_i(E, 32), cdiv_i(NN, 32));
            tr_bf16_k<<<g, 256, 0, stream>>>(QKVb + 2 * Ep, Vt, NN, E, E3p, NN);
            fill_u32_k<<<cdiv_i(NN / 2, 256), 256, 0, stream>>>((unsigned*)(Vt + (size_t)E * NN),
                                                                0x3F803F80u, NN / 2);   // bf16 1.0 pairs
        }
        // attention: S+exp (bf16, into Pb) -> PV with ones-col (split-K -> A4, ld Ep)
        zerof(A4, (long long)NN * Ep);
        for (long long r0 = 0; r0 < NN; r0 += RB){
            mgemm<1,3,1,0,128>(stream, QKVb + (size_t)r0 * E3p, QKVb + Ep, nullptr, Pb,
                               (int)RB, NN, Ep, E3p, E3p, NN, 1, scale);   // exp(v*scale) epilogue
            if (E == FXD_)
                mgemm<0,0,8,0,64>(stream, Pb, Vt, nullptr, A4 + (size_t)r0 * Ep,
                                  (int)RB, E + 1, NN, NN, NN, Ep, 0);
            else
                mgemm<0,0,4,0,64>(stream, Pb, Vt, nullptr, A4 + (size_t)r0 * Ep,
                                  (int)RB, E + 1, NN, NN, NN, Ep, 0);
        }
        norm_cvt_k<<<cdiv_i((long long)NN * Ep, 256), 256, 0, stream>>>(A4, XB, E, Ep);
        // proj + LN1
        cvt(W[2], WOUTb, E, E, E, Ep);
        mgemm<0,0,1,0,64>(stream, XB, WOUTb, W[3], A2, NN, E, Ep, Ep, Ep, E, 0);
        add_ln_k<<<NN, 256, 0, stream>>>(xin, A2, nullptr, W[4], W[5], A3, XB, E, Ep);
        // FF1 (relu, bf16) -> FF2 -> LN2
        cvt(W[6], WL1b, FFD, E, E, Ep);
        mgemm<1,1,1,0,128>(stream, XB, WL1b, W[7], HbPb, NN, FFD, Ep, Ep, Ep, FFD, 0);
        cvt(W[8], WL2b, E, FFD, FFD, FFD);
        mgemm<0,0,1,0,64>(stream, HbPb, WL2b, W[9], A2, NN, E, FFD, FFD, FFD, E, 0);
        add_ln_k<<<NN, 256, 0, stream>>>(A3, A2, nullptr, W[10], W[11], outp, XB, E, Ep);
    };

    // ================= t1 transformer (E=78) =================
    cvt(x, XB, NN, FXD_, FXD_, 96);
    run_tf(x, t1w, X1f, FXD_);          // leaves XB = t1 out (ld 96)

    // ================= graph structure: deg + CSR + segment bounds =================
    fill_u32_k<<<cdiv_i(NN, 256), 256, 0, stream>>>((unsigned*)deg, 0u, NN);
    deg_count_k<<<cdiv_i(NETOT, 256), 256, 0, stream>>>(ei, deg);
    csr_off_k<<<1, 256, 0, stream>>>(deg, csr_off, csr_cur);
    csr_fill_k<<<cdiv_i(NETOT, 256), 256, 0, stream>>>(ei, csr_cur, csr_s, csr_e);
    seg_start_k<<<cdiv_i(NN, 256), 256, 0, stream>>>(batch, seg);

    // ================= GAT =================
    cvt(gat_w, WGb, DD2, FXD_, FXD_, 96);
    mgemm<0,0,1,0,64>(stream, XB, WGb, nullptr, A2, NN, DD2, 96, 96, 96, DD2, 0);   // hfeat
    gat_srcdst_k<<<cdiv_i((long long)NN * NH, 256), 256, 0, stream>>>(A2, gat_asrc, gat_adst, asrc, adst);
    fill_u32_k<<<cdiv_i((long long)NN * NH, 256), 256, 0, stream>>>(amax, 0x007FFFFFu, (long long)NN * NH);
    zerof(denom, (long long)NN * NH);
    gat_alpha_k<<<cdiv_i((long long)NETOT * NH, 256), 256, 0, stream>>>(ei, asrc, adst, alpha, amax);
    gat_expsum_k<<<cdiv_i((long long)NETOT * NH, 256), 256, 0, stream>>>(ei, alpha, amax, denom);
    gat_gather_k<<<NN, 256, 0, stream>>>(csr_off, csr_s, csr_e, alpha, denom, A2, A1);
    bias_relu_k<<<cdiv_i((long long)NN * 800, 256), 256, 0, stream>>>(A1, gat_b, XB, NN, DD2, 800);

    // ================= t2 transformer (E=780) =================
    run_tf(A1, t2w, A1, DD2);           // leaves XB = t2 out (ld 800)

    // ================= GCN =================
    dis_k<<<cdiv_i(NN, 256), 256, 0, stream>>>(deg, dis);
    cvt(gcn_w, WGCNb, DD2, DD2, DD2, 800);
    mgemm<0,0,1,0,64>(stream, XB, WGCNb, nullptr, A2, NN, DD2, 800, 800, 800, DD2, 0); // xw
    gcn_gather_k<<<NN, 256, 0, stream>>>(csr_off, csr_s, dis, A2, A3);
    bias_relu_k<<<cdiv_i((long long)NN * DD2, 256), 256, 0, stream>>>(A3, gcn_b, nullptr, NN, DD2, DD2);

    // ================= pooling (segment gather) + graph head =================
    pool_seg_k<<<NG, 256, 0, stream>>>(A3, seg, XD16);
    cvt(fcg1_w, WFCG1b, 1500, 1560, 1560, 1568);
    zerof(A2, (long long)NG * 1500);
    mgemm<0,0,8,0,64>(stream, XD16, WFCG1b, nullptr, A2, NG, 1500, 1568, 1568, 1568, 1500, 0);
    bias_relu_k<<<cdiv_i((long long)NG * 1504, 256), 256, 0, stream>>>(A2, fcg1_b, FG1b, NG, 1500, 1504);
    cvt(fcg2_w, WFCG2b, 128, 1500, 1500, 1504);
    zerof(xd_out, (long long)NG * 128);
    mgemm<0,0,16,0,128>(stream, FG1b, WFCG2b, nullptr, xd_out, NG, 128, 1504, 1504, 1504, 128, 0);
    bias_add_k<<<cdiv_i((long long)NG * 128, 256), 256, 0, stream>>>(xd_out, fcg2_b, (long long)NG * 128, 128); // OUTPUT 1

    // ================= conv encoder (GEMM-ified; AIM=HbPb arena, Gout=A2) =================
    enc1_b<<<NG, 256, 0, stream>>>(tmut, e1_w, e1_b, bn1_g, bn1_b, c1p);
    // enc2: (21504 x 256) x (64 x 256)^T
    i2c_enc2_k<<<cdiv_i((long long)NG * 84 * 256, 256), 256, 0, stream>>>(c1p, AIM);
    cvt(e2_w, Wcvb, 64, 256, 256, 256);
    mgemm<0,0,1,0,64>(stream, AIM, Wcvb, nullptr, A2, NG * 84, 64, 256, 256, 256, 64, 0);
    post_enc2_k<<<cdiv_i((long long)NG * 768, 256), 256, 0, stream>>>(A2, e2_b, bn2_g, bn2_b, c2p);
    // enc3: (1280 x 512) x (128 x 512)^T, split-K 4
    i2c_enc3_k<<<cdiv_i((long long)NG * 5 * 512, 256), 256, 0, stream>>>(c2p, AIM);
    cvt(e3_w, Wcvb, 128, 512, 512, 512);
    zerof(A2, (long long)NG * 5 * 128);
    mgemm<0,0,4,0,128>(stream, AIM, Wcvb, nullptr, A2, NG * 5, 128, 512, 512, 512, 128, 0);
    post_enc3_k<<<cdiv_i((long long)NG * 640, 256), 256, 0, stream>>>(A2, e3_b, e3o, E3b);
    // z
    cvt(enc_w, WENCb, 128, 640, 640, 640);
    mgemm<0,0,1,0,128>(stream, E3b, WENCb, enc_b, zz, NG, 128, 640, 640, 640, 128, 0);

    // ================= conv decoder (GEMM-ified) =================
    // dec3: (3072 x 1024) x (64 x 1024)^T, split-K 4
    wshuf_k<<<cdiv_i(128 * 64 * 8, 256), 256, 0, stream>>>(d3_w, Wcvb, 128, 64);
    i2c_dec3_k<<<cdiv_i((long long)NG * 12 * 1024, 256), 256, 0, stream>>>(e3o, AIM);
    zerof(A2, (long long)NG * 12 * 64);
    mgemm<0,0,4,0,64>(stream, AIM, Wcvb, nullptr, A2, NG * 12, 64, 1024, 1024, 1024, 64, 0);
    post_dec3_k<<<cdiv_i((long long)NG * 768, 256), 256, 0, stream>>>(A2, d3_b, dbn2_g, dbn2_b, dd3);
    // dec2: (23296 x 512) x (32 x 512)^T
    wshuf_k<<<cdiv_i(64 * 32 * 8, 256), 256, 0, stream>>>(d2_w, Wcvb, 64, 32);
    i2c_dec2_k<<<cdiv_i((long long)NG * 91 * 512, 256), 256, 0, stream>>>(dd3, AIM);
    mgemm<0,0,1,0,64>(stream, AIM, Wcvb, nullptr, A2, NG * 91, 32, 512, 512, 512, 32, 0);
    post_dec2_k<<<cdiv_i((long long)NG * 2912, 256), 256, 0, stream>>>(A2, d2_b, dbn1_g, dbn1_b, dd2b);
    // dec1 (LDS kernel, 768 blocks)
    { dim3 g(NG, 3); dec1_b<<<g, 256, 0, stream>>>(dd2b, d1_w, d1_b, decode); }   // OUTPUT 2

    // ================= final head =================
    concat_xc_k<<<cdiv_i((long long)NG * 256, 256), 256, 0, stream>>>(xd_out, zz, XCb);
    cvt(fc1_w, WFC1b, 1024, 256, 256, 256);
    mgemm<1,1,1,0,128>(stream, XCb, WFC1b, fc1_b, FH1b, NG, 1024, 256, 256, 256, 1024, 0);
    cvt(fc2_w, WFC2b, 128, 1024, 1024, 1024);
    zerof(A3, (long long)NG * 128);
    mgemm<0,0,8,0,128>(stream, FH1b, WFC2b, nullptr, A3, NG, 128, 1024, 1024, 1024, 128, 0);
    bias_relu_k<<<cdiv_i((long long)NG * 128, 256), 256, 0, stream>>>(A3, fc2_b, FH2b, NG, 128, 128);
    cvt(outw, WOUTWb, 1, 128, 128, 128);
    mgemm<0,2,1,0,64>(stream, FH2b, WOUTWb, outb, out0, NG, 1, 128, 128, 128, 1, 0);   // OUTPUT 0 (sigmoid)
}

// Round 14
// 1578.541 us; speedup vs baseline: 1.6536x; 1.0406x over previous
//
#include <hip/hip_runtime.h>
#include <math.h>

// Problem constants
#define NN     8192      // nodes
#define NEDGE  32768     // edges (before self loops)
#define NETOT  40960     // edges + self loops
#define NG     256       // graphs
#define FXD_   78
#define NH     10        // heads
#define DD2    780       // FXD*HEADS
#define FFD    2048
#define LMUT   735

static inline int cdiv_i(long long a, int b){ return (int)((a + (long long)b - 1) / b); }
static inline int pad32(int x){ return (x + 31) & ~31; }

typedef __attribute__((ext_vector_type(8))) short bf16x8;
typedef __attribute__((ext_vector_type(4))) float f32x4;

static __device__ __forceinline__ unsigned short f2bf(float f){
    unsigned u = __float_as_uint(f);
    u += 0x7FFFu + ((u >> 16) & 1u);
    return (unsigned short)(u >> 16);
}

// async global->LDS, 16B per lane; lds dest is wave-uniform base + lane*16
static __device__ __forceinline__ void gload16(const void* g, void* l){
    __builtin_amdgcn_global_load_lds((const __attribute__((address_space(1))) void*)g,
                                     (__attribute__((address_space(3))) void*)l, 16, 0, 0);
}

// ---------------- fills ----------------
__global__ void fill_f32_k(float* __restrict__ p, float v, long long n){
    long long i = (long long)blockIdx.x * 256 + threadIdx.x;
    if (i < n) p[i] = v;
}
__global__ void fill_u32_k(unsigned* __restrict__ p, unsigned v, long long n){
    long long i = (long long)blockIdx.x * 256 + threadIdx.x;
    if (i < n) p[i] = v;
}

// ---------------- f32 -> bf16 convert with K-padding ----------------
__global__ void cvt_pad_k(const float* __restrict__ src, unsigned short* __restrict__ dst,
                          long long n /*R*ldd*/, int C, int lds_, int ldd)
{
    long long i = (long long)blockIdx.x * 256 + threadIdx.x;
    if (i >= n) return;
    int r = (int)(i / ldd), c = (int)(i % ldd);
    dst[i] = (c < C) ? f2bf(src[(size_t)r * lds_ + c]) : (unsigned short)0;
}

// normalize by sum-column + cvt: XB[r][c] = bf16(A4[r][c]/A4[r][E]), pads 0
__global__ void norm_cvt_k(const float* __restrict__ A4, unsigned short* __restrict__ XB,
                           int E, int Ep)
{
    long long i = (long long)blockIdx.x * 256 + threadIdx.x;
    if (i >= (long long)NN * Ep) return;
    int r = (int)(i / Ep), c = (int)(i % Ep);
    XB[i] = (c < E) ? f2bf(A4[(size_t)r * Ep + c] / A4[(size_t)r * Ep + E]) : (unsigned short)0;
}

// bf16 transpose: dst[c][r] = src[r][c]
__global__ void tr_bf16_k(const unsigned short* __restrict__ src, unsigned short* __restrict__ dst,
                          int R, int C, int lds_, int ldd)
{
    __shared__ unsigned short t[32][33];
    int cb = blockIdx.x * 32, rb = blockIdx.y * 32;
    int tx = threadIdx.x & 31, ty = threadIdx.x >> 5;   // 32 x 8
#pragma unroll
    for (int i = 0; i < 4; ++i){
        int r = rb + ty + i * 8, c = cb + tx;
        t[ty + i * 8][tx] = (r < R && c < C) ? src[(size_t)r * lds_ + c] : (unsigned short)0;
    }
    __syncthreads();
#pragma unroll
    for (int i = 0; i < 4; ++i){
        int dr = cb + ty + i * 8, dc = rb + tx;
        if (dr < C && dc < R) dst[(size_t)dr * ldd + dc] = t[tx][ty + i * 8];
    }
}

// padded qkv bias: out[s*Ep+c] = (c<E) ? b3[s*E+c] : 0, s=0..2
__global__ void qkv_bias_k(const float* __restrict__ b3, float* __restrict__ out, int E, int Ep)
{
    int idx = blockIdx.x * 256 + threadIdx.x;
    if (idx >= 3 * Ep) return;
    int s = idx / Ep, c = idx % Ep;
    out[idx] = (c < E) ? b3[s * E + c] : 0.f;
}

__global__ void bias_add_k(float* __restrict__ X, const float* __restrict__ b, long long n, int cols)
{
    long long i = (long long)blockIdx.x * 256 + threadIdx.x;
    if (i < n) X[i] += b[i % cols];
}

// ---------------- MFMA bf16 GEMM: 2-phase dbuf + XCD swizzle + BN=64/128 tiles ----------------
// ACT: 0 none, 1 relu, 2 sigmoid, 3 exp(v*escale)
template<int OUTC, int ACT, int SPLITK, int BROW, int BN>
__global__ __launch_bounds__(256) void mgemm_k(
    const unsigned short* __restrict__ A, const unsigned short* __restrict__ B,
    const float* __restrict__ bias, void* __restrict__ Cv,
    int M, int N, int Kp, int lda, int ldb, int ldc, int swz, float escale)
{
    constexpr int NFJ   = BN / 32;        // col frags per wave
    constexpr int TILEA = 128 * 32;
    constexpr int TILEB = BN * 32;
    __shared__ unsigned short As[2 * TILEA];
    __shared__ unsigned short Bs[2 * TILEB];
    const int tid = threadIdx.x;
    const int lane = tid & 63, wid = tid >> 6;
    const int r16 = lane & 15, q = lane >> 4;
    const int wr = (wid >> 1) * 64, wc = (wid & 1) * (BN / 2);

    // bijective XCD-chunked remap (m204)
    const int gx = gridDim.x, gy = gridDim.y;
    const int nwg = gx * gy;
    int orig = swz ? ((int)blockIdx.x * gy + (int)blockIdx.y)
                   : ((int)blockIdx.y * gx + (int)blockIdx.x);
    int q8 = nwg >> 3, r8 = nwg & 7;
    int xcd = orig & 7, kk8 = orig >> 3;
    int wgid = (xcd < r8 ? xcd * (q8 + 1) : r8 * (q8 + 1) + (xcd - r8) * q8) + kk8;
    int bx, by;
    if (swz){ by = wgid % gy; bx = wgid / gy; }
    else    { bx = wgid % gx; by = wgid / gx; }
    const int row0 = by * 128, col0 = bx * BN;

    int kbeg = 0, kend = Kp;
    if (SPLITK > 1){
        int nt_ = Kp >> 5, cpt = (nt_ + SPLITK - 1) / SPLITK;
        kbeg = (int)blockIdx.z * cpt * 32;
        kend = min(Kp, kbeg + cpt * 32);
    }

    // A staging: 512 chunks of 16B; lane handles chunk c0 and c0+64
    const int c0 = wid * 128 + lane;
    const int r0a = c0 >> 2, k0a = (c0 & 3) << 3;
    const size_t gA0 = (size_t)min(row0 + r0a, M - 1) * lda + k0a;
    const size_t gA1 = (size_t)min(row0 + r0a + 16, M - 1) * lda + k0a;
    unsigned short* lA = As + wid * 1024;
    // B staging
    size_t gB0 = 0, gB1 = 0;
    unsigned short* lB;
    if (BN == 128){
        gB0 = (size_t)min(col0 + r0a, N - 1) * ldb + k0a;
        gB1 = (size_t)min(col0 + r0a + 16, N - 1) * ldb + k0a;
        lB = Bs + wid * 1024;
    } else {               // BN=64: 256 chunks, 1 per lane
        const int cb = wid * 64 + lane;
        const int rb_ = cb >> 2, kb_ = (cb & 3) << 3;
        gB0 = (size_t)min(col0 + rb_, N - 1) * ldb + kb_;
        lB = Bs + wid * 512;
    }

    f32x4 acc[4][NFJ];
#pragma unroll
    for (int i = 0; i < 4; ++i)
#pragma unroll
        for (int j = 0; j < NFJ; ++j){ f32x4 z = {0.f, 0.f, 0.f, 0.f}; acc[i][j] = z; }

    const int nt = (kend - kbeg) >> 5;
    if (nt > 0){
        gload16(A + gA0 + kbeg, lA);
        gload16(A + gA1 + kbeg, lA + 512);
        gload16(B + gB0 + kbeg, lB);
        if (BN == 128) gload16(B + gB1 + kbeg, lB + 512);
        __syncthreads();
        int cur = 0;
        for (int t = 0; t < nt; ++t){
            const int k0 = kbeg + (t << 5);
            if (t + 1 < nt){                  // stage next tile BEFORE compute (overlap)
                const int kn = k0 + 32, nb = cur ^ 1;
                gload16(A + gA0 + kn, lA + nb * TILEA);
                gload16(A + gA1 + kn, lA + nb * TILEA + 512);
                gload16(B + gB0 + kn, lB + nb * TILEB);
                if (BN == 128) gload16(B + gB1 + kn, lB + nb * TILEB + 512);
            }
            const unsigned short* Ab = As + cur * TILEA;
            const unsigned short* Bb = Bs + cur * TILEB;
            bf16x8 af[4], bfv[NFJ];
#pragma unroll
            for (int f = 0; f < 4; ++f)
                af[f] = *(const bf16x8*)(Ab + (size_t)(wr + f * 16 + r16) * 32 + (q << 3));
#pragma unroll
            for (int f = 0; f < NFJ; ++f)
                bfv[f] = *(const bf16x8*)(Bb + (size_t)(wc + f * 16 + r16) * 32 + (q << 3));
#pragma unroll
            for (int fi = 0; fi < 4; ++fi)
#pragma unroll
                for (int fj = 0; fj < NFJ; ++fj)
                    acc[fi][fj] = __builtin_amdgcn_mfma_f32_16x16x32_bf16(af[fi], bfv[fj], acc[fi][fj], 0, 0, 0);
            __syncthreads();
            cur ^= 1;
        }
    }

#pragma unroll
    for (int fi = 0; fi < 4; ++fi){
#pragma unroll
        for (int j = 0; j < 4; ++j){
            int r = row0 + wr + fi * 16 + q * 4 + j;   // C/D: row=(lane>>4)*4+reg
            if (r >= M) continue;
#pragma unroll
            for (int fj = 0; fj < NFJ; ++fj){
                int c = col0 + wc + fj * 16 + r16;     // C/D: col=lane&15
                if (c >= N) continue;
                float v = acc[fi][fj][j];
                if (SPLITK > 1){
                    atomicAdd((float*)Cv + (size_t)r * ldc + c, v);
                } else {
                    if (bias) v += BROW ? bias[r] : bias[c];
                    if (ACT == 1) v = fmaxf(v, 0.f);
                    if (ACT == 2) v = 1.f / (1.f + expf(-v));
                    if (ACT == 3) v = expf(v * escale);
                    if (OUTC == 0) ((float*)Cv)[(size_t)r * ldc + c] = v;
                    else ((unsigned short*)Cv)[(size_t)r * ldc + c] = f2bf(v);
                }
            }
        }
    }
}

template<int OUTC, int ACT, int SPLITK, int BROW, int BN>
static void mgemm(hipStream_t s, const unsigned short* A, const unsigned short* B,
                  const float* bias, void* C, int M, int N, int Kp,
                  int lda, int ldb, int ldc, int swz, float escale = 1.f)
{
    dim3 g(cdiv_i(N, BN), cdiv_i(M, 128), SPLITK);
    mgemm_k<OUTC, ACT, SPLITK, BROW, BN><<<g, 256, 0, s>>>(A, B, bias, C, M, N, Kp, lda, ldb, ldc, swz, escale);
}

// ---------------- fused flash attention for t1 (E=78, Ep=96, E3p=288) ----------------
// grid (NN/128, 8): block = 128 q-rows x 1024-k chunk; atomic f32 partials into A4[NN][96].
// Math identical to materialized path: P = bf16(exp(s*scale)); col 78 of Vt = ones (denominator).
#define E3P1 288
__global__ __launch_bounds__(256) void flash_t1_k(
    const unsigned short* __restrict__ QKV,   // [NN][288]: q@0, k@96, v@192 (pads zero)
    const unsigned short* __restrict__ Vt,    // [*][NN]: rows 0..77 V^T, row 78 ones
    float* __restrict__ A4, float scale)      // [NN][96] pre-zeroed
{
    __shared__ unsigned short Ps[128 * 128];  // 32 KB, XOR-swizzled
    __shared__ unsigned short KV[128 * 96];   // 24 KB: K-tile [128][96] then V-tile [96][128]
    const int tid = threadIdx.x, lane = tid & 63, wid = tid >> 6;
    const int r16 = lane & 15, q = lane >> 4;
    const int wr = (wid >> 1) * 64;      // row base within 128 (S rows and out rows)
    const int sc = (wid & 1) * 64;       // S col base
    const int oc = (wid & 1) * 48;       // out col base (96/2)
    const int qb = (int)blockIdx.x * 128;
    const int kb = (int)blockIdx.y * 1024;

    // Q fragments: rows qb+wr.., K-dim 96 = 3 chunks of 32 (one-time global vector loads)
    bf16x8 qa[4][3];
#pragma unroll
    for (int mi = 0; mi < 4; ++mi)
#pragma unroll
        for (int kc = 0; kc < 3; ++kc)
            qa[mi][kc] = *(const bf16x8*)(QKV + (size_t)(qb + wr + mi * 16 + r16) * E3P1 + kc * 32 + (q << 3));

    f32x4 acco[4][3];
#pragma unroll
    for (int i = 0; i < 4; ++i)
#pragma unroll
        for (int j = 0; j < 3; ++j){ f32x4 z = {0.f, 0.f, 0.f, 0.f}; acco[i][j] = z; }

    for (int t = 0; t < 8; ++t){
        const int k0 = kb + t * 128;
        // load K-tile: KV[n][0..95] (row n = k index)
#pragma unroll
        for (int i = 0; i < 6; ++i){
            int id = tid + i * 256;                 // 0..1535, 12 chunks/row
            int row = id / 12, co = (id % 12) << 3;
            *(bf16x8*)(&KV[row * 96 + co]) =
                *(const bf16x8*)(QKV + (size_t)(k0 + row) * E3P1 + 96 + co);
        }
        __syncthreads();
        // S-tile: wave computes 64x64 at (wr, sc)
        f32x4 accs[4][4];
#pragma unroll
        for (int i = 0; i < 4; ++i)
#pragma unroll
            for (int j = 0; j < 4; ++j){ f32x4 z = {0.f, 0.f, 0.f, 0.f}; accs[i][j] = z; }
#pragma unroll
        for (int kc = 0; kc < 3; ++kc){
            bf16x8 bk[4];
#pragma unroll
            for (int nj = 0; nj < 4; ++nj)
                bk[nj] = *(const bf16x8*)(&KV[(sc + nj * 16 + r16) * 96 + kc * 32 + (q << 3)]);
#pragma unroll
            for (int mi = 0; mi < 4; ++mi)
#pragma unroll
                for (int nj = 0; nj < 4; ++nj)
                    accs[mi][nj] = __builtin_amdgcn_mfma_f32_16x16x32_bf16(qa[mi][kc], bk[nj], accs[mi][nj], 0, 0, 0);
        }
        __syncthreads();   // K-tile reads done before overwrite
        // exp -> Ps (swizzled); load V-tile [96][128] into KV (swizzled)
#pragma unroll
        for (int mi = 0; mi < 4; ++mi)
#pragma unroll
            for (int nj = 0; nj < 4; ++nj)
#pragma unroll
                for (int j = 0; j < 4; ++j){
                    int row = wr + mi * 16 + q * 4 + j;       // C/D: row=(lane>>4)*4+reg
                    int col = sc + nj * 16 + r16;             // C/D: col=lane&15
                    Ps[row * 128 + (col ^ ((row & 7) << 3))] = f2bf(expf(accs[mi][nj][j] * scale));
                }
#pragma unroll
        for (int i = 0; i < 6; ++i){
            int id = tid + i * 256;                 // 16 chunks/row, 96 rows
            int row = id / 16, co = (id % 16) << 3;
            *(bf16x8*)(&KV[row * 128 + (co ^ ((row & 7) << 3))]) =
                *(const bf16x8*)(Vt + (size_t)row * NN + k0 + co);
        }
        __syncthreads();
        // PV: acco += P(128x128) x Vt-tile; wave out = 64 rows x 48 cols at (wr, oc)
#pragma unroll
        for (int ko = 0; ko < 4; ++ko){
            bf16x8 pa[4], vb[3];
#pragma unroll
            for (int mi = 0; mi < 4; ++mi){
                int row = wr + mi * 16 + r16;                 // A: row=lane&15
                pa[mi] = *(const bf16x8*)(&Ps[row * 128 + ((ko * 32 + (q << 3)) ^ ((row & 7) << 3))]);
            }
#pragma unroll
            for (int nj = 0; nj < 3; ++nj){
                int row = oc + nj * 16 + r16;                 // B: n=lane&15
                vb[nj] = *(const bf16x8*)(&KV[row * 128 + ((ko * 32 + (q << 3)) ^ ((row & 7) << 3))]);
            }
#pragma unroll
            for (int mi = 0; mi < 4; ++mi)
#pragma unroll
                for (int nj = 0; nj < 3; ++nj)
                    acco[mi][nj] = __builtin_amdgcn_mfma_f32_16x16x32_bf16(pa[mi], vb[nj], acco[mi][nj], 0, 0, 0);
        }
        __syncthreads();   // Ps / V reads done before next iter writes
    }
    // epilogue: atomic partials, cols <= E (col 78 = denominator)
#pragma unroll
    for (int mi = 0; mi < 4; ++mi)
#pragma unroll
        for (int j = 0; j < 4; ++j){
            int r = qb + wr + mi * 16 + q * 4 + j;
#pragma unroll
            for (int nj = 0; nj < 3; ++nj){
                int c = oc + nj * 16 + r16;
                if (c <= FXD_)
                    atomicAdd(A4 + (size_t)r * 96 + c, acco[mi][nj][j]);
            }
        }
}

// ---------------- residual add + layernorm ----------------
__global__ __launch_bounds__(256) void add_ln_k(
    const float* __restrict__ X, const float* __restrict__ Y, const float* __restrict__ ybias,
    const float* __restrict__ g, const float* __restrict__ b,
    float* __restrict__ out, unsigned short* __restrict__ obf, int E, int Ep)
{
    __shared__ float s1[256], s2[256];
    const int tid = threadIdx.x;
    long long base = (long long)blockIdx.x * E;
    float vals[4];
    float sum = 0.f, sq = 0.f;
    int i = 0;
    for (int c = tid; c < Ep; c += 256, ++i){
        float v = 0.f;
        if (c < E){
            v = X[base + c] + Y[base + c];
            if (ybias) v += ybias[c];
            sum += v; sq += v * v;
        }
        vals[i] = v;
    }
    s1[tid] = sum; s2[tid] = sq; __syncthreads();
    for (int s = 128; s; s >>= 1){
        if (tid < s){ s1[tid] += s1[tid + s]; s2[tid] += s2[tid + s]; }
        __syncthreads();
    }
    float mean = s1[0] / (float)E;
    float var = s2[0] / (float)E - mean * mean;
    if (var < 0.f) var = 0.f;
    float inv = 1.f / sqrtf(var + 1e-5f);
    i = 0;
    for (int c = tid; c < Ep; c += 256, ++i){
        if (c < E){
            float o = (vals[i] - mean) * inv * g[c] + b[c];
            out[base + c] = o;
            if (obf) obf[(size_t)blockIdx.x * Ep + c] = f2bf(o);
        } else if (obf) obf[(size_t)blockIdx.x * Ep + c] = 0;
    }
}

// ---------------- GAT / graph common ----------------
static __device__ __forceinline__ unsigned enc_f(float x){
    unsigned u = __float_as_uint(x);
    return (u & 0x80000000u) ? ~u : (u | 0x80000000u);
}
static __device__ __forceinline__ float dec_f(unsigned u){
    return (u & 0x80000000u) ? __uint_as_float(u & 0x7fffffffu) : __uint_as_float(~u);
}
static __device__ __forceinline__ void edge_sd(const int* __restrict__ ei, int e, int& s, int& d){
    if (e < NEDGE){ s = ei[e]; d = ei[NEDGE + e]; }
    else { s = e - NEDGE; d = e - NEDGE; }
}

__global__ void gat_srcdst_k(const float* __restrict__ h, const float* __restrict__ aw_src,
                             const float* __restrict__ aw_dst, float* __restrict__ asrc,
                             float* __restrict__ adst)
{
    int idx = blockIdx.x * 256 + threadIdx.x;
    if (idx >= NN * NH) return;
    int n = idx / NH, hh = idx % NH;
    const float* hp = h + (long long)n * DD2 + hh * FXD_;
    const float* ws = aw_src + hh * FXD_;
    const float* wd = aw_dst + hh * FXD_;
    float s1 = 0.f, s2 = 0.f;
    for (int f = 0; f < FXD_; ++f){ float v = hp[f]; s1 += v * ws[f]; s2 += v * wd[f]; }
    asrc[idx] = s1; adst[idx] = s2;
}

__global__ void gat_alpha_k(const int* __restrict__ ei, const float* __restrict__ asrc,
                            const float* __restrict__ adst, float* __restrict__ alpha,
                            unsigned* __restrict__ amax)
{
    int idx = blockIdx.x * 256 + threadIdx.x;
    if (idx >= NETOT * NH) return;
    int e = idx / NH, hh = idx % NH;
    int s, d; edge_sd(ei, e, s, d);
    float a = asrc[s * NH + hh] + adst[d * NH + hh];
    a = (a > 0.f) ? a : 0.2f * a;       // leaky_relu 0.2
    alpha[idx] = a;
    atomicMax(&amax[d * NH + hh], enc_f(a));
}

__global__ void gat_expsum_k(const int* __restrict__ ei, float* __restrict__ alpha,
                             const unsigned* __restrict__ amax, float* __restrict__ denom)
{
    int idx = blockIdx.x * 256 + threadIdx.x;
    if (idx >= NETOT * NH) return;
    int e = idx / NH, hh = idx % NH;
    int s, d; edge_sd(ei, e, s, d);
    float m = dec_f(amax[d * NH + hh]);
    float ex = expf(alpha[idx] - m);
    alpha[idx] = ex;
    atomicAdd(&denom[d * NH + hh], ex);
}

__global__ void deg_count_k(const int* __restrict__ ei, int* __restrict__ deg)
{
    int e = blockIdx.x * 256 + threadIdx.x;
    if (e >= NETOT) return;
    int s, d; edge_sd(ei, e, s, d);
    atomicAdd(&deg[d], 1);
}

// ---- CSR build: exclusive scan of deg (single block) + fill ----
__global__ __launch_bounds__(256) void csr_off_k(const int* __restrict__ deg,
                                                 int* __restrict__ off, int* __restrict__ cur)
{
    __shared__ int pref[257];
    const int tid = threadIdx.x;
    int loc[32];
    int base = tid * 32, sum = 0;
#pragma unroll
    for (int i = 0; i < 32; ++i){ loc[i] = sum; sum += deg[base + i]; }
    __shared__ int part[256];
    part[tid] = sum; __syncthreads();
    if (tid == 0){
        pref[0] = 0;
        for (int i = 0; i < 256; ++i) pref[i + 1] = pref[i] + part[i];
    }
    __syncthreads();
    int p0 = pref[tid];
#pragma unroll
    for (int i = 0; i < 32; ++i){ off[base + i] = p0 + loc[i]; cur[base + i] = p0 + loc[i]; }
    if (tid == 0) off[NN] = pref[256];
}

__global__ void csr_fill_k(const int* __restrict__ ei, int* __restrict__ cur,
                           int* __restrict__ csr_s, int* __restrict__ csr_e)
{
    int e = blockIdx.x * 256 + threadIdx.x;
    if (e >= NETOT) return;
    int s, d; edge_sd(ei, e, s, d);
    int pos = atomicAdd(&cur[d], 1);
    csr_s[pos] = s; csr_e[pos] = e;
}

// GAT gather: one block per dst node; no atomics
__global__ __launch_bounds__(256) void gat_gather_k(
    const int* __restrict__ off, const int* __restrict__ csr_s, const int* __restrict__ csr_e,
    const float* __restrict__ ex, const float* __restrict__ denom,
    const float* __restrict__ hfeat, float* __restrict__ out)
{
    const int d = blockIdx.x, tid = threadIdx.x;
    const int beg = off[d], end = off[d + 1];
    for (int f = tid; f < DD2; f += 256){
        int hh = f / FXD_;
        float acc = 0.f;
        for (int p = beg; p < end; ++p)
            acc += ex[csr_e[p] * NH + hh] * hfeat[(size_t)csr_s[p] * DD2 + f];
        out[(size_t)d * DD2 + f] = acc / (denom[d * NH + hh] + 1e-16f);
    }
}

// GCN gather
__global__ __launch_bounds__(256) void gcn_gather_k(
    const int* __restrict__ off, const int* __restrict__ csr_s,
    const float* __restrict__ dis, const float* __restrict__ xw, float* __restrict__ out)
{
    const int d = blockIdx.x, tid = threadIdx.x;
    const int beg = off[d], end = off[d + 1];
    const float dd_ = dis[d];
    for (int f = tid; f < DD2; f += 256){
        float acc = 0.f;
        for (int p = beg; p < end; ++p){
            int s = csr_s[p];
            acc += dis[s] * xw[(size_t)s * DD2 + f];
        }
        out[(size_t)d * DD2 + f] = acc * dd_;
    }
}

// bias+relu on f32 (ld=cols), optional padded-bf16 mirror (ld=ldp)
__global__ void bias_relu_k(float* __restrict__ X, const float* __restrict__ b,
                            unsigned short* __restrict__ obf, int rows, int cols, int ldp)
{
    long long i = (long long)blockIdx.x * 256 + threadIdx.x;
    if (i >= (long long)rows * ldp) return;
    int r = (int)(i / ldp), c = (int)(i % ldp);
    if (c < cols){
        float v = X[(size_t)r * cols + c] + b[c];
        v = v > 0.f ? v : 0.f;
        X[(size_t)r * cols + c] = v;
        if (obf) obf[i] = f2bf(v);
    } else if (obf) obf[i] = 0;
}

__global__ void dis_k(const int* __restrict__ deg, float* __restrict__ dis)
{
    int n = blockIdx.x * 256 + threadIdx.x;
    if (n >= NN) return;
    float d = (float)deg[n];
    dis[n] = (d > 0.f) ? 1.f / sqrtf(fmaxf(d, 1.f)) : 0.f;
}

// ---------------- graph pooling (sorted batch -> segment gather, no atomics) ----------------
__global__ void seg_start_k(const int* __restrict__ batch, int* __restrict__ start)
{
    int n = blockIdx.x * 256 + threadIdx.x;
    if (n >= NN) return;
    int b = batch[n];
    int bp = (n == 0) ? -1 : batch[n - 1];
    for (int g = bp + 1; g <= b; ++g) start[g] = n;
    if (n == NN - 1){
        for (int g = b + 1; g <= NG; ++g) start[g] = NN;
    }
}

// per-graph max/avg gather -> padded bf16 XD16 (ld 1568)
__global__ __launch_bounds__(256) void pool_seg_k(const float* __restrict__ xg,
                                                  const int* __restrict__ start,
                                                  unsigned short* __restrict__ xdb)
{
    const int g = blockIdx.x, tid = threadIdx.x;
    const int s0 = start[g], s1 = start[g + 1];
    const float inv = 1.f / fmaxf((float)(s1 - s0), 1.f);
    for (int f = tid; f < DD2; f += 256){
        float mx = 0.f, sm = 0.f;   // xg >= 0 (post-relu); empty segment -> 0 matches ref
        for (int n = s0; n < s1; ++n){
            float v = xg[(size_t)n * DD2 + f];
            mx = fmaxf(mx, v); sm += v;
        }
        xdb[(size_t)g * 1568 + f] = f2bf(mx);
        xdb[(size_t)g * 1568 + DD2 + f] = f2bf(sm * inv);
    }
    if (tid < 8) xdb[(size_t)g * 1568 + 1560 + tid] = 0;   // pad cols
}

// ---------------- conv autoencoder ----------------
#define BN_SCALE 0.9999950000374996f   // 1/sqrt(1+1e-5)

// enc1: (NG,32,91); tm row (735 f32) + w (32x8) in LDS; grid NG
__global__ __launch_bounds__(256) void enc1_b(const float* __restrict__ tm, const float* __restrict__ w,
                                              const float* __restrict__ bias, const float* __restrict__ bng,
                                              const float* __restrict__ bnb, float* __restrict__ out)
{
    __shared__ float xs[736];
    __shared__ float ws[256], bs[32], gs[32], b2[32];
    const int g = blockIdx.x, tid = threadIdx.x;
    for (int i = tid; i < 735; i += 256) xs[i] = tm[(size_t)g * LMUT + i];
    ws[tid] = w[tid];
    if (tid < 32){ bs[tid] = bias[tid]; gs[tid] = bng[tid]; b2[tid] = bnb[tid]; }
    __syncthreads();
    for (int idx = tid; idx < 32 * 91; idx += 256){
        int o = idx / 91, t = idx % 91;
        float mx = -3.4e38f;
        for (int p = 0; p < 8; ++p){
            float s = bs[o];
#pragma unroll
            for (int k = 0; k < 8; ++k) s += xs[t * 8 + p + k] * ws[o * 8 + k];
            mx = fmaxf(mx, s);
        }
        float v = mx * gs[o] * BN_SCALE + b2[o];
        out[(size_t)g * 2912 + idx] = v > 0.f ? v : 0.01f * v;
    }
}

// ---- GEMM-ified AE middle layers: im2col / weight-reshape / post kernels ----
__global__ void i2c_enc2_k(const float* __restrict__ in, unsigned short* __restrict__ A){
    int idx = blockIdx.x * 256 + threadIdx.x;
    if (idx >= NG * 84 * 256) return;
    int col = idx & 255, row = idx >> 8;
    int g = row / 84, u = row % 84;
    int i = col >> 3, k = col & 7;
    A[idx] = f2bf(in[(size_t)g * 2912 + i * 91 + u + k]);
}
__global__ void post_enc2_k(const float* __restrict__ G, const float* __restrict__ b,
                            const float* __restrict__ bng, const float* __restrict__ bnb,
                            float* __restrict__ out){
    int idx = blockIdx.x * 256 + threadIdx.x;
    if (idx >= NG * 768) return;
    int t = idx % 12, o = (idx / 12) & 63, g = idx / 768;
    float mx = -3.4e38f;
#pragma unroll
    for (int p = 0; p < 7; ++p) mx = fmaxf(mx, G[(size_t)(g * 84 + t * 7 + p) * 64 + o]);
    float v = (mx + b[o]) * bng[o] * BN_SCALE + bnb[o];
    out[(size_t)g * 768 + o * 12 + t] = v > 0.f ? v : 0.01f * v;
}
__global__ void i2c_enc3_k(const float* __restrict__ in, unsigned short* __restrict__ A){
    int idx = blockIdx.x * 256 + threadIdx.x;
    if (idx >= NG * 5 * 512) return;
    int col = idx & 511, row = idx >> 9;
    int g = row / 5, t = row % 5;
    int i2 = col >> 3, k = col & 7;
    A[idx] = f2bf(in[(size_t)g * 768 + i2 * 12 + t + k]);
}
__global__ void post_enc3_k(const float* __restrict__ G, const float* __restrict__ b,
                            float* __restrict__ e3o, unsigned short* __restrict__ obf){
    int idx = blockIdx.x * 256 + threadIdx.x;
    if (idx >= NG * 640) return;
    int t = idx % 5, o = (idx / 5) & 127, g = idx / 640;
    float v = G[(size_t)(g * 5 + t) * 128 + o] + b[o];
    e3o[(size_t)g * 640 + o * 5 + t] = v;
    obf[(size_t)g * 640 + o * 5 + t] = f2bf(v);
}
__global__ void wshuf_k(const float* __restrict__ src, unsigned short* __restrict__ dst, int I, int O){
    int idx = blockIdx.x * 256 + threadIdx.x;
    if (idx >= I * O * 8) return;
    int o = idx / (I * 8), rem = idx % (I * 8);
    int i = rem >> 3, j = rem & 7;
    dst[idx] = f2bf(src[(size_t)(i * O + o) * 8 + j]);
}
__global__ void i2c_dec3_k(const float* __restrict__ e3o, unsigned short* __restrict__ A){
    int idx = blockIdx.x * 256 + threadIdx.x;
    if (idx >= NG * 12 * 1024) return;
    int col = idx & 1023, row = idx >> 10;
    int g = row / 12, t = row % 12;
    int i2 = col >> 3, j = col & 7;
    int tt = t - j;
    A[idx] = (tt >= 0 && tt < 5) ? f2bf(e3o[(size_t)g * 640 + i2 * 5 + tt]) : (unsigned short)0;
}
__global__ void post_dec3_k(const float* __restrict__ G, const float* __restrict__ b,
                            const float* __restrict__ bng, const float* __restrict__ bnb,
                            float* __restrict__ dd3){
    int idx = blockIdx.x * 256 + threadIdx.x;
    if (idx >= NG * 768) return;
    int t = idx % 12, o = (idx / 12) & 63, g = idx / 768;
    float v = (G[(size_t)(g * 12 + t) * 64 + o] + b[o]) * bng[o] * BN_SCALE + bnb[o];
    dd3[(size_t)g * 768 + o * 12 + t] = v > 0.f ? v : 0.01f * v;
}
__global__ void i2c_dec2_k(const float* __restrict__ dd3, unsigned short* __restrict__ A){
    int idx = blockIdx.x * 256 + threadIdx.x;
    if (idx >= NG * 91 * 512) return;
    int col = idx & 511, row = idx >> 9;
    int g = row / 91, t = row % 91;
    int i2 = col >> 3, j = col & 7;
    int tt = t - j;
    A[idx] = (tt >= 0 && tt < 84) ? f2bf(dd3[(size_t)g * 768 + i2 * 12 + tt / 7]) : (unsigned short)0;
}
__global__ void post_dec2_k(const float* __restrict__ G, const float* __restrict__ b,
                            const float* __restrict__ bng, const float* __restrict__ bnb,
                            float* __restrict__ dd2){
    int idx = blockIdx.x * 256 + threadIdx.x;
    if (idx >= NG * 2912) return;
    int t = idx % 91, o = (idx / 91) & 31, g = idx / 2912;
    float v = (G[(size_t)(g * 91 + t) * 32 + o] + b[o]) * bng[o] * BN_SCALE + bnb[o];
    dd2[(size_t)g * 2912 + o * 91 + t] = v > 0.f ? v : 0.01f * v;
}

// dec1: (NG,735); grid (NG,3) t-chunks of 245; dd2 (32x91) + w (32x8) in LDS
__global__ __launch_bounds__(256) void dec1_b(const float* __restrict__ dd2, const float* __restrict__ w,
                                              const float* __restrict__ bias, float* __restrict__ out)
{
    __shared__ float d2s[32][91];
    __shared__ float ws[256];
    const int g = blockIdx.x, tid = threadIdx.x;
    const int t0 = (int)blockIdx.y * 245;
    for (int i = tid; i < 32 * 91; i += 256) d2s[i / 91][i % 91] = dd2[(size_t)g * 2912 + i];
    ws[tid] = w[tid];
    __syncthreads();
    if (tid < 245){
        int t = t0 + tid;
        int id8[8]; bool ok[8];
#pragma unroll
        for (int j = 0; j < 8; ++j){
            int tt = t - j;
            ok[j] = (tt >= 0 && tt < 728);
            id8[j] = ok[j] ? (tt >> 3) : 0;
        }
        float s = bias[0];
        for (int i2 = 0; i2 < 32; ++i2){
            const float* wp = ws + i2 * 8;
            float a = 0.f;
#pragma unroll
            for (int j = 0; j < 8; ++j) if (ok[j]) a += d2s[i2][id8[j]] * wp[j];
            s += a;
        }
        out[(size_t)g * 735 + t] = s;
    }
}

__global__ void concat_xc_k(const float* __restrict__ xd, const float* __restrict__ z,
                            unsigned short* __restrict__ xcb)
{
    int idx = blockIdx.x * 256 + threadIdx.x;
    if (idx >= NG * 256) return;
    int g = idx >> 8, c = idx & 255;
    xcb[idx] = f2bf((c < 128) ? xd[g * 128 + c] : z[g * 128 + (c - 128)]);
}

// ---------------- host-side orchestration ----------------
extern "C" void kernel_launch(void* const* d_in, const int* in_sizes, int n_in,
                              void* d_out, int out_size, void* d_ws, size_t ws_size,
                              hipStream_t stream)
{
    (void)in_sizes; (void)n_in; (void)out_size;

    // ---- input pointers: setup_inputs() DICT order (t1 4-15, t2 16-27, gat 28-31) ----
    const float* x      = (const float*)d_in[0];
    const int*   ei     = (const int*)  d_in[1];
    const int*   batch  = (const int*)  d_in[2];
    const float* tmut   = (const float*)d_in[3];
    const float* t1w[12]; for (int i = 0; i < 12; ++i) t1w[i] = (const float*)d_in[4 + i];
    const float* t2w[12]; for (int i = 0; i < 12; ++i) t2w[i] = (const float*)d_in[16 + i];
    const float* gat_w    = (const float*)d_in[28];
    const float* gat_asrc = (const float*)d_in[29];
    const float* gat_adst = (const float*)d_in[30];
    const float* gat_b    = (const float*)d_in[31];
    const float* gcn_w  = (const float*)d_in[32];
    const float* gcn_b  = (const float*)d_in[33];
    const float* fcg1_w = (const float*)d_in[34];
    const float* fcg1_b = (const float*)d_in[35];
    const float* fcg2_w = (const float*)d_in[36];
    const float* fcg2_b = (const float*)d_in[37];
    const float* e1_w = (const float*)d_in[38]; const float* e1_b = (const float*)d_in[39];
    const float* bn1_g = (const float*)d_in[40]; const float* bn1_b = (const float*)d_in[41];
    const float* e2_w = (const float*)d_in[42]; const float* e2_b = (const float*)d_in[43];
    const float* bn2_g = (const float*)d_in[44]; const float* bn2_b = (const float*)d_in[45];
    const float* e3_w = (const float*)d_in[46]; const float* e3_b = (const float*)d_in[47];
    const float* enc_w = (const float*)d_in[48]; const float* enc_b = (const float*)d_in[49];
    const float* d3_w = (const float*)d_in[50]; const float* d3_b = (const float*)d_in[51];
    const float* dbn2_g = (const float*)d_in[52]; const float* dbn2_b = (const float*)d_in[53];
    const float* d2_w = (const float*)d_in[54]; const float* d2_b = (const float*)d_in[55];
    const float* dbn1_g = (const float*)d_in[56]; const float* dbn1_b = (const float*)d_in[57];
    const float* d1_w = (const float*)d_in[58]; const float* d1_b = (const float*)d_in[59];
    const float* fc1_w = (const float*)d_in[60]; const float* fc1_b = (const float*)d_in[61];
    const float* fc2_w = (const float*)d_in[62]; const float* fc2_b = (const float*)d_in[63];
    const float* outw = (const float*)d_in[64]; const float* outb = (const float*)d_in[65];

    // ---- workspace carve ----
    float *A1, *A2, *A3, *A4, *X1f, *QBIASf;
    unsigned short *XB, *QKVb, *Vt, *HbPb;
    unsigned short *WQKVb, *WOUTb, *WL1b, *WL2b, *WGb, *WGCNb, *WFCG1b, *WFCG2b,
                   *WENCb, *WFC1b, *WFC2b, *WOUTWb, *XD16, *FG1b, *E3b, *XCb, *FH1b, *FH2b, *Wcvb;
    float *asrc, *adst, *alpha, *denom, *dis, *c1p, *c2p, *e3o, *zz, *dd3, *dd2b;
    unsigned *amax; int *deg, *seg, *csr_off, *csr_cur, *csr_s, *csr_e;

    auto carve = [&](long long RB) -> size_t {
        char* wp_ = (char*)d_ws;
        auto alc = [&](size_t bytes) -> char* {
            char* p = wp_;
            wp_ += (bytes + 255) & ~(size_t)255;
            return p;
        };
        A1 = (float*)alc((size_t)NN * DD2 * 4);
        A2 = (float*)alc((size_t)NN * DD2 * 4);
        A3 = (float*)alc((size_t)NN * DD2 * 4);
        A4 = (float*)alc((size_t)NN * 800 * 4);   // attention out + sum column (ld Ep)
        X1f = (float*)alc((size_t)NN * FXD_ * 4);
        XB   = (unsigned short*)alc((size_t)NN * 800 * 2);
        QKVb = (unsigned short*)alc((size_t)NN * 2400 * 2);
        Vt   = (unsigned short*)alc((size_t)801 * NN * 2);   // +1 ones-row
        size_t hb = (size_t)NN * FFD * 2, pb = (size_t)RB * NN * 2;
        HbPb = (unsigned short*)alc(hb > pb ? hb : pb);   // FF hidden / attention P / AE im2col
        WQKVb = (unsigned short*)alc((size_t)2400 * 800 * 2);
        QBIASf= (float*)alc((size_t)2400 * 4);
        WOUTb = (unsigned short*)alc((size_t)780 * 800 * 2);
        WL1b  = (unsigned short*)alc((size_t)2048 * 800 * 2);
        WL2b  = (unsigned short*)alc((size_t)780 * 2048 * 2);
        WGb   = (unsigned short*)alc((size_t)780 * 96 * 2);
        WGCNb = (unsigned short*)alc((size_t)780 * 800 * 2);
        WFCG1b= (unsigned short*)alc((size_t)1500 * 1568 * 2);
        WFCG2b= (unsigned short*)alc((size_t)128 * 1504 * 2);
        WENCb = (unsigned short*)alc((size_t)128 * 640 * 2);
        WFC1b = (unsigned short*)alc((size_t)1024 * 256 * 2);
        WFC2b = (unsigned short*)alc((size_t)128 * 1024 * 2);
        WOUTWb= (unsigned short*)alc((size_t)128 * 2);
        Wcvb  = (unsigned short*)alc((size_t)128 * 1024 * 2);   // AE reshaped weights
        XD16  = (unsigned short*)alc((size_t)NG * 1568 * 2);
        FG1b  = (unsigned short*)alc((size_t)NG * 1504 * 2);
        E3b   = (unsigned short*)alc((size_t)NG * 640 * 2);
        XCb   = (unsigned short*)alc((size_t)NG * 256 * 2);
        FH1b  = (unsigned short*)alc((size_t)NG * 1024 * 2);
        FH2b  = (unsigned short*)alc((size_t)NG * 128 * 2);
        asrc = (float*)alc((size_t)NN * NH * 4);
        adst = (float*)alc((size_t)NN * NH * 4);
        alpha= (float*)alc((size_t)NETOT * NH * 4);
        amax = (unsigned*)alc((size_t)NN * NH * 4);
        denom= (float*)alc((size_t)NN * NH * 4);
        deg  = (int*)alc((size_t)NN * 4);
        dis  = (float*)alc((size_t)NN * 4);
        seg  = (int*)alc((size_t)(NG + 1) * 4);
        csr_off = (int*)alc((size_t)(NN + 1) * 4);
        csr_cur = (int*)alc((size_t)NN * 4);
        csr_s   = (int*)alc((size_t)NETOT * 4);
        csr_e   = (int*)alc((size_t)NETOT * 4);
        c1p  = (float*)alc((size_t)NG * 32 * 91 * 4);
        c2p  = (float*)alc((size_t)NG * 64 * 12 * 4);
        e3o  = (float*)alc((size_t)NG * 128 * 5 * 4);
        zz   = (float*)alc((size_t)NG * 128 * 4);
        dd3  = (float*)alc((size_t)NG * 64 * 12 * 4);
        dd2b = (float*)alc((size_t)NG * 32 * 91 * 4);
        return (size_t)(wp_ - (char*)d_ws);
    };

    long long RB = 512;
    const long long cands[3] = {2048, 1024, 512};
    for (int i = 0; i < 3; ++i){ if (carve(cands[i]) <= ws_size){ RB = cands[i]; break; } }
    carve(RB);   // commit chosen layout
    unsigned short* Pb = HbPb;
    unsigned short* AIM = HbPb;      // AE im2col arena (HbPb dead after t2)

    float* out0   = (float*)d_out;                 // (256,1)
    float* xd_out = (float*)d_out + NG;            // (256,128)
    float* decode = (float*)d_out + NG + NG * 128; // (256,735)

    auto cvt = [&](const float* src, unsigned short* dst, int R, int C, int lds_, int ldd){
        long long n = (long long)R * ldd;
        cvt_pad_k<<<cdiv_i(n, 256), 256, 0, stream>>>(src, dst, n, C, lds_, ldd);
    };
    auto zero16 = [&](unsigned short* p, long long nshorts){
        fill_u32_k<<<cdiv_i(nshorts / 2, 256), 256, 0, stream>>>((unsigned*)p, 0u, nshorts / 2);
    };
    auto zerof = [&](float* p, long long n){
        fill_f32_k<<<cdiv_i(n, 256), 256, 0, stream>>>(p, 0.f, n);
    };

    // ---- transformer (shared for t1/t2); xin_bf = XB (padded Ep), residual xin f32 ----
    auto run_tf = [&](const float* xin, const float* const* W, float* outp, int E){
        const int Ep = pad32(E), E3p = 3 * Ep;
        float scale = (float)(1.0 / sqrt((double)E));
        // merged qkv: weights 3*Ep rows (pad rows zero), bias padded
        zero16(WQKVb, (long long)E3p * Ep);
        for (int s = 0; s < 3; ++s)
            cvt(W[0] + (size_t)s * E * E, WQKVb + (size_t)s * Ep * Ep, E, E, E, Ep);
        qkv_bias_k<<<cdiv_i(E3p, 256), 256, 0, stream>>>(W[1], QBIASf, E, Ep);
        mgemm<1,0,1,0,128>(stream, XB, WQKVb, QBIASf, QKVb, NN, E3p, Ep, Ep, Ep, E3p, 0);
        // V^T via bf16 transpose of the v-part; row E = ones (softmax denominator column)
        {
            dim3 g(cdiv_i(E, 32), cdiv_i(NN, 32));
            tr_bf16_k<<<g, 256, 0, stream>>>(QKVb + 2 * Ep, Vt, NN, E, E3p, NN);
            fill_u32_k<<<cdiv_i(NN / 2, 256), 256, 0, stream>>>((unsigned*)(Vt + (size_t)E * NN),
                                                                0x3F803F80u, NN / 2);   // bf16 1.0 pairs
        }
        zerof(A4, (long long)NN * Ep);
        if (E == FXD_){
            // fused flash attention (no P materialization)
            dim3 g(NN / 128, 8);
            flash_t1_k<<<g, 256, 0, stream>>>(QKVb, Vt, A4, scale);
        } else {
            // t2: S+exp (bf16, into Pb) -> PV with ones-col (split-K -> A4, ld Ep)
            for (long long r0 = 0; r0 < NN; r0 += RB){
                mgemm<1,3,1,0,128>(stream, QKVb + (size_t)r0 * E3p, QKVb + Ep, nullptr, Pb,
                                   (int)RB, NN, Ep, E3p, E3p, NN, 1, scale);   // exp epilogue
                mgemm<0,0,4,0,64>(stream, Pb, Vt, nullptr, A4 + (size_t)r0 * Ep,
                                  (int)RB, E + 1, NN, NN, NN, Ep, 0);
            }
        }
        norm_cvt_k<<<cdiv_i((long long)NN * Ep, 256), 256, 0, stream>>>(A4, XB, E, Ep);
        // proj + LN1
        cvt(W[2], WOUTb, E, E, E, Ep);
        mgemm<0,0,1,0,64>(stream, XB, WOUTb, W[3], A2, NN, E, Ep, Ep, Ep, E, 0);
        add_ln_k<<<NN, 256, 0, stream>>>(xin, A2, nullptr, W[4], W[5], A3, XB, E, Ep);
        // FF1 (relu, bf16) -> FF2 -> LN2
        cvt(W[6], WL1b, FFD, E, E, Ep);
        mgemm<1,1,1,0,128>(stream, XB, WL1b, W[7], HbPb, NN, FFD, Ep, Ep, Ep, FFD, 0);
        cvt(W[8], WL2b, E, FFD, FFD, FFD);
        mgemm<0,0,1,0,64>(stream, HbPb, WL2b, W[9], A2, NN, E, FFD, FFD, FFD, E, 0);
        add_ln_k<<<NN, 256, 0, stream>>>(A3, A2, nullptr, W[10], W[11], outp, XB, E, Ep);
    };

    // ================= t1 transformer (E=78) =================
    cvt(x, XB, NN, FXD_, FXD_, 96);
    run_tf(x, t1w, X1f, FXD_);          // leaves XB = t1 out (ld 96)

    // ================= graph structure: deg + CSR + segment bounds =================
    fill_u32_k<<<cdiv_i(NN, 256), 256, 0, stream>>>((unsigned*)deg, 0u, NN);
    deg_count_k<<<cdiv_i(NETOT, 256), 256, 0, stream>>>(ei, deg);
    csr_off_k<<<1, 256, 0, stream>>>(deg, csr_off, csr_cur);
    csr_fill_k<<<cdiv_i(NETOT, 256), 256, 0, stream>>>(ei, csr_cur, csr_s, csr_e);
    seg_start_k<<<cdiv_i(NN, 256), 256, 0, stream>>>(batch, seg);

    // ================= GAT =================
    cvt(gat_w, WGb, DD2, FXD_, FXD_, 96);
    mgemm<0,0,1,0,64>(stream, XB, WGb, nullptr, A2, NN, DD2, 96, 96, 96, DD2, 0);   // hfeat
    gat_srcdst_k<<<cdiv_i((long long)NN * NH, 256), 256, 0, stream>>>(A2, gat_asrc, gat_adst, asrc, adst);
    fill_u32_k<<<cdiv_i((long long)NN * NH, 256), 256, 0, stream>>>(amax, 0x007FFFFFu, (long long)NN * NH);
    zerof(denom, (long long)NN * NH);
    gat_alpha_k<<<cdiv_i((long long)NETOT * NH, 256), 256, 0, stream>>>(ei, asrc, adst, alpha, amax);
    gat_expsum_k<<<cdiv_i((long long)NETOT * NH, 256), 256, 0, stream>>>(ei, alpha, amax, denom);
    gat_gather_k<<<NN, 256, 0, stream>>>(csr_off, csr_s, csr_e, alpha, denom, A2, A1);
    bias_relu_k<<<cdiv_i((long long)NN * 800, 256), 256, 0, stream>>>(A1, gat_b, XB, NN, DD2, 800);

    // ================= t2 transformer (E=780) =================
    run_tf(A1, t2w, A1, DD2);           // leaves XB = t2 out (ld 800)

    // ================= GCN =================
    dis_k<<<cdiv_i(NN, 256), 256, 0, stream>>>(deg, dis);
    cvt(gcn_w, WGCNb, DD2, DD2, DD2, 800);
    mgemm<0,0,1,0,64>(stream, XB, WGCNb, nullptr, A2, NN, DD2, 800, 800, 800, DD2, 0); // xw
    gcn_gather_k<<<NN, 256, 0, stream>>>(csr_off, csr_s, dis, A2, A3);
    bias_relu_k<<<cdiv_i((long long)NN * DD2, 256), 256, 0, stream>>>(A3, gcn_b, nullptr, NN, DD2, DD2);

    // ================= pooling (segment gather) + graph head =================
    pool_seg_k<<<NG, 256, 0, stream>>>(A3, seg, XD16);
    cvt(fcg1_w, WFCG1b, 1500, 1560, 1560, 1568);
    zerof(A2, (long long)NG * 1500);
    mgemm<0,0,8,0,64>(stream, XD16, WFCG1b, nullptr, A2, NG, 1500, 1568, 1568, 1568, 1500, 0);
    bias_relu_k<<<cdiv_i((long long)NG * 1504, 256), 256, 0, stream>>>(A2, fcg1_b, FG1b, NG, 1500, 1504);
    cvt(fcg2_w, WFCG2b, 128, 1500, 1500, 1504);
    zerof(xd_out, (long long)NG * 128);
    mgemm<0,0,16,0,128>(stream, FG1b, WFCG2b, nullptr, xd_out, NG, 128, 1504, 1504, 1504, 128, 0);
    bias_add_k<<<cdiv_i((long long)NG * 128, 256), 256, 0, stream>>>(xd_out, fcg2_b, (long long)NG * 128, 128); // OUTPUT 1

    // ================= conv encoder (GEMM-ified; AIM=HbPb arena, Gout=A2) =================
    enc1_b<<<NG, 256, 0, stream>>>(tmut, e1_w, e1_b, bn1_g, bn1_b, c1p);
    // enc2: (21504 x 256) x (64 x 256)^T
    i2c_enc2_k<<<cdiv_i((long long)NG * 84 * 256, 256), 256, 0, stream>>>(c1p, AIM);
    cvt(e2_w, Wcvb, 64, 256, 256, 256);
    mgemm<0,0,1,0,64>(stream, AIM, Wcvb, nullptr, A2, NG * 84, 64, 256, 256, 256, 64, 0);
    post_enc2_k<<<cdiv_i((long long)NG * 768, 256), 256, 0, stream>>>(A2, e2_b, bn2_g, bn2_b, c2p);
    // enc3: (1280 x 512) x (128 x 512)^T, split-K 4
    i2c_enc3_k<<<cdiv_i((long long)NG * 5 * 512, 256), 256, 0, stream>>>(c2p, AIM);
    cvt(e3_w, Wcvb, 128, 512, 512, 512);
    zerof(A2, (long long)NG * 5 * 128);
    mgemm<0,0,4,0,128>(stream, AIM, Wcvb, nullptr, A2, NG * 5, 128, 512, 512, 512, 128, 0);
    post_enc3_k<<<cdiv_i((long long)NG * 640, 256), 256, 0, stream>>>(A2, e3_b, e3o, E3b);
    // z
    cvt(enc_w, WENCb, 128, 640, 640, 640);
    mgemm<0,0,1,0,128>(stream, E3b, WENCb, enc_b, zz, NG, 128, 640, 640, 640, 128, 0);

    // ================= conv decoder (GEMM-ified) =================
    // dec3: (3072 x 1024) x (64 x 1024)^T, split-K 4
    wshuf_k<<<cdiv_i(128 * 64 * 8, 256), 256, 0, stream>>>(d3_w, Wcvb, 128, 64);
    i2c_dec3_k<<<cdiv_i((long long)NG * 12 * 1024, 256), 256, 0, stream>>>(e3o, AIM);
    zerof(A2, (long long)NG * 12 * 64);
    mgemm<0,0,4,0,64>(stream, AIM, Wcvb, nullptr, A2, NG * 12, 64, 1024, 1024, 1024, 64, 0);
    post_dec3_k<<<cdiv_i((long long)NG * 768, 256), 256, 0, stream>>>(A2, d3_b, dbn2_g, dbn2_b, dd3);
    // dec2: (23296 x 512) x (32 x 512)^T
    wshuf_k<<<cdiv_i(64 * 32 * 8, 256), 256, 0, stream>>>(d2_w, Wcvb, 64, 32);
    i2c_dec2_k<<<cdiv_i((long long)NG * 91 * 512, 256), 256, 0, stream>>>(dd3, AIM);
    mgemm<0,0,1,0,64>(stream, AIM, Wcvb, nullptr, A2, NG * 91, 32, 512, 512, 512, 32, 0);
    post_dec2_k<<<cdiv_i((long long)NG * 2912, 256), 256, 0, stream>>>(A2, d2_b, dbn1_g, dbn1_b, dd2b);
    // dec1 (LDS kernel, 768 blocks)
    { dim3 g(NG, 3); dec1_b<<<g, 256, 0, stream>>>(dd2b, d1_w, d1_b, decode); }   // OUTPUT 2

    // ================= final head =================
    concat_xc_k<<<cdiv_i((long long)NG * 256, 256), 256, 0, stream>>>(xd_out, zz, XCb);
    cvt(fc1_w, WFC1b, 1024, 256, 256, 256);
    mgemm<1,1,1,0,128>(stream, XCb, WFC1b, fc1_b, FH1b, NG, 1024, 256, 256, 256, 1024, 0);
    cvt(fc2_w, WFC2b, 128, 1024, 1024, 1024);
    zerof(A3, (long long)NG * 128);
    mgemm<0,0,8,0,128>(stream, FH1b, WFC2b, nullptr, A3, NG, 128, 1024, 1024, 1024, 128, 0);
    bias_relu_k<<<cdiv_i((long long)NG * 128, 256), 256, 0, stream>>>(A3, fc2_b, FH2b, NG, 128, 128);
    cvt(outw, WOUTWb, 1, 128, 128, 128);
    mgemm<0,2,1,0,64>(stream, FH2b, WOUTWb, outb, out0, NG, 1, 128, 128, 128, 1, 0);   // OUTPUT 0 (sigmoid)
}

// Round 15
// 1532.354 us; speedup vs baseline: 1.7034x; 1.0301x over previous
//
#include <hip/hip_runtime.h>
#include <math.h>

// Problem constants
#define NN     8192      // nodes
#define NEDGE  32768     // edges (before self loops)
#define NETOT  40960     // edges + self loops
#define NG     256       // graphs
#define FXD_   78
#define NH     10        // heads
#define DD2    780       // FXD*HEADS
#define FFD    2048
#define LMUT   735

static inline int cdiv_i(long long a, int b){ return (int)((a + (long long)b - 1) / b); }
static inline int pad32(int x){ return (x + 31) & ~31; }

typedef __attribute__((ext_vector_type(8))) short bf16x8;
typedef __attribute__((ext_vector_type(4))) float f32x4;

static __device__ __forceinline__ unsigned short f2bf(float f){
    unsigned u = __float_as_uint(f);
    u += 0x7FFFu + ((u >> 16) & 1u);
    return (unsigned short)(u >> 16);
}

// async global->LDS, 16B per lane; lds dest is wave-uniform base + lane*16
static __device__ __forceinline__ void gload16(const void* g, void* l){
    __builtin_amdgcn_global_load_lds((const __attribute__((address_space(1))) void*)g,
                                     (__attribute__((address_space(3))) void*)l, 16, 0, 0);
}

// ---------------- fills ----------------
__global__ void fill_f32_k(float* __restrict__ p, float v, long long n){
    long long i = (long long)blockIdx.x * 256 + threadIdx.x;
    if (i < n) p[i] = v;
}
__global__ void fill_u32_k(unsigned* __restrict__ p, unsigned v, long long n){
    long long i = (long long)blockIdx.x * 256 + threadIdx.x;
    if (i < n) p[i] = v;
}

// ---------------- f32 -> bf16 convert with K-padding ----------------
__global__ void cvt_pad_k(const float* __restrict__ src, unsigned short* __restrict__ dst,
                          long long n /*R*ldd*/, int C, int lds_, int ldd)
{
    long long i = (long long)blockIdx.x * 256 + threadIdx.x;
    if (i >= n) return;
    int r = (int)(i / ldd), c = (int)(i % ldd);
    dst[i] = (c < C) ? f2bf(src[(size_t)r * lds_ + c]) : (unsigned short)0;
}

// normalize by sum-column + cvt: XB[r][c] = bf16(A4[r][c]/A4[r][E]), pads 0
__global__ void norm_cvt_k(const float* __restrict__ A4, unsigned short* __restrict__ XB,
                           int E, int Ep)
{
    long long i = (long long)blockIdx.x * 256 + threadIdx.x;
    if (i >= (long long)NN * Ep) return;
    int r = (int)(i / Ep), c = (int)(i % Ep);
    XB[i] = (c < E) ? f2bf(A4[(size_t)r * Ep + c] / A4[(size_t)r * Ep + E]) : (unsigned short)0;
}

// bf16 transpose: dst[c][r] = src[r][c]
__global__ void tr_bf16_k(const unsigned short* __restrict__ src, unsigned short* __restrict__ dst,
                          int R, int C, int lds_, int ldd)
{
    __shared__ unsigned short t[32][33];
    int cb = blockIdx.x * 32, rb = blockIdx.y * 32;
    int tx = threadIdx.x & 31, ty = threadIdx.x >> 5;   // 32 x 8
#pragma unroll
    for (int i = 0; i < 4; ++i){
        int r = rb + ty + i * 8, c = cb + tx;
        t[ty + i * 8][tx] = (r < R && c < C) ? src[(size_t)r * lds_ + c] : (unsigned short)0;
    }
    __syncthreads();
#pragma unroll
    for (int i = 0; i < 4; ++i){
        int dr = cb + ty + i * 8, dc = rb + tx;
        if (dr < C && dc < R) dst[(size_t)dr * ldd + dc] = t[tx][ty + i * 8];
    }
}

// padded qkv bias: out[s*Ep+c] = (c<E) ? b3[s*E+c] : 0, s=0..2
__global__ void qkv_bias_k(const float* __restrict__ b3, float* __restrict__ out, int E, int Ep)
{
    int idx = blockIdx.x * 256 + threadIdx.x;
    if (idx >= 3 * Ep) return;
    int s = idx / Ep, c = idx % Ep;
    out[idx] = (c < E) ? b3[s * E + c] : 0.f;
}

__global__ void bias_add_k(float* __restrict__ X, const float* __restrict__ b, long long n, int cols)
{
    long long i = (long long)blockIdx.x * 256 + threadIdx.x;
    if (i < n) X[i] += b[i % cols];
}

// ---------------- MFMA bf16 GEMM: 2-phase dbuf + XCD swizzle + BN=64/128 tiles ----------------
// ACT: 0 none, 1 relu, 2 sigmoid, 3 exp(v*escale)
template<int OUTC, int ACT, int SPLITK, int BROW, int BN>
__global__ __launch_bounds__(256) void mgemm_k(
    const unsigned short* __restrict__ A, const unsigned short* __restrict__ B,
    const float* __restrict__ bias, void* __restrict__ Cv,
    int M, int N, int Kp, int lda, int ldb, int ldc, int swz, float escale)
{
    constexpr int NFJ   = BN / 32;        // col frags per wave
    constexpr int TILEA = 128 * 32;
    constexpr int TILEB = BN * 32;
    __shared__ unsigned short As[2 * TILEA];
    __shared__ unsigned short Bs[2 * TILEB];
    const int tid = threadIdx.x;
    const int lane = tid & 63, wid = tid >> 6;
    const int r16 = lane & 15, q = lane >> 4;
    const int wr = (wid >> 1) * 64, wc = (wid & 1) * (BN / 2);

    // bijective XCD-chunked remap (m204)
    const int gx = gridDim.x, gy = gridDim.y;
    const int nwg = gx * gy;
    int orig = swz ? ((int)blockIdx.x * gy + (int)blockIdx.y)
                   : ((int)blockIdx.y * gx + (int)blockIdx.x);
    int q8 = nwg >> 3, r8 = nwg & 7;
    int xcd = orig & 7, kk8 = orig >> 3;
    int wgid = (xcd < r8 ? xcd * (q8 + 1) : r8 * (q8 + 1) + (xcd - r8) * q8) + kk8;
    int bx, by;
    if (swz){ by = wgid % gy; bx = wgid / gy; }
    else    { bx = wgid % gx; by = wgid / gx; }
    const int row0 = by * 128, col0 = bx * BN;

    int kbeg = 0, kend = Kp;
    if (SPLITK > 1){
        int nt_ = Kp >> 5, cpt = (nt_ + SPLITK - 1) / SPLITK;
        kbeg = (int)blockIdx.z * cpt * 32;
        kend = min(Kp, kbeg + cpt * 32);
    }

    // A staging: 512 chunks of 16B; lane handles chunk c0 and c0+64
    const int c0 = wid * 128 + lane;
    const int r0a = c0 >> 2, k0a = (c0 & 3) << 3;
    const size_t gA0 = (size_t)min(row0 + r0a, M - 1) * lda + k0a;
    const size_t gA1 = (size_t)min(row0 + r0a + 16, M - 1) * lda + k0a;
    unsigned short* lA = As + wid * 1024;
    // B staging
    size_t gB0 = 0, gB1 = 0;
    unsigned short* lB;
    if (BN == 128){
        gB0 = (size_t)min(col0 + r0a, N - 1) * ldb + k0a;
        gB1 = (size_t)min(col0 + r0a + 16, N - 1) * ldb + k0a;
        lB = Bs + wid * 1024;
    } else {               // BN=64: 256 chunks, 1 per lane
        const int cb = wid * 64 + lane;
        const int rb_ = cb >> 2, kb_ = (cb & 3) << 3;
        gB0 = (size_t)min(col0 + rb_, N - 1) * ldb + kb_;
        lB = Bs + wid * 512;
    }

    f32x4 acc[4][NFJ];
#pragma unroll
    for (int i = 0; i < 4; ++i)
#pragma unroll
        for (int j = 0; j < NFJ; ++j){ f32x4 z = {0.f, 0.f, 0.f, 0.f}; acc[i][j] = z; }

    const int nt = (kend - kbeg) >> 5;
    if (nt > 0){
        gload16(A + gA0 + kbeg, lA);
        gload16(A + gA1 + kbeg, lA + 512);
        gload16(B + gB0 + kbeg, lB);
        if (BN == 128) gload16(B + gB1 + kbeg, lB + 512);
        __syncthreads();
        int cur = 0;
        for (int t = 0; t < nt; ++t){
            const int k0 = kbeg + (t << 5);
            if (t + 1 < nt){                  // stage next tile BEFORE compute (overlap)
                const int kn = k0 + 32, nb = cur ^ 1;
                gload16(A + gA0 + kn, lA + nb * TILEA);
                gload16(A + gA1 + kn, lA + nb * TILEA + 512);
                gload16(B + gB0 + kn, lB + nb * TILEB);
                if (BN == 128) gload16(B + gB1 + kn, lB + nb * TILEB + 512);
            }
            const unsigned short* Ab = As + cur * TILEA;
            const unsigned short* Bb = Bs + cur * TILEB;
            bf16x8 af[4], bfv[NFJ];
#pragma unroll
            for (int f = 0; f < 4; ++f)
                af[f] = *(const bf16x8*)(Ab + (size_t)(wr + f * 16 + r16) * 32 + (q << 3));
#pragma unroll
            for (int f = 0; f < NFJ; ++f)
                bfv[f] = *(const bf16x8*)(Bb + (size_t)(wc + f * 16 + r16) * 32 + (q << 3));
#pragma unroll
            for (int fi = 0; fi < 4; ++fi)
#pragma unroll
                for (int fj = 0; fj < NFJ; ++fj)
                    acc[fi][fj] = __builtin_amdgcn_mfma_f32_16x16x32_bf16(af[fi], bfv[fj], acc[fi][fj], 0, 0, 0);
            __syncthreads();
            cur ^= 1;
        }
    }

#pragma unroll
    for (int fi = 0; fi < 4; ++fi){
#pragma unroll
        for (int j = 0; j < 4; ++j){
            int r = row0 + wr + fi * 16 + q * 4 + j;   // C/D: row=(lane>>4)*4+reg
            if (r >= M) continue;
#pragma unroll
            for (int fj = 0; fj < NFJ; ++fj){
                int c = col0 + wc + fj * 16 + r16;     // C/D: col=lane&15
                if (c >= N) continue;
                float v = acc[fi][fj][j];
                if (SPLITK > 1){
                    atomicAdd((float*)Cv + (size_t)r * ldc + c, v);
                } else {
                    if (bias) v += BROW ? bias[r] : bias[c];
                    if (ACT == 1) v = fmaxf(v, 0.f);
                    if (ACT == 2) v = 1.f / (1.f + __expf(-v));
                    if (ACT == 3) v = __expf(v * escale);
                    if (OUTC == 0) ((float*)Cv)[(size_t)r * ldc + c] = v;
                    else ((unsigned short*)Cv)[(size_t)r * ldc + c] = f2bf(v);
                }
            }
        }
    }
}

template<int OUTC, int ACT, int SPLITK, int BROW, int BN>
static void mgemm(hipStream_t s, const unsigned short* A, const unsigned short* B,
                  const float* bias, void* C, int M, int N, int Kp,
                  int lda, int ldb, int ldc, int swz, float escale = 1.f)
{
    dim3 g(cdiv_i(N, BN), cdiv_i(M, 128), SPLITK);
    mgemm_k<OUTC, ACT, SPLITK, BROW, BN><<<g, 256, 0, s>>>(A, B, bias, C, M, N, Kp, lda, ldb, ldc, swz, escale);
}

// ---------------- fused flash attention for t1 (E=78, Ep=96, E3p=288) ----------------
// grid (NN/128, 8): block = 128 q-rows x 1024-k chunk; atomic f32 partials into A4[NN][96].
// Math identical to materialized path: P = bf16(exp(s*scale)); col 78 of Vt = ones (denominator).
#define E3P1 288
__global__ __launch_bounds__(256) void flash_t1_k(
    const unsigned short* __restrict__ QKV,   // [NN][288]: q@0, k@96, v@192 (pads zero)
    const unsigned short* __restrict__ Vt,    // [*][NN]: rows 0..77 V^T, row 78 ones
    float* __restrict__ A4, float scale)      // [NN][96] pre-zeroed
{
    __shared__ unsigned short Ps[128 * 128];  // 32 KB, XOR-swizzled
    __shared__ unsigned short KV[128 * 96];   // 24 KB: K-tile [128][96] then V-tile [96][128]
    const int tid = threadIdx.x, lane = tid & 63, wid = tid >> 6;
    const int r16 = lane & 15, q = lane >> 4;
    const int wr = (wid >> 1) * 64;      // row base within 128 (S rows and out rows)
    const int sc = (wid & 1) * 64;       // S col base
    const int oc = (wid & 1) * 48;       // out col base (96/2)
    const int qb = (int)blockIdx.x * 128;
    const int kb = (int)blockIdx.y * 1024;

    // Q fragments: rows qb+wr.., K-dim 96 = 3 chunks of 32 (one-time global vector loads)
    bf16x8 qa[4][3];
#pragma unroll
    for (int mi = 0; mi < 4; ++mi)
#pragma unroll
        for (int kc = 0; kc < 3; ++kc)
            qa[mi][kc] = *(const bf16x8*)(QKV + (size_t)(qb + wr + mi * 16 + r16) * E3P1 + kc * 32 + (q << 3));

    f32x4 acco[4][3];
#pragma unroll
    for (int i = 0; i < 4; ++i)
#pragma unroll
        for (int j = 0; j < 3; ++j){ f32x4 z = {0.f, 0.f, 0.f, 0.f}; acco[i][j] = z; }

    for (int t = 0; t < 8; ++t){
        const int k0 = kb + t * 128;
        // load K-tile: KV[n][0..95] (row n = k index)
#pragma unroll
        for (int i = 0; i < 6; ++i){
            int id = tid + i * 256;                 // 0..1535, 12 chunks/row
            int row = id / 12, co = (id % 12) << 3;
            *(bf16x8*)(&KV[row * 96 + co]) =
                *(const bf16x8*)(QKV + (size_t)(k0 + row) * E3P1 + 96 + co);
        }
        __syncthreads();
        // S-tile: wave computes 64x64 at (wr, sc)
        f32x4 accs[4][4];
#pragma unroll
        for (int i = 0; i < 4; ++i)
#pragma unroll
            for (int j = 0; j < 4; ++j){ f32x4 z = {0.f, 0.f, 0.f, 0.f}; accs[i][j] = z; }
#pragma unroll
        for (int kc = 0; kc < 3; ++kc){
            bf16x8 bk[4];
#pragma unroll
            for (int nj = 0; nj < 4; ++nj)
                bk[nj] = *(const bf16x8*)(&KV[(sc + nj * 16 + r16) * 96 + kc * 32 + (q << 3)]);
#pragma unroll
            for (int mi = 0; mi < 4; ++mi)
#pragma unroll
                for (int nj = 0; nj < 4; ++nj)
                    accs[mi][nj] = __builtin_amdgcn_mfma_f32_16x16x32_bf16(qa[mi][kc], bk[nj], accs[mi][nj], 0, 0, 0);
        }
        __syncthreads();   // K-tile reads done before overwrite
        // exp -> Ps (swizzled); load V-tile [96][128] into KV (swizzled)
#pragma unroll
        for (int mi = 0; mi < 4; ++mi)
#pragma unroll
            for (int nj = 0; nj < 4; ++nj)
#pragma unroll
                for (int j = 0; j < 4; ++j){
                    int row = wr + mi * 16 + q * 4 + j;       // C/D: row=(lane>>4)*4+reg
                    int col = sc + nj * 16 + r16;             // C/D: col=lane&15
                    Ps[row * 128 + (col ^ ((row & 7) << 3))] = f2bf(__expf(accs[mi][nj][j] * scale));
                }
#pragma unroll
        for (int i = 0; i < 6; ++i){
            int id = tid + i * 256;                 // 16 chunks/row, 96 rows
            int row = id / 16, co = (id % 16) << 3;
            *(bf16x8*)(&KV[row * 128 + (co ^ ((row & 7) << 3))]) =
                *(const bf16x8*)(Vt + (size_t)row * NN + k0 + co);
        }
        __syncthreads();
        // PV: acco += P(128x128) x Vt-tile; wave out = 64 rows x 48 cols at (wr, oc)
#pragma unroll
        for (int ko = 0; ko < 4; ++ko){
            bf16x8 pa[4], vb[3];
#pragma unroll
            for (int mi = 0; mi < 4; ++mi){
                int row = wr + mi * 16 + r16;                 // A: row=lane&15
                pa[mi] = *(const bf16x8*)(&Ps[row * 128 + ((ko * 32 + (q << 3)) ^ ((row & 7) << 3))]);
            }
#pragma unroll
            for (int nj = 0; nj < 3; ++nj){
                int row = oc + nj * 16 + r16;                 // B: n=lane&15
                vb[nj] = *(const bf16x8*)(&KV[row * 128 + ((ko * 32 + (q << 3)) ^ ((row & 7) << 3))]);
            }
#pragma unroll
            for (int mi = 0; mi < 4; ++mi)
#pragma unroll
                for (int nj = 0; nj < 3; ++nj)
                    acco[mi][nj] = __builtin_amdgcn_mfma_f32_16x16x32_bf16(pa[mi], vb[nj], acco[mi][nj], 0, 0, 0);
        }
        __syncthreads();   // Ps / V reads done before next iter writes
    }
    // epilogue: atomic partials, cols <= E (col 78 = denominator)
#pragma unroll
    for (int mi = 0; mi < 4; ++mi)
#pragma unroll
        for (int j = 0; j < 4; ++j){
            int r = qb + wr + mi * 16 + q * 4 + j;
#pragma unroll
            for (int nj = 0; nj < 3; ++nj){
                int c = oc + nj * 16 + r16;
                if (c <= FXD_)
                    atomicAdd(A4 + (size_t)r * 96 + c, acco[mi][nj][j]);
            }
        }
}

// ---------------- residual add + layernorm ----------------
__global__ __launch_bounds__(256) void add_ln_k(
    const float* __restrict__ X, const float* __restrict__ Y, const float* __restrict__ ybias,
    const float* __restrict__ g, const float* __restrict__ b,
    float* __restrict__ out, unsigned short* __restrict__ obf, int E, int Ep)
{
    __shared__ float s1[256], s2[256];
    const int tid = threadIdx.x;
    long long base = (long long)blockIdx.x * E;
    float vals[4];
    float sum = 0.f, sq = 0.f;
    int i = 0;
    for (int c = tid; c < Ep; c += 256, ++i){
        float v = 0.f;
        if (c < E){
            v = X[base + c] + Y[base + c];
            if (ybias) v += ybias[c];
            sum += v; sq += v * v;
        }
        vals[i] = v;
    }
    s1[tid] = sum; s2[tid] = sq; __syncthreads();
    for (int s = 128; s; s >>= 1){
        if (tid < s){ s1[tid] += s1[tid + s]; s2[tid] += s2[tid + s]; }
        __syncthreads();
    }
    float mean = s1[0] / (float)E;
    float var = s2[0] / (float)E - mean * mean;
    if (var < 0.f) var = 0.f;
    float inv = 1.f / sqrtf(var + 1e-5f);
    i = 0;
    for (int c = tid; c < Ep; c += 256, ++i){
        if (c < E){
            float o = (vals[i] - mean) * inv * g[c] + b[c];
            out[base + c] = o;
            if (obf) obf[(size_t)blockIdx.x * Ep + c] = f2bf(o);
        } else if (obf) obf[(size_t)blockIdx.x * Ep + c] = 0;
    }
}

// ---------------- GAT / graph common ----------------
static __device__ __forceinline__ unsigned enc_f(float x){
    unsigned u = __float_as_uint(x);
    return (u & 0x80000000u) ? ~u : (u | 0x80000000u);
}
static __device__ __forceinline__ float dec_f(unsigned u){
    return (u & 0x80000000u) ? __uint_as_float(u & 0x7fffffffu) : __uint_as_float(~u);
}
static __device__ __forceinline__ void edge_sd(const int* __restrict__ ei, int e, int& s, int& d){
    if (e < NEDGE){ s = ei[e]; d = ei[NEDGE + e]; }
    else { s = e - NEDGE; d = e - NEDGE; }
}

__global__ void gat_srcdst_k(const float* __restrict__ h, const float* __restrict__ aw_src,
                             const float* __restrict__ aw_dst, float* __restrict__ asrc,
                             float* __restrict__ adst)
{
    int idx = blockIdx.x * 256 + threadIdx.x;
    if (idx >= NN * NH) return;
    int n = idx / NH, hh = idx % NH;
    const float* hp = h + (long long)n * DD2 + hh * FXD_;
    const float* ws = aw_src + hh * FXD_;
    const float* wd = aw_dst + hh * FXD_;
    float s1 = 0.f, s2 = 0.f;
    for (int f = 0; f < FXD_; ++f){ float v = hp[f]; s1 += v * ws[f]; s2 += v * wd[f]; }
    asrc[idx] = s1; adst[idx] = s2;
}

__global__ void gat_alpha_k(const int* __restrict__ ei, const float* __restrict__ asrc,
                            const float* __restrict__ adst, float* __restrict__ alpha,
                            unsigned* __restrict__ amax)
{
    int idx = blockIdx.x * 256 + threadIdx.x;
    if (idx >= NETOT * NH) return;
    int e = idx / NH, hh = idx % NH;
    int s, d; edge_sd(ei, e, s, d);
    float a = asrc[s * NH + hh] + adst[d * NH + hh];
    a = (a > 0.f) ? a : 0.2f * a;       // leaky_relu 0.2
    alpha[idx] = a;
    atomicMax(&amax[d * NH + hh], enc_f(a));
}

__global__ void gat_expsum_k(const int* __restrict__ ei, float* __restrict__ alpha,
                             const unsigned* __restrict__ amax, float* __restrict__ denom)
{
    int idx = blockIdx.x * 256 + threadIdx.x;
    if (idx >= NETOT * NH) return;
    int e = idx / NH, hh = idx % NH;
    int s, d; edge_sd(ei, e, s, d);
    float m = dec_f(amax[d * NH + hh]);
    float ex = expf(alpha[idx] - m);
    alpha[idx] = ex;
    atomicAdd(&denom[d * NH + hh], ex);
}

__global__ void deg_count_k(const int* __restrict__ ei, int* __restrict__ deg)
{
    int e = blockIdx.x * 256 + threadIdx.x;
    if (e >= NETOT) return;
    int s, d; edge_sd(ei, e, s, d);
    atomicAdd(&deg[d], 1);
}

// ---- CSR build: exclusive scan of deg (single block) + fill ----
__global__ __launch_bounds__(256) void csr_off_k(const int* __restrict__ deg,
                                                 int* __restrict__ off, int* __restrict__ cur)
{
    __shared__ int pref[257];
    const int tid = threadIdx.x;
    int loc[32];
    int base = tid * 32, sum = 0;
#pragma unroll
    for (int i = 0; i < 32; ++i){ loc[i] = sum; sum += deg[base + i]; }
    __shared__ int part[256];
    part[tid] = sum; __syncthreads();
    if (tid == 0){
        pref[0] = 0;
        for (int i = 0; i < 256; ++i) pref[i + 1] = pref[i] + part[i];
    }
    __syncthreads();
    int p0 = pref[tid];
#pragma unroll
    for (int i = 0; i < 32; ++i){ off[base + i] = p0 + loc[i]; cur[base + i] = p0 + loc[i]; }
    if (tid == 0) off[NN] = pref[256];
}

__global__ void csr_fill_k(const int* __restrict__ ei, int* __restrict__ cur,
                           int* __restrict__ csr_s, int* __restrict__ csr_e)
{
    int e = blockIdx.x * 256 + threadIdx.x;
    if (e >= NETOT) return;
    int s, d; edge_sd(ei, e, s, d);
    int pos = atomicAdd(&cur[d], 1);
    csr_s[pos] = s; csr_e[pos] = e;
}

// GAT gather: one block per dst node; no atomics
__global__ __launch_bounds__(256) void gat_gather_k(
    const int* __restrict__ off, const int* __restrict__ csr_s, const int* __restrict__ csr_e,
    const float* __restrict__ ex, const float* __restrict__ denom,
    const float* __restrict__ hfeat, float* __restrict__ out)
{
    const int d = blockIdx.x, tid = threadIdx.x;
    const int beg = off[d], end = off[d + 1];
    for (int f = tid; f < DD2; f += 256){
        int hh = f / FXD_;
        float acc = 0.f;
        for (int p = beg; p < end; ++p)
            acc += ex[csr_e[p] * NH + hh] * hfeat[(size_t)csr_s[p] * DD2 + f];
        out[(size_t)d * DD2 + f] = acc / (denom[d * NH + hh] + 1e-16f);
    }
}

// GCN gather
__global__ __launch_bounds__(256) void gcn_gather_k(
    const int* __restrict__ off, const int* __restrict__ csr_s,
    const float* __restrict__ dis, const float* __restrict__ xw, float* __restrict__ out)
{
    const int d = blockIdx.x, tid = threadIdx.x;
    const int beg = off[d], end = off[d + 1];
    const float dd_ = dis[d];
    for (int f = tid; f < DD2; f += 256){
        float acc = 0.f;
        for (int p = beg; p < end; ++p){
            int s = csr_s[p];
            acc += dis[s] * xw[(size_t)s * DD2 + f];
        }
        out[(size_t)d * DD2 + f] = acc * dd_;
    }
}

// bias+relu on f32 (ld=cols), optional padded-bf16 mirror (ld=ldp)
__global__ void bias_relu_k(float* __restrict__ X, const float* __restrict__ b,
                            unsigned short* __restrict__ obf, int rows, int cols, int ldp)
{
    long long i = (long long)blockIdx.x * 256 + threadIdx.x;
    if (i >= (long long)rows * ldp) return;
    int r = (int)(i / ldp), c = (int)(i % ldp);
    if (c < cols){
        float v = X[(size_t)r * cols + c] + b[c];
        v = v > 0.f ? v : 0.f;
        X[(size_t)r * cols + c] = v;
        if (obf) obf[i] = f2bf(v);
    } else if (obf) obf[i] = 0;
}

__global__ void dis_k(const int* __restrict__ deg, float* __restrict__ dis)
{
    int n = blockIdx.x * 256 + threadIdx.x;
    if (n >= NN) return;
    float d = (float)deg[n];
    dis[n] = (d > 0.f) ? 1.f / sqrtf(fmaxf(d, 1.f)) : 0.f;
}

// ---------------- graph pooling (sorted batch -> segment gather, no atomics) ----------------
__global__ void seg_start_k(const int* __restrict__ batch, int* __restrict__ start)
{
    int n = blockIdx.x * 256 + threadIdx.x;
    if (n >= NN) return;
    int b = batch[n];
    int bp = (n == 0) ? -1 : batch[n - 1];
    for (int g = bp + 1; g <= b; ++g) start[g] = n;
    if (n == NN - 1){
        for (int g = b + 1; g <= NG; ++g) start[g] = NN;
    }
}

// per-graph max/avg gather -> padded bf16 XD16 (ld 1568)
__global__ __launch_bounds__(256) void pool_seg_k(const float* __restrict__ xg,
                                                  const int* __restrict__ start,
                                                  unsigned short* __restrict__ xdb)
{
    const int g = blockIdx.x, tid = threadIdx.x;
    const int s0 = start[g], s1 = start[g + 1];
    const float inv = 1.f / fmaxf((float)(s1 - s0), 1.f);
    for (int f = tid; f < DD2; f += 256){
        float mx = 0.f, sm = 0.f;   // xg >= 0 (post-relu); empty segment -> 0 matches ref
        for (int n = s0; n < s1; ++n){
            float v = xg[(size_t)n * DD2 + f];
            mx = fmaxf(mx, v); sm += v;
        }
        xdb[(size_t)g * 1568 + f] = f2bf(mx);
        xdb[(size_t)g * 1568 + DD2 + f] = f2bf(sm * inv);
    }
    if (tid < 8) xdb[(size_t)g * 1568 + 1560 + tid] = 0;   // pad cols
}

// ---------------- conv autoencoder ----------------
#define BN_SCALE 0.9999950000374996f   // 1/sqrt(1+1e-5)

// enc1: (NG,32,91); tm row (735 f32) + w (32x8) in LDS; grid NG
__global__ __launch_bounds__(256) void enc1_b(const float* __restrict__ tm, const float* __restrict__ w,
                                              const float* __restrict__ bias, const float* __restrict__ bng,
                                              const float* __restrict__ bnb, float* __restrict__ out)
{
    __shared__ float xs[736];
    __shared__ float ws[256], bs[32], gs[32], b2[32];
    const int g = blockIdx.x, tid = threadIdx.x;
    for (int i = tid; i < 735; i += 256) xs[i] = tm[(size_t)g * LMUT + i];
    ws[tid] = w[tid];
    if (tid < 32){ bs[tid] = bias[tid]; gs[tid] = bng[tid]; b2[tid] = bnb[tid]; }
    __syncthreads();
    for (int idx = tid; idx < 32 * 91; idx += 256){
        int o = idx / 91, t = idx % 91;
        float mx = -3.4e38f;
        for (int p = 0; p < 8; ++p){
            float s = bs[o];
#pragma unroll
            for (int k = 0; k < 8; ++k) s += xs[t * 8 + p + k] * ws[o * 8 + k];
            mx = fmaxf(mx, s);
        }
        float v = mx * gs[o] * BN_SCALE + b2[o];
        out[(size_t)g * 2912 + idx] = v > 0.f ? v : 0.01f * v;
    }
}

// ---- GEMM-ified AE middle layers: im2col / weight-reshape / post kernels ----
__global__ void i2c_enc2_k(const float* __restrict__ in, unsigned short* __restrict__ A){
    int idx = blockIdx.x * 256 + threadIdx.x;
    if (idx >= NG * 84 * 256) return;
    int col = idx & 255, row = idx >> 8;
    int g = row / 84, u = row % 84;
    int i = col >> 3, k = col & 7;
    A[idx] = f2bf(in[(size_t)g * 2912 + i * 91 + u + k]);
}
__global__ void post_enc2_k(const float* __restrict__ G, const float* __restrict__ b,
                            const float* __restrict__ bng, const float* __restrict__ bnb,
                            float* __restrict__ out){
    int idx = blockIdx.x * 256 + threadIdx.x;
    if (idx >= NG * 768) return;
    int t = idx % 12, o = (idx / 12) & 63, g = idx / 768;
    float mx = -3.4e38f;
#pragma unroll
    for (int p = 0; p < 7; ++p) mx = fmaxf(mx, G[(size_t)(g * 84 + t * 7 + p) * 64 + o]);
    float v = (mx + b[o]) * bng[o] * BN_SCALE + bnb[o];
    out[(size_t)g * 768 + o * 12 + t] = v > 0.f ? v : 0.01f * v;
}
__global__ void i2c_enc3_k(const float* __restrict__ in, unsigned short* __restrict__ A){
    int idx = blockIdx.x * 256 + threadIdx.x;
    if (idx >= NG * 5 * 512) return;
    int col = idx & 511, row = idx >> 9;
    int g = row / 5, t = row % 5;
    int i2 = col >> 3, k = col & 7;
    A[idx] = f2bf(in[(size_t)g * 768 + i2 * 12 + t + k]);
}
__global__ void post_enc3_k(const float* __restrict__ G, const float* __restrict__ b,
                            float* __restrict__ e3o, unsigned short* __restrict__ obf){
    int idx = blockIdx.x * 256 + threadIdx.x;
    if (idx >= NG * 640) return;
    int t = idx % 5, o = (idx / 5) & 127, g = idx / 640;
    float v = G[(size_t)(g * 5 + t) * 128 + o] + b[o];
    e3o[(size_t)g * 640 + o * 5 + t] = v;
    obf[(size_t)g * 640 + o * 5 + t] = f2bf(v);
}
__global__ void wshuf_k(const float* __restrict__ src, unsigned short* __restrict__ dst, int I, int O){
    int idx = blockIdx.x * 256 + threadIdx.x;
    if (idx >= I * O * 8) return;
    int o = idx / (I * 8), rem = idx % (I * 8);
    int i = rem >> 3, j = rem & 7;
    dst[idx] = f2bf(src[(size_t)(i * O + o) * 8 + j]);
}
__global__ void i2c_dec3_k(const float* __restrict__ e3o, unsigned short* __restrict__ A){
    int idx = blockIdx.x * 256 + threadIdx.x;
    if (idx >= NG * 12 * 1024) return;
    int col = idx & 1023, row = idx >> 10;
    int g = row / 12, t = row % 12;
    int i2 = col >> 3, j = col & 7;
    int tt = t - j;
    A[idx] = (tt >= 0 && tt < 5) ? f2bf(e3o[(size_t)g * 640 + i2 * 5 + tt]) : (unsigned short)0;
}
__global__ void post_dec3_k(const float* __restrict__ G, const float* __restrict__ b,
                            const float* __restrict__ bng, const float* __restrict__ bnb,
                            float* __restrict__ dd3){
    int idx = blockIdx.x * 256 + threadIdx.x;
    if (idx >= NG * 768) return;
    int t = idx % 12, o = (idx / 12) & 63, g = idx / 768;
    float v = (G[(size_t)(g * 12 + t) * 64 + o] + b[o]) * bng[o] * BN_SCALE + bnb[o];
    dd3[(size_t)g * 768 + o * 12 + t] = v > 0.f ? v : 0.01f * v;
}
__global__ void i2c_dec2_k(const float* __restrict__ dd3, unsigned short* __restrict__ A){
    int idx = blockIdx.x * 256 + threadIdx.x;
    if (idx >= NG * 91 * 512) return;
    int col = idx & 511, row = idx >> 9;
    int g = row / 91, t = row % 91;
    int i2 = col >> 3, j = col & 7;
    int tt = t - j;
    A[idx] = (tt >= 0 && tt < 84) ? f2bf(dd3[(size_t)g * 768 + i2 * 12 + tt / 7]) : (unsigned short)0;
}
__global__ void post_dec2_k(const float* __restrict__ G, const float* __restrict__ b,
                            const float* __restrict__ bng, const float* __restrict__ bnb,
                            float* __restrict__ dd2){
    int idx = blockIdx.x * 256 + threadIdx.x;
    if (idx >= NG * 2912) return;
    int t = idx % 91, o = (idx / 91) & 31, g = idx / 2912;
    float v = (G[(size_t)(g * 91 + t) * 32 + o] + b[o]) * bng[o] * BN_SCALE + bnb[o];
    dd2[(size_t)g * 2912 + o * 91 + t] = v > 0.f ? v : 0.01f * v;
}

// dec1: (NG,735); grid (NG,3) t-chunks of 245; dd2 (32x91) + w (32x8) in LDS
__global__ __launch_bounds__(256) void dec1_b(const float* __restrict__ dd2, const float* __restrict__ w,
                                              const float* __restrict__ bias, float* __restrict__ out)
{
    __shared__ float d2s[32][91];
    __shared__ float ws[256];
    const int g = blockIdx.x, tid = threadIdx.x;
    const int t0 = (int)blockIdx.y * 245;
    for (int i = tid; i < 32 * 91; i += 256) d2s[i / 91][i % 91] = dd2[(size_t)g * 2912 + i];
    ws[tid] = w[tid];
    __syncthreads();
    if (tid < 245){
        int t = t0 + tid;
        int id8[8]; bool ok[8];
#pragma unroll
        for (int j = 0; j < 8; ++j){
            int tt = t - j;
            ok[j] = (tt >= 0 && tt < 728);
            id8[j] = ok[j] ? (tt >> 3) : 0;
        }
        float s = bias[0];
        for (int i2 = 0; i2 < 32; ++i2){
            const float* wp = ws + i2 * 8;
            float a = 0.f;
#pragma unroll
            for (int j = 0; j < 8; ++j) if (ok[j]) a += d2s[i2][id8[j]] * wp[j];
            s += a;
        }
        out[(size_t)g * 735 + t] = s;
    }
}

__global__ void concat_xc_k(const float* __restrict__ xd, const float* __restrict__ z,
                            unsigned short* __restrict__ xcb)
{
    int idx = blockIdx.x * 256 + threadIdx.x;
    if (idx >= NG * 256) return;
    int g = idx >> 8, c = idx & 255;
    xcb[idx] = f2bf((c < 128) ? xd[g * 128 + c] : z[g * 128 + (c - 128)]);
}

// ---------------- host-side orchestration ----------------
extern "C" void kernel_launch(void* const* d_in, const int* in_sizes, int n_in,
                              void* d_out, int out_size, void* d_ws, size_t ws_size,
                              hipStream_t stream)
{
    (void)in_sizes; (void)n_in; (void)out_size;

    // ---- input pointers: setup_inputs() DICT order (t1 4-15, t2 16-27, gat 28-31) ----
    const float* x      = (const float*)d_in[0];
    const int*   ei     = (const int*)  d_in[1];
    const int*   batch  = (const int*)  d_in[2];
    const float* tmut   = (const float*)d_in[3];
    const float* t1w[12]; for (int i = 0; i < 12; ++i) t1w[i] = (const float*)d_in[4 + i];
    const float* t2w[12]; for (int i = 0; i < 12; ++i) t2w[i] = (const float*)d_in[16 + i];
    const float* gat_w    = (const float*)d_in[28];
    const float* gat_asrc = (const float*)d_in[29];
    const float* gat_adst = (const float*)d_in[30];
    const float* gat_b    = (const float*)d_in[31];
    const float* gcn_w  = (const float*)d_in[32];
    const float* gcn_b  = (const float*)d_in[33];
    const float* fcg1_w = (const float*)d_in[34];
    const float* fcg1_b = (const float*)d_in[35];
    const float* fcg2_w = (const float*)d_in[36];
    const float* fcg2_b = (const float*)d_in[37];
    const float* e1_w = (const float*)d_in[38]; const float* e1_b = (const float*)d_in[39];
    const float* bn1_g = (const float*)d_in[40]; const float* bn1_b = (const float*)d_in[41];
    const float* e2_w = (const float*)d_in[42]; const float* e2_b = (const float*)d_in[43];
    const float* bn2_g = (const float*)d_in[44]; const float* bn2_b = (const float*)d_in[45];
    const float* e3_w = (const float*)d_in[46]; const float* e3_b = (const float*)d_in[47];
    const float* enc_w = (const float*)d_in[48]; const float* enc_b = (const float*)d_in[49];
    const float* d3_w = (const float*)d_in[50]; const float* d3_b = (const float*)d_in[51];
    const float* dbn2_g = (const float*)d_in[52]; const float* dbn2_b = (const float*)d_in[53];
    const float* d2_w = (const float*)d_in[54]; const float* d2_b = (const float*)d_in[55];
    const float* dbn1_g = (const float*)d_in[56]; const float* dbn1_b = (const float*)d_in[57];
    const float* d1_w = (const float*)d_in[58]; const float* d1_b = (const float*)d_in[59];
    const float* fc1_w = (const float*)d_in[60]; const float* fc1_b = (const float*)d_in[61];
    const float* fc2_w = (const float*)d_in[62]; const float* fc2_b = (const float*)d_in[63];
    const float* outw = (const float*)d_in[64]; const float* outb = (const float*)d_in[65];

    // ---- workspace carve ----
    float *A1, *A2, *A3, *A4, *X1f, *QBIASf;
    unsigned short *XB, *QKVb, *Vt, *HbPb;
    unsigned short *WQKVb, *WOUTb, *WL1b, *WL2b, *WGb, *WGCNb, *WFCG1b, *WFCG2b,
                   *WENCb, *WFC1b, *WFC2b, *WOUTWb, *XD16, *FG1b, *E3b, *XCb, *FH1b, *FH2b, *Wcvb;
    float *asrc, *adst, *alpha, *denom, *dis, *c1p, *c2p, *e3o, *zz, *dd3, *dd2b;
    unsigned *amax; int *deg, *seg, *csr_off, *csr_cur, *csr_s, *csr_e;

    auto carve = [&](long long RB) -> size_t {
        char* wp_ = (char*)d_ws;
        auto alc = [&](size_t bytes) -> char* {
            char* p = wp_;
            wp_ += (bytes + 255) & ~(size_t)255;
            return p;
        };
        A1 = (float*)alc((size_t)NN * DD2 * 4);
        A2 = (float*)alc((size_t)NN * DD2 * 4);
        A3 = (float*)alc((size_t)NN * DD2 * 4);
        A4 = (float*)alc((size_t)NN * 800 * 4);   // attention out + sum column (ld Ep)
        X1f = (float*)alc((size_t)NN * FXD_ * 4);
        XB   = (unsigned short*)alc((size_t)NN * 800 * 2);
        QKVb = (unsigned short*)alc((size_t)NN * 2400 * 2);
        Vt   = (unsigned short*)alc((size_t)801 * NN * 2);   // +1 ones-row
        size_t hb = (size_t)NN * FFD * 2, pb = (size_t)RB * NN * 2;
        HbPb = (unsigned short*)alc(hb > pb ? hb : pb);   // FF hidden / attention P / AE im2col
        WQKVb = (unsigned short*)alc((size_t)2400 * 800 * 2);
        QBIASf= (float*)alc((size_t)2400 * 4);
        WOUTb = (unsigned short*)alc((size_t)780 * 800 * 2);
        WL1b  = (unsigned short*)alc((size_t)2048 * 800 * 2);
        WL2b  = (unsigned short*)alc((size_t)780 * 2048 * 2);
        WGb   = (unsigned short*)alc((size_t)780 * 96 * 2);
        WGCNb = (unsigned short*)alc((size_t)780 * 800 * 2);
        WFCG1b= (unsigned short*)alc((size_t)1500 * 1568 * 2);
        WFCG2b= (unsigned short*)alc((size_t)128 * 1504 * 2);
        WENCb = (unsigned short*)alc((size_t)128 * 640 * 2);
        WFC1b = (unsigned short*)alc((size_t)1024 * 256 * 2);
        WFC2b = (unsigned short*)alc((size_t)128 * 1024 * 2);
        WOUTWb= (unsigned short*)alc((size_t)128 * 2);
        Wcvb  = (unsigned short*)alc((size_t)128 * 1024 * 2);   // AE reshaped weights
        XD16  = (unsigned short*)alc((size_t)NG * 1568 * 2);
        FG1b  = (unsigned short*)alc((size_t)NG * 1504 * 2);
        E3b   = (unsigned short*)alc((size_t)NG * 640 * 2);
        XCb   = (unsigned short*)alc((size_t)NG * 256 * 2);
        FH1b  = (unsigned short*)alc((size_t)NG * 1024 * 2);
        FH2b  = (unsigned short*)alc((size_t)NG * 128 * 2);
        asrc = (float*)alc((size_t)NN * NH * 4);
        adst = (float*)alc((size_t)NN * NH * 4);
        alpha= (float*)alc((size_t)NETOT * NH * 4);
        amax = (unsigned*)alc((size_t)NN * NH * 4);
        denom= (float*)alc((size_t)NN * NH * 4);
        deg  = (int*)alc((size_t)NN * 4);
        dis  = (float*)alc((size_t)NN * 4);
        seg  = (int*)alc((size_t)(NG + 1) * 4);
        csr_off = (int*)alc((size_t)(NN + 1) * 4);
        csr_cur = (int*)alc((size_t)NN * 4);
        csr_s   = (int*)alc((size_t)NETOT * 4);
        csr_e   = (int*)alc((size_t)NETOT * 4);
        c1p  = (float*)alc((size_t)NG * 32 * 91 * 4);
        c2p  = (float*)alc((size_t)NG * 64 * 12 * 4);
        e3o  = (float*)alc((size_t)NG * 128 * 5 * 4);
        zz   = (float*)alc((size_t)NG * 128 * 4);
        dd3  = (float*)alc((size_t)NG * 64 * 12 * 4);
        dd2b = (float*)alc((size_t)NG * 32 * 91 * 4);
        return (size_t)(wp_ - (char*)d_ws);
    };

    long long RB = 512;
    const long long cands[3] = {2048, 1024, 512};
    for (int i = 0; i < 3; ++i){ if (carve(cands[i]) <= ws_size){ RB = cands[i]; break; } }
    carve(RB);   // commit chosen layout
    unsigned short* Pb = HbPb;
    unsigned short* AIM = HbPb;      // AE im2col arena (HbPb dead after t2)

    float* out0   = (float*)d_out;                 // (256,1)
    float* xd_out = (float*)d_out + NG;            // (256,128)
    float* decode = (float*)d_out + NG + NG * 128; // (256,735)

    auto cvt = [&](const float* src, unsigned short* dst, int R, int C, int lds_, int ldd){
        long long n = (long long)R * ldd;
        cvt_pad_k<<<cdiv_i(n, 256), 256, 0, stream>>>(src, dst, n, C, lds_, ldd);
    };
    auto zero16 = [&](unsigned short* p, long long nshorts){
        fill_u32_k<<<cdiv_i(nshorts / 2, 256), 256, 0, stream>>>((unsigned*)p, 0u, nshorts / 2);
    };
    auto zerof = [&](float* p, long long n){
        fill_f32_k<<<cdiv_i(n, 256), 256, 0, stream>>>(p, 0.f, n);
    };

    // ---- transformer (shared for t1/t2); xin_bf = XB (padded Ep), residual xin f32 ----
    auto run_tf = [&](const float* xin, const float* const* W, float* outp, int E){
        const int Ep = pad32(E), E3p = 3 * Ep;
        float scale = (float)(1.0 / sqrt((double)E));
        // merged qkv: weights 3*Ep rows (pad rows zero), bias padded
        zero16(WQKVb, (long long)E3p * Ep);
        for (int s = 0; s < 3; ++s)
            cvt(W[0] + (size_t)s * E * E, WQKVb + (size_t)s * Ep * Ep, E, E, E, Ep);
        qkv_bias_k<<<cdiv_i(E3p, 256), 256, 0, stream>>>(W[1], QBIASf, E, Ep);
        mgemm<1,0,1,0,128>(stream, XB, WQKVb, QBIASf, QKVb, NN, E3p, Ep, Ep, Ep, E3p, 0);
        // V^T via bf16 transpose of the v-part; row E = ones (softmax denominator column)
        {
            dim3 g(cdiv_i(E, 32), cdiv_i(NN, 32));
            tr_bf16_k<<<g, 256, 0, stream>>>(QKVb + 2 * Ep, Vt, NN, E, E3p, NN);
            fill_u32_k<<<cdiv_i(NN / 2, 256), 256, 0, stream>>>((unsigned*)(Vt + (size_t)E * NN),
                                                                0x3F803F80u, NN / 2);   // bf16 1.0 pairs
        }
        zerof(A4, (long long)NN * Ep);
        if (E == FXD_){
            // fused flash attention (no P materialization)
            dim3 g(NN / 128, 8);
            flash_t1_k<<<g, 256, 0, stream>>>(QKVb, Vt, A4, scale);
        } else {
            // t2: S+exp (bf16, into Pb) -> PV with ones-col (split-K -> A4, ld Ep)
            for (long long r0 = 0; r0 < NN; r0 += RB){
                mgemm<1,3,1,0,128>(stream, QKVb + (size_t)r0 * E3p, QKVb + Ep, nullptr, Pb,
                                   (int)RB, NN, Ep, E3p, E3p, NN, 1, scale);   // exp epilogue
                mgemm<0,0,4,0,64>(stream, Pb, Vt, nullptr, A4 + (size_t)r0 * Ep,
                                  (int)RB, E + 1, NN, NN, NN, Ep, 0);
            }
        }
        norm_cvt_k<<<cdiv_i((long long)NN * Ep, 256), 256, 0, stream>>>(A4, XB, E, Ep);
        // proj + LN1
        cvt(W[2], WOUTb, E, E, E, Ep);
        mgemm<0,0,1,0,64>(stream, XB, WOUTb, W[3], A2, NN, E, Ep, Ep, Ep, E, 0);
        add_ln_k<<<NN, 256, 0, stream>>>(xin, A2, nullptr, W[4], W[5], A3, XB, E, Ep);
        // FF1 (relu, bf16) -> FF2 -> LN2
        cvt(W[6], WL1b, FFD, E, E, Ep);
        mgemm<1,1,1,0,128>(stream, XB, WL1b, W[7], HbPb, NN, FFD, Ep, Ep, Ep, FFD, 0);
        cvt(W[8], WL2b, E, FFD, FFD, FFD);
        mgemm<0,0,1,0,64>(stream, HbPb, WL2b, W[9], A2, NN, E, FFD, FFD, FFD, E, 0);
        add_ln_k<<<NN, 256, 0, stream>>>(A3, A2, nullptr, W[10], W[11], outp, XB, E, Ep);
    };

    // ================= t1 transformer (E=78) =================
    cvt(x, XB, NN, FXD_, FXD_, 96);
    run_tf(x, t1w, X1f, FXD_);          // leaves XB = t1 out (ld 96)

    // ================= graph structure: deg + CSR + segment bounds =================
    fill_u32_k<<<cdiv_i(NN, 256), 256, 0, stream>>>((unsigned*)deg, 0u, NN);
    deg_count_k<<<cdiv_i(NETOT, 256), 256, 0, stream>>>(ei, deg);
    csr_off_k<<<1, 256, 0, stream>>>(deg, csr_off, csr_cur);
    csr_fill_k<<<cdiv_i(NETOT, 256), 256, 0, stream>>>(ei, csr_cur, csr_s, csr_e);
    seg_start_k<<<cdiv_i(NN, 256), 256, 0, stream>>>(batch, seg);

    // ================= GAT =================
    cvt(gat_w, WGb, DD2, FXD_, FXD_, 96);
    mgemm<0,0,1,0,64>(stream, XB, WGb, nullptr, A2, NN, DD2, 96, 96, 96, DD2, 0);   // hfeat
    gat_srcdst_k<<<cdiv_i((long long)NN * NH, 256), 256, 0, stream>>>(A2, gat_asrc, gat_adst, asrc, adst);
    fill_u32_k<<<cdiv_i((long long)NN * NH, 256), 256, 0, stream>>>(amax, 0x007FFFFFu, (long long)NN * NH);
    zerof(denom, (long long)NN * NH);
    gat_alpha_k<<<cdiv_i((long long)NETOT * NH, 256), 256, 0, stream>>>(ei, asrc, adst, alpha, amax);
    gat_expsum_k<<<cdiv_i((long long)NETOT * NH, 256), 256, 0, stream>>>(ei, alpha, amax, denom);
    gat_gather_k<<<NN, 256, 0, stream>>>(csr_off, csr_s, csr_e, alpha, denom, A2, A1);
    bias_relu_k<<<cdiv_i((long long)NN * 800, 256), 256, 0, stream>>>(A1, gat_b, XB, NN, DD2, 800);

    // ================= t2 transformer (E=780) =================
    run_tf(A1, t2w, A1, DD2);           // leaves XB = t2 out (ld 800)

    // ================= GCN =================
    dis_k<<<cdiv_i(NN, 256), 256, 0, stream>>>(deg, dis);
    cvt(gcn_w, WGCNb, DD2, DD2, DD2, 800);
    mgemm<0,0,1,0,64>(stream, XB, WGCNb, nullptr, A2, NN, DD2, 800, 800, 800, DD2, 0); // xw
    gcn_gather_k<<<NN, 256, 0, stream>>>(csr_off, csr_s, dis, A2, A3);
    bias_relu_k<<<cdiv_i((long long)NN * DD2, 256), 256, 0, stream>>>(A3, gcn_b, nullptr, NN, DD2, DD2);

    // ================= pooling (segment gather) + graph head =================
    pool_seg_k<<<NG, 256, 0, stream>>>(A3, seg, XD16);
    cvt(fcg1_w, WFCG1b, 1500, 1560, 1560, 1568);
    zerof(A2, (long long)NG * 1500);
    mgemm<0,0,8,0,64>(stream, XD16, WFCG1b, nullptr, A2, NG, 1500, 1568, 1568, 1568, 1500, 0);
    bias_relu_k<<<cdiv_i((long long)NG * 1504, 256), 256, 0, stream>>>(A2, fcg1_b, FG1b, NG, 1500, 1504);
    cvt(fcg2_w, WFCG2b, 128, 1500, 1500, 1504);
    zerof(xd_out, (long long)NG * 128);
    mgemm<0,0,16,0,128>(stream, FG1b, WFCG2b, nullptr, xd_out, NG, 128, 1504, 1504, 1504, 128, 0);
    bias_add_k<<<cdiv_i((long long)NG * 128, 256), 256, 0, stream>>>(xd_out, fcg2_b, (long long)NG * 128, 128); // OUTPUT 1

    // ================= conv encoder (GEMM-ified; AIM=HbPb arena, Gout=A2) =================
    enc1_b<<<NG, 256, 0, stream>>>(tmut, e1_w, e1_b, bn1_g, bn1_b, c1p);
    // enc2: (21504 x 256) x (64 x 256)^T
    i2c_enc2_k<<<cdiv_i((long long)NG * 84 * 256, 256), 256, 0, stream>>>(c1p, AIM);
    cvt(e2_w, Wcvb, 64, 256, 256, 256);
    mgemm<0,0,1,0,64>(stream, AIM, Wcvb, nullptr, A2, NG * 84, 64, 256, 256, 256, 64, 0);
    post_enc2_k<<<cdiv_i((long long)NG * 768, 256), 256, 0, stream>>>(A2, e2_b, bn2_g, bn2_b, c2p);
    // enc3: (1280 x 512) x (128 x 512)^T, split-K 4
    i2c_enc3_k<<<cdiv_i((long long)NG * 5 * 512, 256), 256, 0, stream>>>(c2p, AIM);
    cvt(e3_w, Wcvb, 128, 512, 512, 512);
    zerof(A2, (long long)NG * 5 * 128);
    mgemm<0,0,4,0,128>(stream, AIM, Wcvb, nullptr, A2, NG * 5, 128, 512, 512, 512, 128, 0);
    post_enc3_k<<<cdiv_i((long long)NG * 640, 256), 256, 0, stream>>>(A2, e3_b, e3o, E3b);
    // z
    cvt(enc_w, WENCb, 128, 640, 640, 640);
    mgemm<0,0,1,0,128>(stream, E3b, WENCb, enc_b, zz, NG, 128, 640, 640, 640, 128, 0);

    // ================= conv decoder (GEMM-ified) =================
    // dec3: (3072 x 1024) x (64 x 1024)^T, split-K 4
    wshuf_k<<<cdiv_i(128 * 64 * 8, 256), 256, 0, stream>>>(d3_w, Wcvb, 128, 64);
    i2c_dec3_k<<<cdiv_i((long long)NG * 12 * 1024, 256), 256, 0, stream>>>(e3o, AIM);
    zerof(A2, (long long)NG * 12 * 64);
    mgemm<0,0,4,0,64>(stream, AIM, Wcvb, nullptr, A2, NG * 12, 64, 1024, 1024, 1024, 64, 0);
    post_dec3_k<<<cdiv_i((long long)NG * 768, 256), 256, 0, stream>>>(A2, d3_b, dbn2_g, dbn2_b, dd3);
    // dec2: (23296 x 512) x (32 x 512)^T
    wshuf_k<<<cdiv_i(64 * 32 * 8, 256), 256, 0, stream>>>(d2_w, Wcvb, 64, 32);
    i2c_dec2_k<<<cdiv_i((long long)NG * 91 * 512, 256), 256, 0, stream>>>(dd3, AIM);
    mgemm<0,0,1,0,64>(stream, AIM, Wcvb, nullptr, A2, NG * 91, 32, 512, 512, 512, 32, 0);
    post_dec2_k<<<cdiv_i((long long)NG * 2912, 256), 256, 0, stream>>>(A2, d2_b, dbn1_g, dbn1_b, dd2b);
    // dec1 (LDS kernel, 768 blocks)
    { dim3 g(NG, 3); dec1_b<<<g, 256, 0, stream>>>(dd2b, d1_w, d1_b, decode); }   // OUTPUT 2

    // ================= final head =================
    concat_xc_k<<<cdiv_i((long long)NG * 256, 256), 256, 0, stream>>>(xd_out, zz, XCb);
    cvt(fc1_w, WFC1b, 1024, 256, 256, 256);
    mgemm<1,1,1,0,128>(stream, XCb, WFC1b, fc1_b, FH1b, NG, 1024, 256, 256, 256, 1024, 0);
    cvt(fc2_w, WFC2b, 128, 1024, 1024, 1024);
    zerof(A3, (long long)NG * 128);
    mgemm<0,0,8,0,128>(stream, FH1b, WFC2b, nullptr, A3, NG, 128, 1024, 1024, 1024, 128, 0);
    bias_relu_k<<<cdiv_i((long long)NG * 128, 256), 256, 0, stream>>>(A3, fc2_b, FH2b, NG, 128, 128);
    cvt(outw, WOUTWb, 1, 128, 128, 128);
    mgemm<0,2,1,0,64>(stream, FH2b, WOUTWb, outb, out0, NG, 1, 128, 128, 128, 1, 0);   // OUTPUT 0 (sigmoid)
}

// Round 16
// 1513.322 us; speedup vs baseline: 1.7249x; 1.0126x over previous
//
#include <hip/hip_runtime.h>
#include <math.h>

// Problem constants
#define NN     8192      // nodes
#define NEDGE  32768     // edges (before self loops)
#define NETOT  40960     // edges + self loops
#define NG     256       // graphs
#define FXD_   78
#define NH     10        // heads
#define DD2    780       // FXD*HEADS
#define FFD    2048
#define LMUT   735

static inline int cdiv_i(long long a, int b){ return (int)((a + (long long)b - 1) / b); }
static inline int pad32(int x){ return (x + 31) & ~31; }

typedef __attribute__((ext_vector_type(8))) short bf16x8;
typedef __attribute__((ext_vector_type(4))) float f32x4;

static __device__ __forceinline__ unsigned short f2bf(float f){
    unsigned u = __float_as_uint(f);
    u += 0x7FFFu + ((u >> 16) & 1u);
    return (unsigned short)(u >> 16);
}

// async global->LDS, 16B per lane; lds dest is wave-uniform base + lane*16
static __device__ __forceinline__ void gload16(const void* g, void* l){
    __builtin_amdgcn_global_load_lds((const __attribute__((address_space(1))) void*)g,
                                     (__attribute__((address_space(3))) void*)l, 16, 0, 0);
}

// ---------------- fills ----------------
__global__ void fill_f32_k(float* __restrict__ p, float v, long long n){
    long long i = (long long)blockIdx.x * 256 + threadIdx.x;
    if (i < n) p[i] = v;
}
__global__ void fill_u32_k(unsigned* __restrict__ p, unsigned v, long long n){
    long long i = (long long)blockIdx.x * 256 + threadIdx.x;
    if (i < n) p[i] = v;
}

// ---------------- f32 -> bf16 convert with K-padding ----------------
__global__ void cvt_pad_k(const float* __restrict__ src, unsigned short* __restrict__ dst,
                          long long n /*R*ldd*/, int C, int lds_, int ldd)
{
    long long i = (long long)blockIdx.x * 256 + threadIdx.x;
    if (i >= n) return;
    int r = (int)(i / ldd), c = (int)(i % ldd);
    dst[i] = (c < C) ? f2bf(src[(size_t)r * lds_ + c]) : (unsigned short)0;
}

// normalize by sum-column + cvt: XB[r][c] = bf16(A4[r][c]/A4[r][E]), pads 0
__global__ void norm_cvt_k(const float* __restrict__ A4, unsigned short* __restrict__ XB,
                           int E, int Ep)
{
    long long i = (long long)blockIdx.x * 256 + threadIdx.x;
    if (i >= (long long)NN * Ep) return;
    int r = (int)(i / Ep), c = (int)(i % Ep);
    XB[i] = (c < E) ? f2bf(A4[(size_t)r * Ep + c] / A4[(size_t)r * Ep + E]) : (unsigned short)0;
}

// bf16 transpose: dst[c][r] = src[r][c]
__global__ void tr_bf16_k(const unsigned short* __restrict__ src, unsigned short* __restrict__ dst,
                          int R, int C, int lds_, int ldd)
{
    __shared__ unsigned short t[32][33];
    int cb = blockIdx.x * 32, rb = blockIdx.y * 32;
    int tx = threadIdx.x & 31, ty = threadIdx.x >> 5;   // 32 x 8
#pragma unroll
    for (int i = 0; i < 4; ++i){
        int r = rb + ty + i * 8, c = cb + tx;
        t[ty + i * 8][tx] = (r < R && c < C) ? src[(size_t)r * lds_ + c] : (unsigned short)0;
    }
    __syncthreads();
#pragma unroll
    for (int i = 0; i < 4; ++i){
        int dr = cb + ty + i * 8, dc = rb + tx;
        if (dr < C && dc < R) dst[(size_t)dr * ldd + dc] = t[tx][ty + i * 8];
    }
}

// padded qkv bias: out[s*Ep+c] = (c<E) ? b3[s*E+c] : 0, s=0..2
__global__ void qkv_bias_k(const float* __restrict__ b3, float* __restrict__ out, int E, int Ep)
{
    int idx = blockIdx.x * 256 + threadIdx.x;
    if (idx >= 3 * Ep) return;
    int s = idx / Ep, c = idx % Ep;
    out[idx] = (c < E) ? b3[s * E + c] : 0.f;
}

__global__ void bias_add_k(float* __restrict__ X, const float* __restrict__ b, long long n, int cols)
{
    long long i = (long long)blockIdx.x * 256 + threadIdx.x;
    if (i < n) X[i] += b[i % cols];
}

// ---------------- MFMA bf16 GEMM: 2-phase dbuf + XCD swizzle + BN=64/128 tiles ----------------
// ACT: 0 none, 1 relu, 2 sigmoid, 3 exp(v*escale)
template<int OUTC, int ACT, int SPLITK, int BROW, int BN>
__global__ __launch_bounds__(256) void mgemm_k(
    const unsigned short* __restrict__ A, const unsigned short* __restrict__ B,
    const float* __restrict__ bias, void* __restrict__ Cv,
    int M, int N, int Kp, int lda, int ldb, int ldc, int swz, float escale)
{
    constexpr int NFJ   = BN / 32;        // col frags per wave
    constexpr int TILEA = 128 * 32;
    constexpr int TILEB = BN * 32;
    __shared__ unsigned short As[2 * TILEA];
    __shared__ unsigned short Bs[2 * TILEB];
    const int tid = threadIdx.x;
    const int lane = tid & 63, wid = tid >> 6;
    const int r16 = lane & 15, q = lane >> 4;
    const int wr = (wid >> 1) * 64, wc = (wid & 1) * (BN / 2);

    // bijective XCD-chunked remap (m204)
    const int gx = gridDim.x, gy = gridDim.y;
    const int nwg = gx * gy;
    int orig = swz ? ((int)blockIdx.x * gy + (int)blockIdx.y)
                   : ((int)blockIdx.y * gx + (int)blockIdx.x);
    int q8 = nwg >> 3, r8 = nwg & 7;
    int xcd = orig & 7, kk8 = orig >> 3;
    int wgid = (xcd < r8 ? xcd * (q8 + 1) : r8 * (q8 + 1) + (xcd - r8) * q8) + kk8;
    int bx, by;
    if (swz){ by = wgid % gy; bx = wgid / gy; }
    else    { bx = wgid % gx; by = wgid / gx; }
    const int row0 = by * 128, col0 = bx * BN;

    int kbeg = 0, kend = Kp;
    if (SPLITK > 1){
        int nt_ = Kp >> 5, cpt = (nt_ + SPLITK - 1) / SPLITK;
        kbeg = (int)blockIdx.z * cpt * 32;
        kend = min(Kp, kbeg + cpt * 32);
    }

    // A staging: 512 chunks of 16B; lane handles chunk c0 and c0+64
    const int c0 = wid * 128 + lane;
    const int r0a = c0 >> 2, k0a = (c0 & 3) << 3;
    const size_t gA0 = (size_t)min(row0 + r0a, M - 1) * lda + k0a;
    const size_t gA1 = (size_t)min(row0 + r0a + 16, M - 1) * lda + k0a;
    unsigned short* lA = As + wid * 1024;
    // B staging
    size_t gB0 = 0, gB1 = 0;
    unsigned short* lB;
    if (BN == 128){
        gB0 = (size_t)min(col0 + r0a, N - 1) * ldb + k0a;
        gB1 = (size_t)min(col0 + r0a + 16, N - 1) * ldb + k0a;
        lB = Bs + wid * 1024;
    } else {               // BN=64: 256 chunks, 1 per lane
        const int cb = wid * 64 + lane;
        const int rb_ = cb >> 2, kb_ = (cb & 3) << 3;
        gB0 = (size_t)min(col0 + rb_, N - 1) * ldb + kb_;
        lB = Bs + wid * 512;
    }

    f32x4 acc[4][NFJ];
#pragma unroll
    for (int i = 0; i < 4; ++i)
#pragma unroll
        for (int j = 0; j < NFJ; ++j){ f32x4 z = {0.f, 0.f, 0.f, 0.f}; acc[i][j] = z; }

    const int nt = (kend - kbeg) >> 5;
    if (nt > 0){
        gload16(A + gA0 + kbeg, lA);
        gload16(A + gA1 + kbeg, lA + 512);
        gload16(B + gB0 + kbeg, lB);
        if (BN == 128) gload16(B + gB1 + kbeg, lB + 512);
        __syncthreads();
        int cur = 0;
        for (int t = 0; t < nt; ++t){
            const int k0 = kbeg + (t << 5);
            if (t + 1 < nt){                  // stage next tile BEFORE compute (overlap)
                const int kn = k0 + 32, nb = cur ^ 1;
                gload16(A + gA0 + kn, lA + nb * TILEA);
                gload16(A + gA1 + kn, lA + nb * TILEA + 512);
                gload16(B + gB0 + kn, lB + nb * TILEB);
                if (BN == 128) gload16(B + gB1 + kn, lB + nb * TILEB + 512);
            }
            const unsigned short* Ab = As + cur * TILEA;
            const unsigned short* Bb = Bs + cur * TILEB;
            bf16x8 af[4], bfv[NFJ];
#pragma unroll
            for (int f = 0; f < 4; ++f)
                af[f] = *(const bf16x8*)(Ab + (size_t)(wr + f * 16 + r16) * 32 + (q << 3));
#pragma unroll
            for (int f = 0; f < NFJ; ++f)
                bfv[f] = *(const bf16x8*)(Bb + (size_t)(wc + f * 16 + r16) * 32 + (q << 3));
#pragma unroll
            for (int fi = 0; fi < 4; ++fi)
#pragma unroll
                for (int fj = 0; fj < NFJ; ++fj)
                    acc[fi][fj] = __builtin_amdgcn_mfma_f32_16x16x32_bf16(af[fi], bfv[fj], acc[fi][fj], 0, 0, 0);
            __syncthreads();
            cur ^= 1;
        }
    }

#pragma unroll
    for (int fi = 0; fi < 4; ++fi){
#pragma unroll
        for (int j = 0; j < 4; ++j){
            int r = row0 + wr + fi * 16 + q * 4 + j;   // C/D: row=(lane>>4)*4+reg
            if (r >= M) continue;
#pragma unroll
            for (int fj = 0; fj < NFJ; ++fj){
                int c = col0 + wc + fj * 16 + r16;     // C/D: col=lane&15
                if (c >= N) continue;
                float v = acc[fi][fj][j];
                if (SPLITK > 1){
                    atomicAdd((float*)Cv + (size_t)r * ldc + c, v);
                } else {
                    if (bias) v += BROW ? bias[r] : bias[c];
                    if (ACT == 1) v = fmaxf(v, 0.f);
                    if (ACT == 2) v = 1.f / (1.f + __expf(-v));
                    if (ACT == 3) v = __expf(v * escale);
                    if (OUTC == 0) ((float*)Cv)[(size_t)r * ldc + c] = v;
                    else ((unsigned short*)Cv)[(size_t)r * ldc + c] = f2bf(v);
                }
            }
        }
    }
}

template<int OUTC, int ACT, int SPLITK, int BROW, int BN>
static void mgemm(hipStream_t s, const unsigned short* A, const unsigned short* B,
                  const float* bias, void* C, int M, int N, int Kp,
                  int lda, int ldb, int ldc, int swz, float escale = 1.f)
{
    dim3 g(cdiv_i(N, BN), cdiv_i(M, 128), SPLITK);
    mgemm_k<OUTC, ACT, SPLITK, BROW, BN><<<g, 256, 0, s>>>(A, B, bias, C, M, N, Kp, lda, ldb, ldc, swz, escale);
}

// ---------------- fused flash attention for t1 (E=78, Ep=96, E3p=288) ----------------
// grid (NN/128, 16): block = 128 q-rows x 512-k chunk; atomic f32 partials into A4[NN][96].
// Ps buffer double-duty: K-tile [128][104] (stride 104 -> 2-way banks) then P [128][128] swz.
// Vs: 80 rows only (V rows 0..77 + ones row 78 + 1 pad row); wave1 drops its nj=2 fragment
// (cols 80..95 were always discarded). LDS 52KB -> 3 blocks/CU.
#define E3P1 288
#define KLD  104
__global__ __launch_bounds__(256) void flash_t1_k(
    const unsigned short* __restrict__ QKV,   // [NN][288]: q@0, k@96, v@192 (pads zero)
    const unsigned short* __restrict__ Vt,    // [*][NN]: rows 0..77 V^T, row 78 ones
    float* __restrict__ A4, float scale)      // [NN][96] pre-zeroed
{
    __shared__ unsigned short Ps[128 * 128];  // 32 KB: K-tile then P (swizzled)
    __shared__ unsigned short Vs[80 * 128];   // 20 KB: V-tile rows 0..79 (swizzled)
    const int tid = threadIdx.x, lane = tid & 63, wid = tid >> 6;
    const int r16 = lane & 15, q = lane >> 4;
    const int wr = (wid >> 1) * 64;      // row base within 128 (S rows and out rows)
    const int sc = (wid & 1) * 64;       // S col base
    const int oc = (wid & 1) * 48;       // out col base
    const int NJMAX = (wid & 1) ? 2 : 3; // wave1 covers cols 48..79 only
    const int qb = (int)blockIdx.x * 128;
    const int kb = (int)blockIdx.y * 512;

    // Q fragments: rows qb+wr.., K-dim 96 = 3 chunks of 32 (one-time global vector loads)
    bf16x8 qa[4][3];
#pragma unroll
    for (int mi = 0; mi < 4; ++mi)
#pragma unroll
        for (int kc = 0; kc < 3; ++kc)
            qa[mi][kc] = *(const bf16x8*)(QKV + (size_t)(qb + wr + mi * 16 + r16) * E3P1 + kc * 32 + (q << 3));

    f32x4 acco[4][3];
#pragma unroll
    for (int i = 0; i < 4; ++i)
#pragma unroll
        for (int j = 0; j < 3; ++j){ f32x4 z = {0.f, 0.f, 0.f, 0.f}; acco[i][j] = z; }

    for (int t = 0; t < 4; ++t){
        const int k0 = kb + t * 128;
        // load K-tile into Ps: [row][0..95], stride KLD=104 (2-way banks)
#pragma unroll
        for (int i = 0; i < 6; ++i){
            int id = tid + i * 256;                 // 1536 chunks: 12 per row
            int row = id / 12, co = (id % 12) << 3;
            *(bf16x8*)(&Ps[row * KLD + co]) =
                *(const bf16x8*)(QKV + (size_t)(k0 + row) * E3P1 + 96 + co);
        }
        __syncthreads();
        // S-tile: wave computes 64x64 at (wr, sc)
        f32x4 accs[4][4];
#pragma unroll
        for (int i = 0; i < 4; ++i)
#pragma unroll
            for (int j = 0; j < 4; ++j){ f32x4 z = {0.f, 0.f, 0.f, 0.f}; accs[i][j] = z; }
#pragma unroll
        for (int kc = 0; kc < 3; ++kc){
            bf16x8 bk[4];
#pragma unroll
            for (int nj = 0; nj < 4; ++nj)
                bk[nj] = *(const bf16x8*)(&Ps[(sc + nj * 16 + r16) * KLD + kc * 32 + (q << 3)]);
#pragma unroll
            for (int mi = 0; mi < 4; ++mi)
#pragma unroll
                for (int nj = 0; nj < 4; ++nj)
                    accs[mi][nj] = __builtin_amdgcn_mfma_f32_16x16x32_bf16(qa[mi][kc], bk[nj], accs[mi][nj], 0, 0, 0);
        }
        __syncthreads();   // K reads done before P overwrites Ps
        // exp -> Ps (stride 128, swizzled); load V-tile rows 0..79 into Vs (swizzled)
#pragma unroll
        for (int mi = 0; mi < 4; ++mi)
#pragma unroll
            for (int nj = 0; nj < 4; ++nj)
#pragma unroll
                for (int j = 0; j < 4; ++j){
                    int row = wr + mi * 16 + q * 4 + j;       // C/D: row=(lane>>4)*4+reg
                    int col = sc + nj * 16 + r16;             // C/D: col=lane&15
                    Ps[row * 128 + (col ^ ((row & 7) << 3))] = f2bf(__expf(accs[mi][nj][j] * scale));
                }
#pragma unroll
        for (int i = 0; i < 5; ++i){
            int id = tid + i * 256;                 // 1280 chunks: 16 per row, 80 rows
            int row = id / 16, co = (id % 16) << 3;
            *(bf16x8*)(&Vs[row * 128 + (co ^ ((row & 7) << 3))]) =
                *(const bf16x8*)(Vt + (size_t)row * NN + k0 + co);
        }
        __syncthreads();
        // PV: acco += P(128x128) x V-tile; wave out = 64 rows x (NJMAX*16) cols at (wr, oc)
#pragma unroll
        for (int ko = 0; ko < 4; ++ko){
            bf16x8 pa[4], vb[3];
#pragma unroll
            for (int mi = 0; mi < 4; ++mi){
                int row = wr + mi * 16 + r16;                 // A: row=lane&15
                pa[mi] = *(const bf16x8*)(&Ps[row * 128 + ((ko * 32 + (q << 3)) ^ ((row & 7) << 3))]);
            }
#pragma unroll
            for (int nj = 0; nj < 3; ++nj){
                if (nj < NJMAX){
                    int row = oc + nj * 16 + r16;             // B: n=lane&15 (row <= 79)
                    vb[nj] = *(const bf16x8*)(&Vs[row * 128 + ((ko * 32 + (q << 3)) ^ ((row & 7) << 3))]);
                }
            }
#pragma unroll
            for (int mi = 0; mi < 4; ++mi)
#pragma unroll
                for (int nj = 0; nj < 3; ++nj)
                    if (nj < NJMAX)
                        acco[mi][nj] = __builtin_amdgcn_mfma_f32_16x16x32_bf16(pa[mi], vb[nj], acco[mi][nj], 0, 0, 0);
        }
        __syncthreads();   // Ps / Vs reads done before next iter writes
    }
    // epilogue: atomic partials, cols <= E (col 78 = denominator)
#pragma unroll
    for (int mi = 0; mi < 4; ++mi)
#pragma unroll
        for (int j = 0; j < 4; ++j){
            int r = qb + wr + mi * 16 + q * 4 + j;
#pragma unroll
            for (int nj = 0; nj < 3; ++nj){
                if (nj < NJMAX){
                    int c = oc + nj * 16 + r16;
                    if (c <= FXD_)
                        atomicAdd(A4 + (size_t)r * 96 + c, acco[mi][nj][j]);
                }
            }
        }
}

// ---------------- residual add + layernorm ----------------
__global__ __launch_bounds__(256) void add_ln_k(
    const float* __restrict__ X, const float* __restrict__ Y, const float* __restrict__ ybias,
    const float* __restrict__ g, const float* __restrict__ b,
    float* __restrict__ out, unsigned short* __restrict__ obf, int E, int Ep)
{
    __shared__ float s1[256], s2[256];
    const int tid = threadIdx.x;
    long long base = (long long)blockIdx.x * E;
    float vals[4];
    float sum = 0.f, sq = 0.f;
    int i = 0;
    for (int c = tid; c < Ep; c += 256, ++i){
        float v = 0.f;
        if (c < E){
            v = X[base + c] + Y[base + c];
            if (ybias) v += ybias[c];
            sum += v; sq += v * v;
        }
        vals[i] = v;
    }
    s1[tid] = sum; s2[tid] = sq; __syncthreads();
    for (int s = 128; s; s >>= 1){
        if (tid < s){ s1[tid] += s1[tid + s]; s2[tid] += s2[tid + s]; }
        __syncthreads();
    }
    float mean = s1[0] / (float)E;
    float var = s2[0] / (float)E - mean * mean;
    if (var < 0.f) var = 0.f;
    float inv = 1.f / sqrtf(var + 1e-5f);
    i = 0;
    for (int c = tid; c < Ep; c += 256, ++i){
        if (c < E){
            float o = (vals[i] - mean) * inv * g[c] + b[c];
            out[base + c] = o;
            if (obf) obf[(size_t)blockIdx.x * Ep + c] = f2bf(o);
        } else if (obf) obf[(size_t)blockIdx.x * Ep + c] = 0;
    }
}

// ---------------- GAT / graph common ----------------
static __device__ __forceinline__ unsigned enc_f(float x){
    unsigned u = __float_as_uint(x);
    return (u & 0x80000000u) ? ~u : (u | 0x80000000u);
}
static __device__ __forceinline__ float dec_f(unsigned u){
    return (u & 0x80000000u) ? __uint_as_float(u & 0x7fffffffu) : __uint_as_float(~u);
}
static __device__ __forceinline__ void edge_sd(const int* __restrict__ ei, int e, int& s, int& d){
    if (e < NEDGE){ s = ei[e]; d = ei[NEDGE + e]; }
    else { s = e - NEDGE; d = e - NEDGE; }
}

__global__ void gat_srcdst_k(const float* __restrict__ h, const float* __restrict__ aw_src,
                             const float* __restrict__ aw_dst, float* __restrict__ asrc,
                             float* __restrict__ adst)
{
    int idx = blockIdx.x * 256 + threadIdx.x;
    if (idx >= NN * NH) return;
    int n = idx / NH, hh = idx % NH;
    const float* hp = h + (long long)n * DD2 + hh * FXD_;
    const float* ws = aw_src + hh * FXD_;
    const float* wd = aw_dst + hh * FXD_;
    float s1 = 0.f, s2 = 0.f;
    for (int f = 0; f < FXD_; ++f){ float v = hp[f]; s1 += v * ws[f]; s2 += v * wd[f]; }
    asrc[idx] = s1; adst[idx] = s2;
}

__global__ void gat_alpha_k(const int* __restrict__ ei, const float* __restrict__ asrc,
                            const float* __restrict__ adst, float* __restrict__ alpha,
                            unsigned* __restrict__ amax)
{
    int idx = blockIdx.x * 256 + threadIdx.x;
    if (idx >= NETOT * NH) return;
    int e = idx / NH, hh = idx % NH;
    int s, d; edge_sd(ei, e, s, d);
    float a = asrc[s * NH + hh] + adst[d * NH + hh];
    a = (a > 0.f) ? a : 0.2f * a;       // leaky_relu 0.2
    alpha[idx] = a;
    atomicMax(&amax[d * NH + hh], enc_f(a));
}

__global__ void gat_expsum_k(const int* __restrict__ ei, float* __restrict__ alpha,
                             const unsigned* __restrict__ amax, float* __restrict__ denom)
{
    int idx = blockIdx.x * 256 + threadIdx.x;
    if (idx >= NETOT * NH) return;
    int e = idx / NH, hh = idx % NH;
    int s, d; edge_sd(ei, e, s, d);
    float m = dec_f(amax[d * NH + hh]);
    float ex = expf(alpha[idx] - m);
    alpha[idx] = ex;
    atomicAdd(&denom[d * NH + hh], ex);
}

__global__ void deg_count_k(const int* __restrict__ ei, int* __restrict__ deg)
{
    int e = blockIdx.x * 256 + threadIdx.x;
    if (e >= NETOT) return;
    int s, d; edge_sd(ei, e, s, d);
    atomicAdd(&deg[d], 1);
}

// ---- CSR build: exclusive scan of deg (single block) + fill ----
__global__ __launch_bounds__(256) void csr_off_k(const int* __restrict__ deg,
                                                 int* __restrict__ off, int* __restrict__ cur)
{
    __shared__ int pref[257];
    const int tid = threadIdx.x;
    int loc[32];
    int base = tid * 32, sum = 0;
#pragma unroll
    for (int i = 0; i < 32; ++i){ loc[i] = sum; sum += deg[base + i]; }
    __shared__ int part[256];
    part[tid] = sum; __syncthreads();
    if (tid == 0){
        pref[0] = 0;
        for (int i = 0; i < 256; ++i) pref[i + 1] = pref[i] + part[i];
    }
    __syncthreads();
    int p0 = pref[tid];
#pragma unroll
    for (int i = 0; i < 32; ++i){ off[base + i] = p0 + loc[i]; cur[base + i] = p0 + loc[i]; }
    if (tid == 0) off[NN] = pref[256];
}

__global__ void csr_fill_k(const int* __restrict__ ei, int* __restrict__ cur,
                           int* __restrict__ csr_s, int* __restrict__ csr_e)
{
    int e = blockIdx.x * 256 + threadIdx.x;
    if (e >= NETOT) return;
    int s, d; edge_sd(ei, e, s, d);
    int pos = atomicAdd(&cur[d], 1);
    csr_s[pos] = s; csr_e[pos] = e;
}

// GAT gather: one block per dst node; no atomics
__global__ __launch_bounds__(256) void gat_gather_k(
    const int* __restrict__ off, const int* __restrict__ csr_s, const int* __restrict__ csr_e,
    const float* __restrict__ ex, const float* __restrict__ denom,
    const float* __restrict__ hfeat, float* __restrict__ out)
{
    const int d = blockIdx.x, tid = threadIdx.x;
    const int beg = off[d], end = off[d + 1];
    for (int f = tid; f < DD2; f += 256){
        int hh = f / FXD_;
        float acc = 0.f;
        for (int p = beg; p < end; ++p)
            acc += ex[csr_e[p] * NH + hh] * hfeat[(size_t)csr_s[p] * DD2 + f];
        out[(size_t)d * DD2 + f] = acc / (denom[d * NH + hh] + 1e-16f);
    }
}

// GCN gather
__global__ __launch_bounds__(256) void gcn_gather_k(
    const int* __restrict__ off, const int* __restrict__ csr_s,
    const float* __restrict__ dis, const float* __restrict__ xw, float* __restrict__ out)
{
    const int d = blockIdx.x, tid = threadIdx.x;
    const int beg = off[d], end = off[d + 1];
    const float dd_ = dis[d];
    for (int f = tid; f < DD2; f += 256){
        float acc = 0.f;
        for (int p = beg; p < end; ++p){
            int s = csr_s[p];
            acc += dis[s] * xw[(size_t)s * DD2 + f];
        }
        out[(size_t)d * DD2 + f] = acc * dd_;
    }
}

// bias+relu on f32 (ld=cols), optional padded-bf16 mirror (ld=ldp)
__global__ void bias_relu_k(float* __restrict__ X, const float* __restrict__ b,
                            unsigned short* __restrict__ obf, int rows, int cols, int ldp)
{
    long long i = (long long)blockIdx.x * 256 + threadIdx.x;
    if (i >= (long long)rows * ldp) return;
    int r = (int)(i / ldp), c = (int)(i % ldp);
    if (c < cols){
        float v = X[(size_t)r * cols + c] + b[c];
        v = v > 0.f ? v : 0.f;
        X[(size_t)r * cols + c] = v;
        if (obf) obf[i] = f2bf(v);
    } else if (obf) obf[i] = 0;
}

__global__ void dis_k(const int* __restrict__ deg, float* __restrict__ dis)
{
    int n = blockIdx.x * 256 + threadIdx.x;
    if (n >= NN) return;
    float d = (float)deg[n];
    dis[n] = (d > 0.f) ? 1.f / sqrtf(fmaxf(d, 1.f)) : 0.f;
}

// ---------------- graph pooling (sorted batch -> segment gather, no atomics) ----------------
__global__ void seg_start_k(const int* __restrict__ batch, int* __restrict__ start)
{
    int n = blockIdx.x * 256 + threadIdx.x;
    if (n >= NN) return;
    int b = batch[n];
    int bp = (n == 0) ? -1 : batch[n - 1];
    for (int g = bp + 1; g <= b; ++g) start[g] = n;
    if (n == NN - 1){
        for (int g = b + 1; g <= NG; ++g) start[g] = NN;
    }
}

// per-graph max/avg gather -> padded bf16 XD16 (ld 1568)
__global__ __launch_bounds__(256) void pool_seg_k(const float* __restrict__ xg,
                                                  const int* __restrict__ start,
                                                  unsigned short* __restrict__ xdb)
{
    const int g = blockIdx.x, tid = threadIdx.x;
    const int s0 = start[g], s1 = start[g + 1];
    const float inv = 1.f / fmaxf((float)(s1 - s0), 1.f);
    for (int f = tid; f < DD2; f += 256){
        float mx = 0.f, sm = 0.f;   // xg >= 0 (post-relu); empty segment -> 0 matches ref
        for (int n = s0; n < s1; ++n){
            float v = xg[(size_t)n * DD2 + f];
            mx = fmaxf(mx, v); sm += v;
        }
        xdb[(size_t)g * 1568 + f] = f2bf(mx);
        xdb[(size_t)g * 1568 + DD2 + f] = f2bf(sm * inv);
    }
    if (tid < 8) xdb[(size_t)g * 1568 + 1560 + tid] = 0;   // pad cols
}

// ---------------- conv autoencoder ----------------
#define BN_SCALE 0.9999950000374996f   // 1/sqrt(1+1e-5)

// enc1: (NG,32,91); tm row (735 f32) + w (32x8) in LDS; grid NG
__global__ __launch_bounds__(256) void enc1_b(const float* __restrict__ tm, const float* __restrict__ w,
                                              const float* __restrict__ bias, const float* __restrict__ bng,
                                              const float* __restrict__ bnb, float* __restrict__ out)
{
    __shared__ float xs[736];
    __shared__ float ws[256], bs[32], gs[32], b2[32];
    const int g = blockIdx.x, tid = threadIdx.x;
    for (int i = tid; i < 735; i += 256) xs[i] = tm[(size_t)g * LMUT + i];
    ws[tid] = w[tid];
    if (tid < 32){ bs[tid] = bias[tid]; gs[tid] = bng[tid]; b2[tid] = bnb[tid]; }
    __syncthreads();
    for (int idx = tid; idx < 32 * 91; idx += 256){
        int o = idx / 91, t = idx % 91;
        float mx = -3.4e38f;
        for (int p = 0; p < 8; ++p){
            float s = bs[o];
#pragma unroll
            for (int k = 0; k < 8; ++k) s += xs[t * 8 + p + k] * ws[o * 8 + k];
            mx = fmaxf(mx, s);
        }
        float v = mx * gs[o] * BN_SCALE + b2[o];
        out[(size_t)g * 2912 + idx] = v > 0.f ? v : 0.01f * v;
    }
}

// ---- GEMM-ified AE middle layers: im2col / weight-reshape / post kernels ----
__global__ void i2c_enc2_k(const float* __restrict__ in, unsigned short* __restrict__ A){
    int idx = blockIdx.x * 256 + threadIdx.x;
    if (idx >= NG * 84 * 256) return;
    int col = idx & 255, row = idx >> 8;
    int g = row / 84, u = row % 84;
    int i = col >> 3, k = col & 7;
    A[idx] = f2bf(in[(size_t)g * 2912 + i * 91 + u + k]);
}
__global__ void post_enc2_k(const float* __restrict__ G, const float* __restrict__ b,
                            const float* __restrict__ bng, const float* __restrict__ bnb,
                            float* __restrict__ out){
    int idx = blockIdx.x * 256 + threadIdx.x;
    if (idx >= NG * 768) return;
    int t = idx % 12, o = (idx / 12) & 63, g = idx / 768;
    float mx = -3.4e38f;
#pragma unroll
    for (int p = 0; p < 7; ++p) mx = fmaxf(mx, G[(size_t)(g * 84 + t * 7 + p) * 64 + o]);
    float v = (mx + b[o]) * bng[o] * BN_SCALE + bnb[o];
    out[(size_t)g * 768 + o * 12 + t] = v > 0.f ? v : 0.01f * v;
}
__global__ void i2c_enc3_k(const float* __restrict__ in, unsigned short* __restrict__ A){
    int idx = blockIdx.x * 256 + threadIdx.x;
    if (idx >= NG * 5 * 512) return;
    int col = idx & 511, row = idx >> 9;
    int g = row / 5, t = row % 5;
    int i2 = col >> 3, k = col & 7;
    A[idx] = f2bf(in[(size_t)g * 768 + i2 * 12 + t + k]);
}
__global__ void post_enc3_k(const float* __restrict__ G, const float* __restrict__ b,
                            float* __restrict__ e3o, unsigned short* __restrict__ obf){
    int idx = blockIdx.x * 256 + threadIdx.x;
    if (idx >= NG * 640) return;
    int t = idx % 5, o = (idx / 5) & 127, g = idx / 640;
    float v = G[(size_t)(g * 5 + t) * 128 + o] + b[o];
    e3o[(size_t)g * 640 + o * 5 + t] = v;
    obf[(size_t)g * 640 + o * 5 + t] = f2bf(v);
}
__global__ void wshuf_k(const float* __restrict__ src, unsigned short* __restrict__ dst, int I, int O){
    int idx = blockIdx.x * 256 + threadIdx.x;
    if (idx >= I * O * 8) return;
    int o = idx / (I * 8), rem = idx % (I * 8);
    int i = rem >> 3, j = rem & 7;
    dst[idx] = f2bf(src[(size_t)(i * O + o) * 8 + j]);
}
__global__ void i2c_dec3_k(const float* __restrict__ e3o, unsigned short* __restrict__ A){
    int idx = blockIdx.x * 256 + threadIdx.x;
    if (idx >= NG * 12 * 1024) return;
    int col = idx & 1023, row = idx >> 10;
    int g = row / 12, t = row % 12;
    int i2 = col >> 3, j = col & 7;
    int tt = t - j;
    A[idx] = (tt >= 0 && tt < 5) ? f2bf(e3o[(size_t)g * 640 + i2 * 5 + tt]) : (unsigned short)0;
}
__global__ void post_dec3_k(const float* __restrict__ G, const float* __restrict__ b,
                            const float* __restrict__ bng, const float* __restrict__ bnb,
                            float* __restrict__ dd3){
    int idx = blockIdx.x * 256 + threadIdx.x;
    if (idx >= NG * 768) return;
    int t = idx % 12, o = (idx / 12) & 63, g = idx / 768;
    float v = (G[(size_t)(g * 12 + t) * 64 + o] + b[o]) * bng[o] * BN_SCALE + bnb[o];
    dd3[(size_t)g * 768 + o * 12 + t] = v > 0.f ? v : 0.01f * v;
}
__global__ void i2c_dec2_k(const float* __restrict__ dd3, unsigned short* __restrict__ A){
    int idx = blockIdx.x * 256 + threadIdx.x;
    if (idx >= NG * 91 * 512) return;
    int col = idx & 511, row = idx >> 9;
    int g = row / 91, t = row % 91;
    int i2 = col >> 3, j = col & 7;
    int tt = t - j;
    A[idx] = (tt >= 0 && tt < 84) ? f2bf(dd3[(size_t)g * 768 + i2 * 12 + tt / 7]) : (unsigned short)0;
}
__global__ void post_dec2_k(const float* __restrict__ G, const float* __restrict__ b,
                            const float* __restrict__ bng, const float* __restrict__ bnb,
                            float* __restrict__ dd2){
    int idx = blockIdx.x * 256 + threadIdx.x;
    if (idx >= NG * 2912) return;
    int t = idx % 91, o = (idx / 91) & 31, g = idx / 2912;
    float v = (G[(size_t)(g * 91 + t) * 32 + o] + b[o]) * bng[o] * BN_SCALE + bnb[o];
    dd2[(size_t)g * 2912 + o * 91 + t] = v > 0.f ? v : 0.01f * v;
}

// dec1: (NG,735); grid (NG,3) t-chunks of 245; dd2 (32x91) + w (32x8) in LDS
__global__ __launch_bounds__(256) void dec1_b(const float* __restrict__ dd2, const float* __restrict__ w,
                                              const float* __restrict__ bias, float* __restrict__ out)
{
    __shared__ float d2s[32][91];
    __shared__ float ws[256];
    const int g = blockIdx.x, tid = threadIdx.x;
    const int t0 = (int)blockIdx.y * 245;
    for (int i = tid; i < 32 * 91; i += 256) d2s[i / 91][i % 91] = dd2[(size_t)g * 2912 + i];
    ws[tid] = w[tid];
    __syncthreads();
    if (tid < 245){
        int t = t0 + tid;
        int id8[8]; bool ok[8];
#pragma unroll
        for (int j = 0; j < 8; ++j){
            int tt = t - j;
            ok[j] = (tt >= 0 && tt < 728);
            id8[j] = ok[j] ? (tt >> 3) : 0;
        }
        float s = bias[0];
        for (int i2 = 0; i2 < 32; ++i2){
            const float* wp = ws + i2 * 8;
            float a = 0.f;
#pragma unroll
            for (int j = 0; j < 8; ++j) if (ok[j]) a += d2s[i2][id8[j]] * wp[j];
            s += a;
        }
        out[(size_t)g * 735 + t] = s;
    }
}

__global__ void concat_xc_k(const float* __restrict__ xd, const float* __restrict__ z,
                            unsigned short* __restrict__ xcb)
{
    int idx = blockIdx.x * 256 + threadIdx.x;
    if (idx >= NG * 256) return;
    int g = idx >> 8, c = idx & 255;
    xcb[idx] = f2bf((c < 128) ? xd[g * 128 + c] : z[g * 128 + (c - 128)]);
}

// ---------------- host-side orchestration ----------------
extern "C" void kernel_launch(void* const* d_in, const int* in_sizes, int n_in,
                              void* d_out, int out_size, void* d_ws, size_t ws_size,
                              hipStream_t stream)
{
    (void)in_sizes; (void)n_in; (void)out_size;

    // ---- input pointers: setup_inputs() DICT order (t1 4-15, t2 16-27, gat 28-31) ----
    const float* x      = (const float*)d_in[0];
    const int*   ei     = (const int*)  d_in[1];
    const int*   batch  = (const int*)  d_in[2];
    const float* tmut   = (const float*)d_in[3];
    const float* t1w[12]; for (int i = 0; i < 12; ++i) t1w[i] = (const float*)d_in[4 + i];
    const float* t2w[12]; for (int i = 0; i < 12; ++i) t2w[i] = (const float*)d_in[16 + i];
    const float* gat_w    = (const float*)d_in[28];
    const float* gat_asrc = (const float*)d_in[29];
    const float* gat_adst = (const float*)d_in[30];
    const float* gat_b    = (const float*)d_in[31];
    const float* gcn_w  = (const float*)d_in[32];
    const float* gcn_b  = (const float*)d_in[33];
    const float* fcg1_w = (const float*)d_in[34];
    const float* fcg1_b = (const float*)d_in[35];
    const float* fcg2_w = (const float*)d_in[36];
    const float* fcg2_b = (const float*)d_in[37];
    const float* e1_w = (const float*)d_in[38]; const float* e1_b = (const float*)d_in[39];
    const float* bn1_g = (const float*)d_in[40]; const float* bn1_b = (const float*)d_in[41];
    const float* e2_w = (const float*)d_in[42]; const float* e2_b = (const float*)d_in[43];
    const float* bn2_g = (const float*)d_in[44]; const float* bn2_b = (const float*)d_in[45];
    const float* e3_w = (const float*)d_in[46]; const float* e3_b = (const float*)d_in[47];
    const float* enc_w = (const float*)d_in[48]; const float* enc_b = (const float*)d_in[49];
    const float* d3_w = (const float*)d_in[50]; const float* d3_b = (const float*)d_in[51];
    const float* dbn2_g = (const float*)d_in[52]; const float* dbn2_b = (const float*)d_in[53];
    const float* d2_w = (const float*)d_in[54]; const float* d2_b = (const float*)d_in[55];
    const float* dbn1_g = (const float*)d_in[56]; const float* dbn1_b = (const float*)d_in[57];
    const float* d1_w = (const float*)d_in[58]; const float* d1_b = (const float*)d_in[59];
    const float* fc1_w = (const float*)d_in[60]; const float* fc1_b = (const float*)d_in[61];
    const float* fc2_w = (const float*)d_in[62]; const float* fc2_b = (const float*)d_in[63];
    const float* outw = (const float*)d_in[64]; const float* outb = (const float*)d_in[65];

    // ---- workspace carve ----
    float *A1, *A2, *A3, *A4, *X1f, *QBIASf;
    unsigned short *XB, *QKVb, *Vt, *HbPb;
    unsigned short *WQKVb, *WOUTb, *WL1b, *WL2b, *WGb, *WGCNb, *WFCG1b, *WFCG2b,
                   *WENCb, *WFC1b, *WFC2b, *WOUTWb, *XD16, *FG1b, *E3b, *XCb, *FH1b, *FH2b, *Wcvb;
    float *asrc, *adst, *alpha, *denom, *dis, *c1p, *c2p, *e3o, *zz, *dd3, *dd2b;
    unsigned *amax; int *deg, *seg, *csr_off, *csr_cur, *csr_s, *csr_e;

    auto carve = [&](long long RB) -> size_t {
        char* wp_ = (char*)d_ws;
        auto alc = [&](size_t bytes) -> char* {
            char* p = wp_;
            wp_ += (bytes + 255) & ~(size_t)255;
            return p;
        };
        A1 = (float*)alc((size_t)NN * DD2 * 4);
        A2 = (float*)alc((size_t)NN * DD2 * 4);
        A3 = (float*)alc((size_t)NN * DD2 * 4);
        A4 = (float*)alc((size_t)NN * 800 * 4);   // attention out + sum column (ld Ep)
        X1f = (float*)alc((size_t)NN * FXD_ * 4);
        XB   = (unsigned short*)alc((size_t)NN * 800 * 2);
        QKVb = (unsigned short*)alc((size_t)NN * 2400 * 2);
        Vt   = (unsigned short*)alc((size_t)801 * NN * 2);   // +1 ones-row
        size_t hb = (size_t)NN * FFD * 2, pb = (size_t)RB * NN * 2;
        HbPb = (unsigned short*)alc(hb > pb ? hb : pb);   // FF hidden / attention P / AE im2col
        WQKVb = (unsigned short*)alc((size_t)2400 * 800 * 2);
        QBIASf= (float*)alc((size_t)2400 * 4);
        WOUTb = (unsigned short*)alc((size_t)780 * 800 * 2);
        WL1b  = (unsigned short*)alc((size_t)2048 * 800 * 2);
        WL2b  = (unsigned short*)alc((size_t)780 * 2048 * 2);
        WGb   = (unsigned short*)alc((size_t)780 * 96 * 2);
        WGCNb = (unsigned short*)alc((size_t)780 * 800 * 2);
        WFCG1b= (unsigned short*)alc((size_t)1500 * 1568 * 2);
        WFCG2b= (unsigned short*)alc((size_t)128 * 1504 * 2);
        WENCb = (unsigned short*)alc((size_t)128 * 640 * 2);
        WFC1b = (unsigned short*)alc((size_t)1024 * 256 * 2);
        WFC2b = (unsigned short*)alc((size_t)128 * 1024 * 2);
        WOUTWb= (unsigned short*)alc((size_t)128 * 2);
        Wcvb  = (unsigned short*)alc((size_t)128 * 1024 * 2);   // AE reshaped weights
        XD16  = (unsigned short*)alc((size_t)NG * 1568 * 2);
        FG1b  = (unsigned short*)alc((size_t)NG * 1504 * 2);
        E3b   = (unsigned short*)alc((size_t)NG * 640 * 2);
        XCb   = (unsigned short*)alc((size_t)NG * 256 * 2);
        FH1b  = (unsigned short*)alc((size_t)NG * 1024 * 2);
        FH2b  = (unsigned short*)alc((size_t)NG * 128 * 2);
        asrc = (float*)alc((size_t)NN * NH * 4);
        adst = (float*)alc((size_t)NN * NH * 4);
        alpha= (float*)alc((size_t)NETOT * NH * 4);
        amax = (unsigned*)alc((size_t)NN * NH * 4);
        denom= (float*)alc((size_t)NN * NH * 4);
        deg  = (int*)alc((size_t)NN * 4);
        dis  = (float*)alc((size_t)NN * 4);
        seg  = (int*)alc((size_t)(NG + 1) * 4);
        csr_off = (int*)alc((size_t)(NN + 1) * 4);
        csr_cur = (int*)alc((size_t)NN * 4);
        csr_s   = (int*)alc((size_t)NETOT * 4);
        csr_e   = (int*)alc((size_t)NETOT * 4);
        c1p  = (float*)alc((size_t)NG * 32 * 91 * 4);
        c2p  = (float*)alc((size_t)NG * 64 * 12 * 4);
        e3o  = (float*)alc((size_t)NG * 128 * 5 * 4);
        zz   = (float*)alc((size_t)NG * 128 * 4);
        dd3  = (float*)alc((size_t)NG * 64 * 12 * 4);
        dd2b = (float*)alc((size_t)NG * 32 * 91 * 4);
        return (size_t)(wp_ - (char*)d_ws);
    };

    long long RB = 512;
    const long long cands[3] = {2048, 1024, 512};
    for (int i = 0; i < 3; ++i){ if (carve(cands[i]) <= ws_size){ RB = cands[i]; break; } }
    carve(RB);   // commit chosen layout
    unsigned short* Pb = HbPb;
    unsigned short* AIM = HbPb;      // AE im2col arena (HbPb dead after t2)

    float* out0   = (float*)d_out;                 // (256,1)
    float* xd_out = (float*)d_out + NG;            // (256,128)
    float* decode = (float*)d_out + NG + NG * 128; // (256,735)

    auto cvt = [&](const float* src, unsigned short* dst, int R, int C, int lds_, int ldd){
        long long n = (long long)R * ldd;
        cvt_pad_k<<<cdiv_i(n, 256), 256, 0, stream>>>(src, dst, n, C, lds_, ldd);
    };
    auto zero16 = [&](unsigned short* p, long long nshorts){
        fill_u32_k<<<cdiv_i(nshorts / 2, 256), 256, 0, stream>>>((unsigned*)p, 0u, nshorts / 2);
    };
    auto zerof = [&](float* p, long long n){
        fill_f32_k<<<cdiv_i(n, 256), 256, 0, stream>>>(p, 0.f, n);
    };

    // ---- transformer (shared for t1/t2); xin_bf = XB (padded Ep), residual xin f32 ----
    auto run_tf = [&](const float* xin, const float* const* W, float* outp, int E){
        const int Ep = pad32(E), E3p = 3 * Ep;
        float scale = (float)(1.0 / sqrt((double)E));
        // merged qkv: weights 3*Ep rows (pad rows zero), bias padded
        zero16(WQKVb, (long long)E3p * Ep);
        for (int s = 0; s < 3; ++s)
            cvt(W[0] + (size_t)s * E * E, WQKVb + (size_t)s * Ep * Ep, E, E, E, Ep);
        qkv_bias_k<<<cdiv_i(E3p, 256), 256, 0, stream>>>(W[1], QBIASf, E, Ep);
        mgemm<1,0,1,0,128>(stream, XB, WQKVb, QBIASf, QKVb, NN, E3p, Ep, Ep, Ep, E3p, 0);
        // V^T via bf16 transpose of the v-part; row E = ones (softmax denominator column)
        {
            dim3 g(cdiv_i(E, 32), cdiv_i(NN, 32));
            tr_bf16_k<<<g, 256, 0, stream>>>(QKVb + 2 * Ep, Vt, NN, E, E3p, NN);
            fill_u32_k<<<cdiv_i(NN / 2, 256), 256, 0, stream>>>((unsigned*)(Vt + (size_t)E * NN),
                                                                0x3F803F80u, NN / 2);   // bf16 1.0 pairs
        }
        zerof(A4, (long long)NN * Ep);
        if (E == FXD_){
            // fused flash attention (no P materialization); 52KB LDS -> 3 blocks/CU
            dim3 g(NN / 128, 16);
            flash_t1_k<<<g, 256, 0, stream>>>(QKVb, Vt, A4, scale);
        } else {
            // t2: S+exp (bf16, into Pb) -> PV with ones-col (split-K -> A4, ld Ep)
            for (long long r0 = 0; r0 < NN; r0 += RB){
                mgemm<1,3,1,0,128>(stream, QKVb + (size_t)r0 * E3p, QKVb + Ep, nullptr, Pb,
                                   (int)RB, NN, Ep, E3p, E3p, NN, 1, scale);   // exp epilogue
                mgemm<0,0,4,0,64>(stream, Pb, Vt, nullptr, A4 + (size_t)r0 * Ep,
                                  (int)RB, E + 1, NN, NN, NN, Ep, 0);
            }
        }
        norm_cvt_k<<<cdiv_i((long long)NN * Ep, 256), 256, 0, stream>>>(A4, XB, E, Ep);
        // proj + LN1
        cvt(W[2], WOUTb, E, E, E, Ep);
        mgemm<0,0,1,0,64>(stream, XB, WOUTb, W[3], A2, NN, E, Ep, Ep, Ep, E, 0);
        add_ln_k<<<NN, 256, 0, stream>>>(xin, A2, nullptr, W[4], W[5], A3, XB, E, Ep);
        // FF1 (relu, bf16) -> FF2 -> LN2
        cvt(W[6], WL1b, FFD, E, E, Ep);
        mgemm<1,1,1,0,128>(stream, XB, WL1b, W[7], HbPb, NN, FFD, Ep, Ep, Ep, FFD, 0);
        cvt(W[8], WL2b, E, FFD, FFD, FFD);
        mgemm<0,0,1,0,64>(stream, HbPb, WL2b, W[9], A2, NN, E, FFD, FFD, FFD, E, 0);
        add_ln_k<<<NN, 256, 0, stream>>>(A3, A2, nullptr, W[10], W[11], outp, XB, E, Ep);
    };

    // ================= t1 transformer (E=78) =================
    cvt(x, XB, NN, FXD_, FXD_, 96);
    run_tf(x, t1w, X1f, FXD_);          // leaves XB = t1 out (ld 96)

    // ================= graph structure: deg + CSR + segment bounds =================
    fill_u32_k<<<cdiv_i(NN, 256), 256, 0, stream>>>((unsigned*)deg, 0u, NN);
    deg_count_k<<<cdiv_i(NETOT, 256), 256, 0, stream>>>(ei, deg);
    csr_off_k<<<1, 256, 0, stream>>>(deg, csr_off, csr_cur);
    csr_fill_k<<<cdiv_i(NETOT, 256), 256, 0, stream>>>(ei, csr_cur, csr_s, csr_e);
    seg_start_k<<<cdiv_i(NN, 256), 256, 0, stream>>>(batch, seg);

    // ================= GAT =================
    cvt(gat_w, WGb, DD2, FXD_, FXD_, 96);
    mgemm<0,0,1,0,64>(stream, XB, WGb, nullptr, A2, NN, DD2, 96, 96, 96, DD2, 0);   // hfeat
    gat_srcdst_k<<<cdiv_i((long long)NN * NH, 256), 256, 0, stream>>>(A2, gat_asrc, gat_adst, asrc, adst);
    fill_u32_k<<<cdiv_i((long long)NN * NH, 256), 256, 0, stream>>>(amax, 0x007FFFFFu, (long long)NN * NH);
    zerof(denom, (long long)NN * NH);
    gat_alpha_k<<<cdiv_i((long long)NETOT * NH, 256), 256, 0, stream>>>(ei, asrc, adst, alpha, amax);
    gat_expsum_k<<<cdiv_i((long long)NETOT * NH, 256), 256, 0, stream>>>(ei, alpha, amax, denom);
    gat_gather_k<<<NN, 256, 0, stream>>>(csr_off, csr_s, csr_e, alpha, denom, A2, A1);
    bias_relu_k<<<cdiv_i((long long)NN * 800, 256), 256, 0, stream>>>(A1, gat_b, XB, NN, DD2, 800);

    // ================= t2 transformer (E=780) =================
    run_tf(A1, t2w, A1, DD2);           // leaves XB = t2 out (ld 800)

    // ================= GCN =================
    dis_k<<<cdiv_i(NN, 256), 256, 0, stream>>>(deg, dis);
    cvt(gcn_w, WGCNb, DD2, DD2, DD2, 800);
    mgemm<0,0,1,0,64>(stream, XB, WGCNb, nullptr, A2, NN, DD2, 800, 800, 800, DD2, 0); // xw
    gcn_gather_k<<<NN, 256, 0, stream>>>(csr_off, csr_s, dis, A2, A3);
    bias_relu_k<<<cdiv_i((long long)NN * DD2, 256), 256, 0, stream>>>(A3, gcn_b, nullptr, NN, DD2, DD2);

    // ================= pooling (segment gather) + graph head =================
    pool_seg_k<<<NG, 256, 0, stream>>>(A3, seg, XD16);
    cvt(fcg1_w, WFCG1b, 1500, 1560, 1560, 1568);
    zerof(A2, (long long)NG * 1500);
    mgemm<0,0,8,0,64>(stream, XD16, WFCG1b, nullptr, A2, NG, 1500, 1568, 1568, 1568, 1500, 0);
    bias_relu_k<<<cdiv_i((long long)NG * 1504, 256), 256, 0, stream>>>(A2, fcg1_b, FG1b, NG, 1500, 1504);
    cvt(fcg2_w, WFCG2b, 128, 1500, 1500, 1504);
    zerof(xd_out, (long long)NG * 128);
    mgemm<0,0,16,0,128>(stream, FG1b, WFCG2b, nullptr, xd_out, NG, 128, 1504, 1504, 1504, 128, 0);
    bias_add_k<<<cdiv_i((long long)NG * 128, 256), 256, 0, stream>>>(xd_out, fcg2_b, (long long)NG * 128, 128); // OUTPUT 1

    // ================= conv encoder (GEMM-ified; AIM=HbPb arena, Gout=A2) =================
    enc1_b<<<NG, 256, 0, stream>>>(tmut, e1_w, e1_b, bn1_g, bn1_b, c1p);
    // enc2: (21504 x 256) x (64 x 256)^T
    i2c_enc2_k<<<cdiv_i((long long)NG * 84 * 256, 256), 256, 0, stream>>>(c1p, AIM);
    cvt(e2_w, Wcvb, 64, 256, 256, 256);
    mgemm<0,0,1,0,64>(stream, AIM, Wcvb, nullptr, A2, NG * 84, 64, 256, 256, 256, 64, 0);
    post_enc2_k<<<cdiv_i((long long)NG * 768, 256), 256, 0, stream>>>(A2, e2_b, bn2_g, bn2_b, c2p);
    // enc3: (1280 x 512) x (128 x 512)^T, split-K 4
    i2c_enc3_k<<<cdiv_i((long long)NG * 5 * 512, 256), 256, 0, stream>>>(c2p, AIM);
    cvt(e3_w, Wcvb, 128, 512, 512, 512);
    zerof(A2, (long long)NG * 5 * 128);
    mgemm<0,0,4,0,128>(stream, AIM, Wcvb, nullptr, A2, NG * 5, 128, 512, 512, 512, 128, 0);
    post_enc3_k<<<cdiv_i((long long)NG * 640, 256), 256, 0, stream>>>(A2, e3_b, e3o, E3b);
    // z
    cvt(enc_w, WENCb, 128, 640, 640, 640);
    mgemm<0,0,1,0,128>(stream, E3b, WENCb, enc_b, zz, NG, 128, 640, 640, 640, 128, 0);

    // ================= conv decoder (GEMM-ified) =================
    // dec3: (3072 x 1024) x (64 x 1024)^T, split-K 4
    wshuf_k<<<cdiv_i(128 * 64 * 8, 256), 256, 0, stream>>>(d3_w, Wcvb, 128, 64);
    i2c_dec3_k<<<cdiv_i((long long)NG * 12 * 1024, 256), 256, 0, stream>>>(e3o, AIM);
    zerof(A2, (long long)NG * 12 * 64);
    mgemm<0,0,4,0,64>(stream, AIM, Wcvb, nullptr, A2, NG * 12, 64, 1024, 1024, 1024, 64, 0);
    post_dec3_k<<<cdiv_i((long long)NG * 768, 256), 256, 0, stream>>>(A2, d3_b, dbn2_g, dbn2_b, dd3);
    // dec2: (23296 x 512) x (32 x 512)^T
    wshuf_k<<<cdiv_i(64 * 32 * 8, 256), 256, 0, stream>>>(d2_w, Wcvb, 64, 32);
    i2c_dec2_k<<<cdiv_i((long long)NG * 91 * 512, 256), 256, 0, stream>>>(dd3, AIM);
    mgemm<0,0,1,0,64>(stream, AIM, Wcvb, nullptr, A2, NG * 91, 32, 512, 512, 512, 32, 0);
    post_dec2_k<<<cdiv_i((long long)NG * 2912, 256), 256, 0, stream>>>(A2, d2_b, dbn1_g, dbn1_b, dd2b);
    // dec1 (LDS kernel, 768 blocks)
    { dim3 g(NG, 3); dec1_b<<<g, 256, 0, stream>>>(dd2b, d1_w, d1_b, decode); }   // OUTPUT 2

    // ================= final head =================
    concat_xc_k<<<cdiv_i((long long)NG * 256, 256), 256, 0, stream>>>(xd_out, zz, XCb);
    cvt(fc1_w, WFC1b, 1024, 256, 256, 256);
    mgemm<1,1,1,0,128>(stream, XCb, WFC1b, fc1_b, FH1b, NG, 1024, 256, 256, 256, 1024, 0);
    cvt(fc2_w, WFC2b, 128, 1024, 1024, 1024);
    zerof(A3, (long long)NG * 128);
    mgemm<0,0,8,0,128>(stream, FH1b, WFC2b, nullptr, A3, NG, 128, 1024, 1024, 1024, 128, 0);
    bias_relu_k<<<cdiv_i((long long)NG * 128, 256), 256, 0, stream>>>(A3, fc2_b, FH2b, NG, 128, 128);
    cvt(outw, WOUTWb, 1, 128, 128, 128);
    mgemm<0,2,1,0,64>(stream, FH2b, WOUTWb, outb, out0, NG, 1, 128, 128, 128, 1, 0);   // OUTPUT 0 (sigmoid)
}